// Round 3
// baseline (381.480 us; speedup 1.0000x reference)
//
#include <hip/hip_runtime.h>
#include <math.h>

// ---- fixed problem sizes ----
#define NTOK 1024
#define DDIM 1024
#define HEADS 16
#define KVH 4
#define DH 64
#define BSZ 32
#define NSEL 8
#define WBLK 32            // NTOK / BSZ
#define GQ 4               // HEADS / KVH
#define CDIM 2048          // BSZ*DH
#define HIDN 2048
#define QKVD 1536          // (HEADS + 2*KVH)*DH
#define SCALE 0.125f       // DH^-0.5
#define NEGINF (-__builtin_inff())

typedef unsigned short u16;
typedef u16   u16x8  __attribute__((ext_vector_type(8)));
typedef short short8 __attribute__((ext_vector_type(8)));
typedef float f32x4  __attribute__((ext_vector_type(4)));

__device__ __forceinline__ u16 f2bf(float f) {
    unsigned u = __float_as_uint(f);
    return (u16)((u + 0x7fffu + ((u >> 16) & 1u)) >> 16);
}
__device__ __forceinline__ float bf2f(u16 h) { return __uint_as_float(((unsigned)h) << 16); }

__device__ __forceinline__ void glds16(const void* g, void* l) {
    __builtin_amdgcn_global_load_lds(
        (const __attribute__((address_space(1))) unsigned int*)g,
        (__attribute__((address_space(3))) unsigned int*)l, 16, 0, 0);
}

// element offset (in u16) of the 8-element lane-slot for (row, k..k+7) in the
// MFMA-fragment-tiled layout: 16-row x 32-k tiles, 1KB each, contiguous.
__device__ __forceinline__ size_t tiled_off(int row, int k, int K) {
    return ((size_t)((row >> 4) * (K >> 5) + (k >> 5)) * 64 +
            ((row & 15) | (((k >> 3) & 3) << 4))) * 8;
}

// ---------------------------------------------------------------------------
// K1: RMSNorm -> split-bf16 x in TILED layout (K=DDIM). 2 rows per 256-thr block.
// ---------------------------------------------------------------------------
__global__ void rmsnorm_kernel(const float* __restrict__ inp, const float* __restrict__ g,
                               u16* __restrict__ xhi, u16* __restrict__ xlo) {
    int t = threadIdx.x;
    int half = t >> 7, tid = t & 127;
    int n = blockIdx.x * 2 + half;
    const float4* row = (const float4*)(inp + (size_t)n * DDIM);
    float4 v0 = row[tid * 2], v1 = row[tid * 2 + 1];
    float ss = v0.x*v0.x + v0.y*v0.y + v0.z*v0.z + v0.w*v0.w
             + v1.x*v1.x + v1.y*v1.y + v1.z*v1.z + v1.w*v1.w;
    for (int off = 32; off; off >>= 1) ss += __shfl_down(ss, off);
    __shared__ float red[4];
    if ((t & 63) == 0) red[t >> 6] = ss;
    __syncthreads();
    float tot = red[half * 2] + red[half * 2 + 1];
    float r = 1.f / sqrtf(tot * (1.f / DDIM) + 1e-6f);
    const float4* gp = (const float4*)g;
    float4 g0 = gp[tid * 2], g1 = gp[tid * 2 + 1];
    float o[8] = { v0.x*r*g0.x, v0.y*r*g0.y, v0.z*r*g0.z, v0.w*r*g0.w,
                   v1.x*r*g1.x, v1.y*r*g1.y, v1.z*r*g1.z, v1.w*r*g1.w };
    u16x8 h, l;
#pragma unroll
    for (int i = 0; i < 8; ++i) {
        u16 hh = f2bf(o[i]);
        h[i] = hh;
        l[i] = f2bf(o[i] - bf2f(hh));
    }
    size_t ob = tiled_off(n, tid * 8, DDIM);
    *(u16x8*)&xhi[ob] = h;
    *(u16x8*)&xlo[ob] = l;
}

// ---------------------------------------------------------------------------
// K2: weight transpose + split: W[K][N] f32 -> tiled Bt[N][K] bf16 hi/lo
// ---------------------------------------------------------------------------
__global__ void transpose_split(const float* __restrict__ W, u16* __restrict__ Thi,
                                u16* __restrict__ Tlo, int K, int N) {
    __shared__ float tile[64][65];
    int k0 = blockIdx.y * 64, n0 = blockIdx.x * 64;
    int t = threadIdx.x;
    int r = t >> 4, c4 = (t & 15) * 4;
#pragma unroll
    for (int p = 0; p < 4; ++p) {
        float4 v = *(const float4*)&W[(size_t)(k0 + r + p * 16) * N + n0 + c4];
        tile[r + p * 16][c4 + 0] = v.x;
        tile[r + p * 16][c4 + 1] = v.y;
        tile[r + p * 16][c4 + 2] = v.z;
        tile[r + p * 16][c4 + 3] = v.w;
    }
    __syncthreads();
    int n = t >> 2, ks = (t & 3) * 16;
#pragma unroll
    for (int c = 0; c < 2; ++c) {
        u16x8 h, l;
#pragma unroll
        for (int j = 0; j < 8; ++j) {
            float v = tile[ks + c * 8 + j][n];
            u16 hh = f2bf(v);
            h[j] = hh;
            l[j] = f2bf(v - bf2f(hh));
        }
        size_t ob = tiled_off(n0 + n, k0 + ks + c * 8, K);
        *(u16x8*)&Thi[ob] = h;
        if (Tlo) *(u16x8*)&Tlo[ob] = l;
    }
}

// ---------------------------------------------------------------------------
// K2b: pad small weights [K][Xn] (Xn<=64) -> tiled split-bf16 [128][K] + padded bias
// ---------------------------------------------------------------------------
__global__ void pad_small_tiled(const float* __restrict__ W, const float* __restrict__ b,
                                u16* __restrict__ Thi, u16* __restrict__ Tlo,
                                float* __restrict__ bias_pad, int K, int Xn, int KLOG) {
    int idx = blockIdx.x * 256 + threadIdx.x;   // 128 * K/8
    int k = (idx & ((K >> 3) - 1)) * 8;
    int n = idx >> (KLOG - 3);
    if (n >= 128) return;
    u16x8 h, l;
#pragma unroll
    for (int j = 0; j < 8; ++j) {
        float v = (n < Xn) ? W[(size_t)(k + j) * Xn + n] : 0.f;
        u16 hh = f2bf(v);
        h[j] = hh;
        l[j] = f2bf(v - bf2f(hh));
    }
    size_t ob = tiled_off(n, k, K);
    *(u16x8*)&Thi[ob] = h;
    *(u16x8*)&Tlo[ob] = l;
    if (k == 0) bias_pad[n] = (n < Xn) ? b[n] : 0.f;
}

// ---------------------------------------------------------------------------
// K3: tiled MFMA GEMM with software pipeline + optional split-K.
// ---------------------------------------------------------------------------
template<int SPLIT, int ACT, int FINAL>
__global__ __launch_bounds__(256, 1)
void gemm_tiled(const u16* __restrict__ Ahi0, const u16* __restrict__ Alo0,
                const u16* __restrict__ Bhi0, const u16* __restrict__ Blo0,
                const float* __restrict__ bias0, float* __restrict__ C0,
                const u16* __restrict__ Ahi1, const u16* __restrict__ Alo1,
                const u16* __restrict__ Bhi1, const u16* __restrict__ Blo1,
                const float* __restrict__ bias1, float* __restrict__ C1,
                int M, int N, int K, int S) {
    int batch = blockIdx.z / S;
    int s = blockIdx.z - batch * S;
    const u16* Ahi = batch ? Ahi1 : Ahi0;
    const u16* Alo = batch ? Alo1 : Alo0;
    const u16* Bhi = batch ? Bhi1 : Bhi0;
    const u16* Blo = batch ? Blo1 : Blo0;
    const float* bias = batch ? bias1 : bias0;
    float* C = batch ? C1 : C0;

    constexpr int PARTS = (SPLIT == 3) ? 2 : 1;
    __shared__ u16 smA[2 * PARTS * 8 * 512];
    __shared__ u16 smB[2 * PARTS * 8 * 512];

    int tid = threadIdx.x;
    int w = tid >> 6, L = tid & 63;
    int m15 = L & 15, q = L >> 4;
    int KT = K >> 5;
    int rowTile = blockIdx.y * 8, colTile = blockIdx.x * 8;
    int NIT = (K / S) >> 5;
    int kb0 = s * NIT;
    int aw = w & 1, bw = w >> 1;

    f32x4 acc[4][4];
#pragma unroll
    for (int i = 0; i < 4; ++i)
#pragma unroll
        for (int j = 0; j < 4; ++j) acc[i][j] = (f32x4){0.f, 0.f, 0.f, 0.f};

    auto stage = [&](int buf, int kb) {
#pragma unroll
        for (int rl = 0; rl < 2; ++rl) {
            int rb = 2 * w + rl;
            glds16(Ahi + ((size_t)(rowTile + rb) * KT + kb) * 512 + (size_t)L * 8,
                   &smA[((buf * PARTS + 0) * 8 + rb) * 512]);
            glds16(Bhi + ((size_t)(colTile + rb) * KT + kb) * 512 + (size_t)L * 8,
                   &smB[((buf * PARTS + 0) * 8 + rb) * 512]);
            if constexpr (SPLIT == 3) {
                glds16(Alo + ((size_t)(rowTile + rb) * KT + kb) * 512 + (size_t)L * 8,
                       &smA[((buf * PARTS + 1) * 8 + rb) * 512]);
                glds16(Blo + ((size_t)(colTile + rb) * KT + kb) * 512 + (size_t)L * 8,
                       &smB[((buf * PARTS + 1) * 8 + rb) * 512]);
            }
        }
    };

    stage(0, kb0);
    for (int it = 0; it < NIT; ++it) {
        __syncthreads();
        if (it + 1 < NIT) stage((it + 1) & 1, kb0 + it + 1);
        int buf = it & 1;
        short8 ah[4], bh[4];
#pragma unroll
        for (int i = 0; i < 4; ++i) {
            ah[i] = *(const short8*)&smA[((buf * PARTS + 0) * 8 + aw * 4 + i) * 512 + L * 8];
            bh[i] = *(const short8*)&smB[((buf * PARTS + 0) * 8 + bw * 4 + i) * 512 + L * 8];
        }
        if constexpr (SPLIT == 3) {
            short8 al[4], bl[4];
#pragma unroll
            for (int i = 0; i < 4; ++i) {
                al[i] = *(const short8*)&smA[((buf * PARTS + 1) * 8 + aw * 4 + i) * 512 + L * 8];
                bl[i] = *(const short8*)&smB[((buf * PARTS + 1) * 8 + bw * 4 + i) * 512 + L * 8];
            }
#pragma unroll
            for (int i = 0; i < 4; ++i)
#pragma unroll
                for (int j = 0; j < 4; ++j) {
                    acc[i][j] = __builtin_amdgcn_mfma_f32_16x16x32_bf16(ah[i], bl[j], acc[i][j], 0, 0, 0);
                    acc[i][j] = __builtin_amdgcn_mfma_f32_16x16x32_bf16(al[i], bh[j], acc[i][j], 0, 0, 0);
                    acc[i][j] = __builtin_amdgcn_mfma_f32_16x16x32_bf16(ah[i], bh[j], acc[i][j], 0, 0, 0);
                }
        } else {
#pragma unroll
            for (int i = 0; i < 4; ++i)
#pragma unroll
                for (int j = 0; j < 4; ++j)
                    acc[i][j] = __builtin_amdgcn_mfma_f32_16x16x32_bf16(ah[i], bh[j], acc[i][j], 0, 0, 0);
        }
    }

    if constexpr (FINAL == 0) C += (size_t)s * M * N;
#pragma unroll
    for (int i = 0; i < 4; ++i) {
        int row = rowTile * 16 + aw * 64 + i * 16 + q * 4;
#pragma unroll
        for (int j = 0; j < 4; ++j) {
            int col = colTile * 16 + bw * 64 + j * 16 + m15;
            float bv = (FINAL && bias) ? bias[col] : 0.f;
#pragma unroll
            for (int r = 0; r < 4; ++r) {
                float v = acc[i][j][r];
                if constexpr (FINAL) {
                    v += bv;
                    if (ACT == 1) v = fmaxf(v, 0.f);
                    if (ACT == 2) v = 1.f / (1.f + expf(-v));
                }
                C[(size_t)(row + r) * N + col] = v;
            }
        }
    }
}

// ---------------------------------------------------------------------------
// K3b: split-K reduce -> f32 [M][N] with bias/act. Dual pointer sets via blockIdx.y.
// ---------------------------------------------------------------------------
template<int ACT>
__global__ void reduce_f32(const float* __restrict__ P0, const float* __restrict__ bias0,
                           float* __restrict__ C0,
                           const float* __restrict__ P1, const float* __restrict__ bias1,
                           float* __restrict__ C1, int S, int M, int N) {
    const float* P = blockIdx.y ? P1 : P0;
    const float* bias = blockIdx.y ? bias1 : bias0;
    float* C = blockIdx.y ? C1 : C0;
    int idx = blockIdx.x * 256 + threadIdx.x;
    int mn4 = (M * N) >> 2;
    if (idx >= mn4) return;
    f32x4 a = ((const f32x4*)P)[idx];
    for (int s = 1; s < S; ++s) a += ((const f32x4*)P)[(size_t)s * mn4 + idx];
    int col = (idx % (N >> 2)) * 4;
    f32x4 o;
#pragma unroll
    for (int j = 0; j < 4; ++j) {
        float v = a[j] + (bias ? bias[col + j] : 0.f);
        if (ACT == 1) v = fmaxf(v, 0.f);
        if (ACT == 2) v = 1.f / (1.f + expf(-v));
        o[j] = v;
    }
    ((f32x4*)C)[idx] = o;
}

// ---------------------------------------------------------------------------
// K3c: split-K reduce + relu + bias -> split-bf16 TILED (MLP1 hid, M=128, N=HIDN)
// ---------------------------------------------------------------------------
__global__ void reduce_hid(const float* __restrict__ P0, const float* __restrict__ b0,
                           u16* __restrict__ hi0, u16* __restrict__ lo0,
                           const float* __restrict__ P1, const float* __restrict__ b1,
                           u16* __restrict__ hi1, u16* __restrict__ lo1, int S) {
    const float* P = blockIdx.y ? P1 : P0;
    const float* bias = blockIdx.y ? b1 : b0;
    u16* hi = blockIdx.y ? hi1 : hi0;
    u16* lo = blockIdx.y ? lo1 : lo0;
    int idx = blockIdx.x * 256 + threadIdx.x;       // 128*2048/8 = 32768
    int col = (idx & 255) * 8, rowi = idx >> 8;
    size_t base = ((size_t)rowi * HIDN + col) >> 2;
    f32x4 a0 = ((const f32x4*)P)[base], a1 = ((const f32x4*)P)[base + 1];
    for (int s = 1; s < S; ++s) {
        size_t sb = (size_t)s * (128 * HIDN / 4) + base;
        a0 += ((const f32x4*)P)[sb];
        a1 += ((const f32x4*)P)[sb + 1];
    }
    u16x8 h, l;
#pragma unroll
    for (int j = 0; j < 8; ++j) {
        float v = (j < 4 ? a0[j] : a1[j - 4]) + bias[col + j];
        v = fmaxf(v, 0.f);
        u16 hh = f2bf(v);
        h[j] = hh;
        l[j] = f2bf(v - bf2f(hh));
    }
    size_t ob = tiled_off(rowi, col, HIDN);
    *(u16x8*)&hi[ob] = h;
    *(u16x8*)&lo[ob] = l;
}

// ---------------------------------------------------------------------------
// K3d: MLP2 split-K reduce + bias fused with mem_kv concat -> ck/cv [KVH][33][DH]
// ---------------------------------------------------------------------------
__global__ void reduce_ckcv(const float* __restrict__ Pk, const float* __restrict__ Pv,
                            const float* __restrict__ mem_kv,
                            const float* __restrict__ kb2, const float* __restrict__ vb2,
                            float* __restrict__ ck, float* __restrict__ cv, int S) {
    int idx = blockIdx.x * 256 + threadIdx.x;   // 4*33*64 = 8448
    if (idx >= KVH * 33 * DH) return;
    int d = idx & 63;
    int j = (idx >> 6) % 33;
    int h = idx / (33 * 64);
    float kvv, vvv;
    if (j == 0) {
        kvv = mem_kv[(0 * KVH + h) * DH + d];
        vvv = mem_kv[(1 * KVH + h) * DH + d];
    } else {
        size_t base = (size_t)(h * WBLK + (j - 1)) * 128 + d;
        float ak = Pk[base], av = Pv[base];
        for (int s = 1; s < S; ++s) {
            ak += Pk[(size_t)s * (128 * 128) + base];
            av += Pv[(size_t)s * (128 * 128) + base];
        }
        kvv = ak + kb2[d];
        vvv = av + vb2[d];
    }
    ck[idx] = kvv;
    cv[idx] = vvv;
}

// ---------------------------------------------------------------------------
// K5: build compress-MLP inputs -> split-bf16 TILED (K=CDIM)
// ---------------------------------------------------------------------------
__global__ void build_cmlp_in(const float* __restrict__ qkv, const float* __restrict__ k_pos,
                              const float* __restrict__ v_pos,
                              u16* __restrict__ ckhi, u16* __restrict__ cklo,
                              u16* __restrict__ cvhi, u16* __restrict__ cvlo) {
    int idx = blockIdx.x * 256 + threadIdx.x;   // 128 * 256 = 32768
    int k = (idx & 255) * 8;
    int r = idx >> 8;                           // 0..127 = h*W + w
    int p = k >> 6, d = k & 63;
    int h = r >> 5, wb = r & 31;
    int nn = wb * BSZ + p;
    const float* kq = qkv + (size_t)nn * QKVD + (HEADS + h) * DH + d;
    const float* vq = qkv + (size_t)nn * QKVD + (HEADS + KVH + h) * DH + d;
    const float* kp = k_pos + (size_t)(h * BSZ + p) * DH + d;
    const float* vp = v_pos + (size_t)(h * BSZ + p) * DH + d;
    u16x8 kh, kl, vh, vl;
#pragma unroll
    for (int j = 0; j < 8; ++j) {
        float kv = kq[j] + kp[j];
        float vv = vq[j] + vp[j];
        u16 a = f2bf(kv), b = f2bf(vv);
        kh[j] = a; kl[j] = f2bf(kv - bf2f(a));
        vh[j] = b; vl[j] = f2bf(vv - bf2f(b));
    }
    size_t ob = tiled_off(r, k, CDIM);
    *(u16x8*)&ckhi[ob] = kh; *(u16x8*)&cklo[ob] = kl;
    *(u16x8*)&cvhi[ob] = vh; *(u16x8*)&cvlo[ob] = vl;
}

// ---------------------------------------------------------------------------
// K7: interleaved rotary for q (16 heads), k (4 heads) + packed v copy (4 heads)
// ---------------------------------------------------------------------------
__global__ void rotary_kernel(const float* __restrict__ qkv,
                              float* __restrict__ qr, float* __restrict__ kr,
                              float* __restrict__ vr) {
    int idx = blockIdx.x * 256 + threadIdx.x;   // 24*1024*32 = 786432
    int i = idx & 31;
    int n = (idx >> 5) & 1023;
    int hd = idx >> 15;
    if (hd >= 24) return;
    if (hd >= HEADS + KVH) {       // packed v copy
        int h = hd - (HEADS + KVH);
        const float* src = qkv + (size_t)n * QKVD + (HEADS + KVH + h) * DH;
        float* dst = vr + ((size_t)h * NTOK + n) * DH;
        dst[2 * i] = src[2 * i];
        dst[2 * i + 1] = src[2 * i + 1];
        return;
    }
    float inv = powf(10000.f, -(float)i / 32.f);
    float fr = (float)n * inv;
    float c = cosf(fr), s = sinf(fr);
    const float* src; float* dst;
    if (hd < HEADS) { src = qkv + (size_t)n * QKVD + hd * DH;          dst = qr + ((size_t)hd * NTOK + n) * DH; }
    else { int h = hd - HEADS;
           src = qkv + (size_t)n * QKVD + (HEADS + h) * DH;            dst = kr + ((size_t)h * NTOK + n) * DH; }
    float x0 = src[2 * i], x1 = src[2 * i + 1];
    dst[2 * i]     = x0 * c - x1 * s;
    dst[2 * i + 1] = x1 * c + x0 * s;
}

// ---------------------------------------------------------------------------
// K8: compressed attention + importance + top-k. 4 tokens per 256-thr block.
// ---------------------------------------------------------------------------
__global__ __launch_bounds__(256)
void cattn_kernel(const float* __restrict__ qkv, const float* __restrict__ ck,
                  const float* __restrict__ cv, float* __restrict__ c_out,
                  int* __restrict__ sel, int* __restrict__ selmask) {
    int h = blockIdx.y;
    int tid = threadIdx.x;
    int w = tid >> 6, lane = tid & 63;
    int grp = lane >> 4, sub = lane & 15;
    int n = blockIdx.x * 4 + w;
    __shared__ float cks[33 * 68];
    __shared__ float cvs[33 * 68];
    __shared__ float sims[16 * 36];      // [w*4+g][j]

    for (int t4 = tid; t4 < 1056; t4 += 256) {
        int half = (t4 >= 528) ? 1 : 0;
        int u = t4 - half * 528;
        int j = u >> 4, d4 = (u & 15) * 4;
        const float* src = (half ? cv : ck) + (size_t)h * 33 * 64 + j * 64 + d4;
        float* dst = (half ? cvs : cks) + j * 68 + d4;
        *(float4*)dst = *(const float4*)src;
    }
    float qreg[64];
    {
        const float4* qp4 = (const float4*)(qkv + (size_t)n * QKVD + (h * GQ + grp) * DH);
#pragma unroll
        for (int c = 0; c < 16; ++c) {
            float4 v = qp4[c];
            qreg[4 * c] = v.x; qreg[4 * c + 1] = v.y; qreg[4 * c + 2] = v.z; qreg[4 * c + 3] = v.w;
        }
    }
    __syncthreads();

#pragma unroll
    for (int r = 0; r < 3; ++r) {
        int j = r * 16 + sub;
        if (j < 33) {
            float acc = 0.f;
#pragma unroll
            for (int d = 0; d < 64; ++d) acc = fmaf(qreg[d], cks[j * 68 + d], acc);
            sims[(w * 4 + grp) * 36 + j] = acc * SCALE;
        }
    }

    float ival = NEGINF;
    if (lane < 32)
        ival = 0.25f * (sims[(w * 4 + 0) * 36 + 1 + lane] + sims[(w * 4 + 1) * 36 + 1 + lane] +
                        sims[(w * 4 + 2) * 36 + 1 + lane] + sims[(w * 4 + 3) * 36 + 1 + lane]);
    float m = ival;
    for (int off = 32; off; off >>= 1) m = fmaxf(m, __shfl_xor(m, off));
    float e = (lane < 32) ? expf(ival - m) : 0.f;
    float sum = e;
    for (int off = 32; off; off >>= 1) sum += __shfl_xor(sum, off);
    float p = (lane < 32) ? e / sum : NEGINF;

    float v = p;
    int base = (h * NTOK + n) * 9;
    for (int t = 0; t < NSEL; ++t) {
        float bv = v; int bi = lane;
        for (int off = 32; off; off >>= 1) {
            float ov = __shfl_xor(bv, off);
            int   oi = __shfl_xor(bi, off);
            if (ov > bv || (ov == bv && oi < bi)) { bv = ov; bi = oi; }
        }
        if (lane == 0) { sel[base + t] = bi; selmask[base + t] = (bv > 1e-10f) ? 1 : 0; }
        if (lane == bi) v = NEGINF;
    }
    if (lane == 0) { sel[base + NSEL] = n >> 5; selmask[base + NSEL] = 1; }

#pragma unroll
    for (int g = 0; g < 4; ++g) {
        float sv = (lane < 33) ? sims[(w * 4 + g) * 36 + lane] : NEGINF;
        float mm = sv;
        for (int off = 32; off; off >>= 1) mm = fmaxf(mm, __shfl_xor(mm, off));
        float ee = (lane < 33) ? __expf(sv - mm) : 0.f;
        float ssum = ee;
        for (int off = 32; off; off >>= 1) ssum += __shfl_xor(ssum, off);
        if (lane < 33) sims[(w * 4 + g) * 36 + lane] = ee / ssum;
    }

    f32x4 o = (f32x4){0.f, 0.f, 0.f, 0.f};
#pragma unroll
    for (int j = 0; j < 33; ++j) {
        float a = sims[(w * 4 + grp) * 36 + j];
        f32x4 vv = *(const f32x4*)&cvs[j * 68 + sub * 4];
        o += a * vv;
    }
    *(f32x4*)&c_out[(((size_t)(h * GQ + grp)) * NTOK + n) * DH + sub * 4] = o;
}

// ---------------------------------------------------------------------------
// K9: fine attention v10.
// R2 post-mortem: v9's q-to-VGPR hoist spilled to scratch (WRITE_SIZE 4MB->74MB,
// VGPR pinned 64 by launch_bounds while qv[16] alone needs 64) and the
// ^((r&7)<<1) swizzle was a 4-way conflict (SQ_LDS_BANK_CONFLICT 30x).
// v10: (a) q back in LDS (broadcast reads, VGPR ~48, zero spill);
// (b) glds staging kept but with the CORRECT involution slot = c ^ (r&15):
//     bijective over 16 slots -> score reads 16 distinct slots (2-way inherent,
//     free per m136), PV reads bijective over sub, staging write linear 1KB;
// (c) K/V double-buffered (2x16KB): tile bp+1's K+V glds issued at loop top,
//     latency hides under the score phase; barriers 4 -> 3 per iter.
//     Dependencies: buf^1 last read in PV(bp-1) (ended at B3(bp-1)); prefetch
//     drains at B1(bp); scores(bp+1) start after B3(bp). ssc: written in
//     scores, read in softmax (B1 between); ps: written softmax, read PV (B2).
// ---------------------------------------------------------------------------
__global__ __launch_bounds__(256, 8)
void fattn_kernel(const float* __restrict__ qr, const float* __restrict__ kr,
                  const float* __restrict__ vr, const int* __restrict__ sel,
                  const int* __restrict__ selmask, float* __restrict__ f_out) {
    int n = blockIdx.x, h = blockIdx.y;
    int tid = threadIdx.x;
    int w = tid >> 6, lane = tid & 63;
    int grp = lane >> 4, sub = lane & 15;
    __shared__ float qsm[4 * 68];
    __shared__ float KV[2 * 2 * 64 * 64];   // [buf][K/V][row][64]; slot s of row r = global slot s^(r&15)
    __shared__ float ssc[4 * 68];
    __shared__ float ps[4 * 68];
    __shared__ float alphas[4], ls[4];
    __shared__ int sel_s[9], msk_s[9];

    if (tid < 9) {
        sel_s[tid] = sel[(h * NTOK + n) * 9 + tid];
        msk_s[tid] = selmask[(h * NTOK + n) * 9 + tid];
    }
    // q -> LDS once: wave w loads head w's 64 elements
    qsm[w * 68 + lane] = qr[(((size_t)(h * GQ + w)) * NTOK + n) * DH + lane];
    f32x4 o4 = (f32x4){0.f, 0.f, 0.f, 0.f};   // partial over wave's j-slice, dims sub*4..sub*4+3
    float m_run = -3.402823466e38f, l_run = 0.f;
    __syncthreads();                     // sel_s + qsm ready

    const float* krh_ = kr + (size_t)h * NTOK * DH;
    const float* vrh_ = vr + (size_t)h * NTOK * DH;

    // staging geometry: wave w stages rows [w*16, w*16+16); glds chunk cc = 4 rows.
    // lane L -> row_local = L>>4, slot = L&15 (dest linear: base + L*16B).
    int rl = lane >> 4, sl = lane & 15;

    auto stageKV = [&](int buf, int tile) {
        int nrow = (tile < 4) ? 64 : 32;
        if (w * 16 < nrow) {
            int myblk = sel_s[tile * 2 + (w >> 1)];
            const float* kb = krh_ + (size_t)myblk * BSZ * DH;
            const float* vb = vrh_ + (size_t)myblk * BSZ * DH;
#pragma unroll
            for (int cc = 0; cc < 4; ++cc) {
                int r = w * 16 + cc * 4 + rl;
                int sg = sl ^ (r & 15);
                size_t goff = (size_t)(r & 31) * DH + sg * 4;
                glds16(kb + goff, &KV[(buf * 2 + 0) * 4096 + (w * 16 + cc * 4) * 64]);
                glds16(vb + goff, &KV[(buf * 2 + 1) * 4096 + (w * 16 + cc * 4) * 64]);
            }
        }
    };

    stageKV(0, 0);
    __syncthreads();                     // buf0 K+V staged (syncthreads drains vmcnt)

    for (int bp = 0; bp < 5; ++bp) {
        int nrow = (bp < 4) ? 64 : 32;
        int buf = bp & 1;
        // ---- prefetch next tile's K+V into buf^1 (latency hides under scores)
        if (bp < 4) stageKV(buf ^ 1, bp + 1);

        // ---- scores: thread -> (g=grp, jj=w*16+sub); q from LDS (bcast)
        {
            int jj = w * 16 + sub;
            int b = bp * 2 + (jj >> 5);
            float s = -3.402823466e38f;
            if (jj < nrow && msk_s[b]) {
                int sw = jj & 15;
                const float* Kb = &KV[(buf * 2 + 0) * 4096 + jj * 64];
                float acc = 0.f;
#pragma unroll
                for (int c = 0; c < 16; ++c) {
                    f32x4 k4 = *(const f32x4*)&Kb[(c ^ sw) * 4];
                    f32x4 q4 = *(const f32x4*)&qsm[grp * 68 + c * 4];
                    acc = fmaf(q4[0], k4[0], acc);
                    acc = fmaf(q4[1], k4[1], acc);
                    acc = fmaf(q4[2], k4[2], acc);
                    acc = fmaf(q4[3], k4[3], acc);
                }
                s = acc * SCALE;
            }
            ssc[grp * 68 + jj] = s;
        }
        __syncthreads();                  // B1: ssc complete; prefetch drained

        // ---- online softmax (wave w owns head w)
        {
            float sv = ssc[w * 68 + lane];
            float mb = sv;
            for (int off = 32; off; off >>= 1) mb = fmaxf(mb, __shfl_xor(mb, off));
            float m_new = fmaxf(m_run, mb);
            float pp = (sv > -1e37f) ? __expf(sv - m_new) : 0.f;
            float alpha = __expf(m_run - m_new);
            float psum = pp;
            for (int off = 32; off; off >>= 1) psum += __shfl_xor(psum, off);
            l_run = l_run * alpha + psum;
            m_run = m_new;
            ps[w * 68 + lane] = pp;
            if (lane == 0) alphas[w] = alpha;
        }
        __syncthreads();                  // B2: ps/alphas ready

        // ---- PV: wave w owns rows [w*16, w*16+16); thread (g=grp, c=sub)
        {
            o4 *= alphas[grp];            // per-head alpha: same for every wave
            int jbase = w * 16;
            if (jbase < nrow) {
                const float* Vb = &KV[(buf * 2 + 1) * 4096];
#pragma unroll
                for (int jq = 0; jq < 4; ++jq) {
                    f32x4 p4 = *(const f32x4*)&ps[grp * 68 + jbase + jq * 4];
#pragma unroll
                    for (int r = 0; r < 4; ++r) {
                        int row = jbase + jq * 4 + r;
                        int slot = sub ^ (row & 15);
                        f32x4 vv = *(const f32x4*)&Vb[row * 64 + slot * 4];
                        o4 += p4[r] * vv;
                    }
                }
            }
        }
        __syncthreads();                  // B3: PV done (buf^1 safe to reuse next iter)
    }
    if (lane == 0) ls[w] = l_run;
    // cross-wave reduction of the 4 j-slice partials through the free KV buffer
    *(f32x4*)&KV[(w * 4 + grp) * 64 + sub * 4] = o4;
    __syncthreads();
    float sum = KV[(0 * 4 + w) * 64 + lane] + KV[(1 * 4 + w) * 64 + lane]
              + KV[(2 * 4 + w) * 64 + lane] + KV[(3 * 4 + w) * 64 + lane];
    f_out[(((size_t)(h * GQ + w)) * NTOK + n) * DH + lane] = sum / ls[w];
}

// ---------------------------------------------------------------------------
// K10: gated mix -> split-bf16 TILED (K=DDIM). gates f32 [N][128] padded.
// ---------------------------------------------------------------------------
__global__ void mix_kernel(const float* __restrict__ gates, const float* __restrict__ c_out,
                           const float* __restrict__ f_out,
                           u16* __restrict__ mixhi, u16* __restrict__ mixlo) {
    int idx = blockIdx.x * 256 + threadIdx.x;   // 1024*1024/8 = 131072
    int col = (idx & 127) * 8;
    int n = idx >> 7;
    int hd = col >> 6, d = col & 63;
    float g0 = gates[(size_t)n * 128 + hd * 2];
    float g1 = gates[(size_t)n * 128 + hd * 2 + 1];
    size_t hoff = (((size_t)hd) * NTOK + n) * DH + d;
    u16x8 h, l;
#pragma unroll
    for (int j = 0; j < 8; ++j) {
        float v = g0 * c_out[hoff + j] + g1 * f_out[hoff + j];
        u16 hh = f2bf(v);
        h[j] = hh;
        l[j] = f2bf(v - bf2f(hh));
    }
    size_t ob = tiled_off(n, col, DDIM);
    *(u16x8*)&mixhi[ob] = h;
    *(u16x8*)&mixlo[ob] = l;
}

// ---------------------------------------------------------------------------
extern "C" void kernel_launch(void* const* d_in, const int* in_sizes, int n_in,
                              void* d_out, int out_size, void* d_ws, size_t ws_size,
                              hipStream_t stream) {
    const float* inp    = (const float*)d_in[0];
    const float* g_norm = (const float*)d_in[1];
    const float* w_qkv  = (const float*)d_in[2];
    const float* mem_kv = (const float*)d_in[3];
    const float* k_pos  = (const float*)d_in[4];
    const float* v_pos  = (const float*)d_in[5];
    const float* k_w1   = (const float*)d_in[6];
    const float* k_b1   = (const float*)d_in[7];
    const float* k_w2   = (const float*)d_in[8];
    const float* k_b2   = (const float*)d_in[9];
    const float* v_w1   = (const float*)d_in[10];
    const float* v_b1   = (const float*)d_in[11];
    const float* v_w2   = (const float*)d_in[12];
    const float* v_b2   = (const float*)d_in[13];
    const float* gate_w = (const float*)d_in[14];
    const float* gate_b = (const float*)d_in[15];
    const float* w_out  = (const float*)d_in[16];
    float* out = (float*)d_out;

    char* wsb = (char*)d_ws;
    size_t off = 0;
    auto alloc = [&](size_t bytes) -> void* {
        void* p = wsb + off;
        off = (off + bytes + 255) & ~(size_t)255;
        return p;
    };
    u16*   xhi    = (u16*)  alloc((size_t)NTOK * DDIM * 2);
    u16*   xlo    = (u16*)  alloc((size_t)NTOK * DDIM * 2);
    float* qkvb   = (float*)alloc((size_t)NTOK * QKVD * 4);
    u16*   wqThi  = (u16*)  alloc((size_t)QKVD * DDIM * 2);
    u16*   wqTlo  = (u16*)  alloc((size_t)QKVD * DDIM * 2);
    u16*   kw1Thi = (u16*)  alloc((size_t)HIDN * CDIM * 2);
    u16*   kw1Tlo = (u16*)  alloc((size_t)HIDN * CDIM * 2);
    u16*   vw1Thi = (u16*)  alloc((size_t)HIDN * CDIM * 2);
    u16*   vw1Tlo = (u16*)  alloc((size_t)HIDN * CDIM * 2);
    u16*   woThi  = (u16*)  alloc((size_t)DDIM * DDIM * 2);
    u16*   gwThi  = (u16*)  alloc((size_t)128 * DDIM * 2);
    u16*   gwTlo  = (u16*)  alloc((size_t)128 * DDIM * 2);
    float* gbp    = (float*)alloc(128 * 4);
    u16*   kw2Thi = (u16*)  alloc((size_t)128 * HIDN * 2);
    u16*   kw2Tlo = (u16*)  alloc((size_t)128 * HIDN * 2);
    float* kb2p   = (float*)alloc(128 * 4);
    u16*   vw2Thi = (u16*)  alloc((size_t)128 * HIDN * 2);
    u16*   vw2Tlo = (u16*)  alloc((size_t)128 * HIDN * 2);
    float* vb2p   = (float*)alloc(128 * 4);
    u16*   cinkhi = (u16*)  alloc((size_t)128 * CDIM * 2);
    u16*   cinklo = (u16*)  alloc((size_t)128 * CDIM * 2);
    u16*   cinvhi = (u16*)  alloc((size_t)128 * CDIM * 2);
    u16*   cinvlo = (u16*)  alloc((size_t)128 * CDIM * 2);
    u16*   hidkhi = (u16*)  alloc((size_t)128 * HIDN * 2);
    u16*   hidklo = (u16*)  alloc((size_t)128 * HIDN * 2);
    u16*   hidvhi = (u16*)  alloc((size_t)128 * HIDN * 2);
    u16*   hidvlo = (u16*)  alloc((size_t)128 * HIDN * 2);
    float* Pg     = (float*)alloc((size_t)8 * NTOK * 128 * 4);
    float* Pm1k   = (float*)alloc((size_t)4 * 128 * HIDN * 4);
    float* Pm1v   = (float*)alloc((size_t)4 * 128 * HIDN * 4);
    float* Pm2k   = (float*)alloc((size_t)8 * 128 * 128 * 4);
    float* Pm2v   = (float*)alloc((size_t)8 * 128 * 128 * 4);
    float* ck     = (float*)alloc((size_t)KVH * 33 * DH * 4);
    float* cv     = (float*)alloc((size_t)KVH * 33 * DH * 4);
    float* qr     = (float*)alloc((size_t)HEADS * NTOK * DH * 4);
    float* kr     = (float*)alloc((size_t)KVH * NTOK * DH * 4);
    float* vr     = (float*)alloc((size_t)KVH * NTOK * DH * 4);
    float* c_out  = (float*)alloc((size_t)HEADS * NTOK * DH * 4);
    float* f_out  = (float*)alloc((size_t)HEADS * NTOK * DH * 4);
    float* gates  = (float*)alloc((size_t)NTOK * 128 * 4);
    int*   sel    = (int*)  alloc((size_t)KVH * NTOK * 9 * 4);
    int*   selmask= (int*)  alloc((size_t)KVH * NTOK * 9 * 4);
    u16*   mixhi  = (u16*)  alloc((size_t)NTOK * DDIM * 2);
    u16*   mixlo  = (u16*)  alloc((size_t)NTOK * DDIM * 2);

    // weight prep (tiled layouts)
    transpose_split<<<dim3(QKVD / 64, DDIM / 64), 256, 0, stream>>>(w_qkv, wqThi, wqTlo, DDIM, QKVD);
    transpose_split<<<dim3(HIDN / 64, CDIM / 64), 256, 0, stream>>>(k_w1, kw1Thi, kw1Tlo, CDIM, HIDN);
    transpose_split<<<dim3(HIDN / 64, CDIM / 64), 256, 0, stream>>>(v_w1, vw1Thi, vw1Tlo, CDIM, HIDN);
    transpose_split<<<dim3(DDIM / 64, DDIM / 64), 256, 0, stream>>>(w_out, woThi, nullptr, DDIM, DDIM);
    pad_small_tiled<<<(128 * DDIM / 8) / 256, 256, 0, stream>>>(gate_w, gate_b, gwThi, gwTlo, gbp, DDIM, 32, 10);
    pad_small_tiled<<<(128 * HIDN / 8) / 256, 256, 0, stream>>>(k_w2, k_b2, kw2Thi, kw2Tlo, kb2p, HIDN, 64, 11);
    pad_small_tiled<<<(128 * HIDN / 8) / 256, 256, 0, stream>>>(v_w2, v_b2, vw2Thi, vw2Tlo, vb2p, HIDN, 64, 11);

    // 1. RMSNorm -> tiled split-bf16 x
    rmsnorm_kernel<<<NTOK / 2, 256, 0, stream>>>(inp, g_norm, xhi, xlo);
    // 2. qkv = x @ w_qkv (final f32)
    gemm_tiled<3, 0, 1><<<dim3(QKVD / 128, NTOK / 128, 1), 256, 0, stream>>>(
        xhi, xlo, wqThi, wqTlo, nullptr, qkvb,
        xhi, xlo, wqThi, wqTlo, nullptr, qkvb, NTOK, QKVD, DDIM, 1);
    // 3. gates (split-K 8 + sigmoid reduce)
    gemm_tiled<3, 0, 0><<<dim3(1, NTOK / 128, 8), 256, 0, stream>>>(
        xhi, xlo, gwThi, gwTlo, nullptr, Pg,
        xhi, xlo, gwThi, gwTlo, nullptr, Pg, NTOK, 128, DDIM, 8);
    reduce_f32<2><<<dim3(128, 1), 256, 0, stream>>>(Pg, gbp, gates, Pg, gbp, gates, 8, NTOK, 128);
    // 4. compress-MLP inputs (tiled)
    build_cmlp_in<<<128, 256, 0, stream>>>(qkvb, k_pos, v_pos, cinkhi, cinklo, cinvhi, cinvlo);
    // 5. MLP1 (split-K 4, k&v batched; relu+bias+split-tile in reduce)
    gemm_tiled<3, 0, 0><<<dim3(HIDN / 128, 1, 8), 256, 0, stream>>>(
        cinkhi, cinklo, kw1Thi, kw1Tlo, nullptr, Pm1k,
        cinvhi, cinvlo, vw1Thi, vw1Tlo, nullptr, Pm1v, 128, HIDN, CDIM, 4);
    reduce_hid<<<dim3(128, 2), 256, 0, stream>>>(Pm1k, k_b1, hidkhi, hidklo,
                                                 Pm1v, v_b1, hidvhi, hidvlo, 4);
    // 6. MLP2 (split-K 8, k&v batched) + fused reduce/bias/concat
    gemm_tiled<3, 0, 0><<<dim3(1, 1, 16), 256, 0, stream>>>(
        hidkhi, hidklo, kw2Thi, kw2Tlo, nullptr, Pm2k,
        hidvhi, hidvlo, vw2Thi, vw2Tlo, nullptr, Pm2v, 128, 128, HIDN, 8);
    reduce_ckcv<<<33, 256, 0, stream>>>(Pm2k, Pm2v, mem_kv, kb2p, vb2p, ck, cv, 8);
    // 8. rotary + packed v
    rotary_kernel<<<(24 * NTOK * 32) / 256, 256, 0, stream>>>(qkvb, qr, kr, vr);
    // 9. compressed attention + selection (4 tokens per block)
    cattn_kernel<<<dim3(NTOK / 4, KVH), 256, 0, stream>>>(qkvb, ck, cv, c_out, sel, selmask);
    // 10. fine attention (v10: fixed swizzle, q in LDS, double-buffered prefetch)
    fattn_kernel<<<dim3(NTOK, KVH), 256, 0, stream>>>(qr, kr, vr, sel, selmask, f_out);
    // 11. gated mix -> tiled split-bf16
    mix_kernel<<<(NTOK * DDIM / 8) / 256, 256, 0, stream>>>(gates, c_out, f_out, mixhi, mixlo);
    // 12. output projection (bf16, final)
    gemm_tiled<1, 0, 1><<<dim3(DDIM / 128, NTOK / 128, 1), 256, 0, stream>>>(
        mixhi, mixhi, woThi, woThi, nullptr, out,
        mixhi, mixhi, woThi, woThi, nullptr, out, NTOK, DDIM, DDIM, 1);
}

// Round 4
// 367.144 us; speedup vs baseline: 1.0390x; 1.0390x over previous
//
#include <hip/hip_runtime.h>
#include <math.h>

// ---- fixed problem sizes ----
#define NTOK 1024
#define DDIM 1024
#define HEADS 16
#define KVH 4
#define DH 64
#define BSZ 32
#define NSEL 8
#define WBLK 32            // NTOK / BSZ
#define GQ 4               // HEADS / KVH
#define CDIM 2048          // BSZ*DH
#define HIDN 2048
#define QKVD 1536          // (HEADS + 2*KVH)*DH
#define SCALE 0.125f       // DH^-0.5
#define NEGINF (-__builtin_inff())

typedef unsigned short u16;
typedef u16   u16x8  __attribute__((ext_vector_type(8)));
typedef short short8 __attribute__((ext_vector_type(8)));
typedef float f32x4  __attribute__((ext_vector_type(4)));

__device__ __forceinline__ u16 f2bf(float f) {
    unsigned u = __float_as_uint(f);
    return (u16)((u + 0x7fffu + ((u >> 16) & 1u)) >> 16);
}
__device__ __forceinline__ float bf2f(u16 h) { return __uint_as_float(((unsigned)h) << 16); }

__device__ __forceinline__ void glds16(const void* g, void* l) {
    __builtin_amdgcn_global_load_lds(
        (const __attribute__((address_space(1))) unsigned int*)g,
        (__attribute__((address_space(3))) unsigned int*)l, 16, 0, 0);
}

// element offset (in u16) of the 8-element lane-slot for (row, k..k+7) in the
// MFMA-fragment-tiled layout: 16-row x 32-k tiles, 1KB each, contiguous.
__device__ __forceinline__ size_t tiled_off(int row, int k, int K) {
    return ((size_t)((row >> 4) * (K >> 5) + (k >> 5)) * 64 +
            ((row & 15) | (((k >> 3) & 3) << 4))) * 8;
}

// ---------------------------------------------------------------------------
// K1: RMSNorm -> split-bf16 x in TILED layout (K=DDIM). 2 rows per 256-thr block.
// ---------------------------------------------------------------------------
__global__ void rmsnorm_kernel(const float* __restrict__ inp, const float* __restrict__ g,
                               u16* __restrict__ xhi, u16* __restrict__ xlo) {
    int t = threadIdx.x;
    int half = t >> 7, tid = t & 127;
    int n = blockIdx.x * 2 + half;
    const float4* row = (const float4*)(inp + (size_t)n * DDIM);
    float4 v0 = row[tid * 2], v1 = row[tid * 2 + 1];
    float ss = v0.x*v0.x + v0.y*v0.y + v0.z*v0.z + v0.w*v0.w
             + v1.x*v1.x + v1.y*v1.y + v1.z*v1.z + v1.w*v1.w;
    for (int off = 32; off; off >>= 1) ss += __shfl_down(ss, off);
    __shared__ float red[4];
    if ((t & 63) == 0) red[t >> 6] = ss;
    __syncthreads();
    float tot = red[half * 2] + red[half * 2 + 1];
    float r = 1.f / sqrtf(tot * (1.f / DDIM) + 1e-6f);
    const float4* gp = (const float4*)g;
    float4 g0 = gp[tid * 2], g1 = gp[tid * 2 + 1];
    float o[8] = { v0.x*r*g0.x, v0.y*r*g0.y, v0.z*r*g0.z, v0.w*r*g0.w,
                   v1.x*r*g1.x, v1.y*r*g1.y, v1.z*r*g1.z, v1.w*r*g1.w };
    u16x8 h, l;
#pragma unroll
    for (int i = 0; i < 8; ++i) {
        u16 hh = f2bf(o[i]);
        h[i] = hh;
        l[i] = f2bf(o[i] - bf2f(hh));
    }
    size_t ob = tiled_off(n, tid * 8, DDIM);
    *(u16x8*)&xhi[ob] = h;
    *(u16x8*)&xlo[ob] = l;
}

// ---------------------------------------------------------------------------
// K2: weight transpose + split: W[K][N] f32 -> tiled Bt[N][K] bf16 hi/lo
// ---------------------------------------------------------------------------
__global__ void transpose_split(const float* __restrict__ W, u16* __restrict__ Thi,
                                u16* __restrict__ Tlo, int K, int N) {
    __shared__ float tile[64][65];
    int k0 = blockIdx.y * 64, n0 = blockIdx.x * 64;
    int t = threadIdx.x;
    int r = t >> 4, c4 = (t & 15) * 4;
#pragma unroll
    for (int p = 0; p < 4; ++p) {
        float4 v = *(const float4*)&W[(size_t)(k0 + r + p * 16) * N + n0 + c4];
        tile[r + p * 16][c4 + 0] = v.x;
        tile[r + p * 16][c4 + 1] = v.y;
        tile[r + p * 16][c4 + 2] = v.z;
        tile[r + p * 16][c4 + 3] = v.w;
    }
    __syncthreads();
    int n = t >> 2, ks = (t & 3) * 16;
#pragma unroll
    for (int c = 0; c < 2; ++c) {
        u16x8 h, l;
#pragma unroll
        for (int j = 0; j < 8; ++j) {
            float v = tile[ks + c * 8 + j][n];
            u16 hh = f2bf(v);
            h[j] = hh;
            l[j] = f2bf(v - bf2f(hh));
        }
        size_t ob = tiled_off(n0 + n, k0 + ks + c * 8, K);
        *(u16x8*)&Thi[ob] = h;
        if (Tlo) *(u16x8*)&Tlo[ob] = l;
    }
}

// ---------------------------------------------------------------------------
// K2b: pad small weights [K][Xn] (Xn<=64) -> tiled split-bf16 [128][K] + padded bias
// ---------------------------------------------------------------------------
__global__ void pad_small_tiled(const float* __restrict__ W, const float* __restrict__ b,
                                u16* __restrict__ Thi, u16* __restrict__ Tlo,
                                float* __restrict__ bias_pad, int K, int Xn, int KLOG) {
    int idx = blockIdx.x * 256 + threadIdx.x;   // 128 * K/8
    int k = (idx & ((K >> 3) - 1)) * 8;
    int n = idx >> (KLOG - 3);
    if (n >= 128) return;
    u16x8 h, l;
#pragma unroll
    for (int j = 0; j < 8; ++j) {
        float v = (n < Xn) ? W[(size_t)(k + j) * Xn + n] : 0.f;
        u16 hh = f2bf(v);
        h[j] = hh;
        l[j] = f2bf(v - bf2f(hh));
    }
    size_t ob = tiled_off(n, k, K);
    *(u16x8*)&Thi[ob] = h;
    *(u16x8*)&Tlo[ob] = l;
    if (k == 0) bias_pad[n] = (n < Xn) ? b[n] : 0.f;
}

// ---------------------------------------------------------------------------
// K3: tiled MFMA GEMM with software pipeline + optional split-K.
// ---------------------------------------------------------------------------
template<int SPLIT, int ACT, int FINAL>
__global__ __launch_bounds__(256, 1)
void gemm_tiled(const u16* __restrict__ Ahi0, const u16* __restrict__ Alo0,
                const u16* __restrict__ Bhi0, const u16* __restrict__ Blo0,
                const float* __restrict__ bias0, float* __restrict__ C0,
                const u16* __restrict__ Ahi1, const u16* __restrict__ Alo1,
                const u16* __restrict__ Bhi1, const u16* __restrict__ Blo1,
                const float* __restrict__ bias1, float* __restrict__ C1,
                int M, int N, int K, int S) {
    int batch = blockIdx.z / S;
    int s = blockIdx.z - batch * S;
    const u16* Ahi = batch ? Ahi1 : Ahi0;
    const u16* Alo = batch ? Alo1 : Alo0;
    const u16* Bhi = batch ? Bhi1 : Bhi0;
    const u16* Blo = batch ? Blo1 : Blo0;
    const float* bias = batch ? bias1 : bias0;
    float* C = batch ? C1 : C0;

    constexpr int PARTS = (SPLIT == 3) ? 2 : 1;
    __shared__ u16 smA[2 * PARTS * 8 * 512];
    __shared__ u16 smB[2 * PARTS * 8 * 512];

    int tid = threadIdx.x;
    int w = tid >> 6, L = tid & 63;
    int m15 = L & 15, q = L >> 4;
    int KT = K >> 5;
    int rowTile = blockIdx.y * 8, colTile = blockIdx.x * 8;
    int NIT = (K / S) >> 5;
    int kb0 = s * NIT;
    int aw = w & 1, bw = w >> 1;

    f32x4 acc[4][4];
#pragma unroll
    for (int i = 0; i < 4; ++i)
#pragma unroll
        for (int j = 0; j < 4; ++j) acc[i][j] = (f32x4){0.f, 0.f, 0.f, 0.f};

    auto stage = [&](int buf, int kb) {
#pragma unroll
        for (int rl = 0; rl < 2; ++rl) {
            int rb = 2 * w + rl;
            glds16(Ahi + ((size_t)(rowTile + rb) * KT + kb) * 512 + (size_t)L * 8,
                   &smA[((buf * PARTS + 0) * 8 + rb) * 512]);
            glds16(Bhi + ((size_t)(colTile + rb) * KT + kb) * 512 + (size_t)L * 8,
                   &smB[((buf * PARTS + 0) * 8 + rb) * 512]);
            if constexpr (SPLIT == 3) {
                glds16(Alo + ((size_t)(rowTile + rb) * KT + kb) * 512 + (size_t)L * 8,
                       &smA[((buf * PARTS + 1) * 8 + rb) * 512]);
                glds16(Blo + ((size_t)(colTile + rb) * KT + kb) * 512 + (size_t)L * 8,
                       &smB[((buf * PARTS + 1) * 8 + rb) * 512]);
            }
        }
    };

    stage(0, kb0);
    for (int it = 0; it < NIT; ++it) {
        __syncthreads();
        if (it + 1 < NIT) stage((it + 1) & 1, kb0 + it + 1);
        int buf = it & 1;
        short8 ah[4], bh[4];
#pragma unroll
        for (int i = 0; i < 4; ++i) {
            ah[i] = *(const short8*)&smA[((buf * PARTS + 0) * 8 + aw * 4 + i) * 512 + L * 8];
            bh[i] = *(const short8*)&smB[((buf * PARTS + 0) * 8 + bw * 4 + i) * 512 + L * 8];
        }
        if constexpr (SPLIT == 3) {
            short8 al[4], bl[4];
#pragma unroll
            for (int i = 0; i < 4; ++i) {
                al[i] = *(const short8*)&smA[((buf * PARTS + 1) * 8 + aw * 4 + i) * 512 + L * 8];
                bl[i] = *(const short8*)&smB[((buf * PARTS + 1) * 8 + bw * 4 + i) * 512 + L * 8];
            }
#pragma unroll
            for (int i = 0; i < 4; ++i)
#pragma unroll
                for (int j = 0; j < 4; ++j) {
                    acc[i][j] = __builtin_amdgcn_mfma_f32_16x16x32_bf16(ah[i], bl[j], acc[i][j], 0, 0, 0);
                    acc[i][j] = __builtin_amdgcn_mfma_f32_16x16x32_bf16(al[i], bh[j], acc[i][j], 0, 0, 0);
                    acc[i][j] = __builtin_amdgcn_mfma_f32_16x16x32_bf16(ah[i], bh[j], acc[i][j], 0, 0, 0);
                }
        } else {
#pragma unroll
            for (int i = 0; i < 4; ++i)
#pragma unroll
                for (int j = 0; j < 4; ++j)
                    acc[i][j] = __builtin_amdgcn_mfma_f32_16x16x32_bf16(ah[i], bh[j], acc[i][j], 0, 0, 0);
        }
    }

    if constexpr (FINAL == 0) C += (size_t)s * M * N;
#pragma unroll
    for (int i = 0; i < 4; ++i) {
        int row = rowTile * 16 + aw * 64 + i * 16 + q * 4;
#pragma unroll
        for (int j = 0; j < 4; ++j) {
            int col = colTile * 16 + bw * 64 + j * 16 + m15;
            float bv = (FINAL && bias) ? bias[col] : 0.f;
#pragma unroll
            for (int r = 0; r < 4; ++r) {
                float v = acc[i][j][r];
                if constexpr (FINAL) {
                    v += bv;
                    if (ACT == 1) v = fmaxf(v, 0.f);
                    if (ACT == 2) v = 1.f / (1.f + expf(-v));
                }
                C[(size_t)(row + r) * N + col] = v;
            }
        }
    }
}

// ---------------------------------------------------------------------------
// K3b: split-K reduce -> f32 [M][N] with bias/act. Dual pointer sets via blockIdx.y.
// ---------------------------------------------------------------------------
template<int ACT>
__global__ void reduce_f32(const float* __restrict__ P0, const float* __restrict__ bias0,
                           float* __restrict__ C0,
                           const float* __restrict__ P1, const float* __restrict__ bias1,
                           float* __restrict__ C1, int S, int M, int N) {
    const float* P = blockIdx.y ? P1 : P0;
    const float* bias = blockIdx.y ? bias1 : bias0;
    float* C = blockIdx.y ? C1 : C0;
    int idx = blockIdx.x * 256 + threadIdx.x;
    int mn4 = (M * N) >> 2;
    if (idx >= mn4) return;
    f32x4 a = ((const f32x4*)P)[idx];
    for (int s = 1; s < S; ++s) a += ((const f32x4*)P)[(size_t)s * mn4 + idx];
    int col = (idx % (N >> 2)) * 4;
    f32x4 o;
#pragma unroll
    for (int j = 0; j < 4; ++j) {
        float v = a[j] + (bias ? bias[col + j] : 0.f);
        if (ACT == 1) v = fmaxf(v, 0.f);
        if (ACT == 2) v = 1.f / (1.f + expf(-v));
        o[j] = v;
    }
    ((f32x4*)C)[idx] = o;
}

// ---------------------------------------------------------------------------
// K3c: split-K reduce + relu + bias -> split-bf16 TILED (MLP1 hid, M=128, N=HIDN)
// ---------------------------------------------------------------------------
__global__ void reduce_hid(const float* __restrict__ P0, const float* __restrict__ b0,
                           u16* __restrict__ hi0, u16* __restrict__ lo0,
                           const float* __restrict__ P1, const float* __restrict__ b1,
                           u16* __restrict__ hi1, u16* __restrict__ lo1, int S) {
    const float* P = blockIdx.y ? P1 : P0;
    const float* bias = blockIdx.y ? b1 : b0;
    u16* hi = blockIdx.y ? hi1 : hi0;
    u16* lo = blockIdx.y ? lo1 : lo0;
    int idx = blockIdx.x * 256 + threadIdx.x;       // 128*2048/8 = 32768
    int col = (idx & 255) * 8, rowi = idx >> 8;
    size_t base = ((size_t)rowi * HIDN + col) >> 2;
    f32x4 a0 = ((const f32x4*)P)[base], a1 = ((const f32x4*)P)[base + 1];
    for (int s = 1; s < S; ++s) {
        size_t sb = (size_t)s * (128 * HIDN / 4) + base;
        a0 += ((const f32x4*)P)[sb];
        a1 += ((const f32x4*)P)[sb + 1];
    }
    u16x8 h, l;
#pragma unroll
    for (int j = 0; j < 8; ++j) {
        float v = (j < 4 ? a0[j] : a1[j - 4]) + bias[col + j];
        v = fmaxf(v, 0.f);
        u16 hh = f2bf(v);
        h[j] = hh;
        l[j] = f2bf(v - bf2f(hh));
    }
    size_t ob = tiled_off(rowi, col, HIDN);
    *(u16x8*)&hi[ob] = h;
    *(u16x8*)&lo[ob] = l;
}

// ---------------------------------------------------------------------------
// K3d: MLP2 split-K reduce + bias fused with mem_kv concat -> ck/cv [KVH][33][DH]
// ---------------------------------------------------------------------------
__global__ void reduce_ckcv(const float* __restrict__ Pk, const float* __restrict__ Pv,
                            const float* __restrict__ mem_kv,
                            const float* __restrict__ kb2, const float* __restrict__ vb2,
                            float* __restrict__ ck, float* __restrict__ cv, int S) {
    int idx = blockIdx.x * 256 + threadIdx.x;   // 4*33*64 = 8448
    if (idx >= KVH * 33 * DH) return;
    int d = idx & 63;
    int j = (idx >> 6) % 33;
    int h = idx / (33 * 64);
    float kvv, vvv;
    if (j == 0) {
        kvv = mem_kv[(0 * KVH + h) * DH + d];
        vvv = mem_kv[(1 * KVH + h) * DH + d];
    } else {
        size_t base = (size_t)(h * WBLK + (j - 1)) * 128 + d;
        float ak = Pk[base], av = Pv[base];
        for (int s = 1; s < S; ++s) {
            ak += Pk[(size_t)s * (128 * 128) + base];
            av += Pv[(size_t)s * (128 * 128) + base];
        }
        kvv = ak + kb2[d];
        vvv = av + vb2[d];
    }
    ck[idx] = kvv;
    cv[idx] = vvv;
}

// ---------------------------------------------------------------------------
// K5: build compress-MLP inputs -> split-bf16 TILED (K=CDIM)
// ---------------------------------------------------------------------------
__global__ void build_cmlp_in(const float* __restrict__ qkv, const float* __restrict__ k_pos,
                              const float* __restrict__ v_pos,
                              u16* __restrict__ ckhi, u16* __restrict__ cklo,
                              u16* __restrict__ cvhi, u16* __restrict__ cvlo) {
    int idx = blockIdx.x * 256 + threadIdx.x;   // 128 * 256 = 32768
    int k = (idx & 255) * 8;
    int r = idx >> 8;                           // 0..127 = h*W + w
    int p = k >> 6, d = k & 63;
    int h = r >> 5, wb = r & 31;
    int nn = wb * BSZ + p;
    const float* kq = qkv + (size_t)nn * QKVD + (HEADS + h) * DH + d;
    const float* vq = qkv + (size_t)nn * QKVD + (HEADS + KVH + h) * DH + d;
    const float* kp = k_pos + (size_t)(h * BSZ + p) * DH + d;
    const float* vp = v_pos + (size_t)(h * BSZ + p) * DH + d;
    u16x8 kh, kl, vh, vl;
#pragma unroll
    for (int j = 0; j < 8; ++j) {
        float kv = kq[j] + kp[j];
        float vv = vq[j] + vp[j];
        u16 a = f2bf(kv), b = f2bf(vv);
        kh[j] = a; kl[j] = f2bf(kv - bf2f(a));
        vh[j] = b; vl[j] = f2bf(vv - bf2f(b));
    }
    size_t ob = tiled_off(r, k, CDIM);
    *(u16x8*)&ckhi[ob] = kh; *(u16x8*)&cklo[ob] = kl;
    *(u16x8*)&cvhi[ob] = vh; *(u16x8*)&cvlo[ob] = vl;
}

// ---------------------------------------------------------------------------
// K7: interleaved rotary for q (16 heads), k (4 heads) + packed v copy (4 heads)
// ---------------------------------------------------------------------------
__global__ void rotary_kernel(const float* __restrict__ qkv,
                              float* __restrict__ qr, float* __restrict__ kr,
                              float* __restrict__ vr) {
    int idx = blockIdx.x * 256 + threadIdx.x;   // 24*1024*32 = 786432
    int i = idx & 31;
    int n = (idx >> 5) & 1023;
    int hd = idx >> 15;
    if (hd >= 24) return;
    if (hd >= HEADS + KVH) {       // packed v copy
        int h = hd - (HEADS + KVH);
        const float* src = qkv + (size_t)n * QKVD + (HEADS + KVH + h) * DH;
        float* dst = vr + ((size_t)h * NTOK + n) * DH;
        dst[2 * i] = src[2 * i];
        dst[2 * i + 1] = src[2 * i + 1];
        return;
    }
    float inv = powf(10000.f, -(float)i / 32.f);
    float fr = (float)n * inv;
    float c = cosf(fr), s = sinf(fr);
    const float* src; float* dst;
    if (hd < HEADS) { src = qkv + (size_t)n * QKVD + hd * DH;          dst = qr + ((size_t)hd * NTOK + n) * DH; }
    else { int h = hd - HEADS;
           src = qkv + (size_t)n * QKVD + (HEADS + h) * DH;            dst = kr + ((size_t)h * NTOK + n) * DH; }
    float x0 = src[2 * i], x1 = src[2 * i + 1];
    dst[2 * i]     = x0 * c - x1 * s;
    dst[2 * i + 1] = x1 * c + x0 * s;
}

// ---------------------------------------------------------------------------
// K8: compressed attention + importance + top-k. 4 tokens per 256-thr block.
// ---------------------------------------------------------------------------
__global__ __launch_bounds__(256)
void cattn_kernel(const float* __restrict__ qkv, const float* __restrict__ ck,
                  const float* __restrict__ cv, float* __restrict__ c_out,
                  int* __restrict__ sel, int* __restrict__ selmask) {
    int h = blockIdx.y;
    int tid = threadIdx.x;
    int w = tid >> 6, lane = tid & 63;
    int grp = lane >> 4, sub = lane & 15;
    int n = blockIdx.x * 4 + w;
    __shared__ float cks[33 * 68];
    __shared__ float cvs[33 * 68];
    __shared__ float sims[16 * 36];      // [w*4+g][j]

    for (int t4 = tid; t4 < 1056; t4 += 256) {
        int half = (t4 >= 528) ? 1 : 0;
        int u = t4 - half * 528;
        int j = u >> 4, d4 = (u & 15) * 4;
        const float* src = (half ? cv : ck) + (size_t)h * 33 * 64 + j * 64 + d4;
        float* dst = (half ? cvs : cks) + j * 68 + d4;
        *(float4*)dst = *(const float4*)src;
    }
    float qreg[64];
    {
        const float4* qp4 = (const float4*)(qkv + (size_t)n * QKVD + (h * GQ + grp) * DH);
#pragma unroll
        for (int c = 0; c < 16; ++c) {
            float4 v = qp4[c];
            qreg[4 * c] = v.x; qreg[4 * c + 1] = v.y; qreg[4 * c + 2] = v.z; qreg[4 * c + 3] = v.w;
        }
    }
    __syncthreads();

#pragma unroll
    for (int r = 0; r < 3; ++r) {
        int j = r * 16 + sub;
        if (j < 33) {
            float acc = 0.f;
#pragma unroll
            for (int d = 0; d < 64; ++d) acc = fmaf(qreg[d], cks[j * 68 + d], acc);
            sims[(w * 4 + grp) * 36 + j] = acc * SCALE;
        }
    }

    float ival = NEGINF;
    if (lane < 32)
        ival = 0.25f * (sims[(w * 4 + 0) * 36 + 1 + lane] + sims[(w * 4 + 1) * 36 + 1 + lane] +
                        sims[(w * 4 + 2) * 36 + 1 + lane] + sims[(w * 4 + 3) * 36 + 1 + lane]);
    float m = ival;
    for (int off = 32; off; off >>= 1) m = fmaxf(m, __shfl_xor(m, off));
    float e = (lane < 32) ? expf(ival - m) : 0.f;
    float sum = e;
    for (int off = 32; off; off >>= 1) sum += __shfl_xor(sum, off);
    float p = (lane < 32) ? e / sum : NEGINF;

    float v = p;
    int base = (h * NTOK + n) * 9;
    for (int t = 0; t < NSEL; ++t) {
        float bv = v; int bi = lane;
        for (int off = 32; off; off >>= 1) {
            float ov = __shfl_xor(bv, off);
            int   oi = __shfl_xor(bi, off);
            if (ov > bv || (ov == bv && oi < bi)) { bv = ov; bi = oi; }
        }
        if (lane == 0) { sel[base + t] = bi; selmask[base + t] = (bv > 1e-10f) ? 1 : 0; }
        if (lane == bi) v = NEGINF;
    }
    if (lane == 0) { sel[base + NSEL] = n >> 5; selmask[base + NSEL] = 1; }

#pragma unroll
    for (int g = 0; g < 4; ++g) {
        float sv = (lane < 33) ? sims[(w * 4 + g) * 36 + lane] : NEGINF;
        float mm = sv;
        for (int off = 32; off; off >>= 1) mm = fmaxf(mm, __shfl_xor(mm, off));
        float ee = (lane < 33) ? __expf(sv - mm) : 0.f;
        float ssum = ee;
        for (int off = 32; off; off >>= 1) ssum += __shfl_xor(ssum, off);
        if (lane < 33) sims[(w * 4 + g) * 36 + lane] = ee / ssum;
    }

    f32x4 o = (f32x4){0.f, 0.f, 0.f, 0.f};
#pragma unroll
    for (int j = 0; j < 33; ++j) {
        float a = sims[(w * 4 + grp) * 36 + j];
        f32x4 vv = *(const f32x4*)&cvs[j * 68 + sub * 4];
        o += a * vv;
    }
    *(f32x4*)&c_out[(((size_t)(h * GQ + grp)) * NTOK + n) * DH + sub * 4] = o;
}

// ---------------------------------------------------------------------------
// K9: fine attention v11 — v8's single-buffer 4-barrier structure (best: 77.5us,
// 20.5KB LDS, 45% occ) + the two R2-verified grafts, minus the LDS-hungry dbuf
// that killed v10 (69KB LDS -> 22% occ).
//  (a) glds staging, swizzle slot = c ^ (r&15) (R3-verified conflict-free:
//      bank conflicts back to 163840): removes 8 ds_write_b128/wave-iter.
//  (b) q in VGPRs (16xf32x4), NO __launch_bounds__ pin: R1's spill came from
//      the 64-VGPR pin; natural alloc ~104 VGPR -> 4 waves/SIMD = 50% ceiling
//      (>= current 45% achieved). Removes 16 loop-invariant LDS broadcast
//      reads per wave-iter. Tripwire: WRITE_SIZE must stay ~4MB (no spill).
// LDS ops/wave-iter ~101 -> ~53 on the pipe that sets kernel time.
// ---------------------------------------------------------------------------
__global__ void fattn_kernel(const float* __restrict__ qr, const float* __restrict__ kr,
                             const float* __restrict__ vr, const int* __restrict__ sel,
                             const int* __restrict__ selmask, float* __restrict__ f_out) {
    int n = blockIdx.x, h = blockIdx.y;
    int tid = threadIdx.x;
    int w = tid >> 6, lane = tid & 63;
    int grp = lane >> 4, sub = lane & 15;
    __shared__ float qsm[4 * 68];
    __shared__ float KV[64 * 64];        // K then V each pair; slot s of row r = global slot s^(r&15)
    __shared__ float ssc[4 * 68];
    __shared__ float ps[4 * 68];
    __shared__ float alphas[4], ls[4];
    __shared__ int sel_s[9], msk_s[9];

    if (tid < 9) {
        sel_s[tid] = sel[(h * NTOK + n) * 9 + tid];
        msk_s[tid] = selmask[(h * NTOK + n) * 9 + tid];
    }
    // q -> LDS once: wave w loads head w's 64 elements
    qsm[w * 68 + lane] = qr[(((size_t)(h * GQ + w)) * NTOK + n) * DH + lane];
    f32x4 o4 = (f32x4){0.f, 0.f, 0.f, 0.f};   // partial over wave's j-slice, dims sub*4..sub*4+3
    float m_run = -3.402823466e38f, l_run = 0.f;
    __syncthreads();                     // sel_s + qsm ready

    // q -> VGPRs (one-time broadcast; removes 16 LDS reads per wave-iter)
    f32x4 qv[16];
#pragma unroll
    for (int c = 0; c < 16; ++c) qv[c] = *(const f32x4*)&qsm[grp * 68 + c * 4];

    const float* krh_ = kr + (size_t)h * NTOK * DH;
    const float* vrh_ = vr + (size_t)h * NTOK * DH;

    // staging geometry: wave w stages rows [w*16, w*16+16); glds chunk cc = 4 rows.
    // lane L -> row_local rl = L>>4, slot sl = L&15 (dest linear: base + L*16B);
    // source slot = sl ^ (r&15) so that read with slot = c ^ (row&15) is identity.
    int rl = lane >> 4, sl = lane & 15;

    for (int bp = 0; bp < 5; ++bp) {
        int nrow = (bp < 4) ? 64 : 32;
        int myblk = sel_s[bp * 2 + (w >> 1)];
        const float* kb = krh_ + (size_t)myblk * BSZ * DH;
        const float* vb = vrh_ + (size_t)myblk * BSZ * DH;

        // ---- stage K rows via glds (source-swizzled, linear dest)
        if (w * 16 < nrow) {
#pragma unroll
            for (int cc = 0; cc < 4; ++cc) {
                int r = w * 16 + cc * 4 + rl;
                int sg = sl ^ (r & 15);
                glds16(kb + (size_t)(r & 31) * DH + sg * 4, &KV[(w * 16 + cc * 4) * 64]);
            }
        }
        __syncthreads();                  // B1: K staged (barrier drains vmcnt)

        // ---- scores: thread -> (g=grp, jj=w*16+sub); q from VGPRs
        {
            int jj = w * 16 + sub;
            int b = bp * 2 + (jj >> 5);
            float s = -3.402823466e38f;
            if (jj < nrow && msk_s[b]) {
                int sw = jj & 15;
                const float* Kb = &KV[jj * 64];
                float acc = 0.f;
#pragma unroll
                for (int c = 0; c < 16; ++c) {
                    f32x4 k4 = *(const f32x4*)&Kb[(c ^ sw) * 4];
                    acc = fmaf(qv[c][0], k4[0], acc);
                    acc = fmaf(qv[c][1], k4[1], acc);
                    acc = fmaf(qv[c][2], k4[2], acc);
                    acc = fmaf(qv[c][3], k4[3], acc);
                }
                s = acc * SCALE;
            }
            ssc[grp * 68 + jj] = s;
        }
        __syncthreads();                  // B2: scores done, K reads done

        // ---- stage V rows (overwrite KV, async) + online softmax (wave w owns head w)
        if (w * 16 < nrow) {
#pragma unroll
            for (int cc = 0; cc < 4; ++cc) {
                int r = w * 16 + cc * 4 + rl;
                int sg = sl ^ (r & 15);
                glds16(vb + (size_t)(r & 31) * DH + sg * 4, &KV[(w * 16 + cc * 4) * 64]);
            }
        }
        {
            float sv = ssc[w * 68 + lane];
            float mb = sv;
            for (int off = 32; off; off >>= 1) mb = fmaxf(mb, __shfl_xor(mb, off));
            float m_new = fmaxf(m_run, mb);
            float pp = (sv > -1e37f) ? __expf(sv - m_new) : 0.f;
            float alpha = __expf(m_run - m_new);
            float psum = pp;
            for (int off = 32; off; off >>= 1) psum += __shfl_xor(psum, off);
            l_run = l_run * alpha + psum;
            m_run = m_new;
            ps[w * 68 + lane] = pp;
            if (lane == 0) alphas[w] = alpha;
        }
        __syncthreads();                  // B3: V staged, ps/alphas ready

        // ---- PV: wave w owns rows [w*16, w*16+16); thread (g=grp, c=sub)
        {
            o4 *= alphas[grp];            // per-head alpha: same for every wave
            int jbase = w * 16;
            if (jbase < nrow) {
#pragma unroll
                for (int jq = 0; jq < 4; ++jq) {
                    f32x4 p4 = *(const f32x4*)&ps[grp * 68 + jbase + jq * 4];
#pragma unroll
                    for (int r = 0; r < 4; ++r) {
                        int row = jbase + jq * 4 + r;
                        int slot = sub ^ (row & 15);
                        f32x4 vv = *(const f32x4*)&KV[row * 64 + slot * 4];
                        o4 += p4[r] * vv;
                    }
                }
            }
        }
        __syncthreads();                  // B4 = B1 of next pair (KV free)
    }
    if (lane == 0) ls[w] = l_run;
    // cross-wave reduction of the 4 j-slice partials through the free KV buffer
    *(f32x4*)&KV[(w * 4 + grp) * 64 + sub * 4] = o4;
    __syncthreads();
    float sum = KV[(0 * 4 + w) * 64 + lane] + KV[(1 * 4 + w) * 64 + lane]
              + KV[(2 * 4 + w) * 64 + lane] + KV[(3 * 4 + w) * 64 + lane];
    f_out[(((size_t)(h * GQ + w)) * NTOK + n) * DH + lane] = sum / ls[w];
}

// ---------------------------------------------------------------------------
// K10: gated mix -> split-bf16 TILED (K=DDIM). gates f32 [N][128] padded.
// ---------------------------------------------------------------------------
__global__ void mix_kernel(const float* __restrict__ gates, const float* __restrict__ c_out,
                           const float* __restrict__ f_out,
                           u16* __restrict__ mixhi, u16* __restrict__ mixlo) {
    int idx = blockIdx.x * 256 + threadIdx.x;   // 1024*1024/8 = 131072
    int col = (idx & 127) * 8;
    int n = idx >> 7;
    int hd = col >> 6, d = col & 63;
    float g0 = gates[(size_t)n * 128 + hd * 2];
    float g1 = gates[(size_t)n * 128 + hd * 2 + 1];
    size_t hoff = (((size_t)hd) * NTOK + n) * DH + d;
    u16x8 h, l;
#pragma unroll
    for (int j = 0; j < 8; ++j) {
        float v = g0 * c_out[hoff + j] + g1 * f_out[hoff + j];
        u16 hh = f2bf(v);
        h[j] = hh;
        l[j] = f2bf(v - bf2f(hh));
    }
    size_t ob = tiled_off(n, col, DDIM);
    *(u16x8*)&mixhi[ob] = h;
    *(u16x8*)&mixlo[ob] = l;
}

// ---------------------------------------------------------------------------
extern "C" void kernel_launch(void* const* d_in, const int* in_sizes, int n_in,
                              void* d_out, int out_size, void* d_ws, size_t ws_size,
                              hipStream_t stream) {
    const float* inp    = (const float*)d_in[0];
    const float* g_norm = (const float*)d_in[1];
    const float* w_qkv  = (const float*)d_in[2];
    const float* mem_kv = (const float*)d_in[3];
    const float* k_pos  = (const float*)d_in[4];
    const float* v_pos  = (const float*)d_in[5];
    const float* k_w1   = (const float*)d_in[6];
    const float* k_b1   = (const float*)d_in[7];
    const float* k_w2   = (const float*)d_in[8];
    const float* k_b2   = (const float*)d_in[9];
    const float* v_w1   = (const float*)d_in[10];
    const float* v_b1   = (const float*)d_in[11];
    const float* v_w2   = (const float*)d_in[12];
    const float* v_b2   = (const float*)d_in[13];
    const float* gate_w = (const float*)d_in[14];
    const float* gate_b = (const float*)d_in[15];
    const float* w_out  = (const float*)d_in[16];
    float* out = (float*)d_out;

    char* wsb = (char*)d_ws;
    size_t off = 0;
    auto alloc = [&](size_t bytes) -> void* {
        void* p = wsb + off;
        off = (off + bytes + 255) & ~(size_t)255;
        return p;
    };
    u16*   xhi    = (u16*)  alloc((size_t)NTOK * DDIM * 2);
    u16*   xlo    = (u16*)  alloc((size_t)NTOK * DDIM * 2);
    float* qkvb   = (float*)alloc((size_t)NTOK * QKVD * 4);
    u16*   wqThi  = (u16*)  alloc((size_t)QKVD * DDIM * 2);
    u16*   wqTlo  = (u16*)  alloc((size_t)QKVD * DDIM * 2);
    u16*   kw1Thi = (u16*)  alloc((size_t)HIDN * CDIM * 2);
    u16*   kw1Tlo = (u16*)  alloc((size_t)HIDN * CDIM * 2);
    u16*   vw1Thi = (u16*)  alloc((size_t)HIDN * CDIM * 2);
    u16*   vw1Tlo = (u16*)  alloc((size_t)HIDN * CDIM * 2);
    u16*   woThi  = (u16*)  alloc((size_t)DDIM * DDIM * 2);
    u16*   gwThi  = (u16*)  alloc((size_t)128 * DDIM * 2);
    u16*   gwTlo  = (u16*)  alloc((size_t)128 * DDIM * 2);
    float* gbp    = (float*)alloc(128 * 4);
    u16*   kw2Thi = (u16*)  alloc((size_t)128 * HIDN * 2);
    u16*   kw2Tlo = (u16*)  alloc((size_t)128 * HIDN * 2);
    float* kb2p   = (float*)alloc(128 * 4);
    u16*   vw2Thi = (u16*)  alloc((size_t)128 * HIDN * 2);
    u16*   vw2Tlo = (u16*)  alloc((size_t)128 * HIDN * 2);
    float* vb2p   = (float*)alloc(128 * 4);
    u16*   cinkhi = (u16*)  alloc((size_t)128 * CDIM * 2);
    u16*   cinklo = (u16*)  alloc((size_t)128 * CDIM * 2);
    u16*   cinvhi = (u16*)  alloc((size_t)128 * CDIM * 2);
    u16*   cinvlo = (u16*)  alloc((size_t)128 * CDIM * 2);
    u16*   hidkhi = (u16*)  alloc((size_t)128 * HIDN * 2);
    u16*   hidklo = (u16*)  alloc((size_t)128 * HIDN * 2);
    u16*   hidvhi = (u16*)  alloc((size_t)128 * HIDN * 2);
    u16*   hidvlo = (u16*)  alloc((size_t)128 * HIDN * 2);
    float* Pg     = (float*)alloc((size_t)8 * NTOK * 128 * 4);
    float* Pm1k   = (float*)alloc((size_t)4 * 128 * HIDN * 4);
    float* Pm1v   = (float*)alloc((size_t)4 * 128 * HIDN * 4);
    float* Pm2k   = (float*)alloc((size_t)8 * 128 * 128 * 4);
    float* Pm2v   = (float*)alloc((size_t)8 * 128 * 128 * 4);
    float* ck     = (float*)alloc((size_t)KVH * 33 * DH * 4);
    float* cv     = (float*)alloc((size_t)KVH * 33 * DH * 4);
    float* qr     = (float*)alloc((size_t)HEADS * NTOK * DH * 4);
    float* kr     = (float*)alloc((size_t)KVH * NTOK * DH * 4);
    float* vr     = (float*)alloc((size_t)KVH * NTOK * DH * 4);
    float* c_out  = (float*)alloc((size_t)HEADS * NTOK * DH * 4);
    float* f_out  = (float*)alloc((size_t)HEADS * NTOK * DH * 4);
    float* gates  = (float*)alloc((size_t)NTOK * 128 * 4);
    int*   sel    = (int*)  alloc((size_t)KVH * NTOK * 9 * 4);
    int*   selmask= (int*)  alloc((size_t)KVH * NTOK * 9 * 4);
    u16*   mixhi  = (u16*)  alloc((size_t)NTOK * DDIM * 2);
    u16*   mixlo  = (u16*)  alloc((size_t)NTOK * DDIM * 2);

    // weight prep (tiled layouts)
    transpose_split<<<dim3(QKVD / 64, DDIM / 64), 256, 0, stream>>>(w_qkv, wqThi, wqTlo, DDIM, QKVD);
    transpose_split<<<dim3(HIDN / 64, CDIM / 64), 256, 0, stream>>>(k_w1, kw1Thi, kw1Tlo, CDIM, HIDN);
    transpose_split<<<dim3(HIDN / 64, CDIM / 64), 256, 0, stream>>>(v_w1, vw1Thi, vw1Tlo, CDIM, HIDN);
    transpose_split<<<dim3(DDIM / 64, DDIM / 64), 256, 0, stream>>>(w_out, woThi, nullptr, DDIM, DDIM);
    pad_small_tiled<<<(128 * DDIM / 8) / 256, 256, 0, stream>>>(gate_w, gate_b, gwThi, gwTlo, gbp, DDIM, 32, 10);
    pad_small_tiled<<<(128 * HIDN / 8) / 256, 256, 0, stream>>>(k_w2, k_b2, kw2Thi, kw2Tlo, kb2p, HIDN, 64, 11);
    pad_small_tiled<<<(128 * HIDN / 8) / 256, 256, 0, stream>>>(v_w2, v_b2, vw2Thi, vw2Tlo, vb2p, HIDN, 64, 11);

    // 1. RMSNorm -> tiled split-bf16 x
    rmsnorm_kernel<<<NTOK / 2, 256, 0, stream>>>(inp, g_norm, xhi, xlo);
    // 2. qkv = x @ w_qkv (final f32)
    gemm_tiled<3, 0, 1><<<dim3(QKVD / 128, NTOK / 128, 1), 256, 0, stream>>>(
        xhi, xlo, wqThi, wqTlo, nullptr, qkvb,
        xhi, xlo, wqThi, wqTlo, nullptr, qkvb, NTOK, QKVD, DDIM, 1);
    // 3. gates (split-K 8 + sigmoid reduce)
    gemm_tiled<3, 0, 0><<<dim3(1, NTOK / 128, 8), 256, 0, stream>>>(
        xhi, xlo, gwThi, gwTlo, nullptr, Pg,
        xhi, xlo, gwThi, gwTlo, nullptr, Pg, NTOK, 128, DDIM, 8);
    reduce_f32<2><<<dim3(128, 1), 256, 0, stream>>>(Pg, gbp, gates, Pg, gbp, gates, 8, NTOK, 128);
    // 4. compress-MLP inputs (tiled)
    build_cmlp_in<<<128, 256, 0, stream>>>(qkvb, k_pos, v_pos, cinkhi, cinklo, cinvhi, cinvlo);
    // 5. MLP1 (split-K 4, k&v batched; relu+bias+split-tile in reduce)
    gemm_tiled<3, 0, 0><<<dim3(HIDN / 128, 1, 8), 256, 0, stream>>>(
        cinkhi, cinklo, kw1Thi, kw1Tlo, nullptr, Pm1k,
        cinvhi, cinvlo, vw1Thi, vw1Tlo, nullptr, Pm1v, 128, HIDN, CDIM, 4);
    reduce_hid<<<dim3(128, 2), 256, 0, stream>>>(Pm1k, k_b1, hidkhi, hidklo,
                                                 Pm1v, v_b1, hidvhi, hidvlo, 4);
    // 6. MLP2 (split-K 8, k&v batched) + fused reduce/bias/concat
    gemm_tiled<3, 0, 0><<<dim3(1, 1, 16), 256, 0, stream>>>(
        hidkhi, hidklo, kw2Thi, kw2Tlo, nullptr, Pm2k,
        hidvhi, hidvlo, vw2Thi, vw2Tlo, nullptr, Pm2v, 128, 128, HIDN, 8);
    reduce_ckcv<<<33, 256, 0, stream>>>(Pm2k, Pm2v, mem_kv, kb2p, vb2p, ck, cv, 8);
    // 8. rotary + packed v
    rotary_kernel<<<(24 * NTOK * 32) / 256, 256, 0, stream>>>(qkvb, qr, kr, vr);
    // 9. compressed attention + selection (4 tokens per block)
    cattn_kernel<<<dim3(NTOK / 4, KVH), 256, 0, stream>>>(qkvb, ck, cv, c_out, sel, selmask);
    // 10. fine attention (v11: single-buffer + swizzled glds + q in VGPRs)
    fattn_kernel<<<dim3(NTOK, KVH), 256, 0, stream>>>(qr, kr, vr, sel, selmask, f_out);
    // 11. gated mix -> tiled split-bf16
    mix_kernel<<<(NTOK * DDIM / 8) / 256, 256, 0, stream>>>(gates, c_out, f_out, mixhi, mixlo);
    // 12. output projection (bf16, final)
    gemm_tiled<1, 0, 1><<<dim3(DDIM / 128, NTOK / 128, 1), 256, 0, stream>>>(
        mixhi, mixhi, woThi, woThi, nullptr, out,
        mixhi, mixhi, woThi, woThi, nullptr, out, NTOK, DDIM, DDIM, 1);
}

// Round 5
// 356.615 us; speedup vs baseline: 1.0697x; 1.0295x over previous
//
#include <hip/hip_runtime.h>
#include <math.h>

// ---- fixed problem sizes ----
#define NTOK 1024
#define DDIM 1024
#define HEADS 16
#define KVH 4
#define DH 64
#define BSZ 32
#define NSEL 8
#define WBLK 32            // NTOK / BSZ
#define GQ 4               // HEADS / KVH
#define CDIM 2048          // BSZ*DH
#define HIDN 2048
#define QKVD 1536          // (HEADS + 2*KVH)*DH
#define SCALE 0.125f       // DH^-0.5
#define NEGINF (-__builtin_inff())

typedef unsigned short u16;
typedef u16   u16x8  __attribute__((ext_vector_type(8)));
typedef short short8 __attribute__((ext_vector_type(8)));
typedef float f32x4  __attribute__((ext_vector_type(4)));

__device__ __forceinline__ u16 f2bf(float f) {
    unsigned u = __float_as_uint(f);
    return (u16)((u + 0x7fffu + ((u >> 16) & 1u)) >> 16);
}
__device__ __forceinline__ float bf2f(u16 h) { return __uint_as_float(((unsigned)h) << 16); }

__device__ __forceinline__ void glds16(const void* g, void* l) {
    __builtin_amdgcn_global_load_lds(
        (const __attribute__((address_space(1))) unsigned int*)g,
        (__attribute__((address_space(3))) unsigned int*)l, 16, 0, 0);
}

// element offset (in u16) of the 8-element lane-slot for (row, k..k+7) in the
// MFMA-fragment-tiled layout: 16-row x 32-k tiles, 1KB each, contiguous.
__device__ __forceinline__ size_t tiled_off(int row, int k, int K) {
    return ((size_t)((row >> 4) * (K >> 5) + (k >> 5)) * 64 +
            ((row & 15) | (((k >> 3) & 3) << 4))) * 8;
}

// ---------------------------------------------------------------------------
// K1: RMSNorm -> split-bf16 x in TILED layout (K=DDIM). 2 rows per 256-thr block.
// ---------------------------------------------------------------------------
__global__ void rmsnorm_kernel(const float* __restrict__ inp, const float* __restrict__ g,
                               u16* __restrict__ xhi, u16* __restrict__ xlo) {
    int t = threadIdx.x;
    int half = t >> 7, tid = t & 127;
    int n = blockIdx.x * 2 + half;
    const float4* row = (const float4*)(inp + (size_t)n * DDIM);
    float4 v0 = row[tid * 2], v1 = row[tid * 2 + 1];
    float ss = v0.x*v0.x + v0.y*v0.y + v0.z*v0.z + v0.w*v0.w
             + v1.x*v1.x + v1.y*v1.y + v1.z*v1.z + v1.w*v1.w;
    for (int off = 32; off; off >>= 1) ss += __shfl_down(ss, off);
    __shared__ float red[4];
    if ((t & 63) == 0) red[t >> 6] = ss;
    __syncthreads();
    float tot = red[half * 2] + red[half * 2 + 1];
    float r = 1.f / sqrtf(tot * (1.f / DDIM) + 1e-6f);
    const float4* gp = (const float4*)g;
    float4 g0 = gp[tid * 2], g1 = gp[tid * 2 + 1];
    float o[8] = { v0.x*r*g0.x, v0.y*r*g0.y, v0.z*r*g0.z, v0.w*r*g0.w,
                   v1.x*r*g1.x, v1.y*r*g1.y, v1.z*r*g1.z, v1.w*r*g1.w };
    u16x8 h, l;
#pragma unroll
    for (int i = 0; i < 8; ++i) {
        u16 hh = f2bf(o[i]);
        h[i] = hh;
        l[i] = f2bf(o[i] - bf2f(hh));
    }
    size_t ob = tiled_off(n, tid * 8, DDIM);
    *(u16x8*)&xhi[ob] = h;
    *(u16x8*)&xlo[ob] = l;
}

// ---------------------------------------------------------------------------
// K2: weight transpose + split: W[K][N] f32 -> tiled Bt[N][K] bf16 hi/lo
// ---------------------------------------------------------------------------
__global__ void transpose_split(const float* __restrict__ W, u16* __restrict__ Thi,
                                u16* __restrict__ Tlo, int K, int N) {
    __shared__ float tile[64][65];
    int k0 = blockIdx.y * 64, n0 = blockIdx.x * 64;
    int t = threadIdx.x;
    int r = t >> 4, c4 = (t & 15) * 4;
#pragma unroll
    for (int p = 0; p < 4; ++p) {
        float4 v = *(const float4*)&W[(size_t)(k0 + r + p * 16) * N + n0 + c4];
        tile[r + p * 16][c4 + 0] = v.x;
        tile[r + p * 16][c4 + 1] = v.y;
        tile[r + p * 16][c4 + 2] = v.z;
        tile[r + p * 16][c4 + 3] = v.w;
    }
    __syncthreads();
    int n = t >> 2, ks = (t & 3) * 16;
#pragma unroll
    for (int c = 0; c < 2; ++c) {
        u16x8 h, l;
#pragma unroll
        for (int j = 0; j < 8; ++j) {
            float v = tile[ks + c * 8 + j][n];
            u16 hh = f2bf(v);
            h[j] = hh;
            l[j] = f2bf(v - bf2f(hh));
        }
        size_t ob = tiled_off(n0 + n, k0 + ks + c * 8, K);
        *(u16x8*)&Thi[ob] = h;
        if (Tlo) *(u16x8*)&Tlo[ob] = l;
    }
}

// ---------------------------------------------------------------------------
// K2b: pad small weights [K][Xn] (Xn<=64) -> tiled split-bf16 [128][K] + padded bias
// ---------------------------------------------------------------------------
__global__ void pad_small_tiled(const float* __restrict__ W, const float* __restrict__ b,
                                u16* __restrict__ Thi, u16* __restrict__ Tlo,
                                float* __restrict__ bias_pad, int K, int Xn, int KLOG) {
    int idx = blockIdx.x * 256 + threadIdx.x;   // 128 * K/8
    int k = (idx & ((K >> 3) - 1)) * 8;
    int n = idx >> (KLOG - 3);
    if (n >= 128) return;
    u16x8 h, l;
#pragma unroll
    for (int j = 0; j < 8; ++j) {
        float v = (n < Xn) ? W[(size_t)(k + j) * Xn + n] : 0.f;
        u16 hh = f2bf(v);
        h[j] = hh;
        l[j] = f2bf(v - bf2f(hh));
    }
    size_t ob = tiled_off(n, k, K);
    *(u16x8*)&Thi[ob] = h;
    *(u16x8*)&Tlo[ob] = l;
    if (k == 0) bias_pad[n] = (n < Xn) ? b[n] : 0.f;
}

// ---------------------------------------------------------------------------
// K3: tiled MFMA GEMM with software pipeline + optional split-K.
// ---------------------------------------------------------------------------
template<int SPLIT, int ACT, int FINAL>
__global__ __launch_bounds__(256, 1)
void gemm_tiled(const u16* __restrict__ Ahi0, const u16* __restrict__ Alo0,
                const u16* __restrict__ Bhi0, const u16* __restrict__ Blo0,
                const float* __restrict__ bias0, float* __restrict__ C0,
                const u16* __restrict__ Ahi1, const u16* __restrict__ Alo1,
                const u16* __restrict__ Bhi1, const u16* __restrict__ Blo1,
                const float* __restrict__ bias1, float* __restrict__ C1,
                int M, int N, int K, int S) {
    int batch = blockIdx.z / S;
    int s = blockIdx.z - batch * S;
    const u16* Ahi = batch ? Ahi1 : Ahi0;
    const u16* Alo = batch ? Alo1 : Alo0;
    const u16* Bhi = batch ? Bhi1 : Bhi0;
    const u16* Blo = batch ? Blo1 : Blo0;
    const float* bias = batch ? bias1 : bias0;
    float* C = batch ? C1 : C0;

    constexpr int PARTS = (SPLIT == 3) ? 2 : 1;
    __shared__ u16 smA[2 * PARTS * 8 * 512];
    __shared__ u16 smB[2 * PARTS * 8 * 512];

    int tid = threadIdx.x;
    int w = tid >> 6, L = tid & 63;
    int m15 = L & 15, q = L >> 4;
    int KT = K >> 5;
    int rowTile = blockIdx.y * 8, colTile = blockIdx.x * 8;
    int NIT = (K / S) >> 5;
    int kb0 = s * NIT;
    int aw = w & 1, bw = w >> 1;

    f32x4 acc[4][4];
#pragma unroll
    for (int i = 0; i < 4; ++i)
#pragma unroll
        for (int j = 0; j < 4; ++j) acc[i][j] = (f32x4){0.f, 0.f, 0.f, 0.f};

    auto stage = [&](int buf, int kb) {
#pragma unroll
        for (int rl = 0; rl < 2; ++rl) {
            int rb = 2 * w + rl;
            glds16(Ahi + ((size_t)(rowTile + rb) * KT + kb) * 512 + (size_t)L * 8,
                   &smA[((buf * PARTS + 0) * 8 + rb) * 512]);
            glds16(Bhi + ((size_t)(colTile + rb) * KT + kb) * 512 + (size_t)L * 8,
                   &smB[((buf * PARTS + 0) * 8 + rb) * 512]);
            if constexpr (SPLIT == 3) {
                glds16(Alo + ((size_t)(rowTile + rb) * KT + kb) * 512 + (size_t)L * 8,
                       &smA[((buf * PARTS + 1) * 8 + rb) * 512]);
                glds16(Blo + ((size_t)(colTile + rb) * KT + kb) * 512 + (size_t)L * 8,
                       &smB[((buf * PARTS + 1) * 8 + rb) * 512]);
            }
        }
    };

    stage(0, kb0);
    for (int it = 0; it < NIT; ++it) {
        __syncthreads();
        if (it + 1 < NIT) stage((it + 1) & 1, kb0 + it + 1);
        int buf = it & 1;
        short8 ah[4], bh[4];
#pragma unroll
        for (int i = 0; i < 4; ++i) {
            ah[i] = *(const short8*)&smA[((buf * PARTS + 0) * 8 + aw * 4 + i) * 512 + L * 8];
            bh[i] = *(const short8*)&smB[((buf * PARTS + 0) * 8 + bw * 4 + i) * 512 + L * 8];
        }
        if constexpr (SPLIT == 3) {
            short8 al[4], bl[4];
#pragma unroll
            for (int i = 0; i < 4; ++i) {
                al[i] = *(const short8*)&smA[((buf * PARTS + 1) * 8 + aw * 4 + i) * 512 + L * 8];
                bl[i] = *(const short8*)&smB[((buf * PARTS + 1) * 8 + bw * 4 + i) * 512 + L * 8];
            }
#pragma unroll
            for (int i = 0; i < 4; ++i)
#pragma unroll
                for (int j = 0; j < 4; ++j) {
                    acc[i][j] = __builtin_amdgcn_mfma_f32_16x16x32_bf16(ah[i], bl[j], acc[i][j], 0, 0, 0);
                    acc[i][j] = __builtin_amdgcn_mfma_f32_16x16x32_bf16(al[i], bh[j], acc[i][j], 0, 0, 0);
                    acc[i][j] = __builtin_amdgcn_mfma_f32_16x16x32_bf16(ah[i], bh[j], acc[i][j], 0, 0, 0);
                }
        } else {
#pragma unroll
            for (int i = 0; i < 4; ++i)
#pragma unroll
                for (int j = 0; j < 4; ++j)
                    acc[i][j] = __builtin_amdgcn_mfma_f32_16x16x32_bf16(ah[i], bh[j], acc[i][j], 0, 0, 0);
        }
    }

    if constexpr (FINAL == 0) C += (size_t)s * M * N;
#pragma unroll
    for (int i = 0; i < 4; ++i) {
        int row = rowTile * 16 + aw * 64 + i * 16 + q * 4;
#pragma unroll
        for (int j = 0; j < 4; ++j) {
            int col = colTile * 16 + bw * 64 + j * 16 + m15;
            float bv = (FINAL && bias) ? bias[col] : 0.f;
#pragma unroll
            for (int r = 0; r < 4; ++r) {
                float v = acc[i][j][r];
                if constexpr (FINAL) {
                    v += bv;
                    if (ACT == 1) v = fmaxf(v, 0.f);
                    if (ACT == 2) v = 1.f / (1.f + expf(-v));
                }
                C[(size_t)(row + r) * N + col] = v;
            }
        }
    }
}

// ---------------------------------------------------------------------------
// K3b: split-K reduce -> f32 [M][N] with bias/act. Dual pointer sets via blockIdx.y.
// ---------------------------------------------------------------------------
template<int ACT>
__global__ void reduce_f32(const float* __restrict__ P0, const float* __restrict__ bias0,
                           float* __restrict__ C0,
                           const float* __restrict__ P1, const float* __restrict__ bias1,
                           float* __restrict__ C1, int S, int M, int N) {
    const float* P = blockIdx.y ? P1 : P0;
    const float* bias = blockIdx.y ? bias1 : bias0;
    float* C = blockIdx.y ? C1 : C0;
    int idx = blockIdx.x * 256 + threadIdx.x;
    int mn4 = (M * N) >> 2;
    if (idx >= mn4) return;
    f32x4 a = ((const f32x4*)P)[idx];
    for (int s = 1; s < S; ++s) a += ((const f32x4*)P)[(size_t)s * mn4 + idx];
    int col = (idx % (N >> 2)) * 4;
    f32x4 o;
#pragma unroll
    for (int j = 0; j < 4; ++j) {
        float v = a[j] + (bias ? bias[col + j] : 0.f);
        if (ACT == 1) v = fmaxf(v, 0.f);
        if (ACT == 2) v = 1.f / (1.f + expf(-v));
        o[j] = v;
    }
    ((f32x4*)C)[idx] = o;
}

// ---------------------------------------------------------------------------
// K3c: split-K reduce + relu + bias -> split-bf16 TILED (MLP1 hid, M=128, N=HIDN)
// ---------------------------------------------------------------------------
__global__ void reduce_hid(const float* __restrict__ P0, const float* __restrict__ b0,
                           u16* __restrict__ hi0, u16* __restrict__ lo0,
                           const float* __restrict__ P1, const float* __restrict__ b1,
                           u16* __restrict__ hi1, u16* __restrict__ lo1, int S) {
    const float* P = blockIdx.y ? P1 : P0;
    const float* bias = blockIdx.y ? b1 : b0;
    u16* hi = blockIdx.y ? hi1 : hi0;
    u16* lo = blockIdx.y ? lo1 : lo0;
    int idx = blockIdx.x * 256 + threadIdx.x;       // 128*2048/8 = 32768
    int col = (idx & 255) * 8, rowi = idx >> 8;
    size_t base = ((size_t)rowi * HIDN + col) >> 2;
    f32x4 a0 = ((const f32x4*)P)[base], a1 = ((const f32x4*)P)[base + 1];
    for (int s = 1; s < S; ++s) {
        size_t sb = (size_t)s * (128 * HIDN / 4) + base;
        a0 += ((const f32x4*)P)[sb];
        a1 += ((const f32x4*)P)[sb + 1];
    }
    u16x8 h, l;
#pragma unroll
    for (int j = 0; j < 8; ++j) {
        float v = (j < 4 ? a0[j] : a1[j - 4]) + bias[col + j];
        v = fmaxf(v, 0.f);
        u16 hh = f2bf(v);
        h[j] = hh;
        l[j] = f2bf(v - bf2f(hh));
    }
    size_t ob = tiled_off(rowi, col, HIDN);
    *(u16x8*)&hi[ob] = h;
    *(u16x8*)&lo[ob] = l;
}

// ---------------------------------------------------------------------------
// K3d: MLP2 split-K reduce + bias fused with mem_kv concat -> ck/cv [KVH][33][DH]
// ---------------------------------------------------------------------------
__global__ void reduce_ckcv(const float* __restrict__ Pk, const float* __restrict__ Pv,
                            const float* __restrict__ mem_kv,
                            const float* __restrict__ kb2, const float* __restrict__ vb2,
                            float* __restrict__ ck, float* __restrict__ cv, int S) {
    int idx = blockIdx.x * 256 + threadIdx.x;   // 4*33*64 = 8448
    if (idx >= KVH * 33 * DH) return;
    int d = idx & 63;
    int j = (idx >> 6) % 33;
    int h = idx / (33 * 64);
    float kvv, vvv;
    if (j == 0) {
        kvv = mem_kv[(0 * KVH + h) * DH + d];
        vvv = mem_kv[(1 * KVH + h) * DH + d];
    } else {
        size_t base = (size_t)(h * WBLK + (j - 1)) * 128 + d;
        float ak = Pk[base], av = Pv[base];
        for (int s = 1; s < S; ++s) {
            ak += Pk[(size_t)s * (128 * 128) + base];
            av += Pv[(size_t)s * (128 * 128) + base];
        }
        kvv = ak + kb2[d];
        vvv = av + vb2[d];
    }
    ck[idx] = kvv;
    cv[idx] = vvv;
}

// ---------------------------------------------------------------------------
// K5: build compress-MLP inputs -> split-bf16 TILED (K=CDIM)
// ---------------------------------------------------------------------------
__global__ void build_cmlp_in(const float* __restrict__ qkv, const float* __restrict__ k_pos,
                              const float* __restrict__ v_pos,
                              u16* __restrict__ ckhi, u16* __restrict__ cklo,
                              u16* __restrict__ cvhi, u16* __restrict__ cvlo) {
    int idx = blockIdx.x * 256 + threadIdx.x;   // 128 * 256 = 32768
    int k = (idx & 255) * 8;
    int r = idx >> 8;                           // 0..127 = h*W + w
    int p = k >> 6, d = k & 63;
    int h = r >> 5, wb = r & 31;
    int nn = wb * BSZ + p;
    const float* kq = qkv + (size_t)nn * QKVD + (HEADS + h) * DH + d;
    const float* vq = qkv + (size_t)nn * QKVD + (HEADS + KVH + h) * DH + d;
    const float* kp = k_pos + (size_t)(h * BSZ + p) * DH + d;
    const float* vp = v_pos + (size_t)(h * BSZ + p) * DH + d;
    u16x8 kh, kl, vh, vl;
#pragma unroll
    for (int j = 0; j < 8; ++j) {
        float kv = kq[j] + kp[j];
        float vv = vq[j] + vp[j];
        u16 a = f2bf(kv), b = f2bf(vv);
        kh[j] = a; kl[j] = f2bf(kv - bf2f(a));
        vh[j] = b; vl[j] = f2bf(vv - bf2f(b));
    }
    size_t ob = tiled_off(r, k, CDIM);
    *(u16x8*)&ckhi[ob] = kh; *(u16x8*)&cklo[ob] = kl;
    *(u16x8*)&cvhi[ob] = vh; *(u16x8*)&cvlo[ob] = vl;
}

// ---------------------------------------------------------------------------
// K7: interleaved rotary for q (16 heads), k (4 heads) + packed v copy (4 heads)
// ---------------------------------------------------------------------------
__global__ void rotary_kernel(const float* __restrict__ qkv,
                              float* __restrict__ qr, float* __restrict__ kr,
                              float* __restrict__ vr) {
    int idx = blockIdx.x * 256 + threadIdx.x;   // 24*1024*32 = 786432
    int i = idx & 31;
    int n = (idx >> 5) & 1023;
    int hd = idx >> 15;
    if (hd >= 24) return;
    if (hd >= HEADS + KVH) {       // packed v copy
        int h = hd - (HEADS + KVH);
        const float* src = qkv + (size_t)n * QKVD + (HEADS + KVH + h) * DH;
        float* dst = vr + ((size_t)h * NTOK + n) * DH;
        dst[2 * i] = src[2 * i];
        dst[2 * i + 1] = src[2 * i + 1];
        return;
    }
    float inv = powf(10000.f, -(float)i / 32.f);
    float fr = (float)n * inv;
    float c = cosf(fr), s = sinf(fr);
    const float* src; float* dst;
    if (hd < HEADS) { src = qkv + (size_t)n * QKVD + hd * DH;          dst = qr + ((size_t)hd * NTOK + n) * DH; }
    else { int h = hd - HEADS;
           src = qkv + (size_t)n * QKVD + (HEADS + h) * DH;            dst = kr + ((size_t)h * NTOK + n) * DH; }
    float x0 = src[2 * i], x1 = src[2 * i + 1];
    dst[2 * i]     = x0 * c - x1 * s;
    dst[2 * i + 1] = x1 * c + x0 * s;
}

// ---------------------------------------------------------------------------
// K8: compressed attention + importance + top-k. 4 tokens per 256-thr block.
// ---------------------------------------------------------------------------
__global__ __launch_bounds__(256)
void cattn_kernel(const float* __restrict__ qkv, const float* __restrict__ ck,
                  const float* __restrict__ cv, float* __restrict__ c_out,
                  int* __restrict__ sel, int* __restrict__ selmask) {
    int h = blockIdx.y;
    int tid = threadIdx.x;
    int w = tid >> 6, lane = tid & 63;
    int grp = lane >> 4, sub = lane & 15;
    int n = blockIdx.x * 4 + w;
    __shared__ float cks[33 * 68];
    __shared__ float cvs[33 * 68];
    __shared__ float sims[16 * 36];      // [w*4+g][j]

    for (int t4 = tid; t4 < 1056; t4 += 256) {
        int half = (t4 >= 528) ? 1 : 0;
        int u = t4 - half * 528;
        int j = u >> 4, d4 = (u & 15) * 4;
        const float* src = (half ? cv : ck) + (size_t)h * 33 * 64 + j * 64 + d4;
        float* dst = (half ? cvs : cks) + j * 68 + d4;
        *(float4*)dst = *(const float4*)src;
    }
    float qreg[64];
    {
        const float4* qp4 = (const float4*)(qkv + (size_t)n * QKVD + (h * GQ + grp) * DH);
#pragma unroll
        for (int c = 0; c < 16; ++c) {
            float4 v = qp4[c];
            qreg[4 * c] = v.x; qreg[4 * c + 1] = v.y; qreg[4 * c + 2] = v.z; qreg[4 * c + 3] = v.w;
        }
    }
    __syncthreads();

#pragma unroll
    for (int r = 0; r < 3; ++r) {
        int j = r * 16 + sub;
        if (j < 33) {
            float acc = 0.f;
#pragma unroll
            for (int d = 0; d < 64; ++d) acc = fmaf(qreg[d], cks[j * 68 + d], acc);
            sims[(w * 4 + grp) * 36 + j] = acc * SCALE;
        }
    }

    float ival = NEGINF;
    if (lane < 32)
        ival = 0.25f * (sims[(w * 4 + 0) * 36 + 1 + lane] + sims[(w * 4 + 1) * 36 + 1 + lane] +
                        sims[(w * 4 + 2) * 36 + 1 + lane] + sims[(w * 4 + 3) * 36 + 1 + lane]);
    float m = ival;
    for (int off = 32; off; off >>= 1) m = fmaxf(m, __shfl_xor(m, off));
    float e = (lane < 32) ? expf(ival - m) : 0.f;
    float sum = e;
    for (int off = 32; off; off >>= 1) sum += __shfl_xor(sum, off);
    float p = (lane < 32) ? e / sum : NEGINF;

    float v = p;
    int base = (h * NTOK + n) * 9;
    for (int t = 0; t < NSEL; ++t) {
        float bv = v; int bi = lane;
        for (int off = 32; off; off >>= 1) {
            float ov = __shfl_xor(bv, off);
            int   oi = __shfl_xor(bi, off);
            if (ov > bv || (ov == bv && oi < bi)) { bv = ov; bi = oi; }
        }
        if (lane == 0) { sel[base + t] = bi; selmask[base + t] = (bv > 1e-10f) ? 1 : 0; }
        if (lane == bi) v = NEGINF;
    }
    if (lane == 0) { sel[base + NSEL] = n >> 5; selmask[base + NSEL] = 1; }

#pragma unroll
    for (int g = 0; g < 4; ++g) {
        float sv = (lane < 33) ? sims[(w * 4 + g) * 36 + lane] : NEGINF;
        float mm = sv;
        for (int off = 32; off; off >>= 1) mm = fmaxf(mm, __shfl_xor(mm, off));
        float ee = (lane < 33) ? __expf(sv - mm) : 0.f;
        float ssum = ee;
        for (int off = 32; off; off >>= 1) ssum += __shfl_xor(ssum, off);
        if (lane < 33) sims[(w * 4 + g) * 36 + lane] = ee / ssum;
    }

    f32x4 o = (f32x4){0.f, 0.f, 0.f, 0.f};
#pragma unroll
    for (int j = 0; j < 33; ++j) {
        float a = sims[(w * 4 + grp) * 36 + j];
        f32x4 vv = *(const f32x4*)&cvs[j * 68 + sub * 4];
        o += a * vv;
    }
    *(f32x4*)&c_out[(((size_t)(h * GQ + grp)) * NTOK + n) * DH + sub * 4] = o;
}

// ---------------------------------------------------------------------------
// K9: fine attention v12 = v8 structure (best measured: 77.5us) + the single
// verified graft: K/V staging via global_load_lds with source swizzle
// slot = c ^ (r&15) (R3/R4-verified: bank conflicts 163840 = clean, absmax
// unchanged). q stays in LDS (broadcast reads) — R1 AND R4 both showed the
// compiler caps VGPR at 64 and spills any q-register hoist (WRITE_SIZE 74MB /
// 11MB). v8's ds_write staging (8 b128/wave-iter + VGPR round-trip) is
// replaced by async DMA drained at B1. LDS ops/wave-iter ~101 -> ~72.
// Tripwires: WRITE_SIZE ~4MB, FETCH ~10.9MB, VGPR ~48-56.
// ---------------------------------------------------------------------------
__global__ void fattn_kernel(const float* __restrict__ qr, const float* __restrict__ kr,
                             const float* __restrict__ vr, const int* __restrict__ sel,
                             const int* __restrict__ selmask, float* __restrict__ f_out) {
    int n = blockIdx.x, h = blockIdx.y;
    int tid = threadIdx.x;
    int w = tid >> 6, lane = tid & 63;
    int grp = lane >> 4, sub = lane & 15;
    __shared__ float qsm[4 * 68];
    __shared__ float KV[64 * 64];        // K then V each pair; slot s of row r = global slot s^(r&15)
    __shared__ float ssc[4 * 68];
    __shared__ float ps[4 * 68];
    __shared__ float alphas[4], ls[4];
    __shared__ int sel_s[9], msk_s[9];

    if (tid < 9) {
        sel_s[tid] = sel[(h * NTOK + n) * 9 + tid];
        msk_s[tid] = selmask[(h * NTOK + n) * 9 + tid];
    }
    // q -> LDS once: wave w loads head w's 64 elements
    qsm[w * 68 + lane] = qr[(((size_t)(h * GQ + w)) * NTOK + n) * DH + lane];
    f32x4 o4 = (f32x4){0.f, 0.f, 0.f, 0.f};   // partial over wave's j-slice, dims sub*4..sub*4+3
    float m_run = -3.402823466e38f, l_run = 0.f;
    __syncthreads();                     // sel_s + qsm ready

    const float* krh_ = kr + (size_t)h * NTOK * DH;
    const float* vrh_ = vr + (size_t)h * NTOK * DH;

    // staging geometry: wave w stages rows [w*16, w*16+16); glds chunk cc = 4 rows.
    // lane L -> row_local rl = L>>4, slot sl = L&15 (dest linear: base + L*16B);
    // source slot = sl ^ (r&15) so that read with slot = c ^ (row&15) is identity.
    int rl = lane >> 4, sl = lane & 15;

    for (int bp = 0; bp < 5; ++bp) {
        int nrow = (bp < 4) ? 64 : 32;
        int myblk = sel_s[bp * 2 + (w >> 1)];
        const float* kb = krh_ + (size_t)myblk * BSZ * DH;
        const float* vb = vrh_ + (size_t)myblk * BSZ * DH;

        // ---- stage K rows via glds (source-swizzled, linear dest)
        if (w * 16 < nrow) {
#pragma unroll
            for (int cc = 0; cc < 4; ++cc) {
                int r = w * 16 + cc * 4 + rl;
                int sg = sl ^ (r & 15);
                glds16(kb + (size_t)(r & 31) * DH + sg * 4, &KV[(w * 16 + cc * 4) * 64]);
            }
        }
        __syncthreads();                  // B1: K staged (barrier drains vmcnt)

        // ---- scores: thread -> (g=grp, jj=w*16+sub); q from LDS (bcast)
        {
            int jj = w * 16 + sub;
            int b = bp * 2 + (jj >> 5);
            float s = -3.402823466e38f;
            if (jj < nrow && msk_s[b]) {
                int sw = jj & 15;
                const float* Kb = &KV[jj * 64];
                float acc = 0.f;
#pragma unroll
                for (int c = 0; c < 16; ++c) {
                    f32x4 k4 = *(const f32x4*)&Kb[(c ^ sw) * 4];
                    f32x4 q4 = *(const f32x4*)&qsm[grp * 68 + c * 4];
                    acc = fmaf(q4[0], k4[0], acc);
                    acc = fmaf(q4[1], k4[1], acc);
                    acc = fmaf(q4[2], k4[2], acc);
                    acc = fmaf(q4[3], k4[3], acc);
                }
                s = acc * SCALE;
            }
            ssc[grp * 68 + jj] = s;
        }
        __syncthreads();                  // B2: scores done, K reads done

        // ---- stage V rows (overwrite KV, async) + online softmax (wave w owns head w)
        if (w * 16 < nrow) {
#pragma unroll
            for (int cc = 0; cc < 4; ++cc) {
                int r = w * 16 + cc * 4 + rl;
                int sg = sl ^ (r & 15);
                glds16(vb + (size_t)(r & 31) * DH + sg * 4, &KV[(w * 16 + cc * 4) * 64]);
            }
        }
        {
            float sv = ssc[w * 68 + lane];
            float mb = sv;
            for (int off = 32; off; off >>= 1) mb = fmaxf(mb, __shfl_xor(mb, off));
            float m_new = fmaxf(m_run, mb);
            float pp = (sv > -1e37f) ? __expf(sv - m_new) : 0.f;
            float alpha = __expf(m_run - m_new);
            float psum = pp;
            for (int off = 32; off; off >>= 1) psum += __shfl_xor(psum, off);
            l_run = l_run * alpha + psum;
            m_run = m_new;
            ps[w * 68 + lane] = pp;
            if (lane == 0) alphas[w] = alpha;
        }
        __syncthreads();                  // B3: V staged, ps/alphas ready

        // ---- PV: wave w owns rows [w*16, w*16+16); thread (g=grp, c=sub)
        {
            o4 *= alphas[grp];            // per-head alpha: same for every wave
            int jbase = w * 16;
            if (jbase < nrow) {
#pragma unroll
                for (int jq = 0; jq < 4; ++jq) {
                    f32x4 p4 = *(const f32x4*)&ps[grp * 68 + jbase + jq * 4];
#pragma unroll
                    for (int r = 0; r < 4; ++r) {
                        int row = jbase + jq * 4 + r;
                        int slot = sub ^ (row & 15);
                        f32x4 vv = *(const f32x4*)&KV[row * 64 + slot * 4];
                        o4 += p4[r] * vv;
                    }
                }
            }
        }
        __syncthreads();                  // B4 = B1 of next pair (KV free)
    }
    if (lane == 0) ls[w] = l_run;
    // cross-wave reduction of the 4 j-slice partials through the free KV buffer
    *(f32x4*)&KV[(w * 4 + grp) * 64 + sub * 4] = o4;
    __syncthreads();
    float sum = KV[(0 * 4 + w) * 64 + lane] + KV[(1 * 4 + w) * 64 + lane]
              + KV[(2 * 4 + w) * 64 + lane] + KV[(3 * 4 + w) * 64 + lane];
    f_out[(((size_t)(h * GQ + w)) * NTOK + n) * DH + lane] = sum / ls[w];
}

// ---------------------------------------------------------------------------
// K10: gated mix -> split-bf16 TILED (K=DDIM). gates f32 [N][128] padded.
// ---------------------------------------------------------------------------
__global__ void mix_kernel(const float* __restrict__ gates, const float* __restrict__ c_out,
                           const float* __restrict__ f_out,
                           u16* __restrict__ mixhi, u16* __restrict__ mixlo) {
    int idx = blockIdx.x * 256 + threadIdx.x;   // 1024*1024/8 = 131072
    int col = (idx & 127) * 8;
    int n = idx >> 7;
    int hd = col >> 6, d = col & 63;
    float g0 = gates[(size_t)n * 128 + hd * 2];
    float g1 = gates[(size_t)n * 128 + hd * 2 + 1];
    size_t hoff = (((size_t)hd) * NTOK + n) * DH + d;
    u16x8 h, l;
#pragma unroll
    for (int j = 0; j < 8; ++j) {
        float v = g0 * c_out[hoff + j] + g1 * f_out[hoff + j];
        u16 hh = f2bf(v);
        h[j] = hh;
        l[j] = f2bf(v - bf2f(hh));
    }
    size_t ob = tiled_off(n, col, DDIM);
    *(u16x8*)&mixhi[ob] = h;
    *(u16x8*)&mixlo[ob] = l;
}

// ---------------------------------------------------------------------------
extern "C" void kernel_launch(void* const* d_in, const int* in_sizes, int n_in,
                              void* d_out, int out_size, void* d_ws, size_t ws_size,
                              hipStream_t stream) {
    const float* inp    = (const float*)d_in[0];
    const float* g_norm = (const float*)d_in[1];
    const float* w_qkv  = (const float*)d_in[2];
    const float* mem_kv = (const float*)d_in[3];
    const float* k_pos  = (const float*)d_in[4];
    const float* v_pos  = (const float*)d_in[5];
    const float* k_w1   = (const float*)d_in[6];
    const float* k_b1   = (const float*)d_in[7];
    const float* k_w2   = (const float*)d_in[8];
    const float* k_b2   = (const float*)d_in[9];
    const float* v_w1   = (const float*)d_in[10];
    const float* v_b1   = (const float*)d_in[11];
    const float* v_w2   = (const float*)d_in[12];
    const float* v_b2   = (const float*)d_in[13];
    const float* gate_w = (const float*)d_in[14];
    const float* gate_b = (const float*)d_in[15];
    const float* w_out  = (const float*)d_in[16];
    float* out = (float*)d_out;

    char* wsb = (char*)d_ws;
    size_t off = 0;
    auto alloc = [&](size_t bytes) -> void* {
        void* p = wsb + off;
        off = (off + bytes + 255) & ~(size_t)255;
        return p;
    };
    u16*   xhi    = (u16*)  alloc((size_t)NTOK * DDIM * 2);
    u16*   xlo    = (u16*)  alloc((size_t)NTOK * DDIM * 2);
    float* qkvb   = (float*)alloc((size_t)NTOK * QKVD * 4);
    u16*   wqThi  = (u16*)  alloc((size_t)QKVD * DDIM * 2);
    u16*   wqTlo  = (u16*)  alloc((size_t)QKVD * DDIM * 2);
    u16*   kw1Thi = (u16*)  alloc((size_t)HIDN * CDIM * 2);
    u16*   kw1Tlo = (u16*)  alloc((size_t)HIDN * CDIM * 2);
    u16*   vw1Thi = (u16*)  alloc((size_t)HIDN * CDIM * 2);
    u16*   vw1Tlo = (u16*)  alloc((size_t)HIDN * CDIM * 2);
    u16*   woThi  = (u16*)  alloc((size_t)DDIM * DDIM * 2);
    u16*   gwThi  = (u16*)  alloc((size_t)128 * DDIM * 2);
    u16*   gwTlo  = (u16*)  alloc((size_t)128 * DDIM * 2);
    float* gbp    = (float*)alloc(128 * 4);
    u16*   kw2Thi = (u16*)  alloc((size_t)128 * HIDN * 2);
    u16*   kw2Tlo = (u16*)  alloc((size_t)128 * HIDN * 2);
    float* kb2p   = (float*)alloc(128 * 4);
    u16*   vw2Thi = (u16*)  alloc((size_t)128 * HIDN * 2);
    u16*   vw2Tlo = (u16*)  alloc((size_t)128 * HIDN * 2);
    float* vb2p   = (float*)alloc(128 * 4);
    u16*   cinkhi = (u16*)  alloc((size_t)128 * CDIM * 2);
    u16*   cinklo = (u16*)  alloc((size_t)128 * CDIM * 2);
    u16*   cinvhi = (u16*)  alloc((size_t)128 * CDIM * 2);
    u16*   cinvlo = (u16*)  alloc((size_t)128 * CDIM * 2);
    u16*   hidkhi = (u16*)  alloc((size_t)128 * HIDN * 2);
    u16*   hidklo = (u16*)  alloc((size_t)128 * HIDN * 2);
    u16*   hidvhi = (u16*)  alloc((size_t)128 * HIDN * 2);
    u16*   hidvlo = (u16*)  alloc((size_t)128 * HIDN * 2);
    float* Pg     = (float*)alloc((size_t)8 * NTOK * 128 * 4);
    float* Pm1k   = (float*)alloc((size_t)4 * 128 * HIDN * 4);
    float* Pm1v   = (float*)alloc((size_t)4 * 128 * HIDN * 4);
    float* Pm2k   = (float*)alloc((size_t)8 * 128 * 128 * 4);
    float* Pm2v   = (float*)alloc((size_t)8 * 128 * 128 * 4);
    float* ck     = (float*)alloc((size_t)KVH * 33 * DH * 4);
    float* cv     = (float*)alloc((size_t)KVH * 33 * DH * 4);
    float* qr     = (float*)alloc((size_t)HEADS * NTOK * DH * 4);
    float* kr     = (float*)alloc((size_t)KVH * NTOK * DH * 4);
    float* vr     = (float*)alloc((size_t)KVH * NTOK * DH * 4);
    float* c_out  = (float*)alloc((size_t)HEADS * NTOK * DH * 4);
    float* f_out  = (float*)alloc((size_t)HEADS * NTOK * DH * 4);
    float* gates  = (float*)alloc((size_t)NTOK * 128 * 4);
    int*   sel    = (int*)  alloc((size_t)KVH * NTOK * 9 * 4);
    int*   selmask= (int*)  alloc((size_t)KVH * NTOK * 9 * 4);
    u16*   mixhi  = (u16*)  alloc((size_t)NTOK * DDIM * 2);
    u16*   mixlo  = (u16*)  alloc((size_t)NTOK * DDIM * 2);

    // weight prep (tiled layouts)
    transpose_split<<<dim3(QKVD / 64, DDIM / 64), 256, 0, stream>>>(w_qkv, wqThi, wqTlo, DDIM, QKVD);
    transpose_split<<<dim3(HIDN / 64, CDIM / 64), 256, 0, stream>>>(k_w1, kw1Thi, kw1Tlo, CDIM, HIDN);
    transpose_split<<<dim3(HIDN / 64, CDIM / 64), 256, 0, stream>>>(v_w1, vw1Thi, vw1Tlo, CDIM, HIDN);
    transpose_split<<<dim3(DDIM / 64, DDIM / 64), 256, 0, stream>>>(w_out, woThi, nullptr, DDIM, DDIM);
    pad_small_tiled<<<(128 * DDIM / 8) / 256, 256, 0, stream>>>(gate_w, gate_b, gwThi, gwTlo, gbp, DDIM, 32, 10);
    pad_small_tiled<<<(128 * HIDN / 8) / 256, 256, 0, stream>>>(k_w2, k_b2, kw2Thi, kw2Tlo, kb2p, HIDN, 64, 11);
    pad_small_tiled<<<(128 * HIDN / 8) / 256, 256, 0, stream>>>(v_w2, v_b2, vw2Thi, vw2Tlo, vb2p, HIDN, 64, 11);

    // 1. RMSNorm -> tiled split-bf16 x
    rmsnorm_kernel<<<NTOK / 2, 256, 0, stream>>>(inp, g_norm, xhi, xlo);
    // 2. qkv = x @ w_qkv (final f32)
    gemm_tiled<3, 0, 1><<<dim3(QKVD / 128, NTOK / 128, 1), 256, 0, stream>>>(
        xhi, xlo, wqThi, wqTlo, nullptr, qkvb,
        xhi, xlo, wqThi, wqTlo, nullptr, qkvb, NTOK, QKVD, DDIM, 1);
    // 3. gates (split-K 8 + sigmoid reduce)
    gemm_tiled<3, 0, 0><<<dim3(1, NTOK / 128, 8), 256, 0, stream>>>(
        xhi, xlo, gwThi, gwTlo, nullptr, Pg,
        xhi, xlo, gwThi, gwTlo, nullptr, Pg, NTOK, 128, DDIM, 8);
    reduce_f32<2><<<dim3(128, 1), 256, 0, stream>>>(Pg, gbp, gates, Pg, gbp, gates, 8, NTOK, 128);
    // 4. compress-MLP inputs (tiled)
    build_cmlp_in<<<128, 256, 0, stream>>>(qkvb, k_pos, v_pos, cinkhi, cinklo, cinvhi, cinvlo);
    // 5. MLP1 (split-K 4, k&v batched; relu+bias+split-tile in reduce)
    gemm_tiled<3, 0, 0><<<dim3(HIDN / 128, 1, 8), 256, 0, stream>>>(
        cinkhi, cinklo, kw1Thi, kw1Tlo, nullptr, Pm1k,
        cinvhi, cinvlo, vw1Thi, vw1Tlo, nullptr, Pm1v, 128, HIDN, CDIM, 4);
    reduce_hid<<<dim3(128, 2), 256, 0, stream>>>(Pm1k, k_b1, hidkhi, hidklo,
                                                 Pm1v, v_b1, hidvhi, hidvlo, 4);
    // 6. MLP2 (split-K 8, k&v batched) + fused reduce/bias/concat
    gemm_tiled<3, 0, 0><<<dim3(1, 1, 16), 256, 0, stream>>>(
        hidkhi, hidklo, kw2Thi, kw2Tlo, nullptr, Pm2k,
        hidvhi, hidvlo, vw2Thi, vw2Tlo, nullptr, Pm2v, 128, 128, HIDN, 8);
    reduce_ckcv<<<33, 256, 0, stream>>>(Pm2k, Pm2v, mem_kv, kb2p, vb2p, ck, cv, 8);
    // 8. rotary + packed v
    rotary_kernel<<<(24 * NTOK * 32) / 256, 256, 0, stream>>>(qkvb, qr, kr, vr);
    // 9. compressed attention + selection (4 tokens per block)
    cattn_kernel<<<dim3(NTOK / 4, KVH), 256, 0, stream>>>(qkvb, ck, cv, c_out, sel, selmask);
    // 10. fine attention (v12: v8 structure + swizzled glds staging, q in LDS)
    fattn_kernel<<<dim3(NTOK, KVH), 256, 0, stream>>>(qr, kr, vr, sel, selmask, f_out);
    // 11. gated mix -> tiled split-bf16
    mix_kernel<<<(NTOK * DDIM / 8) / 256, 256, 0, stream>>>(gates, c_out, f_out, mixhi, mixlo);
    // 12. output projection (bf16, final)
    gemm_tiled<1, 0, 1><<<dim3(DDIM / 128, NTOK / 128, 1), 256, 0, stream>>>(
        mixhi, mixhi, woThi, woThi, nullptr, out,
        mixhi, mixhi, woThi, woThi, nullptr, out, NTOK, DDIM, DDIM, 1);
}

// Round 6
// 356.389 us; speedup vs baseline: 1.0704x; 1.0006x over previous
//
#include <hip/hip_runtime.h>
#include <math.h>

// ---- fixed problem sizes ----
#define NTOK 1024
#define DDIM 1024
#define HEADS 16
#define KVH 4
#define DH 64
#define BSZ 32
#define NSEL 8
#define WBLK 32            // NTOK / BSZ
#define GQ 4               // HEADS / KVH
#define CDIM 2048          // BSZ*DH
#define HIDN 2048
#define QKVD 1536          // (HEADS + 2*KVH)*DH
#define SCALE 0.125f       // DH^-0.5
#define NEGINF (-__builtin_inff())

typedef unsigned short u16;
typedef u16   u16x8  __attribute__((ext_vector_type(8)));
typedef short short8 __attribute__((ext_vector_type(8)));
typedef float f32x4  __attribute__((ext_vector_type(4)));

__device__ __forceinline__ u16 f2bf(float f) {
    unsigned u = __float_as_uint(f);
    return (u16)((u + 0x7fffu + ((u >> 16) & 1u)) >> 16);
}
__device__ __forceinline__ float bf2f(u16 h) { return __uint_as_float(((unsigned)h) << 16); }

__device__ __forceinline__ void glds16(const void* g, void* l) {
    __builtin_amdgcn_global_load_lds(
        (const __attribute__((address_space(1))) unsigned int*)g,
        (__attribute__((address_space(3))) unsigned int*)l, 16, 0, 0);
}

// element offset (in u16) of the 8-element lane-slot for (row, k..k+7) in the
// MFMA-fragment-tiled layout: 16-row x 32-k tiles, 1KB each, contiguous.
__device__ __forceinline__ size_t tiled_off(int row, int k, int K) {
    return ((size_t)((row >> 4) * (K >> 5) + (k >> 5)) * 64 +
            ((row & 15) | (((k >> 3) & 3) << 4))) * 8;
}

// ---------------------------------------------------------------------------
// K1: RMSNorm -> split-bf16 x in TILED layout (K=DDIM). 2 rows per 256-thr block.
// ---------------------------------------------------------------------------
__global__ void rmsnorm_kernel(const float* __restrict__ inp, const float* __restrict__ g,
                               u16* __restrict__ xhi, u16* __restrict__ xlo) {
    int t = threadIdx.x;
    int half = t >> 7, tid = t & 127;
    int n = blockIdx.x * 2 + half;
    const float4* row = (const float4*)(inp + (size_t)n * DDIM);
    float4 v0 = row[tid * 2], v1 = row[tid * 2 + 1];
    float ss = v0.x*v0.x + v0.y*v0.y + v0.z*v0.z + v0.w*v0.w
             + v1.x*v1.x + v1.y*v1.y + v1.z*v1.z + v1.w*v1.w;
    for (int off = 32; off; off >>= 1) ss += __shfl_down(ss, off);
    __shared__ float red[4];
    if ((t & 63) == 0) red[t >> 6] = ss;
    __syncthreads();
    float tot = red[half * 2] + red[half * 2 + 1];
    float r = 1.f / sqrtf(tot * (1.f / DDIM) + 1e-6f);
    const float4* gp = (const float4*)g;
    float4 g0 = gp[tid * 2], g1 = gp[tid * 2 + 1];
    float o[8] = { v0.x*r*g0.x, v0.y*r*g0.y, v0.z*r*g0.z, v0.w*r*g0.w,
                   v1.x*r*g1.x, v1.y*r*g1.y, v1.z*r*g1.z, v1.w*r*g1.w };
    u16x8 h, l;
#pragma unroll
    for (int i = 0; i < 8; ++i) {
        u16 hh = f2bf(o[i]);
        h[i] = hh;
        l[i] = f2bf(o[i] - bf2f(hh));
    }
    size_t ob = tiled_off(n, tid * 8, DDIM);
    *(u16x8*)&xhi[ob] = h;
    *(u16x8*)&xlo[ob] = l;
}

// ---------------------------------------------------------------------------
// K2: weight transpose + split: W[K][N] f32 -> tiled Bt[N][K] bf16 hi/lo
// ---------------------------------------------------------------------------
__global__ void transpose_split(const float* __restrict__ W, u16* __restrict__ Thi,
                                u16* __restrict__ Tlo, int K, int N) {
    __shared__ float tile[64][65];
    int k0 = blockIdx.y * 64, n0 = blockIdx.x * 64;
    int t = threadIdx.x;
    int r = t >> 4, c4 = (t & 15) * 4;
#pragma unroll
    for (int p = 0; p < 4; ++p) {
        float4 v = *(const float4*)&W[(size_t)(k0 + r + p * 16) * N + n0 + c4];
        tile[r + p * 16][c4 + 0] = v.x;
        tile[r + p * 16][c4 + 1] = v.y;
        tile[r + p * 16][c4 + 2] = v.z;
        tile[r + p * 16][c4 + 3] = v.w;
    }
    __syncthreads();
    int n = t >> 2, ks = (t & 3) * 16;
#pragma unroll
    for (int c = 0; c < 2; ++c) {
        u16x8 h, l;
#pragma unroll
        for (int j = 0; j < 8; ++j) {
            float v = tile[ks + c * 8 + j][n];
            u16 hh = f2bf(v);
            h[j] = hh;
            l[j] = f2bf(v - bf2f(hh));
        }
        size_t ob = tiled_off(n0 + n, k0 + ks + c * 8, K);
        *(u16x8*)&Thi[ob] = h;
        if (Tlo) *(u16x8*)&Tlo[ob] = l;
    }
}

// ---------------------------------------------------------------------------
// K2b: pad small weights [K][Xn] (Xn<=64) -> tiled split-bf16 [128][K] + padded bias
// ---------------------------------------------------------------------------
__global__ void pad_small_tiled(const float* __restrict__ W, const float* __restrict__ b,
                                u16* __restrict__ Thi, u16* __restrict__ Tlo,
                                float* __restrict__ bias_pad, int K, int Xn, int KLOG) {
    int idx = blockIdx.x * 256 + threadIdx.x;   // 128 * K/8
    int k = (idx & ((K >> 3) - 1)) * 8;
    int n = idx >> (KLOG - 3);
    if (n >= 128) return;
    u16x8 h, l;
#pragma unroll
    for (int j = 0; j < 8; ++j) {
        float v = (n < Xn) ? W[(size_t)(k + j) * Xn + n] : 0.f;
        u16 hh = f2bf(v);
        h[j] = hh;
        l[j] = f2bf(v - bf2f(hh));
    }
    size_t ob = tiled_off(n, k, K);
    *(u16x8*)&Thi[ob] = h;
    *(u16x8*)&Tlo[ob] = l;
    if (k == 0) bias_pad[n] = (n < Xn) ? b[n] : 0.f;
}

// ---------------------------------------------------------------------------
// K3: tiled MFMA GEMM with software pipeline + optional split-K.
// ---------------------------------------------------------------------------
template<int SPLIT, int ACT, int FINAL>
__global__ __launch_bounds__(256, 1)
void gemm_tiled(const u16* __restrict__ Ahi0, const u16* __restrict__ Alo0,
                const u16* __restrict__ Bhi0, const u16* __restrict__ Blo0,
                const float* __restrict__ bias0, float* __restrict__ C0,
                const u16* __restrict__ Ahi1, const u16* __restrict__ Alo1,
                const u16* __restrict__ Bhi1, const u16* __restrict__ Blo1,
                const float* __restrict__ bias1, float* __restrict__ C1,
                int M, int N, int K, int S) {
    int batch = blockIdx.z / S;
    int s = blockIdx.z - batch * S;
    const u16* Ahi = batch ? Ahi1 : Ahi0;
    const u16* Alo = batch ? Alo1 : Alo0;
    const u16* Bhi = batch ? Bhi1 : Bhi0;
    const u16* Blo = batch ? Blo1 : Blo0;
    const float* bias = batch ? bias1 : bias0;
    float* C = batch ? C1 : C0;

    constexpr int PARTS = (SPLIT == 3) ? 2 : 1;
    __shared__ u16 smA[2 * PARTS * 8 * 512];
    __shared__ u16 smB[2 * PARTS * 8 * 512];

    int tid = threadIdx.x;
    int w = tid >> 6, L = tid & 63;
    int m15 = L & 15, q = L >> 4;
    int KT = K >> 5;
    int rowTile = blockIdx.y * 8, colTile = blockIdx.x * 8;
    int NIT = (K / S) >> 5;
    int kb0 = s * NIT;
    int aw = w & 1, bw = w >> 1;

    f32x4 acc[4][4];
#pragma unroll
    for (int i = 0; i < 4; ++i)
#pragma unroll
        for (int j = 0; j < 4; ++j) acc[i][j] = (f32x4){0.f, 0.f, 0.f, 0.f};

    auto stage = [&](int buf, int kb) {
#pragma unroll
        for (int rl = 0; rl < 2; ++rl) {
            int rb = 2 * w + rl;
            glds16(Ahi + ((size_t)(rowTile + rb) * KT + kb) * 512 + (size_t)L * 8,
                   &smA[((buf * PARTS + 0) * 8 + rb) * 512]);
            glds16(Bhi + ((size_t)(colTile + rb) * KT + kb) * 512 + (size_t)L * 8,
                   &smB[((buf * PARTS + 0) * 8 + rb) * 512]);
            if constexpr (SPLIT == 3) {
                glds16(Alo + ((size_t)(rowTile + rb) * KT + kb) * 512 + (size_t)L * 8,
                       &smA[((buf * PARTS + 1) * 8 + rb) * 512]);
                glds16(Blo + ((size_t)(colTile + rb) * KT + kb) * 512 + (size_t)L * 8,
                       &smB[((buf * PARTS + 1) * 8 + rb) * 512]);
            }
        }
    };

    stage(0, kb0);
    for (int it = 0; it < NIT; ++it) {
        __syncthreads();
        if (it + 1 < NIT) stage((it + 1) & 1, kb0 + it + 1);
        int buf = it & 1;
        short8 ah[4], bh[4];
#pragma unroll
        for (int i = 0; i < 4; ++i) {
            ah[i] = *(const short8*)&smA[((buf * PARTS + 0) * 8 + aw * 4 + i) * 512 + L * 8];
            bh[i] = *(const short8*)&smB[((buf * PARTS + 0) * 8 + bw * 4 + i) * 512 + L * 8];
        }
        if constexpr (SPLIT == 3) {
            short8 al[4], bl[4];
#pragma unroll
            for (int i = 0; i < 4; ++i) {
                al[i] = *(const short8*)&smA[((buf * PARTS + 1) * 8 + aw * 4 + i) * 512 + L * 8];
                bl[i] = *(const short8*)&smB[((buf * PARTS + 1) * 8 + bw * 4 + i) * 512 + L * 8];
            }
#pragma unroll
            for (int i = 0; i < 4; ++i)
#pragma unroll
                for (int j = 0; j < 4; ++j) {
                    acc[i][j] = __builtin_amdgcn_mfma_f32_16x16x32_bf16(ah[i], bl[j], acc[i][j], 0, 0, 0);
                    acc[i][j] = __builtin_amdgcn_mfma_f32_16x16x32_bf16(al[i], bh[j], acc[i][j], 0, 0, 0);
                    acc[i][j] = __builtin_amdgcn_mfma_f32_16x16x32_bf16(ah[i], bh[j], acc[i][j], 0, 0, 0);
                }
        } else {
#pragma unroll
            for (int i = 0; i < 4; ++i)
#pragma unroll
                for (int j = 0; j < 4; ++j)
                    acc[i][j] = __builtin_amdgcn_mfma_f32_16x16x32_bf16(ah[i], bh[j], acc[i][j], 0, 0, 0);
        }
    }

    if constexpr (FINAL == 0) C += (size_t)s * M * N;
#pragma unroll
    for (int i = 0; i < 4; ++i) {
        int row = rowTile * 16 + aw * 64 + i * 16 + q * 4;
#pragma unroll
        for (int j = 0; j < 4; ++j) {
            int col = colTile * 16 + bw * 64 + j * 16 + m15;
            float bv = (FINAL && bias) ? bias[col] : 0.f;
#pragma unroll
            for (int r = 0; r < 4; ++r) {
                float v = acc[i][j][r];
                if constexpr (FINAL) {
                    v += bv;
                    if (ACT == 1) v = fmaxf(v, 0.f);
                    if (ACT == 2) v = 1.f / (1.f + expf(-v));
                }
                C[(size_t)(row + r) * N + col] = v;
            }
        }
    }
}

// ---------------------------------------------------------------------------
// K3b: split-K reduce -> f32 [M][N] with bias/act. Dual pointer sets via blockIdx.y.
// ---------------------------------------------------------------------------
template<int ACT>
__global__ void reduce_f32(const float* __restrict__ P0, const float* __restrict__ bias0,
                           float* __restrict__ C0,
                           const float* __restrict__ P1, const float* __restrict__ bias1,
                           float* __restrict__ C1, int S, int M, int N) {
    const float* P = blockIdx.y ? P1 : P0;
    const float* bias = blockIdx.y ? bias1 : bias0;
    float* C = blockIdx.y ? C1 : C0;
    int idx = blockIdx.x * 256 + threadIdx.x;
    int mn4 = (M * N) >> 2;
    if (idx >= mn4) return;
    f32x4 a = ((const f32x4*)P)[idx];
    for (int s = 1; s < S; ++s) a += ((const f32x4*)P)[(size_t)s * mn4 + idx];
    int col = (idx % (N >> 2)) * 4;
    f32x4 o;
#pragma unroll
    for (int j = 0; j < 4; ++j) {
        float v = a[j] + (bias ? bias[col + j] : 0.f);
        if (ACT == 1) v = fmaxf(v, 0.f);
        if (ACT == 2) v = 1.f / (1.f + expf(-v));
        o[j] = v;
    }
    ((f32x4*)C)[idx] = o;
}

// ---------------------------------------------------------------------------
// K3c: split-K reduce + relu + bias -> split-bf16 TILED (MLP1 hid, M=128, N=HIDN)
// ---------------------------------------------------------------------------
__global__ void reduce_hid(const float* __restrict__ P0, const float* __restrict__ b0,
                           u16* __restrict__ hi0, u16* __restrict__ lo0,
                           const float* __restrict__ P1, const float* __restrict__ b1,
                           u16* __restrict__ hi1, u16* __restrict__ lo1, int S) {
    const float* P = blockIdx.y ? P1 : P0;
    const float* bias = blockIdx.y ? b1 : b0;
    u16* hi = blockIdx.y ? hi1 : hi0;
    u16* lo = blockIdx.y ? lo1 : lo0;
    int idx = blockIdx.x * 256 + threadIdx.x;       // 128*2048/8 = 32768
    int col = (idx & 255) * 8, rowi = idx >> 8;
    size_t base = ((size_t)rowi * HIDN + col) >> 2;
    f32x4 a0 = ((const f32x4*)P)[base], a1 = ((const f32x4*)P)[base + 1];
    for (int s = 1; s < S; ++s) {
        size_t sb = (size_t)s * (128 * HIDN / 4) + base;
        a0 += ((const f32x4*)P)[sb];
        a1 += ((const f32x4*)P)[sb + 1];
    }
    u16x8 h, l;
#pragma unroll
    for (int j = 0; j < 8; ++j) {
        float v = (j < 4 ? a0[j] : a1[j - 4]) + bias[col + j];
        v = fmaxf(v, 0.f);
        u16 hh = f2bf(v);
        h[j] = hh;
        l[j] = f2bf(v - bf2f(hh));
    }
    size_t ob = tiled_off(rowi, col, HIDN);
    *(u16x8*)&hi[ob] = h;
    *(u16x8*)&lo[ob] = l;
}

// ---------------------------------------------------------------------------
// K3d: MLP2 split-K reduce + bias fused with mem_kv concat -> ck/cv [KVH][33][DH]
// ---------------------------------------------------------------------------
__global__ void reduce_ckcv(const float* __restrict__ Pk, const float* __restrict__ Pv,
                            const float* __restrict__ mem_kv,
                            const float* __restrict__ kb2, const float* __restrict__ vb2,
                            float* __restrict__ ck, float* __restrict__ cv, int S) {
    int idx = blockIdx.x * 256 + threadIdx.x;   // 4*33*64 = 8448
    if (idx >= KVH * 33 * DH) return;
    int d = idx & 63;
    int j = (idx >> 6) % 33;
    int h = idx / (33 * 64);
    float kvv, vvv;
    if (j == 0) {
        kvv = mem_kv[(0 * KVH + h) * DH + d];
        vvv = mem_kv[(1 * KVH + h) * DH + d];
    } else {
        size_t base = (size_t)(h * WBLK + (j - 1)) * 128 + d;
        float ak = Pk[base], av = Pv[base];
        for (int s = 1; s < S; ++s) {
            ak += Pk[(size_t)s * (128 * 128) + base];
            av += Pv[(size_t)s * (128 * 128) + base];
        }
        kvv = ak + kb2[d];
        vvv = av + vb2[d];
    }
    ck[idx] = kvv;
    cv[idx] = vvv;
}

// ---------------------------------------------------------------------------
// K5: build compress-MLP inputs -> split-bf16 TILED (K=CDIM)
// ---------------------------------------------------------------------------
__global__ void build_cmlp_in(const float* __restrict__ qkv, const float* __restrict__ k_pos,
                              const float* __restrict__ v_pos,
                              u16* __restrict__ ckhi, u16* __restrict__ cklo,
                              u16* __restrict__ cvhi, u16* __restrict__ cvlo) {
    int idx = blockIdx.x * 256 + threadIdx.x;   // 128 * 256 = 32768
    int k = (idx & 255) * 8;
    int r = idx >> 8;                           // 0..127 = h*W + w
    int p = k >> 6, d = k & 63;
    int h = r >> 5, wb = r & 31;
    int nn = wb * BSZ + p;
    const float* kq = qkv + (size_t)nn * QKVD + (HEADS + h) * DH + d;
    const float* vq = qkv + (size_t)nn * QKVD + (HEADS + KVH + h) * DH + d;
    const float* kp = k_pos + (size_t)(h * BSZ + p) * DH + d;
    const float* vp = v_pos + (size_t)(h * BSZ + p) * DH + d;
    u16x8 kh, kl, vh, vl;
#pragma unroll
    for (int j = 0; j < 8; ++j) {
        float kv = kq[j] + kp[j];
        float vv = vq[j] + vp[j];
        u16 a = f2bf(kv), b = f2bf(vv);
        kh[j] = a; kl[j] = f2bf(kv - bf2f(a));
        vh[j] = b; vl[j] = f2bf(vv - bf2f(b));
    }
    size_t ob = tiled_off(r, k, CDIM);
    *(u16x8*)&ckhi[ob] = kh; *(u16x8*)&cklo[ob] = kl;
    *(u16x8*)&cvhi[ob] = vh; *(u16x8*)&cvlo[ob] = vl;
}

// ---------------------------------------------------------------------------
// K7: interleaved rotary for q (16 heads), k (4 heads) + packed v copy (4 heads)
// ---------------------------------------------------------------------------
__global__ void rotary_kernel(const float* __restrict__ qkv,
                              float* __restrict__ qr, float* __restrict__ kr,
                              float* __restrict__ vr) {
    int idx = blockIdx.x * 256 + threadIdx.x;   // 24*1024*32 = 786432
    int i = idx & 31;
    int n = (idx >> 5) & 1023;
    int hd = idx >> 15;
    if (hd >= 24) return;
    if (hd >= HEADS + KVH) {       // packed v copy
        int h = hd - (HEADS + KVH);
        const float* src = qkv + (size_t)n * QKVD + (HEADS + KVH + h) * DH;
        float* dst = vr + ((size_t)h * NTOK + n) * DH;
        dst[2 * i] = src[2 * i];
        dst[2 * i + 1] = src[2 * i + 1];
        return;
    }
    float inv = powf(10000.f, -(float)i / 32.f);
    float fr = (float)n * inv;
    float c = cosf(fr), s = sinf(fr);
    const float* src; float* dst;
    if (hd < HEADS) { src = qkv + (size_t)n * QKVD + hd * DH;          dst = qr + ((size_t)hd * NTOK + n) * DH; }
    else { int h = hd - HEADS;
           src = qkv + (size_t)n * QKVD + (HEADS + h) * DH;            dst = kr + ((size_t)h * NTOK + n) * DH; }
    float x0 = src[2 * i], x1 = src[2 * i + 1];
    dst[2 * i]     = x0 * c - x1 * s;
    dst[2 * i + 1] = x1 * c + x0 * s;
}

// ---------------------------------------------------------------------------
// K8: compressed attention + importance + top-k. 4 tokens per 256-thr block.
// ---------------------------------------------------------------------------
__global__ __launch_bounds__(256)
void cattn_kernel(const float* __restrict__ qkv, const float* __restrict__ ck,
                  const float* __restrict__ cv, float* __restrict__ c_out,
                  int* __restrict__ sel, int* __restrict__ selmask) {
    int h = blockIdx.y;
    int tid = threadIdx.x;
    int w = tid >> 6, lane = tid & 63;
    int grp = lane >> 4, sub = lane & 15;
    int n = blockIdx.x * 4 + w;
    __shared__ float cks[33 * 68];
    __shared__ float cvs[33 * 68];
    __shared__ float sims[16 * 36];      // [w*4+g][j]

    for (int t4 = tid; t4 < 1056; t4 += 256) {
        int half = (t4 >= 528) ? 1 : 0;
        int u = t4 - half * 528;
        int j = u >> 4, d4 = (u & 15) * 4;
        const float* src = (half ? cv : ck) + (size_t)h * 33 * 64 + j * 64 + d4;
        float* dst = (half ? cvs : cks) + j * 68 + d4;
        *(float4*)dst = *(const float4*)src;
    }
    float qreg[64];
    {
        const float4* qp4 = (const float4*)(qkv + (size_t)n * QKVD + (h * GQ + grp) * DH);
#pragma unroll
        for (int c = 0; c < 16; ++c) {
            float4 v = qp4[c];
            qreg[4 * c] = v.x; qreg[4 * c + 1] = v.y; qreg[4 * c + 2] = v.z; qreg[4 * c + 3] = v.w;
        }
    }
    __syncthreads();

#pragma unroll
    for (int r = 0; r < 3; ++r) {
        int j = r * 16 + sub;
        if (j < 33) {
            float acc = 0.f;
#pragma unroll
            for (int d = 0; d < 64; ++d) acc = fmaf(qreg[d], cks[j * 68 + d], acc);
            sims[(w * 4 + grp) * 36 + j] = acc * SCALE;
        }
    }

    float ival = NEGINF;
    if (lane < 32)
        ival = 0.25f * (sims[(w * 4 + 0) * 36 + 1 + lane] + sims[(w * 4 + 1) * 36 + 1 + lane] +
                        sims[(w * 4 + 2) * 36 + 1 + lane] + sims[(w * 4 + 3) * 36 + 1 + lane]);
    float m = ival;
    for (int off = 32; off; off >>= 1) m = fmaxf(m, __shfl_xor(m, off));
    float e = (lane < 32) ? expf(ival - m) : 0.f;
    float sum = e;
    for (int off = 32; off; off >>= 1) sum += __shfl_xor(sum, off);
    float p = (lane < 32) ? e / sum : NEGINF;

    float v = p;
    int base = (h * NTOK + n) * 9;
    for (int t = 0; t < NSEL; ++t) {
        float bv = v; int bi = lane;
        for (int off = 32; off; off >>= 1) {
            float ov = __shfl_xor(bv, off);
            int   oi = __shfl_xor(bi, off);
            if (ov > bv || (ov == bv && oi < bi)) { bv = ov; bi = oi; }
        }
        if (lane == 0) { sel[base + t] = bi; selmask[base + t] = (bv > 1e-10f) ? 1 : 0; }
        if (lane == bi) v = NEGINF;
    }
    if (lane == 0) { sel[base + NSEL] = n >> 5; selmask[base + NSEL] = 1; }

#pragma unroll
    for (int g = 0; g < 4; ++g) {
        float sv = (lane < 33) ? sims[(w * 4 + g) * 36 + lane] : NEGINF;
        float mm = sv;
        for (int off = 32; off; off >>= 1) mm = fmaxf(mm, __shfl_xor(mm, off));
        float ee = (lane < 33) ? __expf(sv - mm) : 0.f;
        float ssum = ee;
        for (int off = 32; off; off >>= 1) ssum += __shfl_xor(ssum, off);
        if (lane < 33) sims[(w * 4 + g) * 36 + lane] = ee / ssum;
    }

    f32x4 o = (f32x4){0.f, 0.f, 0.f, 0.f};
#pragma unroll
    for (int j = 0; j < 33; ++j) {
        float a = sims[(w * 4 + grp) * 36 + j];
        f32x4 vv = *(const f32x4*)&cvs[j * 68 + sub * 4];
        o += a * vv;
    }
    *(f32x4*)&c_out[(((size_t)(h * GQ + grp)) * NTOK + n) * DH + sub * 4] = o;
}

// ---------------------------------------------------------------------------
// K9: fine attention v13 — v12 + barrier-halving.
// R5 post-mortem: v12 (76.4us) has clean counters but NO saturated pipe
// (VALU 49%, LDS ~55%, HBM 2.5%, occ 39%) => latency/sync-bound. Key fact:
// K/V staging, scores, and PV are WAVE-PRIVATE (wave w stages/reads only rows
// [w*16,w*16+16)); only ssc/ps/alphas cross waves. So 2 of the 4 barriers per
// iteration only ordered wave-local glds/LDS hazards — replace them with
// per-wave s_waitcnt (no all-wave convoy):
//   [stageK issued end of prev iter] -> vmcnt(0) wave-local -> scores
//   -> B1 (ssc) -> stageV issue + softmax -> B2 (ps/alphas; implicit drain=V)
//   -> PV -> lgkmcnt(0) wave-local -> stageK(next)       [no barrier]
// Hazards: ssc WAR separated by B2(i); ps WAR by B1(i+1); KV WARs wave-local,
// pinned by sched_barrier(0) fences (rule #18). Epilogue barrier added for the
// cross-wave KV-scratch reduce. Barriers/block: 22 -> 13. Math order identical.
// ---------------------------------------------------------------------------
__global__ void fattn_kernel(const float* __restrict__ qr, const float* __restrict__ kr,
                             const float* __restrict__ vr, const int* __restrict__ sel,
                             const int* __restrict__ selmask, float* __restrict__ f_out) {
    int n = blockIdx.x, h = blockIdx.y;
    int tid = threadIdx.x;
    int w = tid >> 6, lane = tid & 63;
    int grp = lane >> 4, sub = lane & 15;
    __shared__ float qsm[4 * 68];
    __shared__ float KV[64 * 64];        // K then V each pair; slot s of row r = global slot s^(r&15)
    __shared__ float ssc[4 * 68];
    __shared__ float ps[4 * 68];
    __shared__ float alphas[4], ls[4];
    __shared__ int sel_s[9], msk_s[9];

    if (tid < 9) {
        sel_s[tid] = sel[(h * NTOK + n) * 9 + tid];
        msk_s[tid] = selmask[(h * NTOK + n) * 9 + tid];
    }
    // q -> LDS once: wave w loads head w's 64 elements
    qsm[w * 68 + lane] = qr[(((size_t)(h * GQ + w)) * NTOK + n) * DH + lane];
    f32x4 o4 = (f32x4){0.f, 0.f, 0.f, 0.f};   // partial over wave's j-slice, dims sub*4..sub*4+3
    float m_run = -3.402823466e38f, l_run = 0.f;
    __syncthreads();                     // B0: sel_s + qsm ready

    const float* krh_ = kr + (size_t)h * NTOK * DH;
    const float* vrh_ = vr + (size_t)h * NTOK * DH;

    // staging geometry: wave w stages rows [w*16, w*16+16); glds chunk cc = 4 rows.
    // lane L -> row_local rl = L>>4, slot sl = L&15 (dest linear: base + L*16B);
    // source slot = sl ^ (r&15) so that read with slot = c ^ (row&15) is identity.
    int rl = lane >> 4, sl = lane & 15;

    auto stageRows = [&](const float* src, int bp) {
        int nrow = (bp < 4) ? 64 : 32;
        if (w * 16 < nrow) {
            int myblk = sel_s[bp * 2 + (w >> 1)];
            const float* b_ = src + (size_t)myblk * BSZ * DH;
#pragma unroll
            for (int cc = 0; cc < 4; ++cc) {
                int r = w * 16 + cc * 4 + rl;
                int sg = sl ^ (r & 15);
                glds16(b_ + (size_t)(r & 31) * DH + sg * 4, &KV[(w * 16 + cc * 4) * 64]);
            }
        }
    };

    stageRows(krh_, 0);                  // prologue: K(0), wave-private

    for (int bp = 0; bp < 5; ++bp) {
        int nrow = (bp < 4) ? 64 : 32;

        // wave-local wait: this wave's K rows staged (no cross-wave convoy)
        asm volatile("s_waitcnt vmcnt(0)" ::: "memory");
        __builtin_amdgcn_sched_barrier(0);

        // ---- scores: thread -> (g=grp, jj=w*16+sub); reads OWN-wave rows only
        {
            int jj = w * 16 + sub;
            int b = bp * 2 + (jj >> 5);
            float s = -3.402823466e38f;
            if (jj < nrow && msk_s[b]) {
                int sw = jj & 15;
                const float* Kb = &KV[jj * 64];
                float acc = 0.f;
#pragma unroll
                for (int c = 0; c < 16; ++c) {
                    f32x4 k4 = *(const f32x4*)&Kb[(c ^ sw) * 4];
                    f32x4 q4 = *(const f32x4*)&qsm[grp * 68 + c * 4];
                    acc = fmaf(q4[0], k4[0], acc);
                    acc = fmaf(q4[1], k4[1], acc);
                    acc = fmaf(q4[2], k4[2], acc);
                    acc = fmaf(q4[3], k4[3], acc);
                }
                s = acc * SCALE;
            }
            ssc[grp * 68 + jj] = s;
        }
        __syncthreads();                  // B1: ssc ready (drains everything incl. K reads)

        // ---- stage V rows (overwrites OWN rows; all scores reads drained at B1)
        stageRows(vrh_, bp);

        // ---- online softmax (wave w owns head w; reads ssc from all waves)
        {
            float sv = ssc[w * 68 + lane];
            float mb = sv;
            for (int off = 32; off; off >>= 1) mb = fmaxf(mb, __shfl_xor(mb, off));
            float m_new = fmaxf(m_run, mb);
            float pp = (sv > -1e37f) ? __expf(sv - m_new) : 0.f;
            float alpha = __expf(m_run - m_new);
            float psum = pp;
            for (int off = 32; off; off >>= 1) psum += __shfl_xor(psum, off);
            l_run = l_run * alpha + psum;
            m_run = m_new;
            ps[w * 68 + lane] = pp;
            if (lane == 0) alphas[w] = alpha;
        }
        __syncthreads();                  // B2: ps/alphas ready; implicit vmcnt(0) drains V

        // ---- PV: wave w reads OWN rows [w*16, w*16+16); thread (g=grp, c=sub)
        {
            o4 *= alphas[grp];            // per-head alpha: same for every wave
            int jbase = w * 16;
            if (jbase < nrow) {
#pragma unroll
                for (int jq = 0; jq < 4; ++jq) {
                    f32x4 p4 = *(const f32x4*)&ps[grp * 68 + jbase + jq * 4];
#pragma unroll
                    for (int r = 0; r < 4; ++r) {
                        int row = jbase + jq * 4 + r;
                        int slot = sub ^ (row & 15);
                        f32x4 vv = *(const f32x4*)&KV[row * 64 + slot * 4];
                        o4 += p4[r] * vv;
                    }
                }
            }
        }
        // ---- stage K(bp+1) into OWN rows: wave-local WAR vs this wave's PV reads.
        // lgkmcnt(0) retires all our ds_reads; sched_barrier pins the glds below it.
        if (bp < 4) {
            __builtin_amdgcn_sched_barrier(0);
            asm volatile("s_waitcnt lgkmcnt(0)" ::: "memory");
            __builtin_amdgcn_sched_barrier(0);
            stageRows(krh_, bp + 1);
        }
        // NO barrier here: next iter's scores wait on vmcnt only (wave-local).
        // ssc WAR: softmax(bp) read pre-B2; scores(bp+1) writes post-B2.  OK
        // ps  WAR: PV(bp) read pre-B1(bp+1); softmax(bp+1) writes post-B1. OK
    }
    if (lane == 0) ls[w] = l_run;
    __syncthreads();                      // epilogue: all PV reads done -> KV reusable as scratch
    // cross-wave reduction of the 4 j-slice partials through the free KV buffer
    *(f32x4*)&KV[(w * 4 + grp) * 64 + sub * 4] = o4;
    __syncthreads();
    float sum = KV[(0 * 4 + w) * 64 + lane] + KV[(1 * 4 + w) * 64 + lane]
              + KV[(2 * 4 + w) * 64 + lane] + KV[(3 * 4 + w) * 64 + lane];
    f_out[(((size_t)(h * GQ + w)) * NTOK + n) * DH + lane] = sum / ls[w];
}

// ---------------------------------------------------------------------------
// K10: gated mix -> split-bf16 TILED (K=DDIM). gates f32 [N][128] padded.
// ---------------------------------------------------------------------------
__global__ void mix_kernel(const float* __restrict__ gates, const float* __restrict__ c_out,
                           const float* __restrict__ f_out,
                           u16* __restrict__ mixhi, u16* __restrict__ mixlo) {
    int idx = blockIdx.x * 256 + threadIdx.x;   // 1024*1024/8 = 131072
    int col = (idx & 127) * 8;
    int n = idx >> 7;
    int hd = col >> 6, d = col & 63;
    float g0 = gates[(size_t)n * 128 + hd * 2];
    float g1 = gates[(size_t)n * 128 + hd * 2 + 1];
    size_t hoff = (((size_t)hd) * NTOK + n) * DH + d;
    u16x8 h, l;
#pragma unroll
    for (int j = 0; j < 8; ++j) {
        float v = g0 * c_out[hoff + j] + g1 * f_out[hoff + j];
        u16 hh = f2bf(v);
        h[j] = hh;
        l[j] = f2bf(v - bf2f(hh));
    }
    size_t ob = tiled_off(n, col, DDIM);
    *(u16x8*)&mixhi[ob] = h;
    *(u16x8*)&mixlo[ob] = l;
}

// ---------------------------------------------------------------------------
extern "C" void kernel_launch(void* const* d_in, const int* in_sizes, int n_in,
                              void* d_out, int out_size, void* d_ws, size_t ws_size,
                              hipStream_t stream) {
    const float* inp    = (const float*)d_in[0];
    const float* g_norm = (const float*)d_in[1];
    const float* w_qkv  = (const float*)d_in[2];
    const float* mem_kv = (const float*)d_in[3];
    const float* k_pos  = (const float*)d_in[4];
    const float* v_pos  = (const float*)d_in[5];
    const float* k_w1   = (const float*)d_in[6];
    const float* k_b1   = (const float*)d_in[7];
    const float* k_w2   = (const float*)d_in[8];
    const float* k_b2   = (const float*)d_in[9];
    const float* v_w1   = (const float*)d_in[10];
    const float* v_b1   = (const float*)d_in[11];
    const float* v_w2   = (const float*)d_in[12];
    const float* v_b2   = (const float*)d_in[13];
    const float* gate_w = (const float*)d_in[14];
    const float* gate_b = (const float*)d_in[15];
    const float* w_out  = (const float*)d_in[16];
    float* out = (float*)d_out;

    char* wsb = (char*)d_ws;
    size_t off = 0;
    auto alloc = [&](size_t bytes) -> void* {
        void* p = wsb + off;
        off = (off + bytes + 255) & ~(size_t)255;
        return p;
    };
    u16*   xhi    = (u16*)  alloc((size_t)NTOK * DDIM * 2);
    u16*   xlo    = (u16*)  alloc((size_t)NTOK * DDIM * 2);
    float* qkvb   = (float*)alloc((size_t)NTOK * QKVD * 4);
    u16*   wqThi  = (u16*)  alloc((size_t)QKVD * DDIM * 2);
    u16*   wqTlo  = (u16*)  alloc((size_t)QKVD * DDIM * 2);
    u16*   kw1Thi = (u16*)  alloc((size_t)HIDN * CDIM * 2);
    u16*   kw1Tlo = (u16*)  alloc((size_t)HIDN * CDIM * 2);
    u16*   vw1Thi = (u16*)  alloc((size_t)HIDN * CDIM * 2);
    u16*   vw1Tlo = (u16*)  alloc((size_t)HIDN * CDIM * 2);
    u16*   woThi  = (u16*)  alloc((size_t)DDIM * DDIM * 2);
    u16*   gwThi  = (u16*)  alloc((size_t)128 * DDIM * 2);
    u16*   gwTlo  = (u16*)  alloc((size_t)128 * DDIM * 2);
    float* gbp    = (float*)alloc(128 * 4);
    u16*   kw2Thi = (u16*)  alloc((size_t)128 * HIDN * 2);
    u16*   kw2Tlo = (u16*)  alloc((size_t)128 * HIDN * 2);
    float* kb2p   = (float*)alloc(128 * 4);
    u16*   vw2Thi = (u16*)  alloc((size_t)128 * HIDN * 2);
    u16*   vw2Tlo = (u16*)  alloc((size_t)128 * HIDN * 2);
    float* vb2p   = (float*)alloc(128 * 4);
    u16*   cinkhi = (u16*)  alloc((size_t)128 * CDIM * 2);
    u16*   cinklo = (u16*)  alloc((size_t)128 * CDIM * 2);
    u16*   cinvhi = (u16*)  alloc((size_t)128 * CDIM * 2);
    u16*   cinvlo = (u16*)  alloc((size_t)128 * CDIM * 2);
    u16*   hidkhi = (u16*)  alloc((size_t)128 * HIDN * 2);
    u16*   hidklo = (u16*)  alloc((size_t)128 * HIDN * 2);
    u16*   hidvhi = (u16*)  alloc((size_t)128 * HIDN * 2);
    u16*   hidvlo = (u16*)  alloc((size_t)128 * HIDN * 2);
    float* Pg     = (float*)alloc((size_t)8 * NTOK * 128 * 4);
    float* Pm1k   = (float*)alloc((size_t)4 * 128 * HIDN * 4);
    float* Pm1v   = (float*)alloc((size_t)4 * 128 * HIDN * 4);
    float* Pm2k   = (float*)alloc((size_t)8 * 128 * 128 * 4);
    float* Pm2v   = (float*)alloc((size_t)8 * 128 * 128 * 4);
    float* ck     = (float*)alloc((size_t)KVH * 33 * DH * 4);
    float* cv     = (float*)alloc((size_t)KVH * 33 * DH * 4);
    float* qr     = (float*)alloc((size_t)HEADS * NTOK * DH * 4);
    float* kr     = (float*)alloc((size_t)KVH * NTOK * DH * 4);
    float* vr     = (float*)alloc((size_t)KVH * NTOK * DH * 4);
    float* c_out  = (float*)alloc((size_t)HEADS * NTOK * DH * 4);
    float* f_out  = (float*)alloc((size_t)HEADS * NTOK * DH * 4);
    float* gates  = (float*)alloc((size_t)NTOK * 128 * 4);
    int*   sel    = (int*)  alloc((size_t)KVH * NTOK * 9 * 4);
    int*   selmask= (int*)  alloc((size_t)KVH * NTOK * 9 * 4);
    u16*   mixhi  = (u16*)  alloc((size_t)NTOK * DDIM * 2);
    u16*   mixlo  = (u16*)  alloc((size_t)NTOK * DDIM * 2);

    // weight prep (tiled layouts)
    transpose_split<<<dim3(QKVD / 64, DDIM / 64), 256, 0, stream>>>(w_qkv, wqThi, wqTlo, DDIM, QKVD);
    transpose_split<<<dim3(HIDN / 64, CDIM / 64), 256, 0, stream>>>(k_w1, kw1Thi, kw1Tlo, CDIM, HIDN);
    transpose_split<<<dim3(HIDN / 64, CDIM / 64), 256, 0, stream>>>(v_w1, vw1Thi, vw1Tlo, CDIM, HIDN);
    transpose_split<<<dim3(DDIM / 64, DDIM / 64), 256, 0, stream>>>(w_out, woThi, nullptr, DDIM, DDIM);
    pad_small_tiled<<<(128 * DDIM / 8) / 256, 256, 0, stream>>>(gate_w, gate_b, gwThi, gwTlo, gbp, DDIM, 32, 10);
    pad_small_tiled<<<(128 * HIDN / 8) / 256, 256, 0, stream>>>(k_w2, k_b2, kw2Thi, kw2Tlo, kb2p, HIDN, 64, 11);
    pad_small_tiled<<<(128 * HIDN / 8) / 256, 256, 0, stream>>>(v_w2, v_b2, vw2Thi, vw2Tlo, vb2p, HIDN, 64, 11);

    // 1. RMSNorm -> tiled split-bf16 x
    rmsnorm_kernel<<<NTOK / 2, 256, 0, stream>>>(inp, g_norm, xhi, xlo);
    // 2. qkv = x @ w_qkv (final f32)
    gemm_tiled<3, 0, 1><<<dim3(QKVD / 128, NTOK / 128, 1), 256, 0, stream>>>(
        xhi, xlo, wqThi, wqTlo, nullptr, qkvb,
        xhi, xlo, wqThi, wqTlo, nullptr, qkvb, NTOK, QKVD, DDIM, 1);
    // 3. gates (split-K 8 + sigmoid reduce)
    gemm_tiled<3, 0, 0><<<dim3(1, NTOK / 128, 8), 256, 0, stream>>>(
        xhi, xlo, gwThi, gwTlo, nullptr, Pg,
        xhi, xlo, gwThi, gwTlo, nullptr, Pg, NTOK, 128, DDIM, 8);
    reduce_f32<2><<<dim3(128, 1), 256, 0, stream>>>(Pg, gbp, gates, Pg, gbp, gates, 8, NTOK, 128);
    // 4. compress-MLP inputs (tiled)
    build_cmlp_in<<<128, 256, 0, stream>>>(qkvb, k_pos, v_pos, cinkhi, cinklo, cinvhi, cinvlo);
    // 5. MLP1 (split-K 4, k&v batched; relu+bias+split-tile in reduce)
    gemm_tiled<3, 0, 0><<<dim3(HIDN / 128, 1, 8), 256, 0, stream>>>(
        cinkhi, cinklo, kw1Thi, kw1Tlo, nullptr, Pm1k,
        cinvhi, cinvlo, vw1Thi, vw1Tlo, nullptr, Pm1v, 128, HIDN, CDIM, 4);
    reduce_hid<<<dim3(128, 2), 256, 0, stream>>>(Pm1k, k_b1, hidkhi, hidklo,
                                                 Pm1v, v_b1, hidvhi, hidvlo, 4);
    // 6. MLP2 (split-K 8, k&v batched) + fused reduce/bias/concat
    gemm_tiled<3, 0, 0><<<dim3(1, 1, 16), 256, 0, stream>>>(
        hidkhi, hidklo, kw2Thi, kw2Tlo, nullptr, Pm2k,
        hidvhi, hidvlo, vw2Thi, vw2Tlo, nullptr, Pm2v, 128, 128, HIDN, 8);
    reduce_ckcv<<<33, 256, 0, stream>>>(Pm2k, Pm2v, mem_kv, kb2p, vb2p, ck, cv, 8);
    // 8. rotary + packed v
    rotary_kernel<<<(24 * NTOK * 32) / 256, 256, 0, stream>>>(qkvb, qr, kr, vr);
    // 9. compressed attention + selection (4 tokens per block)
    cattn_kernel<<<dim3(NTOK / 4, KVH), 256, 0, stream>>>(qkvb, ck, cv, c_out, sel, selmask);
    // 10. fine attention (v13: wave-private staging, 2 barriers/iter)
    fattn_kernel<<<dim3(NTOK, KVH), 256, 0, stream>>>(qr, kr, vr, sel, selmask, f_out);
    // 11. gated mix -> tiled split-bf16
    mix_kernel<<<(NTOK * DDIM / 8) / 256, 256, 0, stream>>>(gates, c_out, f_out, mixhi, mixlo);
    // 12. output projection (bf16, final)
    gemm_tiled<1, 0, 1><<<dim3(DDIM / 128, NTOK / 128, 1), 256, 0, stream>>>(
        mixhi, mixhi, woThi, woThi, nullptr, out,
        mixhi, mixhi, woThi, woThi, nullptr, out, NTOK, DDIM, DDIM, 1);
}

// Round 7
// 346.744 us; speedup vs baseline: 1.1002x; 1.0278x over previous
//
#include <hip/hip_runtime.h>
#include <math.h>

// ---- fixed problem sizes ----
#define NTOK 1024
#define DDIM 1024
#define HEADS 16
#define KVH 4
#define DH 64
#define BSZ 32
#define NSEL 8
#define WBLK 32            // NTOK / BSZ
#define GQ 4               // HEADS / KVH
#define CDIM 2048          // BSZ*DH
#define HIDN 2048
#define QKVD 1536          // (HEADS + 2*KVH)*DH
#define SCALE 0.125f       // DH^-0.5
#define NEGINF (-__builtin_inff())

typedef unsigned short u16;
typedef u16   u16x8  __attribute__((ext_vector_type(8)));
typedef short short8 __attribute__((ext_vector_type(8)));
typedef float f32x4  __attribute__((ext_vector_type(4)));

__device__ __forceinline__ u16 f2bf(float f) {
    unsigned u = __float_as_uint(f);
    return (u16)((u + 0x7fffu + ((u >> 16) & 1u)) >> 16);
}
__device__ __forceinline__ float bf2f(u16 h) { return __uint_as_float(((unsigned)h) << 16); }

__device__ __forceinline__ void glds16(const void* g, void* l) {
    __builtin_amdgcn_global_load_lds(
        (const __attribute__((address_space(1))) unsigned int*)g,
        (__attribute__((address_space(3))) unsigned int*)l, 16, 0, 0);
}

// element offset (in u16) of the 8-element lane-slot for (row, k..k+7) in the
// MFMA-fragment-tiled layout: 16-row x 32-k tiles, 1KB each, contiguous.
__device__ __forceinline__ size_t tiled_off(int row, int k, int K) {
    return ((size_t)((row >> 4) * (K >> 5) + (k >> 5)) * 64 +
            ((row & 15) | (((k >> 3) & 3) << 4))) * 8;
}

// ---------------------------------------------------------------------------
// K1: RMSNorm -> split-bf16 x in TILED layout (K=DDIM). 2 rows per 256-thr block.
// ---------------------------------------------------------------------------
__global__ void rmsnorm_kernel(const float* __restrict__ inp, const float* __restrict__ g,
                               u16* __restrict__ xhi, u16* __restrict__ xlo) {
    int t = threadIdx.x;
    int half = t >> 7, tid = t & 127;
    int n = blockIdx.x * 2 + half;
    const float4* row = (const float4*)(inp + (size_t)n * DDIM);
    float4 v0 = row[tid * 2], v1 = row[tid * 2 + 1];
    float ss = v0.x*v0.x + v0.y*v0.y + v0.z*v0.z + v0.w*v0.w
             + v1.x*v1.x + v1.y*v1.y + v1.z*v1.z + v1.w*v1.w;
    for (int off = 32; off; off >>= 1) ss += __shfl_down(ss, off);
    __shared__ float red[4];
    if ((t & 63) == 0) red[t >> 6] = ss;
    __syncthreads();
    float tot = red[half * 2] + red[half * 2 + 1];
    float r = 1.f / sqrtf(tot * (1.f / DDIM) + 1e-6f);
    const float4* gp = (const float4*)g;
    float4 g0 = gp[tid * 2], g1 = gp[tid * 2 + 1];
    float o[8] = { v0.x*r*g0.x, v0.y*r*g0.y, v0.z*r*g0.z, v0.w*r*g0.w,
                   v1.x*r*g1.x, v1.y*r*g1.y, v1.z*r*g1.z, v1.w*r*g1.w };
    u16x8 h, l;
#pragma unroll
    for (int i = 0; i < 8; ++i) {
        u16 hh = f2bf(o[i]);
        h[i] = hh;
        l[i] = f2bf(o[i] - bf2f(hh));
    }
    size_t ob = tiled_off(n, tid * 8, DDIM);
    *(u16x8*)&xhi[ob] = h;
    *(u16x8*)&xlo[ob] = l;
}

// ---------------------------------------------------------------------------
// K2: weight transpose + split: W[K][N] f32 -> tiled Bt[N][K] bf16 hi/lo
// ---------------------------------------------------------------------------
__global__ void transpose_split(const float* __restrict__ W, u16* __restrict__ Thi,
                                u16* __restrict__ Tlo, int K, int N) {
    __shared__ float tile[64][65];
    int k0 = blockIdx.y * 64, n0 = blockIdx.x * 64;
    int t = threadIdx.x;
    int r = t >> 4, c4 = (t & 15) * 4;
#pragma unroll
    for (int p = 0; p < 4; ++p) {
        float4 v = *(const float4*)&W[(size_t)(k0 + r + p * 16) * N + n0 + c4];
        tile[r + p * 16][c4 + 0] = v.x;
        tile[r + p * 16][c4 + 1] = v.y;
        tile[r + p * 16][c4 + 2] = v.z;
        tile[r + p * 16][c4 + 3] = v.w;
    }
    __syncthreads();
    int n = t >> 2, ks = (t & 3) * 16;
#pragma unroll
    for (int c = 0; c < 2; ++c) {
        u16x8 h, l;
#pragma unroll
        for (int j = 0; j < 8; ++j) {
            float v = tile[ks + c * 8 + j][n];
            u16 hh = f2bf(v);
            h[j] = hh;
            l[j] = f2bf(v - bf2f(hh));
        }
        size_t ob = tiled_off(n0 + n, k0 + ks + c * 8, K);
        *(u16x8*)&Thi[ob] = h;
        if (Tlo) *(u16x8*)&Tlo[ob] = l;
    }
}

// ---------------------------------------------------------------------------
// K2b: pad small weights [K][Xn] (Xn<=64) -> tiled split-bf16 [128][K] + padded bias
// ---------------------------------------------------------------------------
__global__ void pad_small_tiled(const float* __restrict__ W, const float* __restrict__ b,
                                u16* __restrict__ Thi, u16* __restrict__ Tlo,
                                float* __restrict__ bias_pad, int K, int Xn, int KLOG) {
    int idx = blockIdx.x * 256 + threadIdx.x;   // 128 * K/8
    int k = (idx & ((K >> 3) - 1)) * 8;
    int n = idx >> (KLOG - 3);
    if (n >= 128) return;
    u16x8 h, l;
#pragma unroll
    for (int j = 0; j < 8; ++j) {
        float v = (n < Xn) ? W[(size_t)(k + j) * Xn + n] : 0.f;
        u16 hh = f2bf(v);
        h[j] = hh;
        l[j] = f2bf(v - bf2f(hh));
    }
    size_t ob = tiled_off(n, k, K);
    *(u16x8*)&Thi[ob] = h;
    *(u16x8*)&Tlo[ob] = l;
    if (k == 0) bias_pad[n] = (n < Xn) ? b[n] : 0.f;
}

// ---------------------------------------------------------------------------
// K3: tiled MFMA GEMM with software pipeline + optional split-K.
// ---------------------------------------------------------------------------
template<int SPLIT, int ACT, int FINAL>
__global__ __launch_bounds__(256, 1)
void gemm_tiled(const u16* __restrict__ Ahi0, const u16* __restrict__ Alo0,
                const u16* __restrict__ Bhi0, const u16* __restrict__ Blo0,
                const float* __restrict__ bias0, float* __restrict__ C0,
                const u16* __restrict__ Ahi1, const u16* __restrict__ Alo1,
                const u16* __restrict__ Bhi1, const u16* __restrict__ Blo1,
                const float* __restrict__ bias1, float* __restrict__ C1,
                int M, int N, int K, int S) {
    int batch = blockIdx.z / S;
    int s = blockIdx.z - batch * S;
    const u16* Ahi = batch ? Ahi1 : Ahi0;
    const u16* Alo = batch ? Alo1 : Alo0;
    const u16* Bhi = batch ? Bhi1 : Bhi0;
    const u16* Blo = batch ? Blo1 : Blo0;
    const float* bias = batch ? bias1 : bias0;
    float* C = batch ? C1 : C0;

    constexpr int PARTS = (SPLIT == 3) ? 2 : 1;
    __shared__ u16 smA[2 * PARTS * 8 * 512];
    __shared__ u16 smB[2 * PARTS * 8 * 512];

    int tid = threadIdx.x;
    int w = tid >> 6, L = tid & 63;
    int m15 = L & 15, q = L >> 4;
    int KT = K >> 5;
    int rowTile = blockIdx.y * 8, colTile = blockIdx.x * 8;
    int NIT = (K / S) >> 5;
    int kb0 = s * NIT;
    int aw = w & 1, bw = w >> 1;

    f32x4 acc[4][4];
#pragma unroll
    for (int i = 0; i < 4; ++i)
#pragma unroll
        for (int j = 0; j < 4; ++j) acc[i][j] = (f32x4){0.f, 0.f, 0.f, 0.f};

    auto stage = [&](int buf, int kb) {
#pragma unroll
        for (int rl = 0; rl < 2; ++rl) {
            int rb = 2 * w + rl;
            glds16(Ahi + ((size_t)(rowTile + rb) * KT + kb) * 512 + (size_t)L * 8,
                   &smA[((buf * PARTS + 0) * 8 + rb) * 512]);
            glds16(Bhi + ((size_t)(colTile + rb) * KT + kb) * 512 + (size_t)L * 8,
                   &smB[((buf * PARTS + 0) * 8 + rb) * 512]);
            if constexpr (SPLIT == 3) {
                glds16(Alo + ((size_t)(rowTile + rb) * KT + kb) * 512 + (size_t)L * 8,
                       &smA[((buf * PARTS + 1) * 8 + rb) * 512]);
                glds16(Blo + ((size_t)(colTile + rb) * KT + kb) * 512 + (size_t)L * 8,
                       &smB[((buf * PARTS + 1) * 8 + rb) * 512]);
            }
        }
    };

    stage(0, kb0);
    for (int it = 0; it < NIT; ++it) {
        __syncthreads();
        if (it + 1 < NIT) stage((it + 1) & 1, kb0 + it + 1);
        int buf = it & 1;
        short8 ah[4], bh[4];
#pragma unroll
        for (int i = 0; i < 4; ++i) {
            ah[i] = *(const short8*)&smA[((buf * PARTS + 0) * 8 + aw * 4 + i) * 512 + L * 8];
            bh[i] = *(const short8*)&smB[((buf * PARTS + 0) * 8 + bw * 4 + i) * 512 + L * 8];
        }
        if constexpr (SPLIT == 3) {
            short8 al[4], bl[4];
#pragma unroll
            for (int i = 0; i < 4; ++i) {
                al[i] = *(const short8*)&smA[((buf * PARTS + 1) * 8 + aw * 4 + i) * 512 + L * 8];
                bl[i] = *(const short8*)&smB[((buf * PARTS + 1) * 8 + bw * 4 + i) * 512 + L * 8];
            }
#pragma unroll
            for (int i = 0; i < 4; ++i)
#pragma unroll
                for (int j = 0; j < 4; ++j) {
                    acc[i][j] = __builtin_amdgcn_mfma_f32_16x16x32_bf16(ah[i], bl[j], acc[i][j], 0, 0, 0);
                    acc[i][j] = __builtin_amdgcn_mfma_f32_16x16x32_bf16(al[i], bh[j], acc[i][j], 0, 0, 0);
                    acc[i][j] = __builtin_amdgcn_mfma_f32_16x16x32_bf16(ah[i], bh[j], acc[i][j], 0, 0, 0);
                }
        } else {
#pragma unroll
            for (int i = 0; i < 4; ++i)
#pragma unroll
                for (int j = 0; j < 4; ++j)
                    acc[i][j] = __builtin_amdgcn_mfma_f32_16x16x32_bf16(ah[i], bh[j], acc[i][j], 0, 0, 0);
        }
    }

    if constexpr (FINAL == 0) C += (size_t)s * M * N;
#pragma unroll
    for (int i = 0; i < 4; ++i) {
        int row = rowTile * 16 + aw * 64 + i * 16 + q * 4;
#pragma unroll
        for (int j = 0; j < 4; ++j) {
            int col = colTile * 16 + bw * 64 + j * 16 + m15;
            float bv = (FINAL && bias) ? bias[col] : 0.f;
#pragma unroll
            for (int r = 0; r < 4; ++r) {
                float v = acc[i][j][r];
                if constexpr (FINAL) {
                    v += bv;
                    if (ACT == 1) v = fmaxf(v, 0.f);
                    if (ACT == 2) v = 1.f / (1.f + expf(-v));
                }
                C[(size_t)(row + r) * N + col] = v;
            }
        }
    }
}

// ---------------------------------------------------------------------------
// K3b: split-K reduce -> f32 [M][N] with bias/act. Dual pointer sets via blockIdx.y.
// ---------------------------------------------------------------------------
template<int ACT>
__global__ void reduce_f32(const float* __restrict__ P0, const float* __restrict__ bias0,
                           float* __restrict__ C0,
                           const float* __restrict__ P1, const float* __restrict__ bias1,
                           float* __restrict__ C1, int S, int M, int N) {
    const float* P = blockIdx.y ? P1 : P0;
    const float* bias = blockIdx.y ? bias1 : bias0;
    float* C = blockIdx.y ? C1 : C0;
    int idx = blockIdx.x * 256 + threadIdx.x;
    int mn4 = (M * N) >> 2;
    if (idx >= mn4) return;
    f32x4 a = ((const f32x4*)P)[idx];
    for (int s = 1; s < S; ++s) a += ((const f32x4*)P)[(size_t)s * mn4 + idx];
    int col = (idx % (N >> 2)) * 4;
    f32x4 o;
#pragma unroll
    for (int j = 0; j < 4; ++j) {
        float v = a[j] + (bias ? bias[col + j] : 0.f);
        if (ACT == 1) v = fmaxf(v, 0.f);
        if (ACT == 2) v = 1.f / (1.f + expf(-v));
        o[j] = v;
    }
    ((f32x4*)C)[idx] = o;
}

// ---------------------------------------------------------------------------
// K3c: split-K reduce + relu + bias -> split-bf16 TILED (MLP1 hid, M=128, N=HIDN)
// ---------------------------------------------------------------------------
__global__ void reduce_hid(const float* __restrict__ P0, const float* __restrict__ b0,
                           u16* __restrict__ hi0, u16* __restrict__ lo0,
                           const float* __restrict__ P1, const float* __restrict__ b1,
                           u16* __restrict__ hi1, u16* __restrict__ lo1, int S) {
    const float* P = blockIdx.y ? P1 : P0;
    const float* bias = blockIdx.y ? b1 : b0;
    u16* hi = blockIdx.y ? hi1 : hi0;
    u16* lo = blockIdx.y ? lo1 : lo0;
    int idx = blockIdx.x * 256 + threadIdx.x;       // 128*2048/8 = 32768
    int col = (idx & 255) * 8, rowi = idx >> 8;
    size_t base = ((size_t)rowi * HIDN + col) >> 2;
    f32x4 a0 = ((const f32x4*)P)[base], a1 = ((const f32x4*)P)[base + 1];
    for (int s = 1; s < S; ++s) {
        size_t sb = (size_t)s * (128 * HIDN / 4) + base;
        a0 += ((const f32x4*)P)[sb];
        a1 += ((const f32x4*)P)[sb + 1];
    }
    u16x8 h, l;
#pragma unroll
    for (int j = 0; j < 8; ++j) {
        float v = (j < 4 ? a0[j] : a1[j - 4]) + bias[col + j];
        v = fmaxf(v, 0.f);
        u16 hh = f2bf(v);
        h[j] = hh;
        l[j] = f2bf(v - bf2f(hh));
    }
    size_t ob = tiled_off(rowi, col, HIDN);
    *(u16x8*)&hi[ob] = h;
    *(u16x8*)&lo[ob] = l;
}

// ---------------------------------------------------------------------------
// K3d: MLP2 split-K reduce + bias fused with mem_kv concat -> ck/cv [KVH][33][DH]
// ---------------------------------------------------------------------------
__global__ void reduce_ckcv(const float* __restrict__ Pk, const float* __restrict__ Pv,
                            const float* __restrict__ mem_kv,
                            const float* __restrict__ kb2, const float* __restrict__ vb2,
                            float* __restrict__ ck, float* __restrict__ cv, int S) {
    int idx = blockIdx.x * 256 + threadIdx.x;   // 4*33*64 = 8448
    if (idx >= KVH * 33 * DH) return;
    int d = idx & 63;
    int j = (idx >> 6) % 33;
    int h = idx / (33 * 64);
    float kvv, vvv;
    if (j == 0) {
        kvv = mem_kv[(0 * KVH + h) * DH + d];
        vvv = mem_kv[(1 * KVH + h) * DH + d];
    } else {
        size_t base = (size_t)(h * WBLK + (j - 1)) * 128 + d;
        float ak = Pk[base], av = Pv[base];
        for (int s = 1; s < S; ++s) {
            ak += Pk[(size_t)s * (128 * 128) + base];
            av += Pv[(size_t)s * (128 * 128) + base];
        }
        kvv = ak + kb2[d];
        vvv = av + vb2[d];
    }
    ck[idx] = kvv;
    cv[idx] = vvv;
}

// ---------------------------------------------------------------------------
// K5: build compress-MLP inputs -> split-bf16 TILED (K=CDIM)
// ---------------------------------------------------------------------------
__global__ void build_cmlp_in(const float* __restrict__ qkv, const float* __restrict__ k_pos,
                              const float* __restrict__ v_pos,
                              u16* __restrict__ ckhi, u16* __restrict__ cklo,
                              u16* __restrict__ cvhi, u16* __restrict__ cvlo) {
    int idx = blockIdx.x * 256 + threadIdx.x;   // 128 * 256 = 32768
    int k = (idx & 255) * 8;
    int r = idx >> 8;                           // 0..127 = h*W + w
    int p = k >> 6, d = k & 63;
    int h = r >> 5, wb = r & 31;
    int nn = wb * BSZ + p;
    const float* kq = qkv + (size_t)nn * QKVD + (HEADS + h) * DH + d;
    const float* vq = qkv + (size_t)nn * QKVD + (HEADS + KVH + h) * DH + d;
    const float* kp = k_pos + (size_t)(h * BSZ + p) * DH + d;
    const float* vp = v_pos + (size_t)(h * BSZ + p) * DH + d;
    u16x8 kh, kl, vh, vl;
#pragma unroll
    for (int j = 0; j < 8; ++j) {
        float kv = kq[j] + kp[j];
        float vv = vq[j] + vp[j];
        u16 a = f2bf(kv), b = f2bf(vv);
        kh[j] = a; kl[j] = f2bf(kv - bf2f(a));
        vh[j] = b; vl[j] = f2bf(vv - bf2f(b));
    }
    size_t ob = tiled_off(r, k, CDIM);
    *(u16x8*)&ckhi[ob] = kh; *(u16x8*)&cklo[ob] = kl;
    *(u16x8*)&cvhi[ob] = vh; *(u16x8*)&cvlo[ob] = vl;
}

// ---------------------------------------------------------------------------
// K7: interleaved rotary for q (16 heads), k (4 heads) + packed v copy (4 heads)
// ---------------------------------------------------------------------------
__global__ void rotary_kernel(const float* __restrict__ qkv,
                              float* __restrict__ qr, float* __restrict__ kr,
                              float* __restrict__ vr) {
    int idx = blockIdx.x * 256 + threadIdx.x;   // 24*1024*32 = 786432
    int i = idx & 31;
    int n = (idx >> 5) & 1023;
    int hd = idx >> 15;
    if (hd >= 24) return;
    if (hd >= HEADS + KVH) {       // packed v copy
        int h = hd - (HEADS + KVH);
        const float* src = qkv + (size_t)n * QKVD + (HEADS + KVH + h) * DH;
        float* dst = vr + ((size_t)h * NTOK + n) * DH;
        dst[2 * i] = src[2 * i];
        dst[2 * i + 1] = src[2 * i + 1];
        return;
    }
    float inv = powf(10000.f, -(float)i / 32.f);
    float fr = (float)n * inv;
    float c = cosf(fr), s = sinf(fr);
    const float* src; float* dst;
    if (hd < HEADS) { src = qkv + (size_t)n * QKVD + hd * DH;          dst = qr + ((size_t)hd * NTOK + n) * DH; }
    else { int h = hd - HEADS;
           src = qkv + (size_t)n * QKVD + (HEADS + h) * DH;            dst = kr + ((size_t)h * NTOK + n) * DH; }
    float x0 = src[2 * i], x1 = src[2 * i + 1];
    dst[2 * i]     = x0 * c - x1 * s;
    dst[2 * i + 1] = x1 * c + x0 * s;
}

// ---------------------------------------------------------------------------
// K8: compressed attention + importance + top-k. 4 tokens per 256-thr block.
// ---------------------------------------------------------------------------
__global__ __launch_bounds__(256)
void cattn_kernel(const float* __restrict__ qkv, const float* __restrict__ ck,
                  const float* __restrict__ cv, float* __restrict__ c_out,
                  int* __restrict__ sel, int* __restrict__ selmask) {
    int h = blockIdx.y;
    int tid = threadIdx.x;
    int w = tid >> 6, lane = tid & 63;
    int grp = lane >> 4, sub = lane & 15;
    int n = blockIdx.x * 4 + w;
    __shared__ float cks[33 * 68];
    __shared__ float cvs[33 * 68];
    __shared__ float sims[16 * 36];      // [w*4+g][j]

    for (int t4 = tid; t4 < 1056; t4 += 256) {
        int half = (t4 >= 528) ? 1 : 0;
        int u = t4 - half * 528;
        int j = u >> 4, d4 = (u & 15) * 4;
        const float* src = (half ? cv : ck) + (size_t)h * 33 * 64 + j * 64 + d4;
        float* dst = (half ? cvs : cks) + j * 68 + d4;
        *(float4*)dst = *(const float4*)src;
    }
    float qreg[64];
    {
        const float4* qp4 = (const float4*)(qkv + (size_t)n * QKVD + (h * GQ + grp) * DH);
#pragma unroll
        for (int c = 0; c < 16; ++c) {
            float4 v = qp4[c];
            qreg[4 * c] = v.x; qreg[4 * c + 1] = v.y; qreg[4 * c + 2] = v.z; qreg[4 * c + 3] = v.w;
        }
    }
    __syncthreads();

#pragma unroll
    for (int r = 0; r < 3; ++r) {
        int j = r * 16 + sub;
        if (j < 33) {
            float acc = 0.f;
#pragma unroll
            for (int d = 0; d < 64; ++d) acc = fmaf(qreg[d], cks[j * 68 + d], acc);
            sims[(w * 4 + grp) * 36 + j] = acc * SCALE;
        }
    }

    float ival = NEGINF;
    if (lane < 32)
        ival = 0.25f * (sims[(w * 4 + 0) * 36 + 1 + lane] + sims[(w * 4 + 1) * 36 + 1 + lane] +
                        sims[(w * 4 + 2) * 36 + 1 + lane] + sims[(w * 4 + 3) * 36 + 1 + lane]);
    float m = ival;
    for (int off = 32; off; off >>= 1) m = fmaxf(m, __shfl_xor(m, off));
    float e = (lane < 32) ? expf(ival - m) : 0.f;
    float sum = e;
    for (int off = 32; off; off >>= 1) sum += __shfl_xor(sum, off);
    float p = (lane < 32) ? e / sum : NEGINF;

    float v = p;
    int base = (h * NTOK + n) * 9;
    for (int t = 0; t < NSEL; ++t) {
        float bv = v; int bi = lane;
        for (int off = 32; off; off >>= 1) {
            float ov = __shfl_xor(bv, off);
            int   oi = __shfl_xor(bi, off);
            if (ov > bv || (ov == bv && oi < bi)) { bv = ov; bi = oi; }
        }
        if (lane == 0) { sel[base + t] = bi; selmask[base + t] = (bv > 1e-10f) ? 1 : 0; }
        if (lane == bi) v = NEGINF;
    }
    if (lane == 0) { sel[base + NSEL] = n >> 5; selmask[base + NSEL] = 1; }

#pragma unroll
    for (int g = 0; g < 4; ++g) {
        float sv = (lane < 33) ? sims[(w * 4 + g) * 36 + lane] : NEGINF;
        float mm = sv;
        for (int off = 32; off; off >>= 1) mm = fmaxf(mm, __shfl_xor(mm, off));
        float ee = (lane < 33) ? __expf(sv - mm) : 0.f;
        float ssum = ee;
        for (int off = 32; off; off >>= 1) ssum += __shfl_xor(ssum, off);
        if (lane < 33) sims[(w * 4 + g) * 36 + lane] = ee / ssum;
    }

    f32x4 o = (f32x4){0.f, 0.f, 0.f, 0.f};
#pragma unroll
    for (int j = 0; j < 33; ++j) {
        float a = sims[(w * 4 + grp) * 36 + j];
        f32x4 vv = *(const f32x4*)&cvs[j * 68 + sub * 4];
        o += a * vv;
    }
    *(f32x4*)&c_out[(((size_t)(h * GQ + grp)) * NTOK + n) * DH + sub * 4] = o;
}

// ---------------------------------------------------------------------------
// K9: fine attention v14 — barrier-free loop via split-softmax partials.
// R6 post-mortem: v13 (71.2us) removed 2 of 4 loop barriers, gained 7%.
// VALUBusy DROPPED to 39% while time improved -> still latency/sync-bound on
// the remaining 2 all-wave barriers (ssc exchange + ps exchange per iter).
// v14: flash-attention split-K merge. Each 16-lane group keeps a PRIVATE
// online-softmax state (m,l) for its (head grp, j-slice w): scores reduce
// over the 16-group (__shfl_xor 8,4,2,1), p goes to a WAVE-PRIVATE ps row,
// PV reads own rows + own ps. Every loop phase is wave-private (staging,
// scores, softmax, PV) -> ZERO __syncthreads in the loop; waves drift freely
// and hide each other's glds latency. Epilogue merges the 4 partials:
// M=max m_w; o = sum_w o_w*exp(m_w-M) / sum_w l_w*exp(m_w-M). Empty slices:
// m_w=-3.4e38 -> exp underflows to 0 (own block guarantees finite M, L>0).
// Wave-local hazards ordered by s_waitcnt + sched_barrier(0) (rule #18).
// Barriers/block: 13 -> 3. absmax may shift slightly (split-merge reassoc).
// ---------------------------------------------------------------------------
__global__ void fattn_kernel(const float* __restrict__ qr, const float* __restrict__ kr,
                             const float* __restrict__ vr, const int* __restrict__ sel,
                             const int* __restrict__ selmask, float* __restrict__ f_out) {
    int n = blockIdx.x, h = blockIdx.y;
    int tid = threadIdx.x;
    int w = tid >> 6, lane = tid & 63;
    int grp = lane >> 4, sub = lane & 15;
    __shared__ float qsm[4 * 68];
    __shared__ float KV[64 * 64];        // K then V each pair; slot s of row r = global slot s^(r&15)
    __shared__ float ps[4 * 68];         // wave-private p rows: ps[w][g*16+sub]
    __shared__ float msm[16], lsm[16];   // [slice w * 4 + head g]
    __shared__ int sel_s[9], msk_s[9];

    if (tid < 9) {
        sel_s[tid] = sel[(h * NTOK + n) * 9 + tid];
        msk_s[tid] = selmask[(h * NTOK + n) * 9 + tid];
    }
    // q -> LDS once: wave w loads head w's 64 elements
    qsm[w * 68 + lane] = qr[(((size_t)(h * GQ + w)) * NTOK + n) * DH + lane];
    f32x4 o4 = (f32x4){0.f, 0.f, 0.f, 0.f};   // partial over (head grp, slice w), dims sub*4..+3
    float m_run = -3.402823466e38f, l_run = 0.f;
    __syncthreads();                     // B0: sel_s + qsm ready

    const float* krh_ = kr + (size_t)h * NTOK * DH;
    const float* vrh_ = vr + (size_t)h * NTOK * DH;

    // staging geometry: wave w stages rows [w*16, w*16+16); glds chunk cc = 4 rows.
    // lane L -> row_local rl = L>>4, slot sl = L&15 (dest linear: base + L*16B);
    // source slot = sl ^ (r&15) so that read with slot = c ^ (row&15) is identity.
    int rl = lane >> 4, sl = lane & 15;

    auto stageRows = [&](const float* src, int bp) {
        int nrow = (bp < 4) ? 64 : 32;
        if (w * 16 < nrow) {
            int myblk = sel_s[bp * 2 + (w >> 1)];
            const float* b_ = src + (size_t)myblk * BSZ * DH;
#pragma unroll
            for (int cc = 0; cc < 4; ++cc) {
                int r = w * 16 + cc * 4 + rl;
                int sg = sl ^ (r & 15);
                glds16(b_ + (size_t)(r & 31) * DH + sg * 4, &KV[(w * 16 + cc * 4) * 64]);
            }
        }
    };

    stageRows(krh_, 0);                  // prologue: K(0), wave-private

    for (int bp = 0; bp < 5; ++bp) {
        int nrow = (bp < 4) ? 64 : 32;

        // wave-local: own K rows staged
        asm volatile("s_waitcnt vmcnt(0)" ::: "memory");
        __builtin_amdgcn_sched_barrier(0);

        // ---- scores: thread (grp, jj=w*16+sub) reads OWN-wave rows only
        float s = -3.402823466e38f;
        {
            int jj = w * 16 + sub;
            int b = bp * 2 + (jj >> 5);
            if (jj < nrow && msk_s[b]) {
                int sw = jj & 15;
                const float* Kb = &KV[jj * 64];
                float acc = 0.f;
#pragma unroll
                for (int c = 0; c < 16; ++c) {
                    f32x4 k4 = *(const f32x4*)&Kb[(c ^ sw) * 4];
                    f32x4 q4 = *(const f32x4*)&qsm[grp * 68 + c * 4];
                    acc = fmaf(q4[0], k4[0], acc);
                    acc = fmaf(q4[1], k4[1], acc);
                    acc = fmaf(q4[2], k4[2], acc);
                    acc = fmaf(q4[3], k4[3], acc);
                }
                s = acc * SCALE;
            }
        }
        // ---- in-register online softmax over the 16-lane group (head grp, slice w)
        float mb = s;
        for (int off = 8; off; off >>= 1) mb = fmaxf(mb, __shfl_xor(mb, off));
        float m_new = fmaxf(m_run, mb);
        float pp = (s > -1e37f) ? __expf(s - m_new) : 0.f;
        float alpha = __expf(m_run - m_new);   // ==1 when slice empty (both -3.4e38)
        float psum = pp;
        for (int off = 8; off; off >>= 1) psum += __shfl_xor(psum, off);
        l_run = l_run * alpha + psum;
        m_run = m_new;
        ps[w * 68 + grp * 16 + sub] = pp;      // wave-private row

        // retire our K ds_reads + ps ds_write before overwriting own rows with V
        __builtin_amdgcn_sched_barrier(0);
        asm volatile("s_waitcnt lgkmcnt(0)" ::: "memory");
        __builtin_amdgcn_sched_barrier(0);
        stageRows(vrh_, bp);

        asm volatile("s_waitcnt vmcnt(0)" ::: "memory");   // V staged (wave-local)
        __builtin_amdgcn_sched_barrier(0);

        // ---- PV: wave w reads OWN rows + OWN ps; thread (g=grp, c=sub)
        o4 *= alpha;
        {
            int jbase = w * 16;
            if (jbase < nrow) {
#pragma unroll
                for (int jq = 0; jq < 4; ++jq) {
                    f32x4 p4 = *(const f32x4*)&ps[w * 68 + grp * 16 + jq * 4];
#pragma unroll
                    for (int r = 0; r < 4; ++r) {
                        int row = jbase + jq * 4 + r;
                        int slot = sub ^ (row & 15);
                        f32x4 vv = *(const f32x4*)&KV[row * 64 + slot * 4];
                        o4 += p4[r] * vv;
                    }
                }
            }
        }
        // retire PV ds_reads before overwriting own rows with next K
        if (bp < 4) {
            __builtin_amdgcn_sched_barrier(0);
            asm volatile("s_waitcnt lgkmcnt(0)" ::: "memory");
            __builtin_amdgcn_sched_barrier(0);
            stageRows(krh_, bp + 1);
        }
    }
    // ---- epilogue: split-softmax merge of the 4 slice-partials per head
    if (sub == 0) { msm[w * 4 + grp] = m_run; lsm[w * 4 + grp] = l_run; }
    __syncthreads();                      // all loops done -> KV free; msm/lsm visible
    *(f32x4*)&KV[(w * 4 + grp) * 64 + sub * 4] = o4;
    __syncthreads();
    // thread: head = w, dim = lane
    float m0 = msm[0 * 4 + w], m1 = msm[1 * 4 + w], m2 = msm[2 * 4 + w], m3 = msm[3 * 4 + w];
    float M = fmaxf(fmaxf(m0, m1), fmaxf(m2, m3));
    float f0 = __expf(m0 - M), f1 = __expf(m1 - M), f2 = __expf(m2 - M), f3 = __expf(m3 - M);
    float L = lsm[0 * 4 + w] * f0 + lsm[1 * 4 + w] * f1 + lsm[2 * 4 + w] * f2 + lsm[3 * 4 + w] * f3;
    float sum = KV[(0 * 4 + w) * 64 + lane] * f0 + KV[(1 * 4 + w) * 64 + lane] * f1
              + KV[(2 * 4 + w) * 64 + lane] * f2 + KV[(3 * 4 + w) * 64 + lane] * f3;
    f_out[(((size_t)(h * GQ + w)) * NTOK + n) * DH + lane] = sum / L;
}

// ---------------------------------------------------------------------------
// K10: gated mix -> split-bf16 TILED (K=DDIM). gates f32 [N][128] padded.
// ---------------------------------------------------------------------------
__global__ void mix_kernel(const float* __restrict__ gates, const float* __restrict__ c_out,
                           const float* __restrict__ f_out,
                           u16* __restrict__ mixhi, u16* __restrict__ mixlo) {
    int idx = blockIdx.x * 256 + threadIdx.x;   // 1024*1024/8 = 131072
    int col = (idx & 127) * 8;
    int n = idx >> 7;
    int hd = col >> 6, d = col & 63;
    float g0 = gates[(size_t)n * 128 + hd * 2];
    float g1 = gates[(size_t)n * 128 + hd * 2 + 1];
    size_t hoff = (((size_t)hd) * NTOK + n) * DH + d;
    u16x8 h, l;
#pragma unroll
    for (int j = 0; j < 8; ++j) {
        float v = g0 * c_out[hoff + j] + g1 * f_out[hoff + j];
        u16 hh = f2bf(v);
        h[j] = hh;
        l[j] = f2bf(v - bf2f(hh));
    }
    size_t ob = tiled_off(n, col, DDIM);
    *(u16x8*)&mixhi[ob] = h;
    *(u16x8*)&mixlo[ob] = l;
}

// ---------------------------------------------------------------------------
extern "C" void kernel_launch(void* const* d_in, const int* in_sizes, int n_in,
                              void* d_out, int out_size, void* d_ws, size_t ws_size,
                              hipStream_t stream) {
    const float* inp    = (const float*)d_in[0];
    const float* g_norm = (const float*)d_in[1];
    const float* w_qkv  = (const float*)d_in[2];
    const float* mem_kv = (const float*)d_in[3];
    const float* k_pos  = (const float*)d_in[4];
    const float* v_pos  = (const float*)d_in[5];
    const float* k_w1   = (const float*)d_in[6];
    const float* k_b1   = (const float*)d_in[7];
    const float* k_w2   = (const float*)d_in[8];
    const float* k_b2   = (const float*)d_in[9];
    const float* v_w1   = (const float*)d_in[10];
    const float* v_b1   = (const float*)d_in[11];
    const float* v_w2   = (const float*)d_in[12];
    const float* v_b2   = (const float*)d_in[13];
    const float* gate_w = (const float*)d_in[14];
    const float* gate_b = (const float*)d_in[15];
    const float* w_out  = (const float*)d_in[16];
    float* out = (float*)d_out;

    char* wsb = (char*)d_ws;
    size_t off = 0;
    auto alloc = [&](size_t bytes) -> void* {
        void* p = wsb + off;
        off = (off + bytes + 255) & ~(size_t)255;
        return p;
    };
    u16*   xhi    = (u16*)  alloc((size_t)NTOK * DDIM * 2);
    u16*   xlo    = (u16*)  alloc((size_t)NTOK * DDIM * 2);
    float* qkvb   = (float*)alloc((size_t)NTOK * QKVD * 4);
    u16*   wqThi  = (u16*)  alloc((size_t)QKVD * DDIM * 2);
    u16*   wqTlo  = (u16*)  alloc((size_t)QKVD * DDIM * 2);
    u16*   kw1Thi = (u16*)  alloc((size_t)HIDN * CDIM * 2);
    u16*   kw1Tlo = (u16*)  alloc((size_t)HIDN * CDIM * 2);
    u16*   vw1Thi = (u16*)  alloc((size_t)HIDN * CDIM * 2);
    u16*   vw1Tlo = (u16*)  alloc((size_t)HIDN * CDIM * 2);
    u16*   woThi  = (u16*)  alloc((size_t)DDIM * DDIM * 2);
    u16*   gwThi  = (u16*)  alloc((size_t)128 * DDIM * 2);
    u16*   gwTlo  = (u16*)  alloc((size_t)128 * DDIM * 2);
    float* gbp    = (float*)alloc(128 * 4);
    u16*   kw2Thi = (u16*)  alloc((size_t)128 * HIDN * 2);
    u16*   kw2Tlo = (u16*)  alloc((size_t)128 * HIDN * 2);
    float* kb2p   = (float*)alloc(128 * 4);
    u16*   vw2Thi = (u16*)  alloc((size_t)128 * HIDN * 2);
    u16*   vw2Tlo = (u16*)  alloc((size_t)128 * HIDN * 2);
    float* vb2p   = (float*)alloc(128 * 4);
    u16*   cinkhi = (u16*)  alloc((size_t)128 * CDIM * 2);
    u16*   cinklo = (u16*)  alloc((size_t)128 * CDIM * 2);
    u16*   cinvhi = (u16*)  alloc((size_t)128 * CDIM * 2);
    u16*   cinvlo = (u16*)  alloc((size_t)128 * CDIM * 2);
    u16*   hidkhi = (u16*)  alloc((size_t)128 * HIDN * 2);
    u16*   hidklo = (u16*)  alloc((size_t)128 * HIDN * 2);
    u16*   hidvhi = (u16*)  alloc((size_t)128 * HIDN * 2);
    u16*   hidvlo = (u16*)  alloc((size_t)128 * HIDN * 2);
    float* Pg     = (float*)alloc((size_t)8 * NTOK * 128 * 4);
    float* Pm1k   = (float*)alloc((size_t)4 * 128 * HIDN * 4);
    float* Pm1v   = (float*)alloc((size_t)4 * 128 * HIDN * 4);
    float* Pm2k   = (float*)alloc((size_t)8 * 128 * 128 * 4);
    float* Pm2v   = (float*)alloc((size_t)8 * 128 * 128 * 4);
    float* ck     = (float*)alloc((size_t)KVH * 33 * DH * 4);
    float* cv     = (float*)alloc((size_t)KVH * 33 * DH * 4);
    float* qr     = (float*)alloc((size_t)HEADS * NTOK * DH * 4);
    float* kr     = (float*)alloc((size_t)KVH * NTOK * DH * 4);
    float* vr     = (float*)alloc((size_t)KVH * NTOK * DH * 4);
    float* c_out  = (float*)alloc((size_t)HEADS * NTOK * DH * 4);
    float* f_out  = (float*)alloc((size_t)HEADS * NTOK * DH * 4);
    float* gates  = (float*)alloc((size_t)NTOK * 128 * 4);
    int*   sel    = (int*)  alloc((size_t)KVH * NTOK * 9 * 4);
    int*   selmask= (int*)  alloc((size_t)KVH * NTOK * 9 * 4);
    u16*   mixhi  = (u16*)  alloc((size_t)NTOK * DDIM * 2);
    u16*   mixlo  = (u16*)  alloc((size_t)NTOK * DDIM * 2);

    // weight prep (tiled layouts)
    transpose_split<<<dim3(QKVD / 64, DDIM / 64), 256, 0, stream>>>(w_qkv, wqThi, wqTlo, DDIM, QKVD);
    transpose_split<<<dim3(HIDN / 64, CDIM / 64), 256, 0, stream>>>(k_w1, kw1Thi, kw1Tlo, CDIM, HIDN);
    transpose_split<<<dim3(HIDN / 64, CDIM / 64), 256, 0, stream>>>(v_w1, vw1Thi, vw1Tlo, CDIM, HIDN);
    transpose_split<<<dim3(DDIM / 64, DDIM / 64), 256, 0, stream>>>(w_out, woThi, nullptr, DDIM, DDIM);
    pad_small_tiled<<<(128 * DDIM / 8) / 256, 256, 0, stream>>>(gate_w, gate_b, gwThi, gwTlo, gbp, DDIM, 32, 10);
    pad_small_tiled<<<(128 * HIDN / 8) / 256, 256, 0, stream>>>(k_w2, k_b2, kw2Thi, kw2Tlo, kb2p, HIDN, 64, 11);
    pad_small_tiled<<<(128 * HIDN / 8) / 256, 256, 0, stream>>>(v_w2, v_b2, vw2Thi, vw2Tlo, vb2p, HIDN, 64, 11);

    // 1. RMSNorm -> tiled split-bf16 x
    rmsnorm_kernel<<<NTOK / 2, 256, 0, stream>>>(inp, g_norm, xhi, xlo);
    // 2. qkv = x @ w_qkv (final f32)
    gemm_tiled<3, 0, 1><<<dim3(QKVD / 128, NTOK / 128, 1), 256, 0, stream>>>(
        xhi, xlo, wqThi, wqTlo, nullptr, qkvb,
        xhi, xlo, wqThi, wqTlo, nullptr, qkvb, NTOK, QKVD, DDIM, 1);
    // 3. gates (split-K 8 + sigmoid reduce)
    gemm_tiled<3, 0, 0><<<dim3(1, NTOK / 128, 8), 256, 0, stream>>>(
        xhi, xlo, gwThi, gwTlo, nullptr, Pg,
        xhi, xlo, gwThi, gwTlo, nullptr, Pg, NTOK, 128, DDIM, 8);
    reduce_f32<2><<<dim3(128, 1), 256, 0, stream>>>(Pg, gbp, gates, Pg, gbp, gates, 8, NTOK, 128);
    // 4. compress-MLP inputs (tiled)
    build_cmlp_in<<<128, 256, 0, stream>>>(qkvb, k_pos, v_pos, cinkhi, cinklo, cinvhi, cinvlo);
    // 5. MLP1 (split-K 4, k&v batched; relu+bias+split-tile in reduce)
    gemm_tiled<3, 0, 0><<<dim3(HIDN / 128, 1, 8), 256, 0, stream>>>(
        cinkhi, cinklo, kw1Thi, kw1Tlo, nullptr, Pm1k,
        cinvhi, cinvlo, vw1Thi, vw1Tlo, nullptr, Pm1v, 128, HIDN, CDIM, 4);
    reduce_hid<<<dim3(128, 2), 256, 0, stream>>>(Pm1k, k_b1, hidkhi, hidklo,
                                                 Pm1v, v_b1, hidvhi, hidvlo, 4);
    // 6. MLP2 (split-K 8, k&v batched) + fused reduce/bias/concat
    gemm_tiled<3, 0, 0><<<dim3(1, 1, 16), 256, 0, stream>>>(
        hidkhi, hidklo, kw2Thi, kw2Tlo, nullptr, Pm2k,
        hidvhi, hidvlo, vw2Thi, vw2Tlo, nullptr, Pm2v, 128, 128, HIDN, 8);
    reduce_ckcv<<<33, 256, 0, stream>>>(Pm2k, Pm2v, mem_kv, kb2p, vb2p, ck, cv, 8);
    // 8. rotary + packed v
    rotary_kernel<<<(24 * NTOK * 32) / 256, 256, 0, stream>>>(qkvb, qr, kr, vr);
    // 9. compressed attention + selection (4 tokens per block)
    cattn_kernel<<<dim3(NTOK / 4, KVH), 256, 0, stream>>>(qkvb, ck, cv, c_out, sel, selmask);
    // 10. fine attention (v14: barrier-free loop, split-softmax merge)
    fattn_kernel<<<dim3(NTOK, KVH), 256, 0, stream>>>(qr, kr, vr, sel, selmask, f_out);
    // 11. gated mix -> tiled split-bf16
    mix_kernel<<<(NTOK * DDIM / 8) / 256, 256, 0, stream>>>(gates, c_out, f_out, mixhi, mixlo);
    // 12. output projection (bf16, final)
    gemm_tiled<1, 0, 1><<<dim3(DDIM / 128, NTOK / 128, 1), 256, 0, stream>>>(
        mixhi, mixhi, woThi, woThi, nullptr, out,
        mixhi, mixhi, woThi, woThi, nullptr, out, NTOK, DDIM, DDIM, 1);
}

// Round 8
// 345.291 us; speedup vs baseline: 1.1048x; 1.0042x over previous
//
#include <hip/hip_runtime.h>
#include <math.h>

// ---- fixed problem sizes ----
#define NTOK 1024
#define DDIM 1024
#define HEADS 16
#define KVH 4
#define DH 64
#define BSZ 32
#define NSEL 8
#define WBLK 32            // NTOK / BSZ
#define GQ 4               // HEADS / KVH
#define CDIM 2048          // BSZ*DH
#define HIDN 2048
#define QKVD 1536          // (HEADS + 2*KVH)*DH
#define SCALE 0.125f       // DH^-0.5
#define NEGINF (-__builtin_inff())

typedef unsigned short u16;
typedef u16   u16x8  __attribute__((ext_vector_type(8)));
typedef short short8 __attribute__((ext_vector_type(8)));
typedef float f32x4  __attribute__((ext_vector_type(4)));

__device__ __forceinline__ u16 f2bf(float f) {
    unsigned u = __float_as_uint(f);
    return (u16)((u + 0x7fffu + ((u >> 16) & 1u)) >> 16);
}
__device__ __forceinline__ float bf2f(u16 h) { return __uint_as_float(((unsigned)h) << 16); }

__device__ __forceinline__ void glds16(const void* g, void* l) {
    __builtin_amdgcn_global_load_lds(
        (const __attribute__((address_space(1))) unsigned int*)g,
        (__attribute__((address_space(3))) unsigned int*)l, 16, 0, 0);
}

// element offset (in u16) of the 8-element lane-slot for (row, k..k+7) in the
// MFMA-fragment-tiled layout: 16-row x 32-k tiles, 1KB each, contiguous.
__device__ __forceinline__ size_t tiled_off(int row, int k, int K) {
    return ((size_t)((row >> 4) * (K >> 5) + (k >> 5)) * 64 +
            ((row & 15) | (((k >> 3) & 3) << 4))) * 8;
}

// ---------------------------------------------------------------------------
// K1: RMSNorm -> split-bf16 x in TILED layout (K=DDIM). 2 rows per 256-thr block.
// ---------------------------------------------------------------------------
__global__ void rmsnorm_kernel(const float* __restrict__ inp, const float* __restrict__ g,
                               u16* __restrict__ xhi, u16* __restrict__ xlo) {
    int t = threadIdx.x;
    int half = t >> 7, tid = t & 127;
    int n = blockIdx.x * 2 + half;
    const float4* row = (const float4*)(inp + (size_t)n * DDIM);
    float4 v0 = row[tid * 2], v1 = row[tid * 2 + 1];
    float ss = v0.x*v0.x + v0.y*v0.y + v0.z*v0.z + v0.w*v0.w
             + v1.x*v1.x + v1.y*v1.y + v1.z*v1.z + v1.w*v1.w;
    for (int off = 32; off; off >>= 1) ss += __shfl_down(ss, off);
    __shared__ float red[4];
    if ((t & 63) == 0) red[t >> 6] = ss;
    __syncthreads();
    float tot = red[half * 2] + red[half * 2 + 1];
    float r = 1.f / sqrtf(tot * (1.f / DDIM) + 1e-6f);
    const float4* gp = (const float4*)g;
    float4 g0 = gp[tid * 2], g1 = gp[tid * 2 + 1];
    float o[8] = { v0.x*r*g0.x, v0.y*r*g0.y, v0.z*r*g0.z, v0.w*r*g0.w,
                   v1.x*r*g1.x, v1.y*r*g1.y, v1.z*r*g1.z, v1.w*r*g1.w };
    u16x8 h, l;
#pragma unroll
    for (int i = 0; i < 8; ++i) {
        u16 hh = f2bf(o[i]);
        h[i] = hh;
        l[i] = f2bf(o[i] - bf2f(hh));
    }
    size_t ob = tiled_off(n, tid * 8, DDIM);
    *(u16x8*)&xhi[ob] = h;
    *(u16x8*)&xlo[ob] = l;
}

// ---------------------------------------------------------------------------
// K2: weight transpose + split: W[K][N] f32 -> tiled Bt[N][K] bf16 hi/lo
// ---------------------------------------------------------------------------
__global__ void transpose_split(const float* __restrict__ W, u16* __restrict__ Thi,
                                u16* __restrict__ Tlo, int K, int N) {
    __shared__ float tile[64][65];
    int k0 = blockIdx.y * 64, n0 = blockIdx.x * 64;
    int t = threadIdx.x;
    int r = t >> 4, c4 = (t & 15) * 4;
#pragma unroll
    for (int p = 0; p < 4; ++p) {
        float4 v = *(const float4*)&W[(size_t)(k0 + r + p * 16) * N + n0 + c4];
        tile[r + p * 16][c4 + 0] = v.x;
        tile[r + p * 16][c4 + 1] = v.y;
        tile[r + p * 16][c4 + 2] = v.z;
        tile[r + p * 16][c4 + 3] = v.w;
    }
    __syncthreads();
    int n = t >> 2, ks = (t & 3) * 16;
#pragma unroll
    for (int c = 0; c < 2; ++c) {
        u16x8 h, l;
#pragma unroll
        for (int j = 0; j < 8; ++j) {
            float v = tile[ks + c * 8 + j][n];
            u16 hh = f2bf(v);
            h[j] = hh;
            l[j] = f2bf(v - bf2f(hh));
        }
        size_t ob = tiled_off(n0 + n, k0 + ks + c * 8, K);
        *(u16x8*)&Thi[ob] = h;
        if (Tlo) *(u16x8*)&Tlo[ob] = l;
    }
}

// ---------------------------------------------------------------------------
// K2b: pad small weights [K][Xn] (Xn<=64) -> tiled split-bf16 [128][K] + padded bias
// ---------------------------------------------------------------------------
__global__ void pad_small_tiled(const float* __restrict__ W, const float* __restrict__ b,
                                u16* __restrict__ Thi, u16* __restrict__ Tlo,
                                float* __restrict__ bias_pad, int K, int Xn, int KLOG) {
    int idx = blockIdx.x * 256 + threadIdx.x;   // 128 * K/8
    int k = (idx & ((K >> 3) - 1)) * 8;
    int n = idx >> (KLOG - 3);
    if (n >= 128) return;
    u16x8 h, l;
#pragma unroll
    for (int j = 0; j < 8; ++j) {
        float v = (n < Xn) ? W[(size_t)(k + j) * Xn + n] : 0.f;
        u16 hh = f2bf(v);
        h[j] = hh;
        l[j] = f2bf(v - bf2f(hh));
    }
    size_t ob = tiled_off(n, k, K);
    *(u16x8*)&Thi[ob] = h;
    *(u16x8*)&Tlo[ob] = l;
    if (k == 0) bias_pad[n] = (n < Xn) ? b[n] : 0.f;
}

// ---------------------------------------------------------------------------
// K3: tiled MFMA GEMM with software pipeline + optional split-K.
// ---------------------------------------------------------------------------
template<int SPLIT, int ACT, int FINAL>
__global__ __launch_bounds__(256, 1)
void gemm_tiled(const u16* __restrict__ Ahi0, const u16* __restrict__ Alo0,
                const u16* __restrict__ Bhi0, const u16* __restrict__ Blo0,
                const float* __restrict__ bias0, float* __restrict__ C0,
                const u16* __restrict__ Ahi1, const u16* __restrict__ Alo1,
                const u16* __restrict__ Bhi1, const u16* __restrict__ Blo1,
                const float* __restrict__ bias1, float* __restrict__ C1,
                int M, int N, int K, int S) {
    int batch = blockIdx.z / S;
    int s = blockIdx.z - batch * S;
    const u16* Ahi = batch ? Ahi1 : Ahi0;
    const u16* Alo = batch ? Alo1 : Alo0;
    const u16* Bhi = batch ? Bhi1 : Bhi0;
    const u16* Blo = batch ? Blo1 : Blo0;
    const float* bias = batch ? bias1 : bias0;
    float* C = batch ? C1 : C0;

    constexpr int PARTS = (SPLIT == 3) ? 2 : 1;
    __shared__ u16 smA[2 * PARTS * 8 * 512];
    __shared__ u16 smB[2 * PARTS * 8 * 512];

    int tid = threadIdx.x;
    int w = tid >> 6, L = tid & 63;
    int m15 = L & 15, q = L >> 4;
    int KT = K >> 5;
    int rowTile = blockIdx.y * 8, colTile = blockIdx.x * 8;
    int NIT = (K / S) >> 5;
    int kb0 = s * NIT;
    int aw = w & 1, bw = w >> 1;

    f32x4 acc[4][4];
#pragma unroll
    for (int i = 0; i < 4; ++i)
#pragma unroll
        for (int j = 0; j < 4; ++j) acc[i][j] = (f32x4){0.f, 0.f, 0.f, 0.f};

    auto stage = [&](int buf, int kb) {
#pragma unroll
        for (int rl = 0; rl < 2; ++rl) {
            int rb = 2 * w + rl;
            glds16(Ahi + ((size_t)(rowTile + rb) * KT + kb) * 512 + (size_t)L * 8,
                   &smA[((buf * PARTS + 0) * 8 + rb) * 512]);
            glds16(Bhi + ((size_t)(colTile + rb) * KT + kb) * 512 + (size_t)L * 8,
                   &smB[((buf * PARTS + 0) * 8 + rb) * 512]);
            if constexpr (SPLIT == 3) {
                glds16(Alo + ((size_t)(rowTile + rb) * KT + kb) * 512 + (size_t)L * 8,
                       &smA[((buf * PARTS + 1) * 8 + rb) * 512]);
                glds16(Blo + ((size_t)(colTile + rb) * KT + kb) * 512 + (size_t)L * 8,
                       &smB[((buf * PARTS + 1) * 8 + rb) * 512]);
            }
        }
    };

    stage(0, kb0);
    for (int it = 0; it < NIT; ++it) {
        __syncthreads();
        if (it + 1 < NIT) stage((it + 1) & 1, kb0 + it + 1);
        int buf = it & 1;
        short8 ah[4], bh[4];
#pragma unroll
        for (int i = 0; i < 4; ++i) {
            ah[i] = *(const short8*)&smA[((buf * PARTS + 0) * 8 + aw * 4 + i) * 512 + L * 8];
            bh[i] = *(const short8*)&smB[((buf * PARTS + 0) * 8 + bw * 4 + i) * 512 + L * 8];
        }
        if constexpr (SPLIT == 3) {
            short8 al[4], bl[4];
#pragma unroll
            for (int i = 0; i < 4; ++i) {
                al[i] = *(const short8*)&smA[((buf * PARTS + 1) * 8 + aw * 4 + i) * 512 + L * 8];
                bl[i] = *(const short8*)&smB[((buf * PARTS + 1) * 8 + bw * 4 + i) * 512 + L * 8];
            }
#pragma unroll
            for (int i = 0; i < 4; ++i)
#pragma unroll
                for (int j = 0; j < 4; ++j) {
                    acc[i][j] = __builtin_amdgcn_mfma_f32_16x16x32_bf16(ah[i], bl[j], acc[i][j], 0, 0, 0);
                    acc[i][j] = __builtin_amdgcn_mfma_f32_16x16x32_bf16(al[i], bh[j], acc[i][j], 0, 0, 0);
                    acc[i][j] = __builtin_amdgcn_mfma_f32_16x16x32_bf16(ah[i], bh[j], acc[i][j], 0, 0, 0);
                }
        } else {
#pragma unroll
            for (int i = 0; i < 4; ++i)
#pragma unroll
                for (int j = 0; j < 4; ++j)
                    acc[i][j] = __builtin_amdgcn_mfma_f32_16x16x32_bf16(ah[i], bh[j], acc[i][j], 0, 0, 0);
        }
    }

    if constexpr (FINAL == 0) C += (size_t)s * M * N;
#pragma unroll
    for (int i = 0; i < 4; ++i) {
        int row = rowTile * 16 + aw * 64 + i * 16 + q * 4;
#pragma unroll
        for (int j = 0; j < 4; ++j) {
            int col = colTile * 16 + bw * 64 + j * 16 + m15;
            float bv = (FINAL && bias) ? bias[col] : 0.f;
#pragma unroll
            for (int r = 0; r < 4; ++r) {
                float v = acc[i][j][r];
                if constexpr (FINAL) {
                    v += bv;
                    if (ACT == 1) v = fmaxf(v, 0.f);
                    if (ACT == 2) v = 1.f / (1.f + expf(-v));
                }
                C[(size_t)(row + r) * N + col] = v;
            }
        }
    }
}

// ---------------------------------------------------------------------------
// K3b: split-K reduce -> f32 [M][N] with bias/act. Dual pointer sets via blockIdx.y.
// ---------------------------------------------------------------------------
template<int ACT>
__global__ void reduce_f32(const float* __restrict__ P0, const float* __restrict__ bias0,
                           float* __restrict__ C0,
                           const float* __restrict__ P1, const float* __restrict__ bias1,
                           float* __restrict__ C1, int S, int M, int N) {
    const float* P = blockIdx.y ? P1 : P0;
    const float* bias = blockIdx.y ? bias1 : bias0;
    float* C = blockIdx.y ? C1 : C0;
    int idx = blockIdx.x * 256 + threadIdx.x;
    int mn4 = (M * N) >> 2;
    if (idx >= mn4) return;
    f32x4 a = ((const f32x4*)P)[idx];
    for (int s = 1; s < S; ++s) a += ((const f32x4*)P)[(size_t)s * mn4 + idx];
    int col = (idx % (N >> 2)) * 4;
    f32x4 o;
#pragma unroll
    for (int j = 0; j < 4; ++j) {
        float v = a[j] + (bias ? bias[col + j] : 0.f);
        if (ACT == 1) v = fmaxf(v, 0.f);
        if (ACT == 2) v = 1.f / (1.f + expf(-v));
        o[j] = v;
    }
    ((f32x4*)C)[idx] = o;
}

// ---------------------------------------------------------------------------
// K3c: split-K reduce + relu + bias -> split-bf16 TILED (MLP1 hid, M=128, N=HIDN)
// ---------------------------------------------------------------------------
__global__ void reduce_hid(const float* __restrict__ P0, const float* __restrict__ b0,
                           u16* __restrict__ hi0, u16* __restrict__ lo0,
                           const float* __restrict__ P1, const float* __restrict__ b1,
                           u16* __restrict__ hi1, u16* __restrict__ lo1, int S) {
    const float* P = blockIdx.y ? P1 : P0;
    const float* bias = blockIdx.y ? b1 : b0;
    u16* hi = blockIdx.y ? hi1 : hi0;
    u16* lo = blockIdx.y ? lo1 : lo0;
    int idx = blockIdx.x * 256 + threadIdx.x;       // 128*2048/8 = 32768
    int col = (idx & 255) * 8, rowi = idx >> 8;
    size_t base = ((size_t)rowi * HIDN + col) >> 2;
    f32x4 a0 = ((const f32x4*)P)[base], a1 = ((const f32x4*)P)[base + 1];
    for (int s = 1; s < S; ++s) {
        size_t sb = (size_t)s * (128 * HIDN / 4) + base;
        a0 += ((const f32x4*)P)[sb];
        a1 += ((const f32x4*)P)[sb + 1];
    }
    u16x8 h, l;
#pragma unroll
    for (int j = 0; j < 8; ++j) {
        float v = (j < 4 ? a0[j] : a1[j - 4]) + bias[col + j];
        v = fmaxf(v, 0.f);
        u16 hh = f2bf(v);
        h[j] = hh;
        l[j] = f2bf(v - bf2f(hh));
    }
    size_t ob = tiled_off(rowi, col, HIDN);
    *(u16x8*)&hi[ob] = h;
    *(u16x8*)&lo[ob] = l;
}

// ---------------------------------------------------------------------------
// K3d: MLP2 split-K reduce + bias fused with mem_kv concat -> ck/cv [KVH][33][DH]
// ---------------------------------------------------------------------------
__global__ void reduce_ckcv(const float* __restrict__ Pk, const float* __restrict__ Pv,
                            const float* __restrict__ mem_kv,
                            const float* __restrict__ kb2, const float* __restrict__ vb2,
                            float* __restrict__ ck, float* __restrict__ cv, int S) {
    int idx = blockIdx.x * 256 + threadIdx.x;   // 4*33*64 = 8448
    if (idx >= KVH * 33 * DH) return;
    int d = idx & 63;
    int j = (idx >> 6) % 33;
    int h = idx / (33 * 64);
    float kvv, vvv;
    if (j == 0) {
        kvv = mem_kv[(0 * KVH + h) * DH + d];
        vvv = mem_kv[(1 * KVH + h) * DH + d];
    } else {
        size_t base = (size_t)(h * WBLK + (j - 1)) * 128 + d;
        float ak = Pk[base], av = Pv[base];
        for (int s = 1; s < S; ++s) {
            ak += Pk[(size_t)s * (128 * 128) + base];
            av += Pv[(size_t)s * (128 * 128) + base];
        }
        kvv = ak + kb2[d];
        vvv = av + vb2[d];
    }
    ck[idx] = kvv;
    cv[idx] = vvv;
}

// ---------------------------------------------------------------------------
// K5: build compress-MLP inputs -> split-bf16 TILED (K=CDIM)
// ---------------------------------------------------------------------------
__global__ void build_cmlp_in(const float* __restrict__ qkv, const float* __restrict__ k_pos,
                              const float* __restrict__ v_pos,
                              u16* __restrict__ ckhi, u16* __restrict__ cklo,
                              u16* __restrict__ cvhi, u16* __restrict__ cvlo) {
    int idx = blockIdx.x * 256 + threadIdx.x;   // 128 * 256 = 32768
    int k = (idx & 255) * 8;
    int r = idx >> 8;                           // 0..127 = h*W + w
    int p = k >> 6, d = k & 63;
    int h = r >> 5, wb = r & 31;
    int nn = wb * BSZ + p;
    const float* kq = qkv + (size_t)nn * QKVD + (HEADS + h) * DH + d;
    const float* vq = qkv + (size_t)nn * QKVD + (HEADS + KVH + h) * DH + d;
    const float* kp = k_pos + (size_t)(h * BSZ + p) * DH + d;
    const float* vp = v_pos + (size_t)(h * BSZ + p) * DH + d;
    u16x8 kh, kl, vh, vl;
#pragma unroll
    for (int j = 0; j < 8; ++j) {
        float kv = kq[j] + kp[j];
        float vv = vq[j] + vp[j];
        u16 a = f2bf(kv), b = f2bf(vv);
        kh[j] = a; kl[j] = f2bf(kv - bf2f(a));
        vh[j] = b; vl[j] = f2bf(vv - bf2f(b));
    }
    size_t ob = tiled_off(r, k, CDIM);
    *(u16x8*)&ckhi[ob] = kh; *(u16x8*)&cklo[ob] = kl;
    *(u16x8*)&cvhi[ob] = vh; *(u16x8*)&cvlo[ob] = vl;
}

// ---------------------------------------------------------------------------
// K7: interleaved rotary for q (16 heads), k (4 heads) + packed v copy (4 heads)
// ---------------------------------------------------------------------------
__global__ void rotary_kernel(const float* __restrict__ qkv,
                              float* __restrict__ qr, float* __restrict__ kr,
                              float* __restrict__ vr) {
    int idx = blockIdx.x * 256 + threadIdx.x;   // 24*1024*32 = 786432
    int i = idx & 31;
    int n = (idx >> 5) & 1023;
    int hd = idx >> 15;
    if (hd >= 24) return;
    if (hd >= HEADS + KVH) {       // packed v copy
        int h = hd - (HEADS + KVH);
        const float* src = qkv + (size_t)n * QKVD + (HEADS + KVH + h) * DH;
        float* dst = vr + ((size_t)h * NTOK + n) * DH;
        dst[2 * i] = src[2 * i];
        dst[2 * i + 1] = src[2 * i + 1];
        return;
    }
    float inv = powf(10000.f, -(float)i / 32.f);
    float fr = (float)n * inv;
    float c = cosf(fr), s = sinf(fr);
    const float* src; float* dst;
    if (hd < HEADS) { src = qkv + (size_t)n * QKVD + hd * DH;          dst = qr + ((size_t)hd * NTOK + n) * DH; }
    else { int h = hd - HEADS;
           src = qkv + (size_t)n * QKVD + (HEADS + h) * DH;            dst = kr + ((size_t)h * NTOK + n) * DH; }
    float x0 = src[2 * i], x1 = src[2 * i + 1];
    dst[2 * i]     = x0 * c - x1 * s;
    dst[2 * i + 1] = x1 * c + x0 * s;
}

// ---------------------------------------------------------------------------
// K8: compressed attention + importance + top-k. 4 tokens per 256-thr block.
// ---------------------------------------------------------------------------
__global__ __launch_bounds__(256)
void cattn_kernel(const float* __restrict__ qkv, const float* __restrict__ ck,
                  const float* __restrict__ cv, float* __restrict__ c_out,
                  int* __restrict__ sel, int* __restrict__ selmask) {
    int h = blockIdx.y;
    int tid = threadIdx.x;
    int w = tid >> 6, lane = tid & 63;
    int grp = lane >> 4, sub = lane & 15;
    int n = blockIdx.x * 4 + w;
    __shared__ float cks[33 * 68];
    __shared__ float cvs[33 * 68];
    __shared__ float sims[16 * 36];      // [w*4+g][j]

    for (int t4 = tid; t4 < 1056; t4 += 256) {
        int half = (t4 >= 528) ? 1 : 0;
        int u = t4 - half * 528;
        int j = u >> 4, d4 = (u & 15) * 4;
        const float* src = (half ? cv : ck) + (size_t)h * 33 * 64 + j * 64 + d4;
        float* dst = (half ? cvs : cks) + j * 68 + d4;
        *(float4*)dst = *(const float4*)src;
    }
    float qreg[64];
    {
        const float4* qp4 = (const float4*)(qkv + (size_t)n * QKVD + (h * GQ + grp) * DH);
#pragma unroll
        for (int c = 0; c < 16; ++c) {
            float4 v = qp4[c];
            qreg[4 * c] = v.x; qreg[4 * c + 1] = v.y; qreg[4 * c + 2] = v.z; qreg[4 * c + 3] = v.w;
        }
    }
    __syncthreads();

#pragma unroll
    for (int r = 0; r < 3; ++r) {
        int j = r * 16 + sub;
        if (j < 33) {
            float acc = 0.f;
#pragma unroll
            for (int d = 0; d < 64; ++d) acc = fmaf(qreg[d], cks[j * 68 + d], acc);
            sims[(w * 4 + grp) * 36 + j] = acc * SCALE;
        }
    }

    float ival = NEGINF;
    if (lane < 32)
        ival = 0.25f * (sims[(w * 4 + 0) * 36 + 1 + lane] + sims[(w * 4 + 1) * 36 + 1 + lane] +
                        sims[(w * 4 + 2) * 36 + 1 + lane] + sims[(w * 4 + 3) * 36 + 1 + lane]);
    float m = ival;
    for (int off = 32; off; off >>= 1) m = fmaxf(m, __shfl_xor(m, off));
    float e = (lane < 32) ? expf(ival - m) : 0.f;
    float sum = e;
    for (int off = 32; off; off >>= 1) sum += __shfl_xor(sum, off);
    float p = (lane < 32) ? e / sum : NEGINF;

    float v = p;
    int base = (h * NTOK + n) * 9;
    for (int t = 0; t < NSEL; ++t) {
        float bv = v; int bi = lane;
        for (int off = 32; off; off >>= 1) {
            float ov = __shfl_xor(bv, off);
            int   oi = __shfl_xor(bi, off);
            if (ov > bv || (ov == bv && oi < bi)) { bv = ov; bi = oi; }
        }
        if (lane == 0) { sel[base + t] = bi; selmask[base + t] = (bv > 1e-10f) ? 1 : 0; }
        if (lane == bi) v = NEGINF;
    }
    if (lane == 0) { sel[base + NSEL] = n >> 5; selmask[base + NSEL] = 1; }

#pragma unroll
    for (int g = 0; g < 4; ++g) {
        float sv = (lane < 33) ? sims[(w * 4 + g) * 36 + lane] : NEGINF;
        float mm = sv;
        for (int off = 32; off; off >>= 1) mm = fmaxf(mm, __shfl_xor(mm, off));
        float ee = (lane < 33) ? __expf(sv - mm) : 0.f;
        float ssum = ee;
        for (int off = 32; off; off >>= 1) ssum += __shfl_xor(ssum, off);
        if (lane < 33) sims[(w * 4 + g) * 36 + lane] = ee / ssum;
    }

    f32x4 o = (f32x4){0.f, 0.f, 0.f, 0.f};
#pragma unroll
    for (int j = 0; j < 33; ++j) {
        float a = sims[(w * 4 + grp) * 36 + j];
        f32x4 vv = *(const f32x4*)&cvs[j * 68 + sub * 4];
        o += a * vv;
    }
    *(f32x4*)&c_out[(((size_t)(h * GQ + grp)) * NTOK + n) * DH + sub * 4] = o;
}

// ---------------------------------------------------------------------------
// K9: fine attention v15 — v14 + (a) separate K/V LDS buffers with counted-vmcnt
// pipeline (T4): per-wave chain had V issued-then-immediately-waited (full
// ~200-900cy latency exposed 5x/block) and next-K likewise. Now: prologue
// stages K(0)+V(0); per iter: vmcnt(4) [K ready, V in flight] -> scores ->
// softmax -> lgkmcnt(0) -> issue K(bp+1) -> vmcnt(4) [V ready] (bp=4: vmcnt(0))
// -> PV -> lgkmcnt(0) -> issue V(bp+1). Outstanding trace: 8->4->8->4; each
// wait retires exactly the right quad. V latency hides under scores+softmax,
// K latency under V-wait+PV. LDS 18.9->35.1KB (4 blocks/CU cap, >= achieved 3).
// (b) VALU dependency-chain split: scores 2xf32x4 partials (chain 64->8 deep),
// PV per-iter t0/t1 merged into o4 (16->8). Reassoc may nudge absmax.
// Barriers unchanged (0 in loop). All waits wave-local; sched_barrier fences
// per rule #18.
// ---------------------------------------------------------------------------
__global__ void fattn_kernel(const float* __restrict__ qr, const float* __restrict__ kr,
                             const float* __restrict__ vr, const int* __restrict__ sel,
                             const int* __restrict__ selmask, float* __restrict__ f_out) {
    int n = blockIdx.x, h = blockIdx.y;
    int tid = threadIdx.x;
    int w = tid >> 6, lane = tid & 63;
    int grp = lane >> 4, sub = lane & 15;
    __shared__ float qsm[4 * 68];
    __shared__ float Ksm[64 * 64];       // slot s of row r = global slot s^(r&15)
    __shared__ float Vsm[64 * 64];
    __shared__ float ps[4 * 68];         // wave-private p rows: ps[w][g*16+sub]
    __shared__ float msm[16], lsm[16];   // [slice w * 4 + head g]
    __shared__ int sel_s[9], msk_s[9];

    if (tid < 9) {
        sel_s[tid] = sel[(h * NTOK + n) * 9 + tid];
        msk_s[tid] = selmask[(h * NTOK + n) * 9 + tid];
    }
    // q -> LDS once: wave w loads head w's 64 elements
    qsm[w * 68 + lane] = qr[(((size_t)(h * GQ + w)) * NTOK + n) * DH + lane];
    f32x4 o4 = (f32x4){0.f, 0.f, 0.f, 0.f};   // partial over (head grp, slice w), dims sub*4..+3
    float m_run = -3.402823466e38f, l_run = 0.f;
    __syncthreads();                     // B0: sel_s + qsm ready

    const float* krh_ = kr + (size_t)h * NTOK * DH;
    const float* vrh_ = vr + (size_t)h * NTOK * DH;

    // staging geometry: wave w stages rows [w*16, w*16+16); glds chunk cc = 4 rows.
    // lane L -> row_local rl = L>>4, slot sl = L&15 (dest linear: base + L*16B);
    // source slot = sl ^ (r&15) so that read with slot = c ^ (row&15) is identity.
    int rl = lane >> 4, sl = lane & 15;

    auto stageRows = [&](float* dstbuf, const float* src, int bp) {
        int nrow = (bp < 4) ? 64 : 32;
        if (w * 16 < nrow) {
            int myblk = sel_s[bp * 2 + (w >> 1)];
            const float* b_ = src + (size_t)myblk * BSZ * DH;
#pragma unroll
            for (int cc = 0; cc < 4; ++cc) {
                int r = w * 16 + cc * 4 + rl;
                int sg = sl ^ (r & 15);
                glds16(b_ + (size_t)(r & 31) * DH + sg * 4, &dstbuf[(w * 16 + cc * 4) * 64]);
            }
        }
    };

    stageRows(Ksm, krh_, 0);             // prologue: K(0) then V(0) (wave-private)
    stageRows(Vsm, vrh_, 0);

    for (int bp = 0; bp < 5; ++bp) {
        int nrow = (bp < 4) ? 64 : 32;

        // wave-local: own K quad retired (oldest 4 of <=8 outstanding)
        asm volatile("s_waitcnt vmcnt(4)" ::: "memory");
        __builtin_amdgcn_sched_barrier(0);

        // ---- scores: thread (grp, jj=w*16+sub) reads OWN-wave K rows only
        float s = -3.402823466e38f;
        {
            int jj = w * 16 + sub;
            int b = bp * 2 + (jj >> 5);
            if (jj < nrow && msk_s[b]) {
                int sw = jj & 15;
                const float* Kb = &Ksm[jj * 64];
                f32x4 a0 = (f32x4){0.f, 0.f, 0.f, 0.f};
                f32x4 a1 = (f32x4){0.f, 0.f, 0.f, 0.f};
#pragma unroll
                for (int c = 0; c < 16; c += 2) {
                    f32x4 k4a = *(const f32x4*)&Kb[(c ^ sw) * 4];
                    f32x4 q4a = *(const f32x4*)&qsm[grp * 68 + c * 4];
                    f32x4 k4b = *(const f32x4*)&Kb[((c + 1) ^ sw) * 4];
                    f32x4 q4b = *(const f32x4*)&qsm[grp * 68 + (c + 1) * 4];
                    a0 += q4a * k4a;
                    a1 += q4b * k4b;
                }
                f32x4 at = a0 + a1;
                s = ((at[0] + at[1]) + (at[2] + at[3])) * SCALE;
            }
        }
        // ---- in-register online softmax over the 16-lane group (head grp, slice w)
        float mb = s;
        for (int off = 8; off; off >>= 1) mb = fmaxf(mb, __shfl_xor(mb, off));
        float m_new = fmaxf(m_run, mb);
        float pp = (s > -1e37f) ? __expf(s - m_new) : 0.f;
        float alpha = __expf(m_run - m_new);   // ==1 when slice empty (both -3.4e38)
        float psum = pp;
        for (int off = 8; off; off >>= 1) psum += __shfl_xor(psum, off);
        l_run = l_run * alpha + psum;
        m_run = m_new;
        ps[w * 68 + grp * 16 + sub] = pp;      // wave-private row

        // retire our K ds_reads + ps write, then issue K(bp+1) into own rows
        __builtin_amdgcn_sched_barrier(0);
        asm volatile("s_waitcnt lgkmcnt(0)" ::: "memory");
        __builtin_amdgcn_sched_barrier(0);
        if (bp < 4) {
            stageRows(Ksm, krh_, bp + 1);
            // wave-local: V(bp) quad retired (oldest 4; K(bp+1) still in flight)
            asm volatile("s_waitcnt vmcnt(4)" ::: "memory");
        } else {
            asm volatile("s_waitcnt vmcnt(0)" ::: "memory");
        }
        __builtin_amdgcn_sched_barrier(0);

        // ---- PV: wave w reads OWN V rows + OWN ps; thread (g=grp, c=sub)
        {
            f32x4 t0 = (f32x4){0.f, 0.f, 0.f, 0.f};
            f32x4 t1 = (f32x4){0.f, 0.f, 0.f, 0.f};
            int jbase = w * 16;
            if (jbase < nrow) {
#pragma unroll
                for (int jq = 0; jq < 4; ++jq) {
                    f32x4 p4 = *(const f32x4*)&ps[w * 68 + grp * 16 + jq * 4];
#pragma unroll
                    for (int r = 0; r < 4; ++r) {
                        int row = jbase + jq * 4 + r;
                        int slot = sub ^ (row & 15);
                        f32x4 vv = *(const f32x4*)&Vsm[row * 64 + slot * 4];
                        if (r & 1) t1 += p4[r] * vv;
                        else       t0 += p4[r] * vv;
                    }
                }
            }
            o4 = o4 * alpha + (t0 + t1);
        }
        // retire PV ds_reads, then issue V(bp+1) into own rows
        if (bp < 4) {
            __builtin_amdgcn_sched_barrier(0);
            asm volatile("s_waitcnt lgkmcnt(0)" ::: "memory");
            __builtin_amdgcn_sched_barrier(0);
            stageRows(Vsm, vrh_, bp + 1);
        }
    }
    // ---- epilogue: split-softmax merge of the 4 slice-partials per head
    if (sub == 0) { msm[w * 4 + grp] = m_run; lsm[w * 4 + grp] = l_run; }
    __syncthreads();                      // all loops done -> Ksm free; msm/lsm visible
    *(f32x4*)&Ksm[(w * 4 + grp) * 64 + sub * 4] = o4;
    __syncthreads();
    // thread: head = w, dim = lane
    float m0 = msm[0 * 4 + w], m1 = msm[1 * 4 + w], m2 = msm[2 * 4 + w], m3 = msm[3 * 4 + w];
    float M = fmaxf(fmaxf(m0, m1), fmaxf(m2, m3));
    float f0 = __expf(m0 - M), f1 = __expf(m1 - M), f2 = __expf(m2 - M), f3 = __expf(m3 - M);
    float L = lsm[0 * 4 + w] * f0 + lsm[1 * 4 + w] * f1 + lsm[2 * 4 + w] * f2 + lsm[3 * 4 + w] * f3;
    float sum = Ksm[(0 * 4 + w) * 64 + lane] * f0 + Ksm[(1 * 4 + w) * 64 + lane] * f1
              + Ksm[(2 * 4 + w) * 64 + lane] * f2 + Ksm[(3 * 4 + w) * 64 + lane] * f3;
    f_out[(((size_t)(h * GQ + w)) * NTOK + n) * DH + lane] = sum / L;
}

// ---------------------------------------------------------------------------
// K10: gated mix -> split-bf16 TILED (K=DDIM). gates f32 [N][128] padded.
// ---------------------------------------------------------------------------
__global__ void mix_kernel(const float* __restrict__ gates, const float* __restrict__ c_out,
                           const float* __restrict__ f_out,
                           u16* __restrict__ mixhi, u16* __restrict__ mixlo) {
    int idx = blockIdx.x * 256 + threadIdx.x;   // 1024*1024/8 = 131072
    int col = (idx & 127) * 8;
    int n = idx >> 7;
    int hd = col >> 6, d = col & 63;
    float g0 = gates[(size_t)n * 128 + hd * 2];
    float g1 = gates[(size_t)n * 128 + hd * 2 + 1];
    size_t hoff = (((size_t)hd) * NTOK + n) * DH + d;
    u16x8 h, l;
#pragma unroll
    for (int j = 0; j < 8; ++j) {
        float v = g0 * c_out[hoff + j] + g1 * f_out[hoff + j];
        u16 hh = f2bf(v);
        h[j] = hh;
        l[j] = f2bf(v - bf2f(hh));
    }
    size_t ob = tiled_off(n, col, DDIM);
    *(u16x8*)&mixhi[ob] = h;
    *(u16x8*)&mixlo[ob] = l;
}

// ---------------------------------------------------------------------------
extern "C" void kernel_launch(void* const* d_in, const int* in_sizes, int n_in,
                              void* d_out, int out_size, void* d_ws, size_t ws_size,
                              hipStream_t stream) {
    const float* inp    = (const float*)d_in[0];
    const float* g_norm = (const float*)d_in[1];
    const float* w_qkv  = (const float*)d_in[2];
    const float* mem_kv = (const float*)d_in[3];
    const float* k_pos  = (const float*)d_in[4];
    const float* v_pos  = (const float*)d_in[5];
    const float* k_w1   = (const float*)d_in[6];
    const float* k_b1   = (const float*)d_in[7];
    const float* k_w2   = (const float*)d_in[8];
    const float* k_b2   = (const float*)d_in[9];
    const float* v_w1   = (const float*)d_in[10];
    const float* v_b1   = (const float*)d_in[11];
    const float* v_w2   = (const float*)d_in[12];
    const float* v_b2   = (const float*)d_in[13];
    const float* gate_w = (const float*)d_in[14];
    const float* gate_b = (const float*)d_in[15];
    const float* w_out  = (const float*)d_in[16];
    float* out = (float*)d_out;

    char* wsb = (char*)d_ws;
    size_t off = 0;
    auto alloc = [&](size_t bytes) -> void* {
        void* p = wsb + off;
        off = (off + bytes + 255) & ~(size_t)255;
        return p;
    };
    u16*   xhi    = (u16*)  alloc((size_t)NTOK * DDIM * 2);
    u16*   xlo    = (u16*)  alloc((size_t)NTOK * DDIM * 2);
    float* qkvb   = (float*)alloc((size_t)NTOK * QKVD * 4);
    u16*   wqThi  = (u16*)  alloc((size_t)QKVD * DDIM * 2);
    u16*   wqTlo  = (u16*)  alloc((size_t)QKVD * DDIM * 2);
    u16*   kw1Thi = (u16*)  alloc((size_t)HIDN * CDIM * 2);
    u16*   kw1Tlo = (u16*)  alloc((size_t)HIDN * CDIM * 2);
    u16*   vw1Thi = (u16*)  alloc((size_t)HIDN * CDIM * 2);
    u16*   vw1Tlo = (u16*)  alloc((size_t)HIDN * CDIM * 2);
    u16*   woThi  = (u16*)  alloc((size_t)DDIM * DDIM * 2);
    u16*   gwThi  = (u16*)  alloc((size_t)128 * DDIM * 2);
    u16*   gwTlo  = (u16*)  alloc((size_t)128 * DDIM * 2);
    float* gbp    = (float*)alloc(128 * 4);
    u16*   kw2Thi = (u16*)  alloc((size_t)128 * HIDN * 2);
    u16*   kw2Tlo = (u16*)  alloc((size_t)128 * HIDN * 2);
    float* kb2p   = (float*)alloc(128 * 4);
    u16*   vw2Thi = (u16*)  alloc((size_t)128 * HIDN * 2);
    u16*   vw2Tlo = (u16*)  alloc((size_t)128 * HIDN * 2);
    float* vb2p   = (float*)alloc(128 * 4);
    u16*   cinkhi = (u16*)  alloc((size_t)128 * CDIM * 2);
    u16*   cinklo = (u16*)  alloc((size_t)128 * CDIM * 2);
    u16*   cinvhi = (u16*)  alloc((size_t)128 * CDIM * 2);
    u16*   cinvlo = (u16*)  alloc((size_t)128 * CDIM * 2);
    u16*   hidkhi = (u16*)  alloc((size_t)128 * HIDN * 2);
    u16*   hidklo = (u16*)  alloc((size_t)128 * HIDN * 2);
    u16*   hidvhi = (u16*)  alloc((size_t)128 * HIDN * 2);
    u16*   hidvlo = (u16*)  alloc((size_t)128 * HIDN * 2);
    float* Pg     = (float*)alloc((size_t)8 * NTOK * 128 * 4);
    float* Pm1k   = (float*)alloc((size_t)4 * 128 * HIDN * 4);
    float* Pm1v   = (float*)alloc((size_t)4 * 128 * HIDN * 4);
    float* Pm2k   = (float*)alloc((size_t)8 * 128 * 128 * 4);
    float* Pm2v   = (float*)alloc((size_t)8 * 128 * 128 * 4);
    float* ck     = (float*)alloc((size_t)KVH * 33 * DH * 4);
    float* cv     = (float*)alloc((size_t)KVH * 33 * DH * 4);
    float* qr     = (float*)alloc((size_t)HEADS * NTOK * DH * 4);
    float* kr     = (float*)alloc((size_t)KVH * NTOK * DH * 4);
    float* vr     = (float*)alloc((size_t)KVH * NTOK * DH * 4);
    float* c_out  = (float*)alloc((size_t)HEADS * NTOK * DH * 4);
    float* f_out  = (float*)alloc((size_t)HEADS * NTOK * DH * 4);
    float* gates  = (float*)alloc((size_t)NTOK * 128 * 4);
    int*   sel    = (int*)  alloc((size_t)KVH * NTOK * 9 * 4);
    int*   selmask= (int*)  alloc((size_t)KVH * NTOK * 9 * 4);
    u16*   mixhi  = (u16*)  alloc((size_t)NTOK * DDIM * 2);
    u16*   mixlo  = (u16*)  alloc((size_t)NTOK * DDIM * 2);

    // weight prep (tiled layouts)
    transpose_split<<<dim3(QKVD / 64, DDIM / 64), 256, 0, stream>>>(w_qkv, wqThi, wqTlo, DDIM, QKVD);
    transpose_split<<<dim3(HIDN / 64, CDIM / 64), 256, 0, stream>>>(k_w1, kw1Thi, kw1Tlo, CDIM, HIDN);
    transpose_split<<<dim3(HIDN / 64, CDIM / 64), 256, 0, stream>>>(v_w1, vw1Thi, vw1Tlo, CDIM, HIDN);
    transpose_split<<<dim3(DDIM / 64, DDIM / 64), 256, 0, stream>>>(w_out, woThi, nullptr, DDIM, DDIM);
    pad_small_tiled<<<(128 * DDIM / 8) / 256, 256, 0, stream>>>(gate_w, gate_b, gwThi, gwTlo, gbp, DDIM, 32, 10);
    pad_small_tiled<<<(128 * HIDN / 8) / 256, 256, 0, stream>>>(k_w2, k_b2, kw2Thi, kw2Tlo, kb2p, HIDN, 64, 11);
    pad_small_tiled<<<(128 * HIDN / 8) / 256, 256, 0, stream>>>(v_w2, v_b2, vw2Thi, vw2Tlo, vb2p, HIDN, 64, 11);

    // 1. RMSNorm -> tiled split-bf16 x
    rmsnorm_kernel<<<NTOK / 2, 256, 0, stream>>>(inp, g_norm, xhi, xlo);
    // 2. qkv = x @ w_qkv (final f32)
    gemm_tiled<3, 0, 1><<<dim3(QKVD / 128, NTOK / 128, 1), 256, 0, stream>>>(
        xhi, xlo, wqThi, wqTlo, nullptr, qkvb,
        xhi, xlo, wqThi, wqTlo, nullptr, qkvb, NTOK, QKVD, DDIM, 1);
    // 3. gates (split-K 8 + sigmoid reduce)
    gemm_tiled<3, 0, 0><<<dim3(1, NTOK / 128, 8), 256, 0, stream>>>(
        xhi, xlo, gwThi, gwTlo, nullptr, Pg,
        xhi, xlo, gwThi, gwTlo, nullptr, Pg, NTOK, 128, DDIM, 8);
    reduce_f32<2><<<dim3(128, 1), 256, 0, stream>>>(Pg, gbp, gates, Pg, gbp, gates, 8, NTOK, 128);
    // 4. compress-MLP inputs (tiled)
    build_cmlp_in<<<128, 256, 0, stream>>>(qkvb, k_pos, v_pos, cinkhi, cinklo, cinvhi, cinvlo);
    // 5. MLP1 (split-K 4, k&v batched; relu+bias+split-tile in reduce)
    gemm_tiled<3, 0, 0><<<dim3(HIDN / 128, 1, 8), 256, 0, stream>>>(
        cinkhi, cinklo, kw1Thi, kw1Tlo, nullptr, Pm1k,
        cinvhi, cinvlo, vw1Thi, vw1Tlo, nullptr, Pm1v, 128, HIDN, CDIM, 4);
    reduce_hid<<<dim3(128, 2), 256, 0, stream>>>(Pm1k, k_b1, hidkhi, hidklo,
                                                 Pm1v, v_b1, hidvhi, hidvlo, 4);
    // 6. MLP2 (split-K 8, k&v batched) + fused reduce/bias/concat
    gemm_tiled<3, 0, 0><<<dim3(1, 1, 16), 256, 0, stream>>>(
        hidkhi, hidklo, kw2Thi, kw2Tlo, nullptr, Pm2k,
        hidvhi, hidvlo, vw2Thi, vw2Tlo, nullptr, Pm2v, 128, 128, HIDN, 8);
    reduce_ckcv<<<33, 256, 0, stream>>>(Pm2k, Pm2v, mem_kv, kb2p, vb2p, ck, cv, 8);
    // 8. rotary + packed v
    rotary_kernel<<<(24 * NTOK * 32) / 256, 256, 0, stream>>>(qkvb, qr, kr, vr);
    // 9. compressed attention + selection (4 tokens per block)
    cattn_kernel<<<dim3(NTOK / 4, KVH), 256, 0, stream>>>(qkvb, ck, cv, c_out, sel, selmask);
    // 10. fine attention (v15: K/V split buffers, counted-vmcnt pipeline, chain-split)
    fattn_kernel<<<dim3(NTOK, KVH), 256, 0, stream>>>(qr, kr, vr, sel, selmask, f_out);
    // 11. gated mix -> tiled split-bf16
    mix_kernel<<<(NTOK * DDIM / 8) / 256, 256, 0, stream>>>(gates, c_out, f_out, mixhi, mixlo);
    // 12. output projection (bf16, final)
    gemm_tiled<1, 0, 1><<<dim3(DDIM / 128, NTOK / 128, 1), 256, 0, stream>>>(
        mixhi, mixhi, woThi, woThi, nullptr, out,
        mixhi, mixhi, woThi, woThi, nullptr, out, NTOK, DDIM, DDIM, 1);
}

// Round 9
// 329.969 us; speedup vs baseline: 1.1561x; 1.0464x over previous
//
#include <hip/hip_runtime.h>
#include <math.h>

// ---- fixed problem sizes ----
#define NTOK 1024
#define DDIM 1024
#define HEADS 16
#define KVH 4
#define DH 64
#define BSZ 32
#define NSEL 8
#define WBLK 32            // NTOK / BSZ
#define GQ 4               // HEADS / KVH
#define CDIM 2048          // BSZ*DH
#define HIDN 2048
#define QKVD 1536          // (HEADS + 2*KVH)*DH
#define SCALE 0.125f       // DH^-0.5
#define NEGINF (-__builtin_inff())

typedef unsigned short u16;
typedef u16   u16x8  __attribute__((ext_vector_type(8)));
typedef short short8 __attribute__((ext_vector_type(8)));
typedef float f32x4  __attribute__((ext_vector_type(4)));

__device__ __forceinline__ u16 f2bf(float f) {
    unsigned u = __float_as_uint(f);
    return (u16)((u + 0x7fffu + ((u >> 16) & 1u)) >> 16);
}
__device__ __forceinline__ float bf2f(u16 h) { return __uint_as_float(((unsigned)h) << 16); }

__device__ __forceinline__ void glds16(const void* g, void* l) {
    __builtin_amdgcn_global_load_lds(
        (const __attribute__((address_space(1))) unsigned int*)g,
        (__attribute__((address_space(3))) unsigned int*)l, 16, 0, 0);
}

// element offset (in u16) of the 8-element lane-slot for (row, k..k+7) in the
// MFMA-fragment-tiled layout: 16-row x 32-k tiles, 1KB each, contiguous.
__device__ __forceinline__ size_t tiled_off(int row, int k, int K) {
    return ((size_t)((row >> 4) * (K >> 5) + (k >> 5)) * 64 +
            ((row & 15) | (((k >> 3) & 3) << 4))) * 8;
}

// ---------------------------------------------------------------------------
// K0: MEGA-PREP — all weight prep + RMSNorm in ONE dispatch (v16).
// R8 theory: 8 independent prep dispatches serialized on the stream = launch/
// drain gaps + partial-occupancy traffic. One 3520-block kernel with a
// block-range dispatch table overlaps all of it. Bodies identical to the old
// kernels (block-uniform branches; shared tile + red coexist).
// Ranges: [0,384) wqT | [384,1408) kw1T | [1408,2432) vw1T | [2432,2688) woT
//         | [2688,2752) pad gate | [2752,2880) pad kw2 | [2880,3008) pad vw2
//         | [3008,3520) rmsnorm
// ---------------------------------------------------------------------------
__device__ __forceinline__ void transpose_body(const float* __restrict__ W,
                                               u16* __restrict__ Thi, u16* __restrict__ Tlo,
                                               int K, int N, int bx, int by,
                                               float (*tile)[65]) {
    int k0 = by * 64, n0 = bx * 64;
    int t = threadIdx.x;
    int r = t >> 4, c4 = (t & 15) * 4;
#pragma unroll
    for (int p = 0; p < 4; ++p) {
        float4 v = *(const float4*)&W[(size_t)(k0 + r + p * 16) * N + n0 + c4];
        tile[r + p * 16][c4 + 0] = v.x;
        tile[r + p * 16][c4 + 1] = v.y;
        tile[r + p * 16][c4 + 2] = v.z;
        tile[r + p * 16][c4 + 3] = v.w;
    }
    __syncthreads();
    int n = t >> 2, ks = (t & 3) * 16;
#pragma unroll
    for (int c = 0; c < 2; ++c) {
        u16x8 h, l;
#pragma unroll
        for (int j = 0; j < 8; ++j) {
            float v = tile[ks + c * 8 + j][n];
            u16 hh = f2bf(v);
            h[j] = hh;
            l[j] = f2bf(v - bf2f(hh));
        }
        size_t ob = tiled_off(n0 + n, k0 + ks + c * 8, K);
        *(u16x8*)&Thi[ob] = h;
        if (Tlo) *(u16x8*)&Tlo[ob] = l;
    }
}

__device__ __forceinline__ void pad_body(const float* __restrict__ W, const float* __restrict__ b,
                                         u16* __restrict__ Thi, u16* __restrict__ Tlo,
                                         float* __restrict__ bias_pad, int K, int Xn, int KLOG,
                                         int bx) {
    int idx = bx * 256 + threadIdx.x;
    int k = (idx & ((K >> 3) - 1)) * 8;
    int n = idx >> (KLOG - 3);
    if (n >= 128) return;
    u16x8 h, l;
#pragma unroll
    for (int j = 0; j < 8; ++j) {
        float v = (n < Xn) ? W[(size_t)(k + j) * Xn + n] : 0.f;
        u16 hh = f2bf(v);
        h[j] = hh;
        l[j] = f2bf(v - bf2f(hh));
    }
    size_t ob = tiled_off(n, k, K);
    *(u16x8*)&Thi[ob] = h;
    *(u16x8*)&Tlo[ob] = l;
    if (k == 0) bias_pad[n] = (n < Xn) ? b[n] : 0.f;
}

__device__ __forceinline__ void rms_body(const float* __restrict__ inp, const float* __restrict__ g,
                                         u16* __restrict__ xhi, u16* __restrict__ xlo,
                                         int bx, float* red) {
    int t = threadIdx.x;
    int half = t >> 7, tid = t & 127;
    int n = bx * 2 + half;
    const float4* row = (const float4*)(inp + (size_t)n * DDIM);
    float4 v0 = row[tid * 2], v1 = row[tid * 2 + 1];
    float ss = v0.x*v0.x + v0.y*v0.y + v0.z*v0.z + v0.w*v0.w
             + v1.x*v1.x + v1.y*v1.y + v1.z*v1.z + v1.w*v1.w;
    for (int off = 32; off; off >>= 1) ss += __shfl_down(ss, off);
    if ((t & 63) == 0) red[t >> 6] = ss;
    __syncthreads();
    float tot = red[half * 2] + red[half * 2 + 1];
    float r = 1.f / sqrtf(tot * (1.f / DDIM) + 1e-6f);
    const float4* gp = (const float4*)g;
    float4 g0 = gp[tid * 2], g1 = gp[tid * 2 + 1];
    float o[8] = { v0.x*r*g0.x, v0.y*r*g0.y, v0.z*r*g0.z, v0.w*r*g0.w,
                   v1.x*r*g1.x, v1.y*r*g1.y, v1.z*r*g1.z, v1.w*r*g1.w };
    u16x8 h, l;
#pragma unroll
    for (int i = 0; i < 8; ++i) {
        u16 hh = f2bf(o[i]);
        h[i] = hh;
        l[i] = f2bf(o[i] - bf2f(hh));
    }
    size_t ob = tiled_off(n, tid * 8, DDIM);
    *(u16x8*)&xhi[ob] = h;
    *(u16x8*)&xlo[ob] = l;
}

__global__ void prep_kernel(const float* __restrict__ w_qkv, const float* __restrict__ k_w1,
                            const float* __restrict__ v_w1, const float* __restrict__ w_out,
                            const float* __restrict__ gate_w, const float* __restrict__ gate_b,
                            const float* __restrict__ k_w2, const float* __restrict__ k_b2,
                            const float* __restrict__ v_w2, const float* __restrict__ v_b2,
                            const float* __restrict__ inp, const float* __restrict__ g_norm,
                            u16* wqThi, u16* wqTlo, u16* kw1Thi, u16* kw1Tlo,
                            u16* vw1Thi, u16* vw1Tlo, u16* woThi,
                            u16* gwThi, u16* gwTlo, float* gbp,
                            u16* kw2Thi, u16* kw2Tlo, float* kb2p,
                            u16* vw2Thi, u16* vw2Tlo, float* vb2p,
                            u16* xhi, u16* xlo) {
    __shared__ float tile[64][65];
    __shared__ float red[4];
    int b = blockIdx.x;
    if (b < 384) {
        transpose_body(w_qkv, wqThi, wqTlo, DDIM, QKVD, b % 24, b / 24, tile);
    } else if (b < 1408) {
        int r = b - 384;
        transpose_body(k_w1, kw1Thi, kw1Tlo, CDIM, HIDN, r & 31, r >> 5, tile);
    } else if (b < 2432) {
        int r = b - 1408;
        transpose_body(v_w1, vw1Thi, vw1Tlo, CDIM, HIDN, r & 31, r >> 5, tile);
    } else if (b < 2688) {
        int r = b - 2432;
        transpose_body(w_out, woThi, nullptr, DDIM, DDIM, r & 15, r >> 4, tile);
    } else if (b < 2752) {
        pad_body(gate_w, gate_b, gwThi, gwTlo, gbp, DDIM, 32, 10, b - 2688);
    } else if (b < 2880) {
        pad_body(k_w2, k_b2, kw2Thi, kw2Tlo, kb2p, HIDN, 64, 11, b - 2752);
    } else if (b < 3008) {
        pad_body(v_w2, v_b2, vw2Thi, vw2Tlo, vb2p, HIDN, 64, 11, b - 2880);
    } else {
        rms_body(inp, g_norm, xhi, xlo, b - 3008, red);
    }
}

// ---------------------------------------------------------------------------
// K3: tiled MFMA GEMM with software pipeline + optional split-K.
// ---------------------------------------------------------------------------
template<int SPLIT, int ACT, int FINAL>
__global__ __launch_bounds__(256, 1)
void gemm_tiled(const u16* __restrict__ Ahi0, const u16* __restrict__ Alo0,
                const u16* __restrict__ Bhi0, const u16* __restrict__ Blo0,
                const float* __restrict__ bias0, float* __restrict__ C0,
                const u16* __restrict__ Ahi1, const u16* __restrict__ Alo1,
                const u16* __restrict__ Bhi1, const u16* __restrict__ Blo1,
                const float* __restrict__ bias1, float* __restrict__ C1,
                int M, int N, int K, int S) {
    int batch = blockIdx.z / S;
    int s = blockIdx.z - batch * S;
    const u16* Ahi = batch ? Ahi1 : Ahi0;
    const u16* Alo = batch ? Alo1 : Alo0;
    const u16* Bhi = batch ? Bhi1 : Bhi0;
    const u16* Blo = batch ? Blo1 : Blo0;
    const float* bias = batch ? bias1 : bias0;
    float* C = batch ? C1 : C0;

    constexpr int PARTS = (SPLIT == 3) ? 2 : 1;
    __shared__ u16 smA[2 * PARTS * 8 * 512];
    __shared__ u16 smB[2 * PARTS * 8 * 512];

    int tid = threadIdx.x;
    int w = tid >> 6, L = tid & 63;
    int m15 = L & 15, q = L >> 4;
    int KT = K >> 5;
    int rowTile = blockIdx.y * 8, colTile = blockIdx.x * 8;
    int NIT = (K / S) >> 5;
    int kb0 = s * NIT;
    int aw = w & 1, bw = w >> 1;

    f32x4 acc[4][4];
#pragma unroll
    for (int i = 0; i < 4; ++i)
#pragma unroll
        for (int j = 0; j < 4; ++j) acc[i][j] = (f32x4){0.f, 0.f, 0.f, 0.f};

    auto stage = [&](int buf, int kb) {
#pragma unroll
        for (int rl = 0; rl < 2; ++rl) {
            int rb = 2 * w + rl;
            glds16(Ahi + ((size_t)(rowTile + rb) * KT + kb) * 512 + (size_t)L * 8,
                   &smA[((buf * PARTS + 0) * 8 + rb) * 512]);
            glds16(Bhi + ((size_t)(colTile + rb) * KT + kb) * 512 + (size_t)L * 8,
                   &smB[((buf * PARTS + 0) * 8 + rb) * 512]);
            if constexpr (SPLIT == 3) {
                glds16(Alo + ((size_t)(rowTile + rb) * KT + kb) * 512 + (size_t)L * 8,
                       &smA[((buf * PARTS + 1) * 8 + rb) * 512]);
                glds16(Blo + ((size_t)(colTile + rb) * KT + kb) * 512 + (size_t)L * 8,
                       &smB[((buf * PARTS + 1) * 8 + rb) * 512]);
            }
        }
    };

    stage(0, kb0);
    for (int it = 0; it < NIT; ++it) {
        __syncthreads();
        if (it + 1 < NIT) stage((it + 1) & 1, kb0 + it + 1);
        int buf = it & 1;
        short8 ah[4], bh[4];
#pragma unroll
        for (int i = 0; i < 4; ++i) {
            ah[i] = *(const short8*)&smA[((buf * PARTS + 0) * 8 + aw * 4 + i) * 512 + L * 8];
            bh[i] = *(const short8*)&smB[((buf * PARTS + 0) * 8 + bw * 4 + i) * 512 + L * 8];
        }
        if constexpr (SPLIT == 3) {
            short8 al[4], bl[4];
#pragma unroll
            for (int i = 0; i < 4; ++i) {
                al[i] = *(const short8*)&smA[((buf * PARTS + 1) * 8 + aw * 4 + i) * 512 + L * 8];
                bl[i] = *(const short8*)&smB[((buf * PARTS + 1) * 8 + bw * 4 + i) * 512 + L * 8];
            }
#pragma unroll
            for (int i = 0; i < 4; ++i)
#pragma unroll
                for (int j = 0; j < 4; ++j) {
                    acc[i][j] = __builtin_amdgcn_mfma_f32_16x16x32_bf16(ah[i], bl[j], acc[i][j], 0, 0, 0);
                    acc[i][j] = __builtin_amdgcn_mfma_f32_16x16x32_bf16(al[i], bh[j], acc[i][j], 0, 0, 0);
                    acc[i][j] = __builtin_amdgcn_mfma_f32_16x16x32_bf16(ah[i], bh[j], acc[i][j], 0, 0, 0);
                }
        } else {
#pragma unroll
            for (int i = 0; i < 4; ++i)
#pragma unroll
                for (int j = 0; j < 4; ++j)
                    acc[i][j] = __builtin_amdgcn_mfma_f32_16x16x32_bf16(ah[i], bh[j], acc[i][j], 0, 0, 0);
        }
    }

    if constexpr (FINAL == 0) C += (size_t)s * M * N;
#pragma unroll
    for (int i = 0; i < 4; ++i) {
        int row = rowTile * 16 + aw * 64 + i * 16 + q * 4;
#pragma unroll
        for (int j = 0; j < 4; ++j) {
            int col = colTile * 16 + bw * 64 + j * 16 + m15;
            float bv = (FINAL && bias) ? bias[col] : 0.f;
#pragma unroll
            for (int r = 0; r < 4; ++r) {
                float v = acc[i][j][r];
                if constexpr (FINAL) {
                    v += bv;
                    if (ACT == 1) v = fmaxf(v, 0.f);
                    if (ACT == 2) v = 1.f / (1.f + expf(-v));
                }
                C[(size_t)(row + r) * N + col] = v;
            }
        }
    }
}

// ---------------------------------------------------------------------------
// K3b: split-K reduce -> f32 [M][N] with bias/act. Dual pointer sets via blockIdx.y.
// ---------------------------------------------------------------------------
template<int ACT>
__global__ void reduce_f32(const float* __restrict__ P0, const float* __restrict__ bias0,
                           float* __restrict__ C0,
                           const float* __restrict__ P1, const float* __restrict__ bias1,
                           float* __restrict__ C1, int S, int M, int N) {
    const float* P = blockIdx.y ? P1 : P0;
    const float* bias = blockIdx.y ? bias1 : bias0;
    float* C = blockIdx.y ? C1 : C0;
    int idx = blockIdx.x * 256 + threadIdx.x;
    int mn4 = (M * N) >> 2;
    if (idx >= mn4) return;
    f32x4 a = ((const f32x4*)P)[idx];
    for (int s = 1; s < S; ++s) a += ((const f32x4*)P)[(size_t)s * mn4 + idx];
    int col = (idx % (N >> 2)) * 4;
    f32x4 o;
#pragma unroll
    for (int j = 0; j < 4; ++j) {
        float v = a[j] + (bias ? bias[col + j] : 0.f);
        if (ACT == 1) v = fmaxf(v, 0.f);
        if (ACT == 2) v = 1.f / (1.f + expf(-v));
        o[j] = v;
    }
    ((f32x4*)C)[idx] = o;
}

// ---------------------------------------------------------------------------
// K3c: split-K reduce + relu + bias -> split-bf16 TILED (MLP1 hid, M=128, N=HIDN)
// ---------------------------------------------------------------------------
__global__ void reduce_hid(const float* __restrict__ P0, const float* __restrict__ b0,
                           u16* __restrict__ hi0, u16* __restrict__ lo0,
                           const float* __restrict__ P1, const float* __restrict__ b1,
                           u16* __restrict__ hi1, u16* __restrict__ lo1, int S) {
    const float* P = blockIdx.y ? P1 : P0;
    const float* bias = blockIdx.y ? b1 : b0;
    u16* hi = blockIdx.y ? hi1 : hi0;
    u16* lo = blockIdx.y ? lo1 : lo0;
    int idx = blockIdx.x * 256 + threadIdx.x;       // 128*2048/8 = 32768
    int col = (idx & 255) * 8, rowi = idx >> 8;
    size_t base = ((size_t)rowi * HIDN + col) >> 2;
    f32x4 a0 = ((const f32x4*)P)[base], a1 = ((const f32x4*)P)[base + 1];
    for (int s = 1; s < S; ++s) {
        size_t sb = (size_t)s * (128 * HIDN / 4) + base;
        a0 += ((const f32x4*)P)[sb];
        a1 += ((const f32x4*)P)[sb + 1];
    }
    u16x8 h, l;
#pragma unroll
    for (int j = 0; j < 8; ++j) {
        float v = (j < 4 ? a0[j] : a1[j - 4]) + bias[col + j];
        v = fmaxf(v, 0.f);
        u16 hh = f2bf(v);
        h[j] = hh;
        l[j] = f2bf(v - bf2f(hh));
    }
    size_t ob = tiled_off(rowi, col, HIDN);
    *(u16x8*)&hi[ob] = h;
    *(u16x8*)&lo[ob] = l;
}

// ---------------------------------------------------------------------------
// K3d: MLP2 split-K reduce + bias fused with mem_kv concat -> ck/cv [KVH][33][DH]
// ---------------------------------------------------------------------------
__global__ void reduce_ckcv(const float* __restrict__ Pk, const float* __restrict__ Pv,
                            const float* __restrict__ mem_kv,
                            const float* __restrict__ kb2, const float* __restrict__ vb2,
                            float* __restrict__ ck, float* __restrict__ cv, int S) {
    int idx = blockIdx.x * 256 + threadIdx.x;   // 4*33*64 = 8448
    if (idx >= KVH * 33 * DH) return;
    int d = idx & 63;
    int j = (idx >> 6) % 33;
    int h = idx / (33 * 64);
    float kvv, vvv;
    if (j == 0) {
        kvv = mem_kv[(0 * KVH + h) * DH + d];
        vvv = mem_kv[(1 * KVH + h) * DH + d];
    } else {
        size_t base = (size_t)(h * WBLK + (j - 1)) * 128 + d;
        float ak = Pk[base], av = Pv[base];
        for (int s = 1; s < S; ++s) {
            ak += Pk[(size_t)s * (128 * 128) + base];
            av += Pv[(size_t)s * (128 * 128) + base];
        }
        kvv = ak + kb2[d];
        vvv = av + vb2[d];
    }
    ck[idx] = kvv;
    cv[idx] = vvv;
}

// ---------------------------------------------------------------------------
// K5: build compress-MLP inputs -> split-bf16 TILED (K=CDIM)
// ---------------------------------------------------------------------------
__global__ void build_cmlp_in(const float* __restrict__ qkv, const float* __restrict__ k_pos,
                              const float* __restrict__ v_pos,
                              u16* __restrict__ ckhi, u16* __restrict__ cklo,
                              u16* __restrict__ cvhi, u16* __restrict__ cvlo) {
    int idx = blockIdx.x * 256 + threadIdx.x;   // 128 * 256 = 32768
    int k = (idx & 255) * 8;
    int r = idx >> 8;                           // 0..127 = h*W + w
    int p = k >> 6, d = k & 63;
    int h = r >> 5, wb = r & 31;
    int nn = wb * BSZ + p;
    const float* kq = qkv + (size_t)nn * QKVD + (HEADS + h) * DH + d;
    const float* vq = qkv + (size_t)nn * QKVD + (HEADS + KVH + h) * DH + d;
    const float* kp = k_pos + (size_t)(h * BSZ + p) * DH + d;
    const float* vp = v_pos + (size_t)(h * BSZ + p) * DH + d;
    u16x8 kh, kl, vh, vl;
#pragma unroll
    for (int j = 0; j < 8; ++j) {
        float kv = kq[j] + kp[j];
        float vv = vq[j] + vp[j];
        u16 a = f2bf(kv), b = f2bf(vv);
        kh[j] = a; kl[j] = f2bf(kv - bf2f(a));
        vh[j] = b; vl[j] = f2bf(vv - bf2f(b));
    }
    size_t ob = tiled_off(r, k, CDIM);
    *(u16x8*)&ckhi[ob] = kh; *(u16x8*)&cklo[ob] = kl;
    *(u16x8*)&cvhi[ob] = vh; *(u16x8*)&cvlo[ob] = vl;
}

// ---------------------------------------------------------------------------
// K7: rotary (v16: powf -> __expf const-folded, sinf/cosf -> __sincosf,
// float2 loads/stores). Trig error ~1e-5 abs on angles <=1023 rad — negligible
// after attention; the absmax floor is bf16 quantization (2^-11) anyway.
// ---------------------------------------------------------------------------
__global__ void rotary_kernel(const float* __restrict__ qkv,
                              float* __restrict__ qr, float* __restrict__ kr,
                              float* __restrict__ vr) {
    int idx = blockIdx.x * 256 + threadIdx.x;   // 24*1024*32 = 786432
    int i = idx & 31;
    int n = (idx >> 5) & 1023;
    int hd = idx >> 15;
    if (hd >= 24) return;
    if (hd >= HEADS + KVH) {       // packed v copy
        int h = hd - (HEADS + KVH);
        const float* src = qkv + (size_t)n * QKVD + (HEADS + KVH + h) * DH;
        float* dst = vr + ((size_t)h * NTOK + n) * DH;
        *(float2*)&dst[2 * i] = *(const float2*)&src[2 * i];
        return;
    }
    // inv = 10000^(-i/32) = exp(-i * ln(10000)/32)
    float inv = __expf((float)i * -0.28782313662425572f);
    float fr = (float)n * inv;
    float s, c;
    __sincosf(fr, &s, &c);
    const float* src; float* dst;
    if (hd < HEADS) { src = qkv + (size_t)n * QKVD + hd * DH;          dst = qr + ((size_t)hd * NTOK + n) * DH; }
    else { int h = hd - HEADS;
           src = qkv + (size_t)n * QKVD + (HEADS + h) * DH;            dst = kr + ((size_t)h * NTOK + n) * DH; }
    float2 x = *(const float2*)&src[2 * i];
    float2 o;
    o.x = x.x * c - x.y * s;
    o.y = x.y * c + x.x * s;
    *(float2*)&dst[2 * i] = o;
}

// ---------------------------------------------------------------------------
// K8: compressed attention + importance + top-k. 4 tokens per 256-thr block.
// v16: score loop vectorized — was 192 scalar ds_read_b32/wave (LDS-pipe
// dominant, ~1100cyc), now 48 ds_read_b128 (~580cyc) with 2-chain f32x4 acc.
// ---------------------------------------------------------------------------
__global__ __launch_bounds__(256)
void cattn_kernel(const float* __restrict__ qkv, const float* __restrict__ ck,
                  const float* __restrict__ cv, float* __restrict__ c_out,
                  int* __restrict__ sel, int* __restrict__ selmask) {
    int h = blockIdx.y;
    int tid = threadIdx.x;
    int w = tid >> 6, lane = tid & 63;
    int grp = lane >> 4, sub = lane & 15;
    int n = blockIdx.x * 4 + w;
    __shared__ float cks[33 * 68];
    __shared__ float cvs[33 * 68];
    __shared__ float sims[16 * 36];      // [w*4+g][j]

    for (int t4 = tid; t4 < 1056; t4 += 256) {
        int half = (t4 >= 528) ? 1 : 0;
        int u = t4 - half * 528;
        int j = u >> 4, d4 = (u & 15) * 4;
        const float* src = (half ? cv : ck) + (size_t)h * 33 * 64 + j * 64 + d4;
        float* dst = (half ? cvs : cks) + j * 68 + d4;
        *(float4*)dst = *(const float4*)src;
    }
    f32x4 qv[16];
    {
        const float4* qp4 = (const float4*)(qkv + (size_t)n * QKVD + (h * GQ + grp) * DH);
#pragma unroll
        for (int c = 0; c < 16; ++c) {
            float4 v = qp4[c];
            qv[c] = (f32x4){v.x, v.y, v.z, v.w};
        }
    }
    __syncthreads();

#pragma unroll
    for (int r = 0; r < 3; ++r) {
        int j = r * 16 + sub;
        if (j < 33) {
            f32x4 a0 = (f32x4){0.f, 0.f, 0.f, 0.f};
            f32x4 a1 = (f32x4){0.f, 0.f, 0.f, 0.f};
#pragma unroll
            for (int c = 0; c < 16; c += 2) {
                a0 += qv[c]     * (*(const f32x4*)&cks[j * 68 + c * 4]);
                a1 += qv[c + 1] * (*(const f32x4*)&cks[j * 68 + (c + 1) * 4]);
            }
            f32x4 at = a0 + a1;
            sims[(w * 4 + grp) * 36 + j] = ((at[0] + at[1]) + (at[2] + at[3])) * SCALE;
        }
    }

    float ival = NEGINF;
    if (lane < 32)
        ival = 0.25f * (sims[(w * 4 + 0) * 36 + 1 + lane] + sims[(w * 4 + 1) * 36 + 1 + lane] +
                        sims[(w * 4 + 2) * 36 + 1 + lane] + sims[(w * 4 + 3) * 36 + 1 + lane]);
    float m = ival;
    for (int off = 32; off; off >>= 1) m = fmaxf(m, __shfl_xor(m, off));
    float e = (lane < 32) ? expf(ival - m) : 0.f;
    float sum = e;
    for (int off = 32; off; off >>= 1) sum += __shfl_xor(sum, off);
    float p = (lane < 32) ? e / sum : NEGINF;

    float v = p;
    int base = (h * NTOK + n) * 9;
    for (int t = 0; t < NSEL; ++t) {
        float bv = v; int bi = lane;
        for (int off = 32; off; off >>= 1) {
            float ov = __shfl_xor(bv, off);
            int   oi = __shfl_xor(bi, off);
            if (ov > bv || (ov == bv && oi < bi)) { bv = ov; bi = oi; }
        }
        if (lane == 0) { sel[base + t] = bi; selmask[base + t] = (bv > 1e-10f) ? 1 : 0; }
        if (lane == bi) v = NEGINF;
    }
    if (lane == 0) { sel[base + NSEL] = n >> 5; selmask[base + NSEL] = 1; }

#pragma unroll
    for (int g = 0; g < 4; ++g) {
        float sv = (lane < 33) ? sims[(w * 4 + g) * 36 + lane] : NEGINF;
        float mm = sv;
        for (int off = 32; off; off >>= 1) mm = fmaxf(mm, __shfl_xor(mm, off));
        float ee = (lane < 33) ? __expf(sv - mm) : 0.f;
        float ssum = ee;
        for (int off = 32; off; off >>= 1) ssum += __shfl_xor(ssum, off);
        if (lane < 33) sims[(w * 4 + g) * 36 + lane] = ee / ssum;
    }

    f32x4 o = (f32x4){0.f, 0.f, 0.f, 0.f};
#pragma unroll
    for (int j = 0; j < 33; ++j) {
        float a = sims[(w * 4 + grp) * 36 + j];
        f32x4 vv = *(const f32x4*)&cvs[j * 68 + sub * 4];
        o += a * vv;
    }
    *(f32x4*)&c_out[(((size_t)(h * GQ + grp)) * NTOK + n) * DH + sub * 4] = o;
}

// ---------------------------------------------------------------------------
// K9: fine attention v15 (unchanged — control for this round).
// Barrier-free loop via split-softmax partials; K/V split LDS buffers with
// counted-vmcnt pipeline; VALU chain-split. 62.0us measured, conflicts 0.
// ---------------------------------------------------------------------------
__global__ void fattn_kernel(const float* __restrict__ qr, const float* __restrict__ kr,
                             const float* __restrict__ vr, const int* __restrict__ sel,
                             const int* __restrict__ selmask, float* __restrict__ f_out) {
    int n = blockIdx.x, h = blockIdx.y;
    int tid = threadIdx.x;
    int w = tid >> 6, lane = tid & 63;
    int grp = lane >> 4, sub = lane & 15;
    __shared__ float qsm[4 * 68];
    __shared__ float Ksm[64 * 64];       // slot s of row r = global slot s^(r&15)
    __shared__ float Vsm[64 * 64];
    __shared__ float ps[4 * 68];         // wave-private p rows: ps[w][g*16+sub]
    __shared__ float msm[16], lsm[16];   // [slice w * 4 + head g]
    __shared__ int sel_s[9], msk_s[9];

    if (tid < 9) {
        sel_s[tid] = sel[(h * NTOK + n) * 9 + tid];
        msk_s[tid] = selmask[(h * NTOK + n) * 9 + tid];
    }
    // q -> LDS once: wave w loads head w's 64 elements
    qsm[w * 68 + lane] = qr[(((size_t)(h * GQ + w)) * NTOK + n) * DH + lane];
    f32x4 o4 = (f32x4){0.f, 0.f, 0.f, 0.f};   // partial over (head grp, slice w), dims sub*4..+3
    float m_run = -3.402823466e38f, l_run = 0.f;
    __syncthreads();                     // B0: sel_s + qsm ready

    const float* krh_ = kr + (size_t)h * NTOK * DH;
    const float* vrh_ = vr + (size_t)h * NTOK * DH;

    int rl = lane >> 4, sl = lane & 15;

    auto stageRows = [&](float* dstbuf, const float* src, int bp) {
        int nrow = (bp < 4) ? 64 : 32;
        if (w * 16 < nrow) {
            int myblk = sel_s[bp * 2 + (w >> 1)];
            const float* b_ = src + (size_t)myblk * BSZ * DH;
#pragma unroll
            for (int cc = 0; cc < 4; ++cc) {
                int r = w * 16 + cc * 4 + rl;
                int sg = sl ^ (r & 15);
                glds16(b_ + (size_t)(r & 31) * DH + sg * 4, &dstbuf[(w * 16 + cc * 4) * 64]);
            }
        }
    };

    stageRows(Ksm, krh_, 0);             // prologue: K(0) then V(0) (wave-private)
    stageRows(Vsm, vrh_, 0);

    for (int bp = 0; bp < 5; ++bp) {
        int nrow = (bp < 4) ? 64 : 32;

        // wave-local: own K quad retired (oldest 4 of <=8 outstanding)
        asm volatile("s_waitcnt vmcnt(4)" ::: "memory");
        __builtin_amdgcn_sched_barrier(0);

        // ---- scores: thread (grp, jj=w*16+sub) reads OWN-wave K rows only
        float s = -3.402823466e38f;
        {
            int jj = w * 16 + sub;
            int b = bp * 2 + (jj >> 5);
            if (jj < nrow && msk_s[b]) {
                int sw = jj & 15;
                const float* Kb = &Ksm[jj * 64];
                f32x4 a0 = (f32x4){0.f, 0.f, 0.f, 0.f};
                f32x4 a1 = (f32x4){0.f, 0.f, 0.f, 0.f};
#pragma unroll
                for (int c = 0; c < 16; c += 2) {
                    f32x4 k4a = *(const f32x4*)&Kb[(c ^ sw) * 4];
                    f32x4 q4a = *(const f32x4*)&qsm[grp * 68 + c * 4];
                    f32x4 k4b = *(const f32x4*)&Kb[((c + 1) ^ sw) * 4];
                    f32x4 q4b = *(const f32x4*)&qsm[grp * 68 + (c + 1) * 4];
                    a0 += q4a * k4a;
                    a1 += q4b * k4b;
                }
                f32x4 at = a0 + a1;
                s = ((at[0] + at[1]) + (at[2] + at[3])) * SCALE;
            }
        }
        // ---- in-register online softmax over the 16-lane group (head grp, slice w)
        float mb = s;
        for (int off = 8; off; off >>= 1) mb = fmaxf(mb, __shfl_xor(mb, off));
        float m_new = fmaxf(m_run, mb);
        float pp = (s > -1e37f) ? __expf(s - m_new) : 0.f;
        float alpha = __expf(m_run - m_new);   // ==1 when slice empty (both -3.4e38)
        float psum = pp;
        for (int off = 8; off; off >>= 1) psum += __shfl_xor(psum, off);
        l_run = l_run * alpha + psum;
        m_run = m_new;
        ps[w * 68 + grp * 16 + sub] = pp;      // wave-private row

        // retire our K ds_reads + ps write, then issue K(bp+1) into own rows
        __builtin_amdgcn_sched_barrier(0);
        asm volatile("s_waitcnt lgkmcnt(0)" ::: "memory");
        __builtin_amdgcn_sched_barrier(0);
        if (bp < 4) {
            stageRows(Ksm, krh_, bp + 1);
            // wave-local: V(bp) quad retired (oldest 4; K(bp+1) still in flight)
            asm volatile("s_waitcnt vmcnt(4)" ::: "memory");
        } else {
            asm volatile("s_waitcnt vmcnt(0)" ::: "memory");
        }
        __builtin_amdgcn_sched_barrier(0);

        // ---- PV: wave w reads OWN V rows + OWN ps; thread (g=grp, c=sub)
        {
            f32x4 t0 = (f32x4){0.f, 0.f, 0.f, 0.f};
            f32x4 t1 = (f32x4){0.f, 0.f, 0.f, 0.f};
            int jbase = w * 16;
            if (jbase < nrow) {
#pragma unroll
                for (int jq = 0; jq < 4; ++jq) {
                    f32x4 p4 = *(const f32x4*)&ps[w * 68 + grp * 16 + jq * 4];
#pragma unroll
                    for (int r = 0; r < 4; ++r) {
                        int row = jbase + jq * 4 + r;
                        int slot = sub ^ (row & 15);
                        f32x4 vv = *(const f32x4*)&Vsm[row * 64 + slot * 4];
                        if (r & 1) t1 += p4[r] * vv;
                        else       t0 += p4[r] * vv;
                    }
                }
            }
            o4 = o4 * alpha + (t0 + t1);
        }
        // retire PV ds_reads, then issue V(bp+1) into own rows
        if (bp < 4) {
            __builtin_amdgcn_sched_barrier(0);
            asm volatile("s_waitcnt lgkmcnt(0)" ::: "memory");
            __builtin_amdgcn_sched_barrier(0);
            stageRows(Vsm, vrh_, bp + 1);
        }
    }
    // ---- epilogue: split-softmax merge of the 4 slice-partials per head
    if (sub == 0) { msm[w * 4 + grp] = m_run; lsm[w * 4 + grp] = l_run; }
    __syncthreads();                      // all loops done -> Ksm free; msm/lsm visible
    *(f32x4*)&Ksm[(w * 4 + grp) * 64 + sub * 4] = o4;
    __syncthreads();
    // thread: head = w, dim = lane
    float m0 = msm[0 * 4 + w], m1 = msm[1 * 4 + w], m2 = msm[2 * 4 + w], m3 = msm[3 * 4 + w];
    float M = fmaxf(fmaxf(m0, m1), fmaxf(m2, m3));
    float f0 = __expf(m0 - M), f1 = __expf(m1 - M), f2 = __expf(m2 - M), f3 = __expf(m3 - M);
    float L = lsm[0 * 4 + w] * f0 + lsm[1 * 4 + w] * f1 + lsm[2 * 4 + w] * f2 + lsm[3 * 4 + w] * f3;
    float sum = Ksm[(0 * 4 + w) * 64 + lane] * f0 + Ksm[(1 * 4 + w) * 64 + lane] * f1
              + Ksm[(2 * 4 + w) * 64 + lane] * f2 + Ksm[(3 * 4 + w) * 64 + lane] * f3;
    f_out[(((size_t)(h * GQ + w)) * NTOK + n) * DH + lane] = sum / L;
}

// ---------------------------------------------------------------------------
// K10: gated mix -> split-bf16 TILED (K=DDIM). gates f32 [N][128] padded.
// ---------------------------------------------------------------------------
__global__ void mix_kernel(const float* __restrict__ gates, const float* __restrict__ c_out,
                           const float* __restrict__ f_out,
                           u16* __restrict__ mixhi, u16* __restrict__ mixlo) {
    int idx = blockIdx.x * 256 + threadIdx.x;   // 1024*1024/8 = 131072
    int col = (idx & 127) * 8;
    int n = idx >> 7;
    int hd = col >> 6, d = col & 63;
    float g0 = gates[(size_t)n * 128 + hd * 2];
    float g1 = gates[(size_t)n * 128 + hd * 2 + 1];
    size_t hoff = (((size_t)hd) * NTOK + n) * DH + d;
    u16x8 h, l;
#pragma unroll
    for (int j = 0; j < 8; ++j) {
        float v = g0 * c_out[hoff + j] + g1 * f_out[hoff + j];
        u16 hh = f2bf(v);
        h[j] = hh;
        l[j] = f2bf(v - bf2f(hh));
    }
    size_t ob = tiled_off(n, col, DDIM);
    *(u16x8*)&mixhi[ob] = h;
    *(u16x8*)&mixlo[ob] = l;
}

// ---------------------------------------------------------------------------
extern "C" void kernel_launch(void* const* d_in, const int* in_sizes, int n_in,
                              void* d_out, int out_size, void* d_ws, size_t ws_size,
                              hipStream_t stream) {
    const float* inp    = (const float*)d_in[0];
    const float* g_norm = (const float*)d_in[1];
    const float* w_qkv  = (const float*)d_in[2];
    const float* mem_kv = (const float*)d_in[3];
    const float* k_pos  = (const float*)d_in[4];
    const float* v_pos  = (const float*)d_in[5];
    const float* k_w1   = (const float*)d_in[6];
    const float* k_b1   = (const float*)d_in[7];
    const float* k_w2   = (const float*)d_in[8];
    const float* k_b2   = (const float*)d_in[9];
    const float* v_w1   = (const float*)d_in[10];
    const float* v_b1   = (const float*)d_in[11];
    const float* v_w2   = (const float*)d_in[12];
    const float* v_b2   = (const float*)d_in[13];
    const float* gate_w = (const float*)d_in[14];
    const float* gate_b = (const float*)d_in[15];
    const float* w_out  = (const float*)d_in[16];
    float* out = (float*)d_out;

    char* wsb = (char*)d_ws;
    size_t off = 0;
    auto alloc = [&](size_t bytes) -> void* {
        void* p = wsb + off;
        off = (off + bytes + 255) & ~(size_t)255;
        return p;
    };
    u16*   xhi    = (u16*)  alloc((size_t)NTOK * DDIM * 2);
    u16*   xlo    = (u16*)  alloc((size_t)NTOK * DDIM * 2);
    float* qkvb   = (float*)alloc((size_t)NTOK * QKVD * 4);
    u16*   wqThi  = (u16*)  alloc((size_t)QKVD * DDIM * 2);
    u16*   wqTlo  = (u16*)  alloc((size_t)QKVD * DDIM * 2);
    u16*   kw1Thi = (u16*)  alloc((size_t)HIDN * CDIM * 2);
    u16*   kw1Tlo = (u16*)  alloc((size_t)HIDN * CDIM * 2);
    u16*   vw1Thi = (u16*)  alloc((size_t)HIDN * CDIM * 2);
    u16*   vw1Tlo = (u16*)  alloc((size_t)HIDN * CDIM * 2);
    u16*   woThi  = (u16*)  alloc((size_t)DDIM * DDIM * 2);
    u16*   gwThi  = (u16*)  alloc((size_t)128 * DDIM * 2);
    u16*   gwTlo  = (u16*)  alloc((size_t)128 * DDIM * 2);
    float* gbp    = (float*)alloc(128 * 4);
    u16*   kw2Thi = (u16*)  alloc((size_t)128 * HIDN * 2);
    u16*   kw2Tlo = (u16*)  alloc((size_t)128 * HIDN * 2);
    float* kb2p   = (float*)alloc(128 * 4);
    u16*   vw2Thi = (u16*)  alloc((size_t)128 * HIDN * 2);
    u16*   vw2Tlo = (u16*)  alloc((size_t)128 * HIDN * 2);
    float* vb2p   = (float*)alloc(128 * 4);
    u16*   cinkhi = (u16*)  alloc((size_t)128 * CDIM * 2);
    u16*   cinklo = (u16*)  alloc((size_t)128 * CDIM * 2);
    u16*   cinvhi = (u16*)  alloc((size_t)128 * CDIM * 2);
    u16*   cinvlo = (u16*)  alloc((size_t)128 * CDIM * 2);
    u16*   hidkhi = (u16*)  alloc((size_t)128 * HIDN * 2);
    u16*   hidklo = (u16*)  alloc((size_t)128 * HIDN * 2);
    u16*   hidvhi = (u16*)  alloc((size_t)128 * HIDN * 2);
    u16*   hidvlo = (u16*)  alloc((size_t)128 * HIDN * 2);
    float* Pg     = (float*)alloc((size_t)8 * NTOK * 128 * 4);
    float* Pm1k   = (float*)alloc((size_t)4 * 128 * HIDN * 4);
    float* Pm1v   = (float*)alloc((size_t)4 * 128 * HIDN * 4);
    float* Pm2k   = (float*)alloc((size_t)8 * 128 * 128 * 4);
    float* Pm2v   = (float*)alloc((size_t)8 * 128 * 128 * 4);
    float* ck     = (float*)alloc((size_t)KVH * 33 * DH * 4);
    float* cv     = (float*)alloc((size_t)KVH * 33 * DH * 4);
    float* qr     = (float*)alloc((size_t)HEADS * NTOK * DH * 4);
    float* kr     = (float*)alloc((size_t)KVH * NTOK * DH * 4);
    float* vr     = (float*)alloc((size_t)KVH * NTOK * DH * 4);
    float* c_out  = (float*)alloc((size_t)HEADS * NTOK * DH * 4);
    float* f_out  = (float*)alloc((size_t)HEADS * NTOK * DH * 4);
    float* gates  = (float*)alloc((size_t)NTOK * 128 * 4);
    int*   sel    = (int*)  alloc((size_t)KVH * NTOK * 9 * 4);
    int*   selmask= (int*)  alloc((size_t)KVH * NTOK * 9 * 4);
    u16*   mixhi  = (u16*)  alloc((size_t)NTOK * DDIM * 2);
    u16*   mixlo  = (u16*)  alloc((size_t)NTOK * DDIM * 2);

    // 0. ALL weight prep + RMSNorm in one dispatch (v16 mega-prep)
    prep_kernel<<<3520, 256, 0, stream>>>(
        w_qkv, k_w1, v_w1, w_out, gate_w, gate_b, k_w2, k_b2, v_w2, v_b2,
        inp, g_norm,
        wqThi, wqTlo, kw1Thi, kw1Tlo, vw1Thi, vw1Tlo, woThi,
        gwThi, gwTlo, gbp, kw2Thi, kw2Tlo, kb2p, vw2Thi, vw2Tlo, vb2p,
        xhi, xlo);

    // 2. qkv = x @ w_qkv (final f32)
    gemm_tiled<3, 0, 1><<<dim3(QKVD / 128, NTOK / 128, 1), 256, 0, stream>>>(
        xhi, xlo, wqThi, wqTlo, nullptr, qkvb,
        xhi, xlo, wqThi, wqTlo, nullptr, qkvb, NTOK, QKVD, DDIM, 1);
    // 3. gates (split-K 8 + sigmoid reduce)
    gemm_tiled<3, 0, 0><<<dim3(1, NTOK / 128, 8), 256, 0, stream>>>(
        xhi, xlo, gwThi, gwTlo, nullptr, Pg,
        xhi, xlo, gwThi, gwTlo, nullptr, Pg, NTOK, 128, DDIM, 8);
    reduce_f32<2><<<dim3(128, 1), 256, 0, stream>>>(Pg, gbp, gates, Pg, gbp, gates, 8, NTOK, 128);
    // 4. compress-MLP inputs (tiled)
    build_cmlp_in<<<128, 256, 0, stream>>>(qkvb, k_pos, v_pos, cinkhi, cinklo, cinvhi, cinvlo);
    // 5. MLP1 (split-K 4, k&v batched; relu+bias+split-tile in reduce)
    gemm_tiled<3, 0, 0><<<dim3(HIDN / 128, 1, 8), 256, 0, stream>>>(
        cinkhi, cinklo, kw1Thi, kw1Tlo, nullptr, Pm1k,
        cinvhi, cinvlo, vw1Thi, vw1Tlo, nullptr, Pm1v, 128, HIDN, CDIM, 4);
    reduce_hid<<<dim3(128, 2), 256, 0, stream>>>(Pm1k, k_b1, hidkhi, hidklo,
                                                 Pm1v, v_b1, hidvhi, hidvlo, 4);
    // 6. MLP2 (split-K 8, k&v batched) + fused reduce/bias/concat
    gemm_tiled<3, 0, 0><<<dim3(1, 1, 16), 256, 0, stream>>>(
        hidkhi, hidklo, kw2Thi, kw2Tlo, nullptr, Pm2k,
        hidvhi, hidvlo, vw2Thi, vw2Tlo, nullptr, Pm2v, 128, 128, HIDN, 8);
    reduce_ckcv<<<33, 256, 0, stream>>>(Pm2k, Pm2v, mem_kv, kb2p, vb2p, ck, cv, 8);
    // 8. rotary + packed v (fast-math)
    rotary_kernel<<<(24 * NTOK * 32) / 256, 256, 0, stream>>>(qkvb, qr, kr, vr);
    // 9. compressed attention + selection (vectorized scores)
    cattn_kernel<<<dim3(NTOK / 4, KVH), 256, 0, stream>>>(qkvb, ck, cv, c_out, sel, selmask);
    // 10. fine attention (v15, unchanged — control)
    fattn_kernel<<<dim3(NTOK, KVH), 256, 0, stream>>>(qr, kr, vr, sel, selmask, f_out);
    // 11. gated mix -> tiled split-bf16
    mix_kernel<<<(NTOK * DDIM / 8) / 256, 256, 0, stream>>>(gates, c_out, f_out, mixhi, mixlo);
    // 12. output projection (bf16, final)
    gemm_tiled<1, 0, 1><<<dim3(DDIM / 128, NTOK / 128, 1), 256, 0, stream>>>(
        mixhi, mixhi, woThi, woThi, nullptr, out,
        mixhi, mixhi, woThi, woThi, nullptr, out, NTOK, DDIM, DDIM, 1);
}

// Round 10
// 308.813 us; speedup vs baseline: 1.2353x; 1.0685x over previous
//
#include <hip/hip_runtime.h>
#include <math.h>

// ---- fixed problem sizes ----
#define NTOK 1024
#define DDIM 1024
#define HEADS 16
#define KVH 4
#define DH 64
#define BSZ 32
#define NSEL 8
#define WBLK 32            // NTOK / BSZ
#define GQ 4               // HEADS / KVH
#define CDIM 2048          // BSZ*DH
#define HIDN 2048
#define QKVD 1536          // (HEADS + 2*KVH)*DH
#define QKVG 1664          // QKVD + 128 (gate block appended, v17 fusion)
#define SCALE 0.125f       // DH^-0.5
#define NEGINF (-__builtin_inff())

// u16-element offset of the gate block (rows 1536..1663) inside the extended
// tiled weight matrix: (1536>>4) * (DDIM>>5) * 64 * 8
#define OFFGATE ((size_t)96 * 32 * 512)

typedef unsigned short u16;
typedef u16   u16x8  __attribute__((ext_vector_type(8)));
typedef short short8 __attribute__((ext_vector_type(8)));
typedef float f32x4  __attribute__((ext_vector_type(4)));

__device__ __forceinline__ u16 f2bf(float f) {
    unsigned u = __float_as_uint(f);
    return (u16)((u + 0x7fffu + ((u >> 16) & 1u)) >> 16);
}
__device__ __forceinline__ float bf2f(u16 h) { return __uint_as_float(((unsigned)h) << 16); }

__device__ __forceinline__ void glds16(const void* g, void* l) {
    __builtin_amdgcn_global_load_lds(
        (const __attribute__((address_space(1))) unsigned int*)g,
        (__attribute__((address_space(3))) unsigned int*)l, 16, 0, 0);
}

// element offset (in u16) of the 8-element lane-slot for (row, k..k+7) in the
// MFMA-fragment-tiled layout: 16-row x 32-k tiles, 1KB each, contiguous.
__device__ __forceinline__ size_t tiled_off(int row, int k, int K) {
    return ((size_t)((row >> 4) * (K >> 5) + (k >> 5)) * 64 +
            ((row & 15) | (((k >> 3) & 3) << 4))) * 8;
}

// ---------------------------------------------------------------------------
// K0: MEGA-PREP — all weight prep + RMSNorm in ONE dispatch.
// v17: gate_w pad now writes into the EXTENDED wqT matrix at row offset 1536
// (pointer offset OFFGATE — tiled layout makes the append exact).
// Ranges: [0,384) wqT | [384,1408) kw1T | [1408,2432) vw1T | [2432,2688) woT
//         | [2688,2752) pad gate->wqT+OFF | [2752,2880) pad kw2
//         | [2880,3008) pad vw2 | [3008,3520) rmsnorm
// ---------------------------------------------------------------------------
__device__ __forceinline__ void transpose_body(const float* __restrict__ W,
                                               u16* __restrict__ Thi, u16* __restrict__ Tlo,
                                               int K, int N, int bx, int by,
                                               float (*tile)[65]) {
    int k0 = by * 64, n0 = bx * 64;
    int t = threadIdx.x;
    int r = t >> 4, c4 = (t & 15) * 4;
#pragma unroll
    for (int p = 0; p < 4; ++p) {
        float4 v = *(const float4*)&W[(size_t)(k0 + r + p * 16) * N + n0 + c4];
        tile[r + p * 16][c4 + 0] = v.x;
        tile[r + p * 16][c4 + 1] = v.y;
        tile[r + p * 16][c4 + 2] = v.z;
        tile[r + p * 16][c4 + 3] = v.w;
    }
    __syncthreads();
    int n = t >> 2, ks = (t & 3) * 16;
#pragma unroll
    for (int c = 0; c < 2; ++c) {
        u16x8 h, l;
#pragma unroll
        for (int j = 0; j < 8; ++j) {
            float v = tile[ks + c * 8 + j][n];
            u16 hh = f2bf(v);
            h[j] = hh;
            l[j] = f2bf(v - bf2f(hh));
        }
        size_t ob = tiled_off(n0 + n, k0 + ks + c * 8, K);
        *(u16x8*)&Thi[ob] = h;
        if (Tlo) *(u16x8*)&Tlo[ob] = l;
    }
}

__device__ __forceinline__ void pad_body(const float* __restrict__ W, const float* __restrict__ b,
                                         u16* __restrict__ Thi, u16* __restrict__ Tlo,
                                         float* __restrict__ bias_pad, int K, int Xn, int KLOG,
                                         int bx) {
    int idx = bx * 256 + threadIdx.x;
    int k = (idx & ((K >> 3) - 1)) * 8;
    int n = idx >> (KLOG - 3);
    if (n >= 128) return;
    u16x8 h, l;
#pragma unroll
    for (int j = 0; j < 8; ++j) {
        float v = (n < Xn) ? W[(size_t)(k + j) * Xn + n] : 0.f;
        u16 hh = f2bf(v);
        h[j] = hh;
        l[j] = f2bf(v - bf2f(hh));
    }
    size_t ob = tiled_off(n, k, K);
    *(u16x8*)&Thi[ob] = h;
    *(u16x8*)&Tlo[ob] = l;
    if (bias_pad && k == 0) bias_pad[n] = (n < Xn) ? b[n] : 0.f;
}

__device__ __forceinline__ void rms_body(const float* __restrict__ inp, const float* __restrict__ g,
                                         u16* __restrict__ xhi, u16* __restrict__ xlo,
                                         int bx, float* red) {
    int t = threadIdx.x;
    int half = t >> 7, tid = t & 127;
    int n = bx * 2 + half;
    const float4* row = (const float4*)(inp + (size_t)n * DDIM);
    float4 v0 = row[tid * 2], v1 = row[tid * 2 + 1];
    float ss = v0.x*v0.x + v0.y*v0.y + v0.z*v0.z + v0.w*v0.w
             + v1.x*v1.x + v1.y*v1.y + v1.z*v1.z + v1.w*v1.w;
    for (int off = 32; off; off >>= 1) ss += __shfl_down(ss, off);
    if ((t & 63) == 0) red[t >> 6] = ss;
    __syncthreads();
    float tot = red[half * 2] + red[half * 2 + 1];
    float r = 1.f / sqrtf(tot * (1.f / DDIM) + 1e-6f);
    const float4* gp = (const float4*)g;
    float4 g0 = gp[tid * 2], g1 = gp[tid * 2 + 1];
    float o[8] = { v0.x*r*g0.x, v0.y*r*g0.y, v0.z*r*g0.z, v0.w*r*g0.w,
                   v1.x*r*g1.x, v1.y*r*g1.y, v1.z*r*g1.z, v1.w*r*g1.w };
    u16x8 h, l;
#pragma unroll
    for (int i = 0; i < 8; ++i) {
        u16 hh = f2bf(o[i]);
        h[i] = hh;
        l[i] = f2bf(o[i] - bf2f(hh));
    }
    size_t ob = tiled_off(n, tid * 8, DDIM);
    *(u16x8*)&xhi[ob] = h;
    *(u16x8*)&xlo[ob] = l;
}

__global__ void prep_kernel(const float* __restrict__ w_qkv, const float* __restrict__ k_w1,
                            const float* __restrict__ v_w1, const float* __restrict__ w_out,
                            const float* __restrict__ gate_w,
                            const float* __restrict__ k_w2, const float* __restrict__ k_b2,
                            const float* __restrict__ v_w2, const float* __restrict__ v_b2,
                            const float* __restrict__ inp, const float* __restrict__ g_norm,
                            u16* wqThi, u16* wqTlo, u16* kw1Thi, u16* kw1Tlo,
                            u16* vw1Thi, u16* vw1Tlo, u16* woThi,
                            u16* kw2Thi, u16* kw2Tlo, float* kb2p,
                            u16* vw2Thi, u16* vw2Tlo, float* vb2p,
                            u16* xhi, u16* xlo) {
    __shared__ float tile[64][65];
    __shared__ float red[4];
    int b = blockIdx.x;
    if (b < 384) {
        transpose_body(w_qkv, wqThi, wqTlo, DDIM, QKVD, b % 24, b / 24, tile);
    } else if (b < 1408) {
        int r = b - 384;
        transpose_body(k_w1, kw1Thi, kw1Tlo, CDIM, HIDN, r & 31, r >> 5, tile);
    } else if (b < 2432) {
        int r = b - 1408;
        transpose_body(v_w1, vw1Thi, vw1Tlo, CDIM, HIDN, r & 31, r >> 5, tile);
    } else if (b < 2688) {
        int r = b - 2432;
        transpose_body(w_out, woThi, nullptr, DDIM, DDIM, r & 15, r >> 4, tile);
    } else if (b < 2752) {
        // gate_w -> extended wqT rows [1536,1664)
        pad_body(gate_w, nullptr, wqThi + OFFGATE, wqTlo + OFFGATE, nullptr, DDIM, 32, 10, b - 2688);
    } else if (b < 2880) {
        pad_body(k_w2, k_b2, kw2Thi, kw2Tlo, kb2p, HIDN, 64, 11, b - 2752);
    } else if (b < 3008) {
        pad_body(v_w2, v_b2, vw2Thi, vw2Tlo, vb2p, HIDN, 64, 11, b - 2880);
    } else {
        rms_body(inp, g_norm, xhi, xlo, b - 3008, red);
    }
}

// ---------------------------------------------------------------------------
// K3: tiled MFMA GEMM with software pipeline + optional split-K.
// ---------------------------------------------------------------------------
template<int SPLIT, int ACT, int FINAL>
__global__ __launch_bounds__(256, 1)
void gemm_tiled(const u16* __restrict__ Ahi0, const u16* __restrict__ Alo0,
                const u16* __restrict__ Bhi0, const u16* __restrict__ Blo0,
                const float* __restrict__ bias0, float* __restrict__ C0,
                const u16* __restrict__ Ahi1, const u16* __restrict__ Alo1,
                const u16* __restrict__ Bhi1, const u16* __restrict__ Blo1,
                const float* __restrict__ bias1, float* __restrict__ C1,
                int M, int N, int K, int S) {
    int batch = blockIdx.z / S;
    int s = blockIdx.z - batch * S;
    const u16* Ahi = batch ? Ahi1 : Ahi0;
    const u16* Alo = batch ? Alo1 : Alo0;
    const u16* Bhi = batch ? Bhi1 : Bhi0;
    const u16* Blo = batch ? Blo1 : Blo0;
    const float* bias = batch ? bias1 : bias0;
    float* C = batch ? C1 : C0;

    constexpr int PARTS = (SPLIT == 3) ? 2 : 1;
    __shared__ u16 smA[2 * PARTS * 8 * 512];
    __shared__ u16 smB[2 * PARTS * 8 * 512];

    int tid = threadIdx.x;
    int w = tid >> 6, L = tid & 63;
    int m15 = L & 15, q = L >> 4;
    int KT = K >> 5;
    int rowTile = blockIdx.y * 8, colTile = blockIdx.x * 8;
    int NIT = (K / S) >> 5;
    int kb0 = s * NIT;
    int aw = w & 1, bw = w >> 1;

    f32x4 acc[4][4];
#pragma unroll
    for (int i = 0; i < 4; ++i)
#pragma unroll
        for (int j = 0; j < 4; ++j) acc[i][j] = (f32x4){0.f, 0.f, 0.f, 0.f};

    auto stage = [&](int buf, int kb) {
#pragma unroll
        for (int rl = 0; rl < 2; ++rl) {
            int rb = 2 * w + rl;
            glds16(Ahi + ((size_t)(rowTile + rb) * KT + kb) * 512 + (size_t)L * 8,
                   &smA[((buf * PARTS + 0) * 8 + rb) * 512]);
            glds16(Bhi + ((size_t)(colTile + rb) * KT + kb) * 512 + (size_t)L * 8,
                   &smB[((buf * PARTS + 0) * 8 + rb) * 512]);
            if constexpr (SPLIT == 3) {
                glds16(Alo + ((size_t)(rowTile + rb) * KT + kb) * 512 + (size_t)L * 8,
                       &smA[((buf * PARTS + 1) * 8 + rb) * 512]);
                glds16(Blo + ((size_t)(colTile + rb) * KT + kb) * 512 + (size_t)L * 8,
                       &smB[((buf * PARTS + 1) * 8 + rb) * 512]);
            }
        }
    };

    stage(0, kb0);
    for (int it = 0; it < NIT; ++it) {
        __syncthreads();
        if (it + 1 < NIT) stage((it + 1) & 1, kb0 + it + 1);
        int buf = it & 1;
        short8 ah[4], bh[4];
#pragma unroll
        for (int i = 0; i < 4; ++i) {
            ah[i] = *(const short8*)&smA[((buf * PARTS + 0) * 8 + aw * 4 + i) * 512 + L * 8];
            bh[i] = *(const short8*)&smB[((buf * PARTS + 0) * 8 + bw * 4 + i) * 512 + L * 8];
        }
        if constexpr (SPLIT == 3) {
            short8 al[4], bl[4];
#pragma unroll
            for (int i = 0; i < 4; ++i) {
                al[i] = *(const short8*)&smA[((buf * PARTS + 1) * 8 + aw * 4 + i) * 512 + L * 8];
                bl[i] = *(const short8*)&smB[((buf * PARTS + 1) * 8 + bw * 4 + i) * 512 + L * 8];
            }
#pragma unroll
            for (int i = 0; i < 4; ++i)
#pragma unroll
                for (int j = 0; j < 4; ++j) {
                    acc[i][j] = __builtin_amdgcn_mfma_f32_16x16x32_bf16(ah[i], bl[j], acc[i][j], 0, 0, 0);
                    acc[i][j] = __builtin_amdgcn_mfma_f32_16x16x32_bf16(al[i], bh[j], acc[i][j], 0, 0, 0);
                    acc[i][j] = __builtin_amdgcn_mfma_f32_16x16x32_bf16(ah[i], bh[j], acc[i][j], 0, 0, 0);
                }
        } else {
#pragma unroll
            for (int i = 0; i < 4; ++i)
#pragma unroll
                for (int j = 0; j < 4; ++j)
                    acc[i][j] = __builtin_amdgcn_mfma_f32_16x16x32_bf16(ah[i], bh[j], acc[i][j], 0, 0, 0);
        }
    }

    if constexpr (FINAL == 0) C += (size_t)s * M * N;
#pragma unroll
    for (int i = 0; i < 4; ++i) {
        int row = rowTile * 16 + aw * 64 + i * 16 + q * 4;
#pragma unroll
        for (int j = 0; j < 4; ++j) {
            int col = colTile * 16 + bw * 64 + j * 16 + m15;
            float bv = (FINAL && bias) ? bias[col] : 0.f;
#pragma unroll
            for (int r = 0; r < 4; ++r) {
                float v = acc[i][j][r];
                if constexpr (FINAL) {
                    v += bv;
                    if (ACT == 1) v = fmaxf(v, 0.f);
                    if (ACT == 2) v = 1.f / (1.f + expf(-v));
                }
                C[(size_t)(row + r) * N + col] = v;
            }
        }
    }
}

// ---------------------------------------------------------------------------
// K3b: split-K reduce -> f32 [M][N] with bias/act. Dual pointer sets via blockIdx.y.
// ---------------------------------------------------------------------------
template<int ACT>
__global__ void reduce_f32(const float* __restrict__ P0, const float* __restrict__ bias0,
                           float* __restrict__ C0,
                           const float* __restrict__ P1, const float* __restrict__ bias1,
                           float* __restrict__ C1, int S, int M, int N) {
    const float* P = blockIdx.y ? P1 : P0;
    const float* bias = blockIdx.y ? bias1 : bias0;
    float* C = blockIdx.y ? C1 : C0;
    int idx = blockIdx.x * 256 + threadIdx.x;
    int mn4 = (M * N) >> 2;
    if (idx >= mn4) return;
    f32x4 a = ((const f32x4*)P)[idx];
    for (int s = 1; s < S; ++s) a += ((const f32x4*)P)[(size_t)s * mn4 + idx];
    int col = (idx % (N >> 2)) * 4;
    f32x4 o;
#pragma unroll
    for (int j = 0; j < 4; ++j) {
        float v = a[j] + (bias ? bias[col + j] : 0.f);
        if (ACT == 1) v = fmaxf(v, 0.f);
        if (ACT == 2) v = 1.f / (1.f + expf(-v));
        o[j] = v;
    }
    ((f32x4*)C)[idx] = o;
}

// ---------------------------------------------------------------------------
// K3c: split-K reduce + relu + bias -> split-bf16 TILED (MLP1 hid, M=128, N=HIDN)
// ---------------------------------------------------------------------------
__global__ void reduce_hid(const float* __restrict__ P0, const float* __restrict__ b0,
                           u16* __restrict__ hi0, u16* __restrict__ lo0,
                           const float* __restrict__ P1, const float* __restrict__ b1,
                           u16* __restrict__ hi1, u16* __restrict__ lo1, int S) {
    const float* P = blockIdx.y ? P1 : P0;
    const float* bias = blockIdx.y ? b1 : b0;
    u16* hi = blockIdx.y ? hi1 : hi0;
    u16* lo = blockIdx.y ? lo1 : lo0;
    int idx = blockIdx.x * 256 + threadIdx.x;       // 128*2048/8 = 32768
    int col = (idx & 255) * 8, rowi = idx >> 8;
    size_t base = ((size_t)rowi * HIDN + col) >> 2;
    f32x4 a0 = ((const f32x4*)P)[base], a1 = ((const f32x4*)P)[base + 1];
    for (int s = 1; s < S; ++s) {
        size_t sb = (size_t)s * (128 * HIDN / 4) + base;
        a0 += ((const f32x4*)P)[sb];
        a1 += ((const f32x4*)P)[sb + 1];
    }
    u16x8 h, l;
#pragma unroll
    for (int j = 0; j < 8; ++j) {
        float v = (j < 4 ? a0[j] : a1[j - 4]) + bias[col + j];
        v = fmaxf(v, 0.f);
        u16 hh = f2bf(v);
        h[j] = hh;
        l[j] = f2bf(v - bf2f(hh));
    }
    size_t ob = tiled_off(rowi, col, HIDN);
    *(u16x8*)&hi[ob] = h;
    *(u16x8*)&lo[ob] = l;
}

// ---------------------------------------------------------------------------
// K3d: MLP2 split-K reduce + bias fused with mem_kv concat -> ck/cv [KVH][33][DH]
// ---------------------------------------------------------------------------
__global__ void reduce_ckcv(const float* __restrict__ Pk, const float* __restrict__ Pv,
                            const float* __restrict__ mem_kv,
                            const float* __restrict__ kb2, const float* __restrict__ vb2,
                            float* __restrict__ ck, float* __restrict__ cv, int S) {
    int idx = blockIdx.x * 256 + threadIdx.x;   // 4*33*64 = 8448
    if (idx >= KVH * 33 * DH) return;
    int d = idx & 63;
    int j = (idx >> 6) % 33;
    int h = idx / (33 * 64);
    float kvv, vvv;
    if (j == 0) {
        kvv = mem_kv[(0 * KVH + h) * DH + d];
        vvv = mem_kv[(1 * KVH + h) * DH + d];
    } else {
        size_t base = (size_t)(h * WBLK + (j - 1)) * 128 + d;
        float ak = Pk[base], av = Pv[base];
        for (int s = 1; s < S; ++s) {
            ak += Pk[(size_t)s * (128 * 128) + base];
            av += Pv[(size_t)s * (128 * 128) + base];
        }
        kvv = ak + kb2[d];
        vvv = av + vb2[d];
    }
    ck[idx] = kvv;
    cv[idx] = vvv;
}

// ---------------------------------------------------------------------------
// K5: build compress-MLP inputs -> split-bf16 TILED (K=CDIM). qkv stride QKVG.
// ---------------------------------------------------------------------------
__global__ void build_cmlp_in(const float* __restrict__ qkv, const float* __restrict__ k_pos,
                              const float* __restrict__ v_pos,
                              u16* __restrict__ ckhi, u16* __restrict__ cklo,
                              u16* __restrict__ cvhi, u16* __restrict__ cvlo) {
    int idx = blockIdx.x * 256 + threadIdx.x;   // 128 * 256 = 32768
    int k = (idx & 255) * 8;
    int r = idx >> 8;                           // 0..127 = h*W + w
    int p = k >> 6, d = k & 63;
    int h = r >> 5, wb = r & 31;
    int nn = wb * BSZ + p;
    const float* kq = qkv + (size_t)nn * QKVG + (HEADS + h) * DH + d;
    const float* vq = qkv + (size_t)nn * QKVG + (HEADS + KVH + h) * DH + d;
    const float* kp = k_pos + (size_t)(h * BSZ + p) * DH + d;
    const float* vp = v_pos + (size_t)(h * BSZ + p) * DH + d;
    u16x8 kh, kl, vh, vl;
#pragma unroll
    for (int j = 0; j < 8; ++j) {
        float kv = kq[j] + kp[j];
        float vv = vq[j] + vp[j];
        u16 a = f2bf(kv), b = f2bf(vv);
        kh[j] = a; kl[j] = f2bf(kv - bf2f(a));
        vh[j] = b; vl[j] = f2bf(vv - bf2f(b));
    }
    size_t ob = tiled_off(r, k, CDIM);
    *(u16x8*)&ckhi[ob] = kh; *(u16x8*)&cklo[ob] = kl;
    *(u16x8*)&cvhi[ob] = vh; *(u16x8*)&cvlo[ob] = vl;
}

// ---------------------------------------------------------------------------
// K7: rotary (fast-math, float2). qkv stride QKVG.
// ---------------------------------------------------------------------------
__global__ void rotary_kernel(const float* __restrict__ qkv,
                              float* __restrict__ qr, float* __restrict__ kr,
                              float* __restrict__ vr) {
    int idx = blockIdx.x * 256 + threadIdx.x;   // 24*1024*32 = 786432
    int i = idx & 31;
    int n = (idx >> 5) & 1023;
    int hd = idx >> 15;
    if (hd >= 24) return;
    if (hd >= HEADS + KVH) {       // packed v copy
        int h = hd - (HEADS + KVH);
        const float* src = qkv + (size_t)n * QKVG + (HEADS + KVH + h) * DH;
        float* dst = vr + ((size_t)h * NTOK + n) * DH;
        *(float2*)&dst[2 * i] = *(const float2*)&src[2 * i];
        return;
    }
    float inv = __expf((float)i * -0.28782313662425572f);
    float fr = (float)n * inv;
    float s, c;
    __sincosf(fr, &s, &c);
    const float* src; float* dst;
    if (hd < HEADS) { src = qkv + (size_t)n * QKVG + hd * DH;          dst = qr + ((size_t)hd * NTOK + n) * DH; }
    else { int h = hd - HEADS;
           src = qkv + (size_t)n * QKVG + (HEADS + h) * DH;            dst = kr + ((size_t)h * NTOK + n) * DH; }
    float2 x = *(const float2*)&src[2 * i];
    float2 o;
    o.x = x.x * c - x.y * s;
    o.y = x.y * c + x.x * s;
    *(float2*)&dst[2 * i] = o;
}

// ---------------------------------------------------------------------------
// K8: compressed attention + importance + top-k (vectorized scores). Stride QKVG.
// ---------------------------------------------------------------------------
__global__ __launch_bounds__(256)
void cattn_kernel(const float* __restrict__ qkv, const float* __restrict__ ck,
                  const float* __restrict__ cv, float* __restrict__ c_out,
                  int* __restrict__ sel, int* __restrict__ selmask) {
    int h = blockIdx.y;
    int tid = threadIdx.x;
    int w = tid >> 6, lane = tid & 63;
    int grp = lane >> 4, sub = lane & 15;
    int n = blockIdx.x * 4 + w;
    __shared__ float cks[33 * 68];
    __shared__ float cvs[33 * 68];
    __shared__ float sims[16 * 36];      // [w*4+g][j]

    for (int t4 = tid; t4 < 1056; t4 += 256) {
        int half = (t4 >= 528) ? 1 : 0;
        int u = t4 - half * 528;
        int j = u >> 4, d4 = (u & 15) * 4;
        const float* src = (half ? cv : ck) + (size_t)h * 33 * 64 + j * 64 + d4;
        float* dst = (half ? cvs : cks) + j * 68 + d4;
        *(float4*)dst = *(const float4*)src;
    }
    f32x4 qv[16];
    {
        const float4* qp4 = (const float4*)(qkv + (size_t)n * QKVG + (h * GQ + grp) * DH);
#pragma unroll
        for (int c = 0; c < 16; ++c) {
            float4 v = qp4[c];
            qv[c] = (f32x4){v.x, v.y, v.z, v.w};
        }
    }
    __syncthreads();

#pragma unroll
    for (int r = 0; r < 3; ++r) {
        int j = r * 16 + sub;
        if (j < 33) {
            f32x4 a0 = (f32x4){0.f, 0.f, 0.f, 0.f};
            f32x4 a1 = (f32x4){0.f, 0.f, 0.f, 0.f};
#pragma unroll
            for (int c = 0; c < 16; c += 2) {
                a0 += qv[c]     * (*(const f32x4*)&cks[j * 68 + c * 4]);
                a1 += qv[c + 1] * (*(const f32x4*)&cks[j * 68 + (c + 1) * 4]);
            }
            f32x4 at = a0 + a1;
            sims[(w * 4 + grp) * 36 + j] = ((at[0] + at[1]) + (at[2] + at[3])) * SCALE;
        }
    }

    float ival = NEGINF;
    if (lane < 32)
        ival = 0.25f * (sims[(w * 4 + 0) * 36 + 1 + lane] + sims[(w * 4 + 1) * 36 + 1 + lane] +
                        sims[(w * 4 + 2) * 36 + 1 + lane] + sims[(w * 4 + 3) * 36 + 1 + lane]);
    float m = ival;
    for (int off = 32; off; off >>= 1) m = fmaxf(m, __shfl_xor(m, off));
    float e = (lane < 32) ? expf(ival - m) : 0.f;
    float sum = e;
    for (int off = 32; off; off >>= 1) sum += __shfl_xor(sum, off);
    float p = (lane < 32) ? e / sum : NEGINF;

    float v = p;
    int base = (h * NTOK + n) * 9;
    for (int t = 0; t < NSEL; ++t) {
        float bv = v; int bi = lane;
        for (int off = 32; off; off >>= 1) {
            float ov = __shfl_xor(bv, off);
            int   oi = __shfl_xor(bi, off);
            if (ov > bv || (ov == bv && oi < bi)) { bv = ov; bi = oi; }
        }
        if (lane == 0) { sel[base + t] = bi; selmask[base + t] = (bv > 1e-10f) ? 1 : 0; }
        if (lane == bi) v = NEGINF;
    }
    if (lane == 0) { sel[base + NSEL] = n >> 5; selmask[base + NSEL] = 1; }

#pragma unroll
    for (int g = 0; g < 4; ++g) {
        float sv = (lane < 33) ? sims[(w * 4 + g) * 36 + lane] : NEGINF;
        float mm = sv;
        for (int off = 32; off; off >>= 1) mm = fmaxf(mm, __shfl_xor(mm, off));
        float ee = (lane < 33) ? __expf(sv - mm) : 0.f;
        float ssum = ee;
        for (int off = 32; off; off >>= 1) ssum += __shfl_xor(ssum, off);
        if (lane < 33) sims[(w * 4 + g) * 36 + lane] = ee / ssum;
    }

    f32x4 o = (f32x4){0.f, 0.f, 0.f, 0.f};
#pragma unroll
    for (int j = 0; j < 33; ++j) {
        float a = sims[(w * 4 + grp) * 36 + j];
        f32x4 vv = *(const f32x4*)&cvs[j * 68 + sub * 4];
        o += a * vv;
    }
    *(f32x4*)&c_out[(((size_t)(h * GQ + grp)) * NTOK + n) * DH + sub * 4] = o;
}

// ---------------------------------------------------------------------------
// K9: fine attention v15 (unchanged — control). 62.8us measured, conflicts 0.
// ---------------------------------------------------------------------------
__global__ void fattn_kernel(const float* __restrict__ qr, const float* __restrict__ kr,
                             const float* __restrict__ vr, const int* __restrict__ sel,
                             const int* __restrict__ selmask, float* __restrict__ f_out) {
    int n = blockIdx.x, h = blockIdx.y;
    int tid = threadIdx.x;
    int w = tid >> 6, lane = tid & 63;
    int grp = lane >> 4, sub = lane & 15;
    __shared__ float qsm[4 * 68];
    __shared__ float Ksm[64 * 64];       // slot s of row r = global slot s^(r&15)
    __shared__ float Vsm[64 * 64];
    __shared__ float ps[4 * 68];         // wave-private p rows: ps[w][g*16+sub]
    __shared__ float msm[16], lsm[16];   // [slice w * 4 + head g]
    __shared__ int sel_s[9], msk_s[9];

    if (tid < 9) {
        sel_s[tid] = sel[(h * NTOK + n) * 9 + tid];
        msk_s[tid] = selmask[(h * NTOK + n) * 9 + tid];
    }
    qsm[w * 68 + lane] = qr[(((size_t)(h * GQ + w)) * NTOK + n) * DH + lane];
    f32x4 o4 = (f32x4){0.f, 0.f, 0.f, 0.f};
    float m_run = -3.402823466e38f, l_run = 0.f;
    __syncthreads();                     // B0: sel_s + qsm ready

    const float* krh_ = kr + (size_t)h * NTOK * DH;
    const float* vrh_ = vr + (size_t)h * NTOK * DH;

    int rl = lane >> 4, sl = lane & 15;

    auto stageRows = [&](float* dstbuf, const float* src, int bp) {
        int nrow = (bp < 4) ? 64 : 32;
        if (w * 16 < nrow) {
            int myblk = sel_s[bp * 2 + (w >> 1)];
            const float* b_ = src + (size_t)myblk * BSZ * DH;
#pragma unroll
            for (int cc = 0; cc < 4; ++cc) {
                int r = w * 16 + cc * 4 + rl;
                int sg = sl ^ (r & 15);
                glds16(b_ + (size_t)(r & 31) * DH + sg * 4, &dstbuf[(w * 16 + cc * 4) * 64]);
            }
        }
    };

    stageRows(Ksm, krh_, 0);
    stageRows(Vsm, vrh_, 0);

    for (int bp = 0; bp < 5; ++bp) {
        int nrow = (bp < 4) ? 64 : 32;

        asm volatile("s_waitcnt vmcnt(4)" ::: "memory");
        __builtin_amdgcn_sched_barrier(0);

        float s = -3.402823466e38f;
        {
            int jj = w * 16 + sub;
            int b = bp * 2 + (jj >> 5);
            if (jj < nrow && msk_s[b]) {
                int sw = jj & 15;
                const float* Kb = &Ksm[jj * 64];
                f32x4 a0 = (f32x4){0.f, 0.f, 0.f, 0.f};
                f32x4 a1 = (f32x4){0.f, 0.f, 0.f, 0.f};
#pragma unroll
                for (int c = 0; c < 16; c += 2) {
                    f32x4 k4a = *(const f32x4*)&Kb[(c ^ sw) * 4];
                    f32x4 q4a = *(const f32x4*)&qsm[grp * 68 + c * 4];
                    f32x4 k4b = *(const f32x4*)&Kb[((c + 1) ^ sw) * 4];
                    f32x4 q4b = *(const f32x4*)&qsm[grp * 68 + (c + 1) * 4];
                    a0 += q4a * k4a;
                    a1 += q4b * k4b;
                }
                f32x4 at = a0 + a1;
                s = ((at[0] + at[1]) + (at[2] + at[3])) * SCALE;
            }
        }
        float mb = s;
        for (int off = 8; off; off >>= 1) mb = fmaxf(mb, __shfl_xor(mb, off));
        float m_new = fmaxf(m_run, mb);
        float pp = (s > -1e37f) ? __expf(s - m_new) : 0.f;
        float alpha = __expf(m_run - m_new);
        float psum = pp;
        for (int off = 8; off; off >>= 1) psum += __shfl_xor(psum, off);
        l_run = l_run * alpha + psum;
        m_run = m_new;
        ps[w * 68 + grp * 16 + sub] = pp;

        __builtin_amdgcn_sched_barrier(0);
        asm volatile("s_waitcnt lgkmcnt(0)" ::: "memory");
        __builtin_amdgcn_sched_barrier(0);
        if (bp < 4) {
            stageRows(Ksm, krh_, bp + 1);
            asm volatile("s_waitcnt vmcnt(4)" ::: "memory");
        } else {
            asm volatile("s_waitcnt vmcnt(0)" ::: "memory");
        }
        __builtin_amdgcn_sched_barrier(0);

        {
            f32x4 t0 = (f32x4){0.f, 0.f, 0.f, 0.f};
            f32x4 t1 = (f32x4){0.f, 0.f, 0.f, 0.f};
            int jbase = w * 16;
            if (jbase < nrow) {
#pragma unroll
                for (int jq = 0; jq < 4; ++jq) {
                    f32x4 p4 = *(const f32x4*)&ps[w * 68 + grp * 16 + jq * 4];
#pragma unroll
                    for (int r = 0; r < 4; ++r) {
                        int row = jbase + jq * 4 + r;
                        int slot = sub ^ (row & 15);
                        f32x4 vv = *(const f32x4*)&Vsm[row * 64 + slot * 4];
                        if (r & 1) t1 += p4[r] * vv;
                        else       t0 += p4[r] * vv;
                    }
                }
            }
            o4 = o4 * alpha + (t0 + t1);
        }
        if (bp < 4) {
            __builtin_amdgcn_sched_barrier(0);
            asm volatile("s_waitcnt lgkmcnt(0)" ::: "memory");
            __builtin_amdgcn_sched_barrier(0);
            stageRows(Vsm, vrh_, bp + 1);
        }
    }
    if (sub == 0) { msm[w * 4 + grp] = m_run; lsm[w * 4 + grp] = l_run; }
    __syncthreads();
    *(f32x4*)&Ksm[(w * 4 + grp) * 64 + sub * 4] = o4;
    __syncthreads();
    float m0 = msm[0 * 4 + w], m1 = msm[1 * 4 + w], m2 = msm[2 * 4 + w], m3 = msm[3 * 4 + w];
    float M = fmaxf(fmaxf(m0, m1), fmaxf(m2, m3));
    float f0 = __expf(m0 - M), f1 = __expf(m1 - M), f2 = __expf(m2 - M), f3 = __expf(m3 - M);
    float L = lsm[0 * 4 + w] * f0 + lsm[1 * 4 + w] * f1 + lsm[2 * 4 + w] * f2 + lsm[3 * 4 + w] * f3;
    float sum = Ksm[(0 * 4 + w) * 64 + lane] * f0 + Ksm[(1 * 4 + w) * 64 + lane] * f1
              + Ksm[(2 * 4 + w) * 64 + lane] * f2 + Ksm[(3 * 4 + w) * 64 + lane] * f3;
    f_out[(((size_t)(h * GQ + w)) * NTOK + n) * DH + lane] = sum / L;
}

// ---------------------------------------------------------------------------
// K10: gated mix -> split-bf16 TILED (K=DDIM).
// v17: gates computed inline from fused qkvg (cols 1536+) + gate_b + sigmoid.
// ---------------------------------------------------------------------------
__global__ void mix_kernel(const float* __restrict__ qkvg, const float* __restrict__ gate_b,
                           const float* __restrict__ c_out, const float* __restrict__ f_out,
                           u16* __restrict__ mixhi, u16* __restrict__ mixlo) {
    int idx = blockIdx.x * 256 + threadIdx.x;   // 1024*1024/8 = 131072
    int col = (idx & 127) * 8;
    int n = idx >> 7;
    int hd = col >> 6, d = col & 63;
    float r0 = qkvg[(size_t)n * QKVG + QKVD + hd * 2]     + gate_b[hd * 2];
    float r1 = qkvg[(size_t)n * QKVG + QKVD + hd * 2 + 1] + gate_b[hd * 2 + 1];
    float g0 = 1.f / (1.f + expf(-r0));
    float g1 = 1.f / (1.f + expf(-r1));
    size_t hoff = (((size_t)hd) * NTOK + n) * DH + d;
    u16x8 h, l;
#pragma unroll
    for (int j = 0; j < 8; ++j) {
        float v = g0 * c_out[hoff + j] + g1 * f_out[hoff + j];
        u16 hh = f2bf(v);
        h[j] = hh;
        l[j] = f2bf(v - bf2f(hh));
    }
    size_t ob = tiled_off(n, col, DDIM);
    *(u16x8*)&mixhi[ob] = h;
    *(u16x8*)&mixlo[ob] = l;
}

// ---------------------------------------------------------------------------
extern "C" void kernel_launch(void* const* d_in, const int* in_sizes, int n_in,
                              void* d_out, int out_size, void* d_ws, size_t ws_size,
                              hipStream_t stream) {
    const float* inp    = (const float*)d_in[0];
    const float* g_norm = (const float*)d_in[1];
    const float* w_qkv  = (const float*)d_in[2];
    const float* mem_kv = (const float*)d_in[3];
    const float* k_pos  = (const float*)d_in[4];
    const float* v_pos  = (const float*)d_in[5];
    const float* k_w1   = (const float*)d_in[6];
    const float* k_b1   = (const float*)d_in[7];
    const float* k_w2   = (const float*)d_in[8];
    const float* k_b2   = (const float*)d_in[9];
    const float* v_w1   = (const float*)d_in[10];
    const float* v_b1   = (const float*)d_in[11];
    const float* v_w2   = (const float*)d_in[12];
    const float* v_b2   = (const float*)d_in[13];
    const float* gate_w = (const float*)d_in[14];
    const float* gate_b = (const float*)d_in[15];
    const float* w_out  = (const float*)d_in[16];
    float* out = (float*)d_out;

    char* wsb = (char*)d_ws;
    size_t off = 0;
    auto alloc = [&](size_t bytes) -> void* {
        void* p = wsb + off;
        off = (off + bytes + 255) & ~(size_t)255;
        return p;
    };
    u16*   xhi    = (u16*)  alloc((size_t)NTOK * DDIM * 2);
    u16*   xlo    = (u16*)  alloc((size_t)NTOK * DDIM * 2);
    float* qkvg   = (float*)alloc((size_t)NTOK * QKVG * 4);      // fused qkv+gates
    u16*   wqThi  = (u16*)  alloc((size_t)QKVG * DDIM * 2);      // extended (+gate rows)
    u16*   wqTlo  = (u16*)  alloc((size_t)QKVG * DDIM * 2);
    u16*   kw1Thi = (u16*)  alloc((size_t)HIDN * CDIM * 2);
    u16*   kw1Tlo = (u16*)  alloc((size_t)HIDN * CDIM * 2);
    u16*   vw1Thi = (u16*)  alloc((size_t)HIDN * CDIM * 2);
    u16*   vw1Tlo = (u16*)  alloc((size_t)HIDN * CDIM * 2);
    u16*   woThi  = (u16*)  alloc((size_t)DDIM * DDIM * 2);
    u16*   kw2Thi = (u16*)  alloc((size_t)128 * HIDN * 2);
    u16*   kw2Tlo = (u16*)  alloc((size_t)128 * HIDN * 2);
    float* kb2p   = (float*)alloc(128 * 4);
    u16*   vw2Thi = (u16*)  alloc((size_t)128 * HIDN * 2);
    u16*   vw2Tlo = (u16*)  alloc((size_t)128 * HIDN * 2);
    float* vb2p   = (float*)alloc(128 * 4);
    u16*   cinkhi = (u16*)  alloc((size_t)128 * CDIM * 2);
    u16*   cinklo = (u16*)  alloc((size_t)128 * CDIM * 2);
    u16*   cinvhi = (u16*)  alloc((size_t)128 * CDIM * 2);
    u16*   cinvlo = (u16*)  alloc((size_t)128 * CDIM * 2);
    u16*   hidkhi = (u16*)  alloc((size_t)128 * HIDN * 2);
    u16*   hidklo = (u16*)  alloc((size_t)128 * HIDN * 2);
    u16*   hidvhi = (u16*)  alloc((size_t)128 * HIDN * 2);
    u16*   hidvlo = (u16*)  alloc((size_t)128 * HIDN * 2);
    float* Pm1k   = (float*)alloc((size_t)4 * 128 * HIDN * 4);   // also reused as out-proj partials
    float* Pm1v   = (float*)alloc((size_t)4 * 128 * HIDN * 4);
    float* Pm2k   = (float*)alloc((size_t)8 * 128 * 128 * 4);
    float* Pm2v   = (float*)alloc((size_t)8 * 128 * 128 * 4);
    float* ck     = (float*)alloc((size_t)KVH * 33 * DH * 4);
    float* cv     = (float*)alloc((size_t)KVH * 33 * DH * 4);
    float* qr     = (float*)alloc((size_t)HEADS * NTOK * DH * 4);
    float* kr     = (float*)alloc((size_t)KVH * NTOK * DH * 4);
    float* vr     = (float*)alloc((size_t)KVH * NTOK * DH * 4);
    float* c_out  = (float*)alloc((size_t)HEADS * NTOK * DH * 4);
    float* f_out  = (float*)alloc((size_t)HEADS * NTOK * DH * 4);
    int*   sel    = (int*)  alloc((size_t)KVH * NTOK * 9 * 4);
    int*   selmask= (int*)  alloc((size_t)KVH * NTOK * 9 * 4);
    u16*   mixhi  = (u16*)  alloc((size_t)NTOK * DDIM * 2);
    u16*   mixlo  = (u16*)  alloc((size_t)NTOK * DDIM * 2);
    float* Pout   = Pm1k;   // 8MB contiguous (Pm1k+Pm1v), dead after reduce_hid

    // 0. ALL weight prep + RMSNorm in one dispatch
    prep_kernel<<<3520, 256, 0, stream>>>(
        w_qkv, k_w1, v_w1, w_out, gate_w, k_w2, k_b2, v_w2, v_b2,
        inp, g_norm,
        wqThi, wqTlo, kw1Thi, kw1Tlo, vw1Thi, vw1Tlo, woThi,
        kw2Thi, kw2Tlo, kb2p, vw2Thi, vw2Tlo, vb2p,
        xhi, xlo);

    // 2. qkv+gates fused = x @ [w_qkv | gate_w]  (N=1664, final f32, raw gates)
    gemm_tiled<3, 0, 1><<<dim3(QKVG / 128, NTOK / 128, 1), 256, 0, stream>>>(
        xhi, xlo, wqThi, wqTlo, nullptr, qkvg,
        xhi, xlo, wqThi, wqTlo, nullptr, qkvg, NTOK, QKVG, DDIM, 1);
    // 4. compress-MLP inputs (tiled)
    build_cmlp_in<<<128, 256, 0, stream>>>(qkvg, k_pos, v_pos, cinkhi, cinklo, cinvhi, cinvlo);
    // 5. MLP1 (split-K 4, k&v batched; relu+bias+split-tile in reduce)
    gemm_tiled<3, 0, 0><<<dim3(HIDN / 128, 1, 8), 256, 0, stream>>>(
        cinkhi, cinklo, kw1Thi, kw1Tlo, nullptr, Pm1k,
        cinvhi, cinvlo, vw1Thi, vw1Tlo, nullptr, Pm1v, 128, HIDN, CDIM, 4);
    reduce_hid<<<dim3(128, 2), 256, 0, stream>>>(Pm1k, k_b1, hidkhi, hidklo,
                                                 Pm1v, v_b1, hidvhi, hidvlo, 4);
    // 6. MLP2 (split-K 8, k&v batched) + fused reduce/bias/concat
    gemm_tiled<3, 0, 0><<<dim3(1, 1, 16), 256, 0, stream>>>(
        hidkhi, hidklo, kw2Thi, kw2Tlo, nullptr, Pm2k,
        hidvhi, hidvlo, vw2Thi, vw2Tlo, nullptr, Pm2v, 128, 128, HIDN, 8);
    reduce_ckcv<<<33, 256, 0, stream>>>(Pm2k, Pm2v, mem_kv, kb2p, vb2p, ck, cv, 8);
    // 8. rotary + packed v (fast-math)
    rotary_kernel<<<(24 * NTOK * 32) / 256, 256, 0, stream>>>(qkvg, qr, kr, vr);
    // 9. compressed attention + selection (vectorized scores)
    cattn_kernel<<<dim3(NTOK / 4, KVH), 256, 0, stream>>>(qkvg, ck, cv, c_out, sel, selmask);
    // 10. fine attention (v15, unchanged — control)
    fattn_kernel<<<dim3(NTOK, KVH), 256, 0, stream>>>(qr, kr, vr, sel, selmask, f_out);
    // 11. gated mix (inline sigmoid gates from qkvg) -> tiled split-bf16
    mix_kernel<<<(NTOK * DDIM / 8) / 256, 256, 0, stream>>>(qkvg, gate_b, c_out, f_out, mixhi, mixlo);
    // 12. output projection, split-K=2 (128 blocks) + reduce
    gemm_tiled<1, 0, 0><<<dim3(DDIM / 128, NTOK / 128, 2), 256, 0, stream>>>(
        mixhi, mixhi, woThi, woThi, nullptr, Pout,
        mixhi, mixhi, woThi, woThi, nullptr, Pout, NTOK, DDIM, DDIM, 2);
    reduce_f32<0><<<dim3((NTOK * DDIM / 4) / 256, 1), 256, 0, stream>>>(
        Pout, nullptr, out, Pout, nullptr, out, 2, NTOK, DDIM);
}

// Round 11
// 287.692 us; speedup vs baseline: 1.3260x; 1.0734x over previous
//
#include <hip/hip_runtime.h>
#include <math.h>

// ---- fixed problem sizes ----
#define NTOK 1024
#define DDIM 1024
#define HEADS 16
#define KVH 4
#define DH 64
#define BSZ 32
#define NSEL 8
#define WBLK 32            // NTOK / BSZ
#define GQ 4               // HEADS / KVH
#define CDIM 2048          // BSZ*DH
#define HIDN 2048
#define QKVD 1536          // (HEADS + 2*KVH)*DH
#define QKVG 1664          // QKVD + 128 (gate block appended)
#define SCALE 0.125f       // DH^-0.5
#define NEGINF (-__builtin_inff())

// u16-element offset of the gate block (rows 1536..1663) inside the extended
// tiled weight matrix: (1536>>4) * (DDIM>>5) * 64 * 8
#define OFFGATE ((size_t)96 * 32 * 512)

typedef unsigned short u16;
typedef u16   u16x8  __attribute__((ext_vector_type(8)));
typedef short short8 __attribute__((ext_vector_type(8)));
typedef float f32x4  __attribute__((ext_vector_type(4)));

__device__ __forceinline__ u16 f2bf(float f) {
    unsigned u = __float_as_uint(f);
    return (u16)((u + 0x7fffu + ((u >> 16) & 1u)) >> 16);
}
__device__ __forceinline__ float bf2f(u16 h) { return __uint_as_float(((unsigned)h) << 16); }

__device__ __forceinline__ void glds16(const void* g, void* l) {
    __builtin_amdgcn_global_load_lds(
        (const __attribute__((address_space(1))) unsigned int*)g,
        (__attribute__((address_space(3))) unsigned int*)l, 16, 0, 0);
}

// element offset (in u16) of the 8-element lane-slot for (row, k..k+7) in the
// MFMA-fragment-tiled layout: 16-row x 32-k tiles, 1KB each, contiguous.
__device__ __forceinline__ size_t tiled_off(int row, int k, int K) {
    return ((size_t)((row >> 4) * (K >> 5) + (k >> 5)) * 64 +
            ((row & 15) | (((k >> 3) & 3) << 4))) * 8;
}

// ---------------------------------------------------------------------------
// K0: MEGA-PREP — all weight prep + RMSNorm in ONE dispatch.
// Ranges: [0,384) wqT | [384,1408) kw1T | [1408,2432) vw1T | [2432,2688) woT
//         | [2688,2752) pad gate->wqT+OFF | [2752,2880) pad kw2
//         | [2880,3008) pad vw2 | [3008,3520) rmsnorm
// ---------------------------------------------------------------------------
__device__ __forceinline__ void transpose_body(const float* __restrict__ W,
                                               u16* __restrict__ Thi, u16* __restrict__ Tlo,
                                               int K, int N, int bx, int by,
                                               float (*tile)[65]) {
    int k0 = by * 64, n0 = bx * 64;
    int t = threadIdx.x;
    int r = t >> 4, c4 = (t & 15) * 4;
#pragma unroll
    for (int p = 0; p < 4; ++p) {
        float4 v = *(const float4*)&W[(size_t)(k0 + r + p * 16) * N + n0 + c4];
        tile[r + p * 16][c4 + 0] = v.x;
        tile[r + p * 16][c4 + 1] = v.y;
        tile[r + p * 16][c4 + 2] = v.z;
        tile[r + p * 16][c4 + 3] = v.w;
    }
    __syncthreads();
    int n = t >> 2, ks = (t & 3) * 16;
#pragma unroll
    for (int c = 0; c < 2; ++c) {
        u16x8 h, l;
#pragma unroll
        for (int j = 0; j < 8; ++j) {
            float v = tile[ks + c * 8 + j][n];
            u16 hh = f2bf(v);
            h[j] = hh;
            l[j] = f2bf(v - bf2f(hh));
        }
        size_t ob = tiled_off(n0 + n, k0 + ks + c * 8, K);
        *(u16x8*)&Thi[ob] = h;
        if (Tlo) *(u16x8*)&Tlo[ob] = l;
    }
}

__device__ __forceinline__ void pad_body(const float* __restrict__ W, const float* __restrict__ b,
                                         u16* __restrict__ Thi, u16* __restrict__ Tlo,
                                         float* __restrict__ bias_pad, int K, int Xn, int KLOG,
                                         int bx) {
    int idx = bx * 256 + threadIdx.x;
    int k = (idx & ((K >> 3) - 1)) * 8;
    int n = idx >> (KLOG - 3);
    if (n >= 128) return;
    u16x8 h, l;
#pragma unroll
    for (int j = 0; j < 8; ++j) {
        float v = (n < Xn) ? W[(size_t)(k + j) * Xn + n] : 0.f;
        u16 hh = f2bf(v);
        h[j] = hh;
        l[j] = f2bf(v - bf2f(hh));
    }
    size_t ob = tiled_off(n, k, K);
    *(u16x8*)&Thi[ob] = h;
    *(u16x8*)&Tlo[ob] = l;
    if (bias_pad && k == 0) bias_pad[n] = (n < Xn) ? b[n] : 0.f;
}

__device__ __forceinline__ void rms_body(const float* __restrict__ inp, const float* __restrict__ g,
                                         u16* __restrict__ xhi, u16* __restrict__ xlo,
                                         int bx, float* red) {
    int t = threadIdx.x;
    int half = t >> 7, tid = t & 127;
    int n = bx * 2 + half;
    const float4* row = (const float4*)(inp + (size_t)n * DDIM);
    float4 v0 = row[tid * 2], v1 = row[tid * 2 + 1];
    float ss = v0.x*v0.x + v0.y*v0.y + v0.z*v0.z + v0.w*v0.w
             + v1.x*v1.x + v1.y*v1.y + v1.z*v1.z + v1.w*v1.w;
    for (int off = 32; off; off >>= 1) ss += __shfl_down(ss, off);
    if ((t & 63) == 0) red[t >> 6] = ss;
    __syncthreads();
    float tot = red[half * 2] + red[half * 2 + 1];
    float r = 1.f / sqrtf(tot * (1.f / DDIM) + 1e-6f);
    const float4* gp = (const float4*)g;
    float4 g0 = gp[tid * 2], g1 = gp[tid * 2 + 1];
    float o[8] = { v0.x*r*g0.x, v0.y*r*g0.y, v0.z*r*g0.z, v0.w*r*g0.w,
                   v1.x*r*g1.x, v1.y*r*g1.y, v1.z*r*g1.z, v1.w*r*g1.w };
    u16x8 h, l;
#pragma unroll
    for (int i = 0; i < 8; ++i) {
        u16 hh = f2bf(o[i]);
        h[i] = hh;
        l[i] = f2bf(o[i] - bf2f(hh));
    }
    size_t ob = tiled_off(n, tid * 8, DDIM);
    *(u16x8*)&xhi[ob] = h;
    *(u16x8*)&xlo[ob] = l;
}

__global__ void prep_kernel(const float* __restrict__ w_qkv, const float* __restrict__ k_w1,
                            const float* __restrict__ v_w1, const float* __restrict__ w_out,
                            const float* __restrict__ gate_w,
                            const float* __restrict__ k_w2, const float* __restrict__ k_b2,
                            const float* __restrict__ v_w2, const float* __restrict__ v_b2,
                            const float* __restrict__ inp, const float* __restrict__ g_norm,
                            u16* wqThi, u16* wqTlo, u16* kw1Thi, u16* kw1Tlo,
                            u16* vw1Thi, u16* vw1Tlo, u16* woThi,
                            u16* kw2Thi, u16* kw2Tlo, float* kb2p,
                            u16* vw2Thi, u16* vw2Tlo, float* vb2p,
                            u16* xhi, u16* xlo) {
    __shared__ float tile[64][65];
    __shared__ float red[4];
    int b = blockIdx.x;
    if (b < 384) {
        transpose_body(w_qkv, wqThi, wqTlo, DDIM, QKVD, b % 24, b / 24, tile);
    } else if (b < 1408) {
        int r = b - 384;
        transpose_body(k_w1, kw1Thi, kw1Tlo, CDIM, HIDN, r & 31, r >> 5, tile);
    } else if (b < 2432) {
        int r = b - 1408;
        transpose_body(v_w1, vw1Thi, vw1Tlo, CDIM, HIDN, r & 31, r >> 5, tile);
    } else if (b < 2688) {
        int r = b - 2432;
        transpose_body(w_out, woThi, nullptr, DDIM, DDIM, r & 15, r >> 4, tile);
    } else if (b < 2752) {
        pad_body(gate_w, nullptr, wqThi + OFFGATE, wqTlo + OFFGATE, nullptr, DDIM, 32, 10, b - 2688);
    } else if (b < 2880) {
        pad_body(k_w2, k_b2, kw2Thi, kw2Tlo, kb2p, HIDN, 64, 11, b - 2752);
    } else if (b < 3008) {
        pad_body(v_w2, v_b2, vw2Thi, vw2Tlo, vb2p, HIDN, 64, 11, b - 2880);
    } else {
        rms_body(inp, g_norm, xhi, xlo, b - 3008, red);
    }
}

// ---------------------------------------------------------------------------
// K3: tiled MFMA GEMM with software pipeline + optional split-K.
// ---------------------------------------------------------------------------
template<int SPLIT, int ACT, int FINAL>
__global__ __launch_bounds__(256, 1)
void gemm_tiled(const u16* __restrict__ Ahi0, const u16* __restrict__ Alo0,
                const u16* __restrict__ Bhi0, const u16* __restrict__ Blo0,
                const float* __restrict__ bias0, float* __restrict__ C0,
                const u16* __restrict__ Ahi1, const u16* __restrict__ Alo1,
                const u16* __restrict__ Bhi1, const u16* __restrict__ Blo1,
                const float* __restrict__ bias1, float* __restrict__ C1,
                int M, int N, int K, int S) {
    int batch = blockIdx.z / S;
    int s = blockIdx.z - batch * S;
    const u16* Ahi = batch ? Ahi1 : Ahi0;
    const u16* Alo = batch ? Alo1 : Alo0;
    const u16* Bhi = batch ? Bhi1 : Bhi0;
    const u16* Blo = batch ? Blo1 : Blo0;
    const float* bias = batch ? bias1 : bias0;
    float* C = batch ? C1 : C0;

    constexpr int PARTS = (SPLIT == 3) ? 2 : 1;
    __shared__ u16 smA[2 * PARTS * 8 * 512];
    __shared__ u16 smB[2 * PARTS * 8 * 512];

    int tid = threadIdx.x;
    int w = tid >> 6, L = tid & 63;
    int m15 = L & 15, q = L >> 4;
    int KT = K >> 5;
    int rowTile = blockIdx.y * 8, colTile = blockIdx.x * 8;
    int NIT = (K / S) >> 5;
    int kb0 = s * NIT;
    int aw = w & 1, bw = w >> 1;

    f32x4 acc[4][4];
#pragma unroll
    for (int i = 0; i < 4; ++i)
#pragma unroll
        for (int j = 0; j < 4; ++j) acc[i][j] = (f32x4){0.f, 0.f, 0.f, 0.f};

    auto stage = [&](int buf, int kb) {
#pragma unroll
        for (int rl = 0; rl < 2; ++rl) {
            int rb = 2 * w + rl;
            glds16(Ahi + ((size_t)(rowTile + rb) * KT + kb) * 512 + (size_t)L * 8,
                   &smA[((buf * PARTS + 0) * 8 + rb) * 512]);
            glds16(Bhi + ((size_t)(colTile + rb) * KT + kb) * 512 + (size_t)L * 8,
                   &smB[((buf * PARTS + 0) * 8 + rb) * 512]);
            if constexpr (SPLIT == 3) {
                glds16(Alo + ((size_t)(rowTile + rb) * KT + kb) * 512 + (size_t)L * 8,
                       &smA[((buf * PARTS + 1) * 8 + rb) * 512]);
                glds16(Blo + ((size_t)(colTile + rb) * KT + kb) * 512 + (size_t)L * 8,
                       &smB[((buf * PARTS + 1) * 8 + rb) * 512]);
            }
        }
    };

    stage(0, kb0);
    for (int it = 0; it < NIT; ++it) {
        __syncthreads();
        if (it + 1 < NIT) stage((it + 1) & 1, kb0 + it + 1);
        int buf = it & 1;
        short8 ah[4], bh[4];
#pragma unroll
        for (int i = 0; i < 4; ++i) {
            ah[i] = *(const short8*)&smA[((buf * PARTS + 0) * 8 + aw * 4 + i) * 512 + L * 8];
            bh[i] = *(const short8*)&smB[((buf * PARTS + 0) * 8 + bw * 4 + i) * 512 + L * 8];
        }
        if constexpr (SPLIT == 3) {
            short8 al[4], bl[4];
#pragma unroll
            for (int i = 0; i < 4; ++i) {
                al[i] = *(const short8*)&smA[((buf * PARTS + 1) * 8 + aw * 4 + i) * 512 + L * 8];
                bl[i] = *(const short8*)&smB[((buf * PARTS + 1) * 8 + bw * 4 + i) * 512 + L * 8];
            }
#pragma unroll
            for (int i = 0; i < 4; ++i)
#pragma unroll
                for (int j = 0; j < 4; ++j) {
                    acc[i][j] = __builtin_amdgcn_mfma_f32_16x16x32_bf16(ah[i], bl[j], acc[i][j], 0, 0, 0);
                    acc[i][j] = __builtin_amdgcn_mfma_f32_16x16x32_bf16(al[i], bh[j], acc[i][j], 0, 0, 0);
                    acc[i][j] = __builtin_amdgcn_mfma_f32_16x16x32_bf16(ah[i], bh[j], acc[i][j], 0, 0, 0);
                }
        } else {
#pragma unroll
            for (int i = 0; i < 4; ++i)
#pragma unroll
                for (int j = 0; j < 4; ++j)
                    acc[i][j] = __builtin_amdgcn_mfma_f32_16x16x32_bf16(ah[i], bh[j], acc[i][j], 0, 0, 0);
        }
    }

    if constexpr (FINAL == 0) C += (size_t)s * M * N;
#pragma unroll
    for (int i = 0; i < 4; ++i) {
        int row = rowTile * 16 + aw * 64 + i * 16 + q * 4;
#pragma unroll
        for (int j = 0; j < 4; ++j) {
            int col = colTile * 16 + bw * 64 + j * 16 + m15;
            float bv = (FINAL && bias) ? bias[col] : 0.f;
#pragma unroll
            for (int r = 0; r < 4; ++r) {
                float v = acc[i][j][r];
                if constexpr (FINAL) {
                    v += bv;
                    if (ACT == 1) v = fmaxf(v, 0.f);
                    if (ACT == 2) v = 1.f / (1.f + expf(-v));
                }
                C[(size_t)(row + r) * N + col] = v;
            }
        }
    }
}

// ---------------------------------------------------------------------------
// K3b: split-K reduce -> f32 [M][N] with bias/act. Dual pointer sets via blockIdx.y.
// ---------------------------------------------------------------------------
template<int ACT>
__global__ void reduce_f32(const float* __restrict__ P0, const float* __restrict__ bias0,
                           float* __restrict__ C0,
                           const float* __restrict__ P1, const float* __restrict__ bias1,
                           float* __restrict__ C1, int S, int M, int N) {
    const float* P = blockIdx.y ? P1 : P0;
    const float* bias = blockIdx.y ? bias1 : bias0;
    float* C = blockIdx.y ? C1 : C0;
    int idx = blockIdx.x * 256 + threadIdx.x;
    int mn4 = (M * N) >> 2;
    if (idx >= mn4) return;
    f32x4 a = ((const f32x4*)P)[idx];
    for (int s = 1; s < S; ++s) a += ((const f32x4*)P)[(size_t)s * mn4 + idx];
    int col = (idx % (N >> 2)) * 4;
    f32x4 o;
#pragma unroll
    for (int j = 0; j < 4; ++j) {
        float v = a[j] + (bias ? bias[col + j] : 0.f);
        if (ACT == 1) v = fmaxf(v, 0.f);
        if (ACT == 2) v = 1.f / (1.f + expf(-v));
        o[j] = v;
    }
    ((f32x4*)C)[idx] = o;
}

// ---------------------------------------------------------------------------
// K3c: split-K reduce + relu + bias -> split-bf16 TILED (MLP1 hid, M=128, N=HIDN)
// ---------------------------------------------------------------------------
__global__ void reduce_hid(const float* __restrict__ P0, const float* __restrict__ b0,
                           u16* __restrict__ hi0, u16* __restrict__ lo0,
                           const float* __restrict__ P1, const float* __restrict__ b1,
                           u16* __restrict__ hi1, u16* __restrict__ lo1, int S) {
    const float* P = blockIdx.y ? P1 : P0;
    const float* bias = blockIdx.y ? b1 : b0;
    u16* hi = blockIdx.y ? hi1 : hi0;
    u16* lo = blockIdx.y ? lo1 : lo0;
    int idx = blockIdx.x * 256 + threadIdx.x;       // 128*2048/8 = 32768
    int col = (idx & 255) * 8, rowi = idx >> 8;
    size_t base = ((size_t)rowi * HIDN + col) >> 2;
    f32x4 a0 = ((const f32x4*)P)[base], a1 = ((const f32x4*)P)[base + 1];
    for (int s = 1; s < S; ++s) {
        size_t sb = (size_t)s * (128 * HIDN / 4) + base;
        a0 += ((const f32x4*)P)[sb];
        a1 += ((const f32x4*)P)[sb + 1];
    }
    u16x8 h, l;
#pragma unroll
    for (int j = 0; j < 8; ++j) {
        float v = (j < 4 ? a0[j] : a1[j - 4]) + bias[col + j];
        v = fmaxf(v, 0.f);
        u16 hh = f2bf(v);
        h[j] = hh;
        l[j] = f2bf(v - bf2f(hh));
    }
    size_t ob = tiled_off(rowi, col, HIDN);
    *(u16x8*)&hi[ob] = h;
    *(u16x8*)&lo[ob] = l;
}

// ---------------------------------------------------------------------------
// K3d: MLP2 split-K reduce + bias fused with mem_kv concat -> ck/cv [KVH][33][DH]
// ---------------------------------------------------------------------------
__global__ void reduce_ckcv(const float* __restrict__ Pk, const float* __restrict__ Pv,
                            const float* __restrict__ mem_kv,
                            const float* __restrict__ kb2, const float* __restrict__ vb2,
                            float* __restrict__ ck, float* __restrict__ cv, int S) {
    int idx = blockIdx.x * 256 + threadIdx.x;   // 4*33*64 = 8448
    if (idx >= KVH * 33 * DH) return;
    int d = idx & 63;
    int j = (idx >> 6) % 33;
    int h = idx / (33 * 64);
    float kvv, vvv;
    if (j == 0) {
        kvv = mem_kv[(0 * KVH + h) * DH + d];
        vvv = mem_kv[(1 * KVH + h) * DH + d];
    } else {
        size_t base = (size_t)(h * WBLK + (j - 1)) * 128 + d;
        float ak = Pk[base], av = Pv[base];
        for (int s = 1; s < S; ++s) {
            ak += Pk[(size_t)s * (128 * 128) + base];
            av += Pv[(size_t)s * (128 * 128) + base];
        }
        kvv = ak + kb2[d];
        vvv = av + vb2[d];
    }
    ck[idx] = kvv;
    cv[idx] = vvv;
}

// ---------------------------------------------------------------------------
// K7: FUSED rotary + build_cmlp_in (v18) — both depend only on qkvg.
// Ranges: [0,3072) rotary | [3072,3200) build_cmlp.
// ---------------------------------------------------------------------------
__global__ void rotcmlp_kernel(const float* __restrict__ qkv, const float* __restrict__ k_pos,
                               const float* __restrict__ v_pos,
                               float* __restrict__ qr, float* __restrict__ kr,
                               float* __restrict__ vr,
                               u16* __restrict__ ckhi, u16* __restrict__ cklo,
                               u16* __restrict__ cvhi, u16* __restrict__ cvlo) {
    int b = blockIdx.x;
    if (b < 3072) {
        int idx = b * 256 + threadIdx.x;
        int i = idx & 31;
        int n = (idx >> 5) & 1023;
        int hd = idx >> 15;
        if (hd >= HEADS + KVH) {       // packed v copy
            int h = hd - (HEADS + KVH);
            const float* src = qkv + (size_t)n * QKVG + (HEADS + KVH + h) * DH;
            float* dst = vr + ((size_t)h * NTOK + n) * DH;
            *(float2*)&dst[2 * i] = *(const float2*)&src[2 * i];
            return;
        }
        float inv = __expf((float)i * -0.28782313662425572f);
        float fr = (float)n * inv;
        float s, c;
        __sincosf(fr, &s, &c);
        const float* src; float* dst;
        if (hd < HEADS) { src = qkv + (size_t)n * QKVG + hd * DH;        dst = qr + ((size_t)hd * NTOK + n) * DH; }
        else { int h = hd - HEADS;
               src = qkv + (size_t)n * QKVG + (HEADS + h) * DH;          dst = kr + ((size_t)h * NTOK + n) * DH; }
        float2 x = *(const float2*)&src[2 * i];
        float2 o;
        o.x = x.x * c - x.y * s;
        o.y = x.y * c + x.x * s;
        *(float2*)&dst[2 * i] = o;
    } else {
        int idx = (b - 3072) * 256 + threadIdx.x;   // 128 * 256 = 32768
        int k = (idx & 255) * 8;
        int r = idx >> 8;                           // 0..127 = h*W + w
        int p = k >> 6, d = k & 63;
        int h = r >> 5, wb = r & 31;
        int nn = wb * BSZ + p;
        const float* kq = qkv + (size_t)nn * QKVG + (HEADS + h) * DH + d;
        const float* vq = qkv + (size_t)nn * QKVG + (HEADS + KVH + h) * DH + d;
        const float* kp = k_pos + (size_t)(h * BSZ + p) * DH + d;
        const float* vp = v_pos + (size_t)(h * BSZ + p) * DH + d;
        u16x8 kh, kl, vh, vl;
#pragma unroll
        for (int j = 0; j < 8; ++j) {
            float kv = kq[j] + kp[j];
            float vv = vq[j] + vp[j];
            u16 a = f2bf(kv), bb = f2bf(vv);
            kh[j] = a;  kl[j] = f2bf(kv - bf2f(a));
            vh[j] = bb; vl[j] = f2bf(vv - bf2f(bb));
        }
        size_t ob = tiled_off(r, k, CDIM);
        *(u16x8*)&ckhi[ob] = kh; *(u16x8*)&cklo[ob] = kl;
        *(u16x8*)&cvhi[ob] = vh; *(u16x8*)&cvlo[ob] = vl;
    }
}

// ---------------------------------------------------------------------------
// K8: compressed attention + importance + top-k (vectorized scores). Stride QKVG.
// ---------------------------------------------------------------------------
__global__ __launch_bounds__(256)
void cattn_kernel(const float* __restrict__ qkv, const float* __restrict__ ck,
                  const float* __restrict__ cv, float* __restrict__ c_out,
                  int* __restrict__ sel, int* __restrict__ selmask) {
    int h = blockIdx.y;
    int tid = threadIdx.x;
    int w = tid >> 6, lane = tid & 63;
    int grp = lane >> 4, sub = lane & 15;
    int n = blockIdx.x * 4 + w;
    __shared__ float cks[33 * 68];
    __shared__ float cvs[33 * 68];
    __shared__ float sims[16 * 36];      // [w*4+g][j]

    for (int t4 = tid; t4 < 1056; t4 += 256) {
        int half = (t4 >= 528) ? 1 : 0;
        int u = t4 - half * 528;
        int j = u >> 4, d4 = (u & 15) * 4;
        const float* src = (half ? cv : ck) + (size_t)h * 33 * 64 + j * 64 + d4;
        float* dst = (half ? cvs : cks) + j * 68 + d4;
        *(float4*)dst = *(const float4*)src;
    }
    f32x4 qv[16];
    {
        const float4* qp4 = (const float4*)(qkv + (size_t)n * QKVG + (h * GQ + grp) * DH);
#pragma unroll
        for (int c = 0; c < 16; ++c) {
            float4 v = qp4[c];
            qv[c] = (f32x4){v.x, v.y, v.z, v.w};
        }
    }
    __syncthreads();

#pragma unroll
    for (int r = 0; r < 3; ++r) {
        int j = r * 16 + sub;
        if (j < 33) {
            f32x4 a0 = (f32x4){0.f, 0.f, 0.f, 0.f};
            f32x4 a1 = (f32x4){0.f, 0.f, 0.f, 0.f};
#pragma unroll
            for (int c = 0; c < 16; c += 2) {
                a0 += qv[c]     * (*(const f32x4*)&cks[j * 68 + c * 4]);
                a1 += qv[c + 1] * (*(const f32x4*)&cks[j * 68 + (c + 1) * 4]);
            }
            f32x4 at = a0 + a1;
            sims[(w * 4 + grp) * 36 + j] = ((at[0] + at[1]) + (at[2] + at[3])) * SCALE;
        }
    }

    float ival = NEGINF;
    if (lane < 32)
        ival = 0.25f * (sims[(w * 4 + 0) * 36 + 1 + lane] + sims[(w * 4 + 1) * 36 + 1 + lane] +
                        sims[(w * 4 + 2) * 36 + 1 + lane] + sims[(w * 4 + 3) * 36 + 1 + lane]);
    float m = ival;
    for (int off = 32; off; off >>= 1) m = fmaxf(m, __shfl_xor(m, off));
    float e = (lane < 32) ? expf(ival - m) : 0.f;
    float sum = e;
    for (int off = 32; off; off >>= 1) sum += __shfl_xor(sum, off);
    float p = (lane < 32) ? e / sum : NEGINF;

    float v = p;
    int base = (h * NTOK + n) * 9;
    for (int t = 0; t < NSEL; ++t) {
        float bv = v; int bi = lane;
        for (int off = 32; off; off >>= 1) {
            float ov = __shfl_xor(bv, off);
            int   oi = __shfl_xor(bi, off);
            if (ov > bv || (ov == bv && oi < bi)) { bv = ov; bi = oi; }
        }
        if (lane == 0) { sel[base + t] = bi; selmask[base + t] = (bv > 1e-10f) ? 1 : 0; }
        if (lane == bi) v = NEGINF;
    }
    if (lane == 0) { sel[base + NSEL] = n >> 5; selmask[base + NSEL] = 1; }

#pragma unroll
    for (int g = 0; g < 4; ++g) {
        float sv = (lane < 33) ? sims[(w * 4 + g) * 36 + lane] : NEGINF;
        float mm = sv;
        for (int off = 32; off; off >>= 1) mm = fmaxf(mm, __shfl_xor(mm, off));
        float ee = (lane < 33) ? __expf(sv - mm) : 0.f;
        float ssum = ee;
        for (int off = 32; off; off >>= 1) ssum += __shfl_xor(ssum, off);
        if (lane < 33) sims[(w * 4 + g) * 36 + lane] = ee / ssum;
    }

    f32x4 o = (f32x4){0.f, 0.f, 0.f, 0.f};
#pragma unroll
    for (int j = 0; j < 33; ++j) {
        float a = sims[(w * 4 + grp) * 36 + j];
        f32x4 vv = *(const f32x4*)&cvs[j * 68 + sub * 4];
        o += a * vv;
    }
    *(f32x4*)&c_out[(((size_t)(h * GQ + grp)) * NTOK + n) * DH + sub * 4] = o;
}

// ---------------------------------------------------------------------------
// K9: fine attention v15 (unchanged — control). 62.5us, LDS-throughput bound.
// ---------------------------------------------------------------------------
__global__ void fattn_kernel(const float* __restrict__ qr, const float* __restrict__ kr,
                             const float* __restrict__ vr, const int* __restrict__ sel,
                             const int* __restrict__ selmask, float* __restrict__ f_out) {
    int n = blockIdx.x, h = blockIdx.y;
    int tid = threadIdx.x;
    int w = tid >> 6, lane = tid & 63;
    int grp = lane >> 4, sub = lane & 15;
    __shared__ float qsm[4 * 68];
    __shared__ float Ksm[64 * 64];       // slot s of row r = global slot s^(r&15)
    __shared__ float Vsm[64 * 64];
    __shared__ float ps[4 * 68];         // wave-private p rows: ps[w][g*16+sub]
    __shared__ float msm[16], lsm[16];   // [slice w * 4 + head g]
    __shared__ int sel_s[9], msk_s[9];

    if (tid < 9) {
        sel_s[tid] = sel[(h * NTOK + n) * 9 + tid];
        msk_s[tid] = selmask[(h * NTOK + n) * 9 + tid];
    }
    qsm[w * 68 + lane] = qr[(((size_t)(h * GQ + w)) * NTOK + n) * DH + lane];
    f32x4 o4 = (f32x4){0.f, 0.f, 0.f, 0.f};
    float m_run = -3.402823466e38f, l_run = 0.f;
    __syncthreads();                     // B0: sel_s + qsm ready

    const float* krh_ = kr + (size_t)h * NTOK * DH;
    const float* vrh_ = vr + (size_t)h * NTOK * DH;

    int rl = lane >> 4, sl = lane & 15;

    auto stageRows = [&](float* dstbuf, const float* src, int bp) {
        int nrow = (bp < 4) ? 64 : 32;
        if (w * 16 < nrow) {
            int myblk = sel_s[bp * 2 + (w >> 1)];
            const float* b_ = src + (size_t)myblk * BSZ * DH;
#pragma unroll
            for (int cc = 0; cc < 4; ++cc) {
                int r = w * 16 + cc * 4 + rl;
                int sg = sl ^ (r & 15);
                glds16(b_ + (size_t)(r & 31) * DH + sg * 4, &dstbuf[(w * 16 + cc * 4) * 64]);
            }
        }
    };

    stageRows(Ksm, krh_, 0);
    stageRows(Vsm, vrh_, 0);

    for (int bp = 0; bp < 5; ++bp) {
        int nrow = (bp < 4) ? 64 : 32;

        asm volatile("s_waitcnt vmcnt(4)" ::: "memory");
        __builtin_amdgcn_sched_barrier(0);

        float s = -3.402823466e38f;
        {
            int jj = w * 16 + sub;
            int b = bp * 2 + (jj >> 5);
            if (jj < nrow && msk_s[b]) {
                int sw = jj & 15;
                const float* Kb = &Ksm[jj * 64];
                f32x4 a0 = (f32x4){0.f, 0.f, 0.f, 0.f};
                f32x4 a1 = (f32x4){0.f, 0.f, 0.f, 0.f};
#pragma unroll
                for (int c = 0; c < 16; c += 2) {
                    f32x4 k4a = *(const f32x4*)&Kb[(c ^ sw) * 4];
                    f32x4 q4a = *(const f32x4*)&qsm[grp * 68 + c * 4];
                    f32x4 k4b = *(const f32x4*)&Kb[((c + 1) ^ sw) * 4];
                    f32x4 q4b = *(const f32x4*)&qsm[grp * 68 + (c + 1) * 4];
                    a0 += q4a * k4a;
                    a1 += q4b * k4b;
                }
                f32x4 at = a0 + a1;
                s = ((at[0] + at[1]) + (at[2] + at[3])) * SCALE;
            }
        }
        float mb = s;
        for (int off = 8; off; off >>= 1) mb = fmaxf(mb, __shfl_xor(mb, off));
        float m_new = fmaxf(m_run, mb);
        float pp = (s > -1e37f) ? __expf(s - m_new) : 0.f;
        float alpha = __expf(m_run - m_new);
        float psum = pp;
        for (int off = 8; off; off >>= 1) psum += __shfl_xor(psum, off);
        l_run = l_run * alpha + psum;
        m_run = m_new;
        ps[w * 68 + grp * 16 + sub] = pp;

        __builtin_amdgcn_sched_barrier(0);
        asm volatile("s_waitcnt lgkmcnt(0)" ::: "memory");
        __builtin_amdgcn_sched_barrier(0);
        if (bp < 4) {
            stageRows(Ksm, krh_, bp + 1);
            asm volatile("s_waitcnt vmcnt(4)" ::: "memory");
        } else {
            asm volatile("s_waitcnt vmcnt(0)" ::: "memory");
        }
        __builtin_amdgcn_sched_barrier(0);

        {
            f32x4 t0 = (f32x4){0.f, 0.f, 0.f, 0.f};
            f32x4 t1 = (f32x4){0.f, 0.f, 0.f, 0.f};
            int jbase = w * 16;
            if (jbase < nrow) {
#pragma unroll
                for (int jq = 0; jq < 4; ++jq) {
                    f32x4 p4 = *(const f32x4*)&ps[w * 68 + grp * 16 + jq * 4];
#pragma unroll
                    for (int r = 0; r < 4; ++r) {
                        int row = jbase + jq * 4 + r;
                        int slot = sub ^ (row & 15);
                        f32x4 vv = *(const f32x4*)&Vsm[row * 64 + slot * 4];
                        if (r & 1) t1 += p4[r] * vv;
                        else       t0 += p4[r] * vv;
                    }
                }
            }
            o4 = o4 * alpha + (t0 + t1);
        }
        if (bp < 4) {
            __builtin_amdgcn_sched_barrier(0);
            asm volatile("s_waitcnt lgkmcnt(0)" ::: "memory");
            __builtin_amdgcn_sched_barrier(0);
            stageRows(Vsm, vrh_, bp + 1);
        }
    }
    if (sub == 0) { msm[w * 4 + grp] = m_run; lsm[w * 4 + grp] = l_run; }
    __syncthreads();
    *(f32x4*)&Ksm[(w * 4 + grp) * 64 + sub * 4] = o4;
    __syncthreads();
    float m0 = msm[0 * 4 + w], m1 = msm[1 * 4 + w], m2 = msm[2 * 4 + w], m3 = msm[3 * 4 + w];
    float M = fmaxf(fmaxf(m0, m1), fmaxf(m2, m3));
    float f0 = __expf(m0 - M), f1 = __expf(m1 - M), f2 = __expf(m2 - M), f3 = __expf(m3 - M);
    float L = lsm[0 * 4 + w] * f0 + lsm[1 * 4 + w] * f1 + lsm[2 * 4 + w] * f2 + lsm[3 * 4 + w] * f3;
    float sum = Ksm[(0 * 4 + w) * 64 + lane] * f0 + Ksm[(1 * 4 + w) * 64 + lane] * f1
              + Ksm[(2 * 4 + w) * 64 + lane] * f2 + Ksm[(3 * 4 + w) * 64 + lane] * f3;
    f_out[(((size_t)(h * GQ + w)) * NTOK + n) * DH + lane] = sum / L;
}

// ---------------------------------------------------------------------------
// K10: gated mix -> split-bf16 TILED (K=DDIM). Inline sigmoid gates from qkvg.
// ---------------------------------------------------------------------------
__global__ void mix_kernel(const float* __restrict__ qkvg, const float* __restrict__ gate_b,
                           const float* __restrict__ c_out, const float* __restrict__ f_out,
                           u16* __restrict__ mixhi, u16* __restrict__ mixlo) {
    int idx = blockIdx.x * 256 + threadIdx.x;   // 1024*1024/8 = 131072
    int col = (idx & 127) * 8;
    int n = idx >> 7;
    int hd = col >> 6, d = col & 63;
    float r0 = qkvg[(size_t)n * QKVG + QKVD + hd * 2]     + gate_b[hd * 2];
    float r1 = qkvg[(size_t)n * QKVG + QKVD + hd * 2 + 1] + gate_b[hd * 2 + 1];
    float g0 = 1.f / (1.f + expf(-r0));
    float g1 = 1.f / (1.f + expf(-r1));
    size_t hoff = (((size_t)hd) * NTOK + n) * DH + d;
    u16x8 h, l;
#pragma unroll
    for (int j = 0; j < 8; ++j) {
        float v = g0 * c_out[hoff + j] + g1 * f_out[hoff + j];
        u16 hh = f2bf(v);
        h[j] = hh;
        l[j] = f2bf(v - bf2f(hh));
    }
    size_t ob = tiled_off(n, col, DDIM);
    *(u16x8*)&mixhi[ob] = h;
    *(u16x8*)&mixlo[ob] = l;
}

// ---------------------------------------------------------------------------
extern "C" void kernel_launch(void* const* d_in, const int* in_sizes, int n_in,
                              void* d_out, int out_size, void* d_ws, size_t ws_size,
                              hipStream_t stream) {
    const float* inp    = (const float*)d_in[0];
    const float* g_norm = (const float*)d_in[1];
    const float* w_qkv  = (const float*)d_in[2];
    const float* mem_kv = (const float*)d_in[3];
    const float* k_pos  = (const float*)d_in[4];
    const float* v_pos  = (const float*)d_in[5];
    const float* k_w1   = (const float*)d_in[6];
    const float* k_b1   = (const float*)d_in[7];
    const float* k_w2   = (const float*)d_in[8];
    const float* k_b2   = (const float*)d_in[9];
    const float* v_w1   = (const float*)d_in[10];
    const float* v_b1   = (const float*)d_in[11];
    const float* v_w2   = (const float*)d_in[12];
    const float* v_b2   = (const float*)d_in[13];
    const float* gate_w = (const float*)d_in[14];
    const float* gate_b = (const float*)d_in[15];
    const float* w_out  = (const float*)d_in[16];
    float* out = (float*)d_out;

    char* wsb = (char*)d_ws;
    size_t off = 0;
    auto alloc = [&](size_t bytes) -> void* {
        void* p = wsb + off;
        off = (off + bytes + 255) & ~(size_t)255;
        return p;
    };
    u16*   xhi    = (u16*)  alloc((size_t)NTOK * DDIM * 2);
    u16*   xlo    = (u16*)  alloc((size_t)NTOK * DDIM * 2);
    float* qkvg   = (float*)alloc((size_t)NTOK * QKVG * 4);      // fused qkv+gates
    float* Pqkv   = (float*)alloc((size_t)2 * NTOK * QKVG * 4);  // qkv split-K partials
    u16*   wqThi  = (u16*)  alloc((size_t)QKVG * DDIM * 2);      // extended (+gate rows)
    u16*   wqTlo  = (u16*)  alloc((size_t)QKVG * DDIM * 2);
    u16*   kw1Thi = (u16*)  alloc((size_t)HIDN * CDIM * 2);
    u16*   kw1Tlo = (u16*)  alloc((size_t)HIDN * CDIM * 2);
    u16*   vw1Thi = (u16*)  alloc((size_t)HIDN * CDIM * 2);
    u16*   vw1Tlo = (u16*)  alloc((size_t)HIDN * CDIM * 2);
    u16*   woThi  = (u16*)  alloc((size_t)DDIM * DDIM * 2);
    u16*   kw2Thi = (u16*)  alloc((size_t)128 * HIDN * 2);
    u16*   kw2Tlo = (u16*)  alloc((size_t)128 * HIDN * 2);
    float* kb2p   = (float*)alloc(128 * 4);
    u16*   vw2Thi = (u16*)  alloc((size_t)128 * HIDN * 2);
    u16*   vw2Tlo = (u16*)  alloc((size_t)128 * HIDN * 2);
    float* vb2p   = (float*)alloc(128 * 4);
    u16*   cinkhi = (u16*)  alloc((size_t)128 * CDIM * 2);
    u16*   cinklo = (u16*)  alloc((size_t)128 * CDIM * 2);
    u16*   cinvhi = (u16*)  alloc((size_t)128 * CDIM * 2);
    u16*   cinvlo = (u16*)  alloc((size_t)128 * CDIM * 2);
    u16*   hidkhi = (u16*)  alloc((size_t)128 * HIDN * 2);
    u16*   hidklo = (u16*)  alloc((size_t)128 * HIDN * 2);
    u16*   hidvhi = (u16*)  alloc((size_t)128 * HIDN * 2);
    u16*   hidvlo = (u16*)  alloc((size_t)128 * HIDN * 2);
    float* Pm1k   = (float*)alloc((size_t)8 * 128 * HIDN * 4);   // MLP1 S=8 partials / out-proj reuse
    float* Pm1v   = (float*)alloc((size_t)8 * 128 * HIDN * 4);
    float* Pm2k   = (float*)alloc((size_t)16 * 128 * 128 * 4);   // MLP2 S=16 partials
    float* Pm2v   = (float*)alloc((size_t)16 * 128 * 128 * 4);
    float* ck     = (float*)alloc((size_t)KVH * 33 * DH * 4);
    float* cv     = (float*)alloc((size_t)KVH * 33 * DH * 4);
    float* qr     = (float*)alloc((size_t)HEADS * NTOK * DH * 4);
    float* kr     = (float*)alloc((size_t)KVH * NTOK * DH * 4);
    float* vr     = (float*)alloc((size_t)KVH * NTOK * DH * 4);
    float* c_out  = (float*)alloc((size_t)HEADS * NTOK * DH * 4);
    float* f_out  = (float*)alloc((size_t)HEADS * NTOK * DH * 4);
    int*   sel    = (int*)  alloc((size_t)KVH * NTOK * 9 * 4);
    int*   selmask= (int*)  alloc((size_t)KVH * NTOK * 9 * 4);
    u16*   mixhi  = (u16*)  alloc((size_t)NTOK * DDIM * 2);
    u16*   mixlo  = (u16*)  alloc((size_t)NTOK * DDIM * 2);
    float* Pout   = Pm1k;   // 16MB contiguous (Pm1k+Pm1v), dead after reduce_hid

    // 0. ALL weight prep + RMSNorm in one dispatch
    prep_kernel<<<3520, 256, 0, stream>>>(
        w_qkv, k_w1, v_w1, w_out, gate_w, k_w2, k_b2, v_w2, v_b2,
        inp, g_norm,
        wqThi, wqTlo, kw1Thi, kw1Tlo, vw1Thi, vw1Tlo, woThi,
        kw2Thi, kw2Tlo, kb2p, vw2Thi, vw2Tlo, vb2p,
        xhi, xlo);

    // 2. qkv+gates fused = x @ [w_qkv | gate_w]  (split-K=2, 208 blocks) + reduce
    gemm_tiled<3, 0, 0><<<dim3(QKVG / 128, NTOK / 128, 2), 256, 0, stream>>>(
        xhi, xlo, wqThi, wqTlo, nullptr, Pqkv,
        xhi, xlo, wqThi, wqTlo, nullptr, Pqkv, NTOK, QKVG, DDIM, 2);
    reduce_f32<0><<<dim3((NTOK * QKVG / 4) / 256, 1), 256, 0, stream>>>(
        Pqkv, nullptr, qkvg, Pqkv, nullptr, qkvg, 2, NTOK, QKVG);
    // 7/4. FUSED rotary + build_cmlp (both read only qkvg)
    rotcmlp_kernel<<<3200, 256, 0, stream>>>(qkvg, k_pos, v_pos, qr, kr, vr,
                                             cinkhi, cinklo, cinvhi, cinvlo);
    // 5. MLP1 (split-K 8, k&v batched -> 256 blocks; relu+bias+split-tile in reduce)
    gemm_tiled<3, 0, 0><<<dim3(HIDN / 128, 1, 16), 256, 0, stream>>>(
        cinkhi, cinklo, kw1Thi, kw1Tlo, nullptr, Pm1k,
        cinvhi, cinvlo, vw1Thi, vw1Tlo, nullptr, Pm1v, 128, HIDN, CDIM, 8);
    reduce_hid<<<dim3(128, 2), 256, 0, stream>>>(Pm1k, k_b1, hidkhi, hidklo,
                                                 Pm1v, v_b1, hidvhi, hidvlo, 8);
    // 6. MLP2 (split-K 16, k&v batched -> 32 blocks) + fused reduce/bias/concat
    gemm_tiled<3, 0, 0><<<dim3(1, 1, 32), 256, 0, stream>>>(
        hidkhi, hidklo, kw2Thi, kw2Tlo, nullptr, Pm2k,
        hidvhi, hidvlo, vw2Thi, vw2Tlo, nullptr, Pm2v, 128, 128, HIDN, 16);
    reduce_ckcv<<<33, 256, 0, stream>>>(Pm2k, Pm2v, mem_kv, kb2p, vb2p, ck, cv, 16);
    // 9. compressed attention + selection (vectorized scores)
    cattn_kernel<<<dim3(NTOK / 4, KVH), 256, 0, stream>>>(qkvg, ck, cv, c_out, sel, selmask);
    // 10. fine attention (v15, unchanged — control)
    fattn_kernel<<<dim3(NTOK, KVH), 256, 0, stream>>>(qr, kr, vr, sel, selmask, f_out);
    // 11. gated mix (inline sigmoid gates from qkvg) -> tiled split-bf16
    mix_kernel<<<(NTOK * DDIM / 8) / 256, 256, 0, stream>>>(qkvg, gate_b, c_out, f_out, mixhi, mixlo);
    // 12. output projection, split-K=2 (128 blocks) + reduce
    gemm_tiled<1, 0, 0><<<dim3(DDIM / 128, NTOK / 128, 2), 256, 0, stream>>>(
        mixhi, mixhi, woThi, woThi, nullptr, Pout,
        mixhi, mixhi, woThi, woThi, nullptr, Pout, NTOK, DDIM, DDIM, 2);
    reduce_f32<0><<<dim3((NTOK * DDIM / 4) / 256, 1), 256, 0, stream>>>(
        Pout, nullptr, out, Pout, nullptr, out, 2, NTOK, DDIM);
}

// Round 12
// 279.006 us; speedup vs baseline: 1.3673x; 1.0311x over previous
//
#include <hip/hip_runtime.h>
#include <math.h>

// ---- fixed problem sizes ----
#define NTOK 1024
#define DDIM 1024
#define HEADS 16
#define KVH 4
#define DH 64
#define BSZ 32
#define NSEL 8
#define WBLK 32            // NTOK / BSZ
#define GQ 4               // HEADS / KVH
#define CDIM 2048          // BSZ*DH
#define HIDN 2048
#define QKVD 1536          // (HEADS + 2*KVH)*DH
#define QKVG 1664          // QKVD + 128 (gate block appended)
#define SCALE 0.125f       // DH^-0.5
#define NEGINF (-__builtin_inff())

// u16-element offset of the gate block (rows 1536..1663) inside the extended
// tiled weight matrix: (1536>>4) * (DDIM>>5) * 64 * 8
#define OFFGATE ((size_t)96 * 32 * 512)

typedef unsigned short u16;
typedef u16   u16x8  __attribute__((ext_vector_type(8)));
typedef short short8 __attribute__((ext_vector_type(8)));
typedef float f32x4  __attribute__((ext_vector_type(4)));

__device__ __forceinline__ u16 f2bf(float f) {
    unsigned u = __float_as_uint(f);
    return (u16)((u + 0x7fffu + ((u >> 16) & 1u)) >> 16);
}
__device__ __forceinline__ float bf2f(u16 h) { return __uint_as_float(((unsigned)h) << 16); }

__device__ __forceinline__ void glds16(const void* g, void* l) {
    __builtin_amdgcn_global_load_lds(
        (const __attribute__((address_space(1))) unsigned int*)g,
        (__attribute__((address_space(3))) unsigned int*)l, 16, 0, 0);
}

// element offset (in u16) of the 8-element lane-slot for (row, k..k+7) in the
// MFMA-fragment-tiled layout: 16-row x 32-k tiles, 1KB each, contiguous.
// For non-8-aligned k, add (k&7) to the returned slot base.
__device__ __forceinline__ size_t tiled_off(int row, int k, int K) {
    return ((size_t)((row >> 4) * (K >> 5) + (k >> 5)) * 64 +
            ((row & 15) | (((k >> 3) & 3) << 4))) * 8;
}

// ---------------------------------------------------------------------------
// K0: MEGA-PREP — all weight prep + RMSNorm in ONE dispatch.
// Ranges: [0,384) wqT | [384,1408) kw1T | [1408,2432) vw1T | [2432,2688) woT
//         | [2688,2752) pad gate->wqT+OFF | [2752,2880) pad kw2
//         | [2880,3008) pad vw2 | [3008,3520) rmsnorm
// ---------------------------------------------------------------------------
__device__ __forceinline__ void transpose_body(const float* __restrict__ W,
                                               u16* __restrict__ Thi, u16* __restrict__ Tlo,
                                               int K, int N, int bx, int by,
                                               float (*tile)[65]) {
    int k0 = by * 64, n0 = bx * 64;
    int t = threadIdx.x;
    int r = t >> 4, c4 = (t & 15) * 4;
#pragma unroll
    for (int p = 0; p < 4; ++p) {
        float4 v = *(const float4*)&W[(size_t)(k0 + r + p * 16) * N + n0 + c4];
        tile[r + p * 16][c4 + 0] = v.x;
        tile[r + p * 16][c4 + 1] = v.y;
        tile[r + p * 16][c4 + 2] = v.z;
        tile[r + p * 16][c4 + 3] = v.w;
    }
    __syncthreads();
    int n = t >> 2, ks = (t & 3) * 16;
#pragma unroll
    for (int c = 0; c < 2; ++c) {
        u16x8 h, l;
#pragma unroll
        for (int j = 0; j < 8; ++j) {
            float v = tile[ks + c * 8 + j][n];
            u16 hh = f2bf(v);
            h[j] = hh;
            l[j] = f2bf(v - bf2f(hh));
        }
        size_t ob = tiled_off(n0 + n, k0 + ks + c * 8, K);
        *(u16x8*)&Thi[ob] = h;
        if (Tlo) *(u16x8*)&Tlo[ob] = l;
    }
}

__device__ __forceinline__ void pad_body(const float* __restrict__ W, const float* __restrict__ b,
                                         u16* __restrict__ Thi, u16* __restrict__ Tlo,
                                         float* __restrict__ bias_pad, int K, int Xn, int KLOG,
                                         int bx) {
    int idx = bx * 256 + threadIdx.x;
    int k = (idx & ((K >> 3) - 1)) * 8;
    int n = idx >> (KLOG - 3);
    if (n >= 128) return;
    u16x8 h, l;
#pragma unroll
    for (int j = 0; j < 8; ++j) {
        float v = (n < Xn) ? W[(size_t)(k + j) * Xn + n] : 0.f;
        u16 hh = f2bf(v);
        h[j] = hh;
        l[j] = f2bf(v - bf2f(hh));
    }
    size_t ob = tiled_off(n, k, K);
    *(u16x8*)&Thi[ob] = h;
    *(u16x8*)&Tlo[ob] = l;
    if (bias_pad && k == 0) bias_pad[n] = (n < Xn) ? b[n] : 0.f;
}

__device__ __forceinline__ void rms_body(const float* __restrict__ inp, const float* __restrict__ g,
                                         u16* __restrict__ xhi, u16* __restrict__ xlo,
                                         int bx, float* red) {
    int t = threadIdx.x;
    int half = t >> 7, tid = t & 127;
    int n = bx * 2 + half;
    const float4* row = (const float4*)(inp + (size_t)n * DDIM);
    float4 v0 = row[tid * 2], v1 = row[tid * 2 + 1];
    float ss = v0.x*v0.x + v0.y*v0.y + v0.z*v0.z + v0.w*v0.w
             + v1.x*v1.x + v1.y*v1.y + v1.z*v1.z + v1.w*v1.w;
    for (int off = 32; off; off >>= 1) ss += __shfl_down(ss, off);
    if ((t & 63) == 0) red[t >> 6] = ss;
    __syncthreads();
    float tot = red[half * 2] + red[half * 2 + 1];
    float r = 1.f / sqrtf(tot * (1.f / DDIM) + 1e-6f);
    const float4* gp = (const float4*)g;
    float4 g0 = gp[tid * 2], g1 = gp[tid * 2 + 1];
    float o[8] = { v0.x*r*g0.x, v0.y*r*g0.y, v0.z*r*g0.z, v0.w*r*g0.w,
                   v1.x*r*g1.x, v1.y*r*g1.y, v1.z*r*g1.z, v1.w*r*g1.w };
    u16x8 h, l;
#pragma unroll
    for (int i = 0; i < 8; ++i) {
        u16 hh = f2bf(o[i]);
        h[i] = hh;
        l[i] = f2bf(o[i] - bf2f(hh));
    }
    size_t ob = tiled_off(n, tid * 8, DDIM);
    *(u16x8*)&xhi[ob] = h;
    *(u16x8*)&xlo[ob] = l;
}

__global__ void prep_kernel(const float* __restrict__ w_qkv, const float* __restrict__ k_w1,
                            const float* __restrict__ v_w1, const float* __restrict__ w_out,
                            const float* __restrict__ gate_w,
                            const float* __restrict__ k_w2, const float* __restrict__ k_b2,
                            const float* __restrict__ v_w2, const float* __restrict__ v_b2,
                            const float* __restrict__ inp, const float* __restrict__ g_norm,
                            u16* wqThi, u16* wqTlo, u16* kw1Thi, u16* kw1Tlo,
                            u16* vw1Thi, u16* vw1Tlo, u16* woThi,
                            u16* kw2Thi, u16* kw2Tlo, float* kb2p,
                            u16* vw2Thi, u16* vw2Tlo, float* vb2p,
                            u16* xhi, u16* xlo) {
    __shared__ float tile[64][65];
    __shared__ float red[4];
    int b = blockIdx.x;
    if (b < 384) {
        transpose_body(w_qkv, wqThi, wqTlo, DDIM, QKVD, b % 24, b / 24, tile);
    } else if (b < 1408) {
        int r = b - 384;
        transpose_body(k_w1, kw1Thi, kw1Tlo, CDIM, HIDN, r & 31, r >> 5, tile);
    } else if (b < 2432) {
        int r = b - 1408;
        transpose_body(v_w1, vw1Thi, vw1Tlo, CDIM, HIDN, r & 31, r >> 5, tile);
    } else if (b < 2688) {
        int r = b - 2432;
        transpose_body(w_out, woThi, nullptr, DDIM, DDIM, r & 15, r >> 4, tile);
    } else if (b < 2752) {
        pad_body(gate_w, nullptr, wqThi + OFFGATE, wqTlo + OFFGATE, nullptr, DDIM, 32, 10, b - 2688);
    } else if (b < 2880) {
        pad_body(k_w2, k_b2, kw2Thi, kw2Tlo, kb2p, HIDN, 64, 11, b - 2752);
    } else if (b < 3008) {
        pad_body(v_w2, v_b2, vw2Thi, vw2Tlo, vb2p, HIDN, 64, 11, b - 2880);
    } else {
        rms_body(inp, g_norm, xhi, xlo, b - 3008, red);
    }
}

// ---------------------------------------------------------------------------
// K3: tiled MFMA GEMM with software pipeline + optional split-K.
// ---------------------------------------------------------------------------
template<int SPLIT, int ACT, int FINAL>
__global__ __launch_bounds__(256, 1)
void gemm_tiled(const u16* __restrict__ Ahi0, const u16* __restrict__ Alo0,
                const u16* __restrict__ Bhi0, const u16* __restrict__ Blo0,
                const float* __restrict__ bias0, float* __restrict__ C0,
                const u16* __restrict__ Ahi1, const u16* __restrict__ Alo1,
                const u16* __restrict__ Bhi1, const u16* __restrict__ Blo1,
                const float* __restrict__ bias1, float* __restrict__ C1,
                int M, int N, int K, int S) {
    int batch = blockIdx.z / S;
    int s = blockIdx.z - batch * S;
    const u16* Ahi = batch ? Ahi1 : Ahi0;
    const u16* Alo = batch ? Alo1 : Alo0;
    const u16* Bhi = batch ? Bhi1 : Bhi0;
    const u16* Blo = batch ? Blo1 : Blo0;
    const float* bias = batch ? bias1 : bias0;
    float* C = batch ? C1 : C0;

    constexpr int PARTS = (SPLIT == 3) ? 2 : 1;
    __shared__ u16 smA[2 * PARTS * 8 * 512];
    __shared__ u16 smB[2 * PARTS * 8 * 512];

    int tid = threadIdx.x;
    int w = tid >> 6, L = tid & 63;
    int m15 = L & 15, q = L >> 4;
    int KT = K >> 5;
    int rowTile = blockIdx.y * 8, colTile = blockIdx.x * 8;
    int NIT = (K / S) >> 5;
    int kb0 = s * NIT;
    int aw = w & 1, bw = w >> 1;

    f32x4 acc[4][4];
#pragma unroll
    for (int i = 0; i < 4; ++i)
#pragma unroll
        for (int j = 0; j < 4; ++j) acc[i][j] = (f32x4){0.f, 0.f, 0.f, 0.f};

    auto stage = [&](int buf, int kb) {
#pragma unroll
        for (int rl = 0; rl < 2; ++rl) {
            int rb = 2 * w + rl;
            glds16(Ahi + ((size_t)(rowTile + rb) * KT + kb) * 512 + (size_t)L * 8,
                   &smA[((buf * PARTS + 0) * 8 + rb) * 512]);
            glds16(Bhi + ((size_t)(colTile + rb) * KT + kb) * 512 + (size_t)L * 8,
                   &smB[((buf * PARTS + 0) * 8 + rb) * 512]);
            if constexpr (SPLIT == 3) {
                glds16(Alo + ((size_t)(rowTile + rb) * KT + kb) * 512 + (size_t)L * 8,
                       &smA[((buf * PARTS + 1) * 8 + rb) * 512]);
                glds16(Blo + ((size_t)(colTile + rb) * KT + kb) * 512 + (size_t)L * 8,
                       &smB[((buf * PARTS + 1) * 8 + rb) * 512]);
            }
        }
    };

    stage(0, kb0);
    for (int it = 0; it < NIT; ++it) {
        __syncthreads();
        if (it + 1 < NIT) stage((it + 1) & 1, kb0 + it + 1);
        int buf = it & 1;
        short8 ah[4], bh[4];
#pragma unroll
        for (int i = 0; i < 4; ++i) {
            ah[i] = *(const short8*)&smA[((buf * PARTS + 0) * 8 + aw * 4 + i) * 512 + L * 8];
            bh[i] = *(const short8*)&smB[((buf * PARTS + 0) * 8 + bw * 4 + i) * 512 + L * 8];
        }
        if constexpr (SPLIT == 3) {
            short8 al[4], bl[4];
#pragma unroll
            for (int i = 0; i < 4; ++i) {
                al[i] = *(const short8*)&smA[((buf * PARTS + 1) * 8 + aw * 4 + i) * 512 + L * 8];
                bl[i] = *(const short8*)&smB[((buf * PARTS + 1) * 8 + bw * 4 + i) * 512 + L * 8];
            }
#pragma unroll
            for (int i = 0; i < 4; ++i)
#pragma unroll
                for (int j = 0; j < 4; ++j) {
                    acc[i][j] = __builtin_amdgcn_mfma_f32_16x16x32_bf16(ah[i], bl[j], acc[i][j], 0, 0, 0);
                    acc[i][j] = __builtin_amdgcn_mfma_f32_16x16x32_bf16(al[i], bh[j], acc[i][j], 0, 0, 0);
                    acc[i][j] = __builtin_amdgcn_mfma_f32_16x16x32_bf16(ah[i], bh[j], acc[i][j], 0, 0, 0);
                }
        } else {
#pragma unroll
            for (int i = 0; i < 4; ++i)
#pragma unroll
                for (int j = 0; j < 4; ++j)
                    acc[i][j] = __builtin_amdgcn_mfma_f32_16x16x32_bf16(ah[i], bh[j], acc[i][j], 0, 0, 0);
        }
    }

    if constexpr (FINAL == 0) C += (size_t)s * M * N;
#pragma unroll
    for (int i = 0; i < 4; ++i) {
        int row = rowTile * 16 + aw * 64 + i * 16 + q * 4;
#pragma unroll
        for (int j = 0; j < 4; ++j) {
            int col = colTile * 16 + bw * 64 + j * 16 + m15;
            float bv = (FINAL && bias) ? bias[col] : 0.f;
#pragma unroll
            for (int r = 0; r < 4; ++r) {
                float v = acc[i][j][r];
                if constexpr (FINAL) {
                    v += bv;
                    if (ACT == 1) v = fmaxf(v, 0.f);
                    if (ACT == 2) v = 1.f / (1.f + expf(-v));
                }
                C[(size_t)(row + r) * N + col] = v;
            }
        }
    }
}

// ---------------------------------------------------------------------------
// K3b: split-K reduce -> f32 [M][N] with bias/act. Dual pointer sets via blockIdx.y.
// ---------------------------------------------------------------------------
template<int ACT>
__global__ void reduce_f32(const float* __restrict__ P0, const float* __restrict__ bias0,
                           float* __restrict__ C0,
                           const float* __restrict__ P1, const float* __restrict__ bias1,
                           float* __restrict__ C1, int S, int M, int N) {
    const float* P = blockIdx.y ? P1 : P0;
    const float* bias = blockIdx.y ? bias1 : bias0;
    float* C = blockIdx.y ? C1 : C0;
    int idx = blockIdx.x * 256 + threadIdx.x;
    int mn4 = (M * N) >> 2;
    if (idx >= mn4) return;
    f32x4 a = ((const f32x4*)P)[idx];
    for (int s = 1; s < S; ++s) a += ((const f32x4*)P)[(size_t)s * mn4 + idx];
    int col = (idx % (N >> 2)) * 4;
    f32x4 o;
#pragma unroll
    for (int j = 0; j < 4; ++j) {
        float v = a[j] + (bias ? bias[col + j] : 0.f);
        if (ACT == 1) v = fmaxf(v, 0.f);
        if (ACT == 2) v = 1.f / (1.f + expf(-v));
        o[j] = v;
    }
    ((f32x4*)C)[idx] = o;
}

// ---------------------------------------------------------------------------
// K3c: split-K reduce + relu + bias -> split-bf16 TILED (MLP1 hid, M=128, N=HIDN)
// ---------------------------------------------------------------------------
__global__ void reduce_hid(const float* __restrict__ P0, const float* __restrict__ b0,
                           u16* __restrict__ hi0, u16* __restrict__ lo0,
                           const float* __restrict__ P1, const float* __restrict__ b1,
                           u16* __restrict__ hi1, u16* __restrict__ lo1, int S) {
    const float* P = blockIdx.y ? P1 : P0;
    const float* bias = blockIdx.y ? b1 : b0;
    u16* hi = blockIdx.y ? hi1 : hi0;
    u16* lo = blockIdx.y ? lo1 : lo0;
    int idx = blockIdx.x * 256 + threadIdx.x;       // 128*2048/8 = 32768
    int col = (idx & 255) * 8, rowi = idx >> 8;
    size_t base = ((size_t)rowi * HIDN + col) >> 2;
    f32x4 a0 = ((const f32x4*)P)[base], a1 = ((const f32x4*)P)[base + 1];
    for (int s = 1; s < S; ++s) {
        size_t sb = (size_t)s * (128 * HIDN / 4) + base;
        a0 += ((const f32x4*)P)[sb];
        a1 += ((const f32x4*)P)[sb + 1];
    }
    u16x8 h, l;
#pragma unroll
    for (int j = 0; j < 8; ++j) {
        float v = (j < 4 ? a0[j] : a1[j - 4]) + bias[col + j];
        v = fmaxf(v, 0.f);
        u16 hh = f2bf(v);
        h[j] = hh;
        l[j] = f2bf(v - bf2f(hh));
    }
    size_t ob = tiled_off(rowi, col, HIDN);
    *(u16x8*)&hi[ob] = h;
    *(u16x8*)&lo[ob] = l;
}

// ---------------------------------------------------------------------------
// K3d: MLP2 split-K reduce + bias fused with mem_kv concat -> ck/cv [KVH][33][DH]
// ---------------------------------------------------------------------------
__global__ void reduce_ckcv(const float* __restrict__ Pk, const float* __restrict__ Pv,
                            const float* __restrict__ mem_kv,
                            const float* __restrict__ kb2, const float* __restrict__ vb2,
                            float* __restrict__ ck, float* __restrict__ cv, int S) {
    int idx = blockIdx.x * 256 + threadIdx.x;   // 4*33*64 = 8448
    if (idx >= KVH * 33 * DH) return;
    int d = idx & 63;
    int j = (idx >> 6) % 33;
    int h = idx / (33 * 64);
    float kvv, vvv;
    if (j == 0) {
        kvv = mem_kv[(0 * KVH + h) * DH + d];
        vvv = mem_kv[(1 * KVH + h) * DH + d];
    } else {
        size_t base = (size_t)(h * WBLK + (j - 1)) * 128 + d;
        float ak = Pk[base], av = Pv[base];
        for (int s = 1; s < S; ++s) {
            ak += Pk[(size_t)s * (128 * 128) + base];
            av += Pv[(size_t)s * (128 * 128) + base];
        }
        kvv = ak + kb2[d];
        vvv = av + vb2[d];
    }
    ck[idx] = kvv;
    cv[idx] = vvv;
}

// ---------------------------------------------------------------------------
// K7: FUSED rotary + build_cmlp_in — both depend only on qkvg.
// Ranges: [0,3072) rotary | [3072,3200) build_cmlp.
// ---------------------------------------------------------------------------
__global__ void rotcmlp_kernel(const float* __restrict__ qkv, const float* __restrict__ k_pos,
                               const float* __restrict__ v_pos,
                               float* __restrict__ qr, float* __restrict__ kr,
                               float* __restrict__ vr,
                               u16* __restrict__ ckhi, u16* __restrict__ cklo,
                               u16* __restrict__ cvhi, u16* __restrict__ cvlo) {
    int b = blockIdx.x;
    if (b < 3072) {
        int idx = b * 256 + threadIdx.x;
        int i = idx & 31;
        int n = (idx >> 5) & 1023;
        int hd = idx >> 15;
        if (hd >= HEADS + KVH) {       // packed v copy
            int h = hd - (HEADS + KVH);
            const float* src = qkv + (size_t)n * QKVG + (HEADS + KVH + h) * DH;
            float* dst = vr + ((size_t)h * NTOK + n) * DH;
            *(float2*)&dst[2 * i] = *(const float2*)&src[2 * i];
            return;
        }
        float inv = __expf((float)i * -0.28782313662425572f);
        float fr = (float)n * inv;
        float s, c;
        __sincosf(fr, &s, &c);
        const float* src; float* dst;
        if (hd < HEADS) { src = qkv + (size_t)n * QKVG + hd * DH;        dst = qr + ((size_t)hd * NTOK + n) * DH; }
        else { int h = hd - HEADS;
               src = qkv + (size_t)n * QKVG + (HEADS + h) * DH;          dst = kr + ((size_t)h * NTOK + n) * DH; }
        float2 x = *(const float2*)&src[2 * i];
        float2 o;
        o.x = x.x * c - x.y * s;
        o.y = x.y * c + x.x * s;
        *(float2*)&dst[2 * i] = o;
    } else {
        int idx = (b - 3072) * 256 + threadIdx.x;   // 128 * 256 = 32768
        int k = (idx & 255) * 8;
        int r = idx >> 8;                           // 0..127 = h*W + w
        int p = k >> 6, d = k & 63;
        int h = r >> 5, wb = r & 31;
        int nn = wb * BSZ + p;
        const float* kq = qkv + (size_t)nn * QKVG + (HEADS + h) * DH + d;
        const float* vq = qkv + (size_t)nn * QKVG + (HEADS + KVH + h) * DH + d;
        const float* kp = k_pos + (size_t)(h * BSZ + p) * DH + d;
        const float* vp = v_pos + (size_t)(h * BSZ + p) * DH + d;
        u16x8 kh, kl, vh, vl;
#pragma unroll
        for (int j = 0; j < 8; ++j) {
            float kv = kq[j] + kp[j];
            float vv = vq[j] + vp[j];
            u16 a = f2bf(kv), bb = f2bf(vv);
            kh[j] = a;  kl[j] = f2bf(kv - bf2f(a));
            vh[j] = bb; vl[j] = f2bf(vv - bf2f(bb));
        }
        size_t ob = tiled_off(r, k, CDIM);
        *(u16x8*)&ckhi[ob] = kh; *(u16x8*)&cklo[ob] = kl;
        *(u16x8*)&cvhi[ob] = vh; *(u16x8*)&cvlo[ob] = vl;
    }
}

// ---------------------------------------------------------------------------
// K8: compressed attention + importance + top-k (vectorized scores). Stride QKVG.
// ---------------------------------------------------------------------------
__global__ __launch_bounds__(256)
void cattn_kernel(const float* __restrict__ qkv, const float* __restrict__ ck,
                  const float* __restrict__ cv, float* __restrict__ c_out,
                  int* __restrict__ sel, int* __restrict__ selmask) {
    int h = blockIdx.y;
    int tid = threadIdx.x;
    int w = tid >> 6, lane = tid & 63;
    int grp = lane >> 4, sub = lane & 15;
    int n = blockIdx.x * 4 + w;
    __shared__ float cks[33 * 68];
    __shared__ float cvs[33 * 68];
    __shared__ float sims[16 * 36];      // [w*4+g][j]

    for (int t4 = tid; t4 < 1056; t4 += 256) {
        int half = (t4 >= 528) ? 1 : 0;
        int u = t4 - half * 528;
        int j = u >> 4, d4 = (u & 15) * 4;
        const float* src = (half ? cv : ck) + (size_t)h * 33 * 64 + j * 64 + d4;
        float* dst = (half ? cvs : cks) + j * 68 + d4;
        *(float4*)dst = *(const float4*)src;
    }
    f32x4 qv[16];
    {
        const float4* qp4 = (const float4*)(qkv + (size_t)n * QKVG + (h * GQ + grp) * DH);
#pragma unroll
        for (int c = 0; c < 16; ++c) {
            float4 v = qp4[c];
            qv[c] = (f32x4){v.x, v.y, v.z, v.w};
        }
    }
    __syncthreads();

#pragma unroll
    for (int r = 0; r < 3; ++r) {
        int j = r * 16 + sub;
        if (j < 33) {
            f32x4 a0 = (f32x4){0.f, 0.f, 0.f, 0.f};
            f32x4 a1 = (f32x4){0.f, 0.f, 0.f, 0.f};
#pragma unroll
            for (int c = 0; c < 16; c += 2) {
                a0 += qv[c]     * (*(const f32x4*)&cks[j * 68 + c * 4]);
                a1 += qv[c + 1] * (*(const f32x4*)&cks[j * 68 + (c + 1) * 4]);
            }
            f32x4 at = a0 + a1;
            sims[(w * 4 + grp) * 36 + j] = ((at[0] + at[1]) + (at[2] + at[3])) * SCALE;
        }
    }

    float ival = NEGINF;
    if (lane < 32)
        ival = 0.25f * (sims[(w * 4 + 0) * 36 + 1 + lane] + sims[(w * 4 + 1) * 36 + 1 + lane] +
                        sims[(w * 4 + 2) * 36 + 1 + lane] + sims[(w * 4 + 3) * 36 + 1 + lane]);
    float m = ival;
    for (int off = 32; off; off >>= 1) m = fmaxf(m, __shfl_xor(m, off));
    float e = (lane < 32) ? expf(ival - m) : 0.f;
    float sum = e;
    for (int off = 32; off; off >>= 1) sum += __shfl_xor(sum, off);
    float p = (lane < 32) ? e / sum : NEGINF;

    float v = p;
    int base = (h * NTOK + n) * 9;
    for (int t = 0; t < NSEL; ++t) {
        float bv = v; int bi = lane;
        for (int off = 32; off; off >>= 1) {
            float ov = __shfl_xor(bv, off);
            int   oi = __shfl_xor(bi, off);
            if (ov > bv || (ov == bv && oi < bi)) { bv = ov; bi = oi; }
        }
        if (lane == 0) { sel[base + t] = bi; selmask[base + t] = (bv > 1e-10f) ? 1 : 0; }
        if (lane == bi) v = NEGINF;
    }
    if (lane == 0) { sel[base + NSEL] = n >> 5; selmask[base + NSEL] = 1; }

#pragma unroll
    for (int g = 0; g < 4; ++g) {
        float sv = (lane < 33) ? sims[(w * 4 + g) * 36 + lane] : NEGINF;
        float mm = sv;
        for (int off = 32; off; off >>= 1) mm = fmaxf(mm, __shfl_xor(mm, off));
        float ee = (lane < 33) ? __expf(sv - mm) : 0.f;
        float ssum = ee;
        for (int off = 32; off; off >>= 1) ssum += __shfl_xor(ssum, off);
        if (lane < 33) sims[(w * 4 + g) * 36 + lane] = ee / ssum;
    }

    f32x4 o = (f32x4){0.f, 0.f, 0.f, 0.f};
#pragma unroll
    for (int j = 0; j < 33; ++j) {
        float a = sims[(w * 4 + grp) * 36 + j];
        f32x4 vv = *(const f32x4*)&cvs[j * 68 + sub * 4];
        o += a * vv;
    }
    *(f32x4*)&c_out[(((size_t)(h * GQ + grp)) * NTOK + n) * DH + sub * 4] = o;
}

// ---------------------------------------------------------------------------
// K9: fine attention v19 = v15 loop (unchanged) + FUSED gated-mix epilogue.
// The f_out round-trip (4MB write + 4MB read) and the mix dispatch are gone:
// block (n,h) holds exactly the 4 heads mix needs; gate scalars from qkvg,
// c_out read here, bf16-hi tiled write directly (mixlo was never consumed).
// Math bit-identical: gated sum uses the same f32 value previously stored.
// ---------------------------------------------------------------------------
__global__ void fattn_kernel(const float* __restrict__ qr, const float* __restrict__ kr,
                             const float* __restrict__ vr, const int* __restrict__ sel,
                             const int* __restrict__ selmask,
                             const float* __restrict__ qkvg, const float* __restrict__ gate_b,
                             const float* __restrict__ c_out, u16* __restrict__ mixhi) {
    int n = blockIdx.x, h = blockIdx.y;
    int tid = threadIdx.x;
    int w = tid >> 6, lane = tid & 63;
    int grp = lane >> 4, sub = lane & 15;
    __shared__ float qsm[4 * 68];
    __shared__ float Ksm[64 * 64];       // slot s of row r = global slot s^(r&15)
    __shared__ float Vsm[64 * 64];
    __shared__ float ps[4 * 68];         // wave-private p rows: ps[w][g*16+sub]
    __shared__ float msm[16], lsm[16];   // [slice w * 4 + head g]
    __shared__ int sel_s[9], msk_s[9];

    if (tid < 9) {
        sel_s[tid] = sel[(h * NTOK + n) * 9 + tid];
        msk_s[tid] = selmask[(h * NTOK + n) * 9 + tid];
    }
    qsm[w * 68 + lane] = qr[(((size_t)(h * GQ + w)) * NTOK + n) * DH + lane];
    f32x4 o4 = (f32x4){0.f, 0.f, 0.f, 0.f};
    float m_run = -3.402823466e38f, l_run = 0.f;
    __syncthreads();                     // B0: sel_s + qsm ready

    const float* krh_ = kr + (size_t)h * NTOK * DH;
    const float* vrh_ = vr + (size_t)h * NTOK * DH;

    int rl = lane >> 4, sl = lane & 15;

    auto stageRows = [&](float* dstbuf, const float* src, int bp) {
        int nrow = (bp < 4) ? 64 : 32;
        if (w * 16 < nrow) {
            int myblk = sel_s[bp * 2 + (w >> 1)];
            const float* b_ = src + (size_t)myblk * BSZ * DH;
#pragma unroll
            for (int cc = 0; cc < 4; ++cc) {
                int r = w * 16 + cc * 4 + rl;
                int sg = sl ^ (r & 15);
                glds16(b_ + (size_t)(r & 31) * DH + sg * 4, &dstbuf[(w * 16 + cc * 4) * 64]);
            }
        }
    };

    stageRows(Ksm, krh_, 0);
    stageRows(Vsm, vrh_, 0);

    for (int bp = 0; bp < 5; ++bp) {
        int nrow = (bp < 4) ? 64 : 32;

        asm volatile("s_waitcnt vmcnt(4)" ::: "memory");
        __builtin_amdgcn_sched_barrier(0);

        float s = -3.402823466e38f;
        {
            int jj = w * 16 + sub;
            int b = bp * 2 + (jj >> 5);
            if (jj < nrow && msk_s[b]) {
                int sw = jj & 15;
                const float* Kb = &Ksm[jj * 64];
                f32x4 a0 = (f32x4){0.f, 0.f, 0.f, 0.f};
                f32x4 a1 = (f32x4){0.f, 0.f, 0.f, 0.f};
#pragma unroll
                for (int c = 0; c < 16; c += 2) {
                    f32x4 k4a = *(const f32x4*)&Kb[(c ^ sw) * 4];
                    f32x4 q4a = *(const f32x4*)&qsm[grp * 68 + c * 4];
                    f32x4 k4b = *(const f32x4*)&Kb[((c + 1) ^ sw) * 4];
                    f32x4 q4b = *(const f32x4*)&qsm[grp * 68 + (c + 1) * 4];
                    a0 += q4a * k4a;
                    a1 += q4b * k4b;
                }
                f32x4 at = a0 + a1;
                s = ((at[0] + at[1]) + (at[2] + at[3])) * SCALE;
            }
        }
        float mb = s;
        for (int off = 8; off; off >>= 1) mb = fmaxf(mb, __shfl_xor(mb, off));
        float m_new = fmaxf(m_run, mb);
        float pp = (s > -1e37f) ? __expf(s - m_new) : 0.f;
        float alpha = __expf(m_run - m_new);
        float psum = pp;
        for (int off = 8; off; off >>= 1) psum += __shfl_xor(psum, off);
        l_run = l_run * alpha + psum;
        m_run = m_new;
        ps[w * 68 + grp * 16 + sub] = pp;

        __builtin_amdgcn_sched_barrier(0);
        asm volatile("s_waitcnt lgkmcnt(0)" ::: "memory");
        __builtin_amdgcn_sched_barrier(0);
        if (bp < 4) {
            stageRows(Ksm, krh_, bp + 1);
            asm volatile("s_waitcnt vmcnt(4)" ::: "memory");
        } else {
            asm volatile("s_waitcnt vmcnt(0)" ::: "memory");
        }
        __builtin_amdgcn_sched_barrier(0);

        {
            f32x4 t0 = (f32x4){0.f, 0.f, 0.f, 0.f};
            f32x4 t1 = (f32x4){0.f, 0.f, 0.f, 0.f};
            int jbase = w * 16;
            if (jbase < nrow) {
#pragma unroll
                for (int jq = 0; jq < 4; ++jq) {
                    f32x4 p4 = *(const f32x4*)&ps[w * 68 + grp * 16 + jq * 4];
#pragma unroll
                    for (int r = 0; r < 4; ++r) {
                        int row = jbase + jq * 4 + r;
                        int slot = sub ^ (row & 15);
                        f32x4 vv = *(const f32x4*)&Vsm[row * 64 + slot * 4];
                        if (r & 1) t1 += p4[r] * vv;
                        else       t0 += p4[r] * vv;
                    }
                }
            }
            o4 = o4 * alpha + (t0 + t1);
        }
        if (bp < 4) {
            __builtin_amdgcn_sched_barrier(0);
            asm volatile("s_waitcnt lgkmcnt(0)" ::: "memory");
            __builtin_amdgcn_sched_barrier(0);
            stageRows(Vsm, vrh_, bp + 1);
        }
    }
    if (sub == 0) { msm[w * 4 + grp] = m_run; lsm[w * 4 + grp] = l_run; }
    __syncthreads();
    *(f32x4*)&Ksm[(w * 4 + grp) * 64 + sub * 4] = o4;
    __syncthreads();
    // thread: head-in-group = w, dim = lane
    float m0 = msm[0 * 4 + w], m1 = msm[1 * 4 + w], m2 = msm[2 * 4 + w], m3 = msm[3 * 4 + w];
    float M = fmaxf(fmaxf(m0, m1), fmaxf(m2, m3));
    float f0 = __expf(m0 - M), f1 = __expf(m1 - M), f2 = __expf(m2 - M), f3 = __expf(m3 - M);
    float L = lsm[0 * 4 + w] * f0 + lsm[1 * 4 + w] * f1 + lsm[2 * 4 + w] * f2 + lsm[3 * 4 + w] * f3;
    float sum = Ksm[(0 * 4 + w) * 64 + lane] * f0 + Ksm[(1 * 4 + w) * 64 + lane] * f1
              + Ksm[(2 * 4 + w) * 64 + lane] * f2 + Ksm[(3 * 4 + w) * 64 + lane] * f3;
    float fo = sum / L;                                  // = old f_out value
    // ---- fused gated mix (bit-identical to old mix_kernel math) ----
    int head = h * GQ + w;
    float rg0 = qkvg[(size_t)n * QKVG + QKVD + head * 2]     + gate_b[head * 2];
    float rg1 = qkvg[(size_t)n * QKVG + QKVD + head * 2 + 1] + gate_b[head * 2 + 1];
    float g0 = 1.f / (1.f + expf(-rg0));
    float g1 = 1.f / (1.f + expf(-rg1));
    float cval = c_out[((size_t)head * NTOK + n) * DH + lane];
    float v = g0 * cval + g1 * fo;
    int col = head * DH + lane;
    mixhi[tiled_off(n, col, DDIM) + (col & 7)] = f2bf(v);
}

// ---------------------------------------------------------------------------
extern "C" void kernel_launch(void* const* d_in, const int* in_sizes, int n_in,
                              void* d_out, int out_size, void* d_ws, size_t ws_size,
                              hipStream_t stream) {
    const float* inp    = (const float*)d_in[0];
    const float* g_norm = (const float*)d_in[1];
    const float* w_qkv  = (const float*)d_in[2];
    const float* mem_kv = (const float*)d_in[3];
    const float* k_pos  = (const float*)d_in[4];
    const float* v_pos  = (const float*)d_in[5];
    const float* k_w1   = (const float*)d_in[6];
    const float* k_b1   = (const float*)d_in[7];
    const float* k_w2   = (const float*)d_in[8];
    const float* k_b2   = (const float*)d_in[9];
    const float* v_w1   = (const float*)d_in[10];
    const float* v_b1   = (const float*)d_in[11];
    const float* v_w2   = (const float*)d_in[12];
    const float* v_b2   = (const float*)d_in[13];
    const float* gate_w = (const float*)d_in[14];
    const float* gate_b = (const float*)d_in[15];
    const float* w_out  = (const float*)d_in[16];
    float* out = (float*)d_out;

    char* wsb = (char*)d_ws;
    size_t off = 0;
    auto alloc = [&](size_t bytes) -> void* {
        void* p = wsb + off;
        off = (off + bytes + 255) & ~(size_t)255;
        return p;
    };
    u16*   xhi    = (u16*)  alloc((size_t)NTOK * DDIM * 2);
    u16*   xlo    = (u16*)  alloc((size_t)NTOK * DDIM * 2);
    float* qkvg   = (float*)alloc((size_t)NTOK * QKVG * 4);      // fused qkv+gates
    float* Pqkv   = (float*)alloc((size_t)4 * NTOK * QKVG * 4);  // qkv split-K=4 partials
    u16*   wqThi  = (u16*)  alloc((size_t)QKVG * DDIM * 2);      // extended (+gate rows)
    u16*   wqTlo  = (u16*)  alloc((size_t)QKVG * DDIM * 2);
    u16*   kw1Thi = (u16*)  alloc((size_t)HIDN * CDIM * 2);
    u16*   kw1Tlo = (u16*)  alloc((size_t)HIDN * CDIM * 2);
    u16*   vw1Thi = (u16*)  alloc((size_t)HIDN * CDIM * 2);
    u16*   vw1Tlo = (u16*)  alloc((size_t)HIDN * CDIM * 2);
    u16*   woThi  = (u16*)  alloc((size_t)DDIM * DDIM * 2);
    u16*   kw2Thi = (u16*)  alloc((size_t)128 * HIDN * 2);
    u16*   kw2Tlo = (u16*)  alloc((size_t)128 * HIDN * 2);
    float* kb2p   = (float*)alloc(128 * 4);
    u16*   vw2Thi = (u16*)  alloc((size_t)128 * HIDN * 2);
    u16*   vw2Tlo = (u16*)  alloc((size_t)128 * HIDN * 2);
    float* vb2p   = (float*)alloc(128 * 4);
    u16*   cinkhi = (u16*)  alloc((size_t)128 * CDIM * 2);
    u16*   cinklo = (u16*)  alloc((size_t)128 * CDIM * 2);
    u16*   cinvhi = (u16*)  alloc((size_t)128 * CDIM * 2);
    u16*   cinvlo = (u16*)  alloc((size_t)128 * CDIM * 2);
    u16*   hidkhi = (u16*)  alloc((size_t)128 * HIDN * 2);
    u16*   hidklo = (u16*)  alloc((size_t)128 * HIDN * 2);
    u16*   hidvhi = (u16*)  alloc((size_t)128 * HIDN * 2);
    u16*   hidvlo = (u16*)  alloc((size_t)128 * HIDN * 2);
    float* Pm1k   = (float*)alloc((size_t)8 * 128 * HIDN * 4);   // MLP1 S=8 partials / out-proj reuse
    float* Pm1v   = (float*)alloc((size_t)8 * 128 * HIDN * 4);
    float* Pm2k   = (float*)alloc((size_t)16 * 128 * 128 * 4);   // MLP2 S=16 partials
    float* Pm2v   = (float*)alloc((size_t)16 * 128 * 128 * 4);
    float* ck     = (float*)alloc((size_t)KVH * 33 * DH * 4);
    float* cv     = (float*)alloc((size_t)KVH * 33 * DH * 4);
    float* qr     = (float*)alloc((size_t)HEADS * NTOK * DH * 4);
    float* kr     = (float*)alloc((size_t)KVH * NTOK * DH * 4);
    float* vr     = (float*)alloc((size_t)KVH * NTOK * DH * 4);
    float* c_out  = (float*)alloc((size_t)HEADS * NTOK * DH * 4);
    int*   sel    = (int*)  alloc((size_t)KVH * NTOK * 9 * 4);
    int*   selmask= (int*)  alloc((size_t)KVH * NTOK * 9 * 4);
    u16*   mixhi  = (u16*)  alloc((size_t)NTOK * DDIM * 2);
    float* Pout   = Pm1k;   // 16.8MB contiguous (Pm1k+Pm1v), dead after reduce_hid; fits S=4

    // 0. ALL weight prep + RMSNorm in one dispatch
    prep_kernel<<<3520, 256, 0, stream>>>(
        w_qkv, k_w1, v_w1, w_out, gate_w, k_w2, k_b2, v_w2, v_b2,
        inp, g_norm,
        wqThi, wqTlo, kw1Thi, kw1Tlo, vw1Thi, vw1Tlo, woThi,
        kw2Thi, kw2Tlo, kb2p, vw2Thi, vw2Tlo, vb2p,
        xhi, xlo);

    // 2. qkv+gates fused = x @ [w_qkv | gate_w]  (split-K=4, 416 blocks) + reduce
    gemm_tiled<3, 0, 0><<<dim3(QKVG / 128, NTOK / 128, 4), 256, 0, stream>>>(
        xhi, xlo, wqThi, wqTlo, nullptr, Pqkv,
        xhi, xlo, wqThi, wqTlo, nullptr, Pqkv, NTOK, QKVG, DDIM, 4);
    reduce_f32<0><<<dim3((NTOK * QKVG / 4) / 256, 1), 256, 0, stream>>>(
        Pqkv, nullptr, qkvg, Pqkv, nullptr, qkvg, 4, NTOK, QKVG);
    // 7/4. FUSED rotary + build_cmlp (both read only qkvg)
    rotcmlp_kernel<<<3200, 256, 0, stream>>>(qkvg, k_pos, v_pos, qr, kr, vr,
                                             cinkhi, cinklo, cinvhi, cinvlo);
    // 5. MLP1 (split-K 8, k&v batched -> 256 blocks; relu+bias+split-tile in reduce)
    gemm_tiled<3, 0, 0><<<dim3(HIDN / 128, 1, 16), 256, 0, stream>>>(
        cinkhi, cinklo, kw1Thi, kw1Tlo, nullptr, Pm1k,
        cinvhi, cinvlo, vw1Thi, vw1Tlo, nullptr, Pm1v, 128, HIDN, CDIM, 8);
    reduce_hid<<<dim3(128, 2), 256, 0, stream>>>(Pm1k, k_b1, hidkhi, hidklo,
                                                 Pm1v, v_b1, hidvhi, hidvlo, 8);
    // 6. MLP2 (split-K 16, k&v batched -> 32 blocks) + fused reduce/bias/concat
    gemm_tiled<3, 0, 0><<<dim3(1, 1, 32), 256, 0, stream>>>(
        hidkhi, hidklo, kw2Thi, kw2Tlo, nullptr, Pm2k,
        hidvhi, hidvlo, vw2Thi, vw2Tlo, nullptr, Pm2v, 128, 128, HIDN, 16);
    reduce_ckcv<<<33, 256, 0, stream>>>(Pm2k, Pm2v, mem_kv, kb2p, vb2p, ck, cv, 16);
    // 9. compressed attention + selection (vectorized scores)
    cattn_kernel<<<dim3(NTOK / 4, KVH), 256, 0, stream>>>(qkvg, ck, cv, c_out, sel, selmask);
    // 10. fine attention + FUSED gated mix -> tiled bf16 (mix dispatch eliminated)
    fattn_kernel<<<dim3(NTOK, KVH), 256, 0, stream>>>(qr, kr, vr, sel, selmask,
                                                      qkvg, gate_b, c_out, mixhi);
    // 12. output projection, split-K=4 (256 blocks) + reduce
    gemm_tiled<1, 0, 0><<<dim3(DDIM / 128, NTOK / 128, 4), 256, 0, stream>>>(
        mixhi, mixhi, woThi, woThi, nullptr, Pout,
        mixhi, mixhi, woThi, woThi, nullptr, Pout, NTOK, DDIM, DDIM, 4);
    reduce_f32<0><<<dim3((NTOK * DDIM / 4) / 256, 1), 256, 0, stream>>>(
        Pout, nullptr, out, Pout, nullptr, out, 4, NTOK, DDIM);
}